// Round 11
// baseline (1200.221 us; speedup 1.0000x reference)
//
#include <hip/hip_runtime.h>
#include <math.h>

#define NB 16
#define NC 256
#define NP 4096      // 64*64
#define NHEADS 8
#define NDH 32
#define NBH 128
#define NFF 1024
#define CEPS 1e-5f

typedef short s16x8 __attribute__((ext_vector_type(8)));
typedef float f32x4 __attribute__((ext_vector_type(4)));

// ---------------- diagnostic fill (guard trip) ----------------
__global__ __launch_bounds__(256) void diag_fill(float* __restrict__ out, float val, int n)
{
    int i = blockIdx.x * 256 + threadIdx.x;
    if (i < n) out[i] = val;
}

// ---------------- bf16 split helpers ----------------
__device__ inline unsigned short f2bf(float f) {
    unsigned u = __float_as_uint(f);
    return (unsigned short)((u + 0x7FFFu + ((u >> 16) & 1u)) >> 16);
}
__device__ inline float bf2f(unsigned short h) { return __uint_as_float(((unsigned)h) << 16); }
__device__ inline void split2(float f, unsigned short& hi, unsigned short& lo) {
    hi = f2bf(f);
    lo = f2bf(f - bf2f(hi));
}
// fast round-to-nearest split (6 ops); same 2^-17 error class as RNE split
__device__ inline void split_rn(float f, unsigned short& hi, unsigned short& lo) {
    unsigned u = __float_as_uint(f);
    unsigned tt = u + 0x8000u;
    hi = (unsigned short)(tt >> 16);
    float r = f - __uint_as_float(tt & 0xffff0000u);
    lo = (unsigned short)((__float_as_uint(r) + 0x8000u) >> 16);
}
// packed: (hi<<16)|lo
__device__ inline unsigned pack_hl(float f) {
    unsigned short h, lo; split2(f, h, lo);
    return ((unsigned)h << 16) | (unsigned)lo;
}
__device__ inline float packf(float f) { return __uint_as_float(pack_hl(f)); }

// ---------------- channel layer norm -> PACKED xn ----------------
__global__ __launch_bounds__(256) void cln_kernel(
    const float* __restrict__ x, const float* __restrict__ g, const float* __restrict__ bc,
    float* __restrict__ xn)
{
    int gp = blockIdx.x * 256 + threadIdx.x;
    int b = gp >> 12, p = gp & 4095;
    const float* src = x + (size_t)b * NC * NP + p;
    double s = 0.0, s2 = 0.0;
    for (int c = 0; c < NC; c++) { float v = src[(size_t)c * NP]; s += v; s2 += (double)v * v; }
    double mean = s * (1.0 / NC);
    double var = s2 * (1.0 / NC) - mean * mean;
    float rs = (float)(1.0 / sqrt(var + (double)CEPS));
    float mf = (float)mean;
    float* dst = xn + (size_t)b * NC * NP + p;
    for (int c = 0; c < NC; c++)
        dst[(size_t)c * NP] = packf((src[(size_t)c * NP] - mf) * rs * g[c] + bc[c]);
}

// ---------------- split-bf16 MFMA GEMM: 128o x 128p tile, 4 waves, K-step 32 --------
// LDS double-buffered (64 KB static), one barrier per K-step.
// B-input PACKED hi/lo uint32; weights raw fp32 (split in-kernel, RN split).
template<bool PACKO>
__global__ __launch_bounds__(256) void gemm_mfma(
    const float* __restrict__ inA, int sA, int C1,
    const float* __restrict__ inB, int sB, int Ctot,
    const float* __restrict__ Wt, const float* __restrict__ bias,
    const float* __restrict__ resid, float* __restrict__ out, int sO, int O)
{
    __shared__ __align__(16) unsigned short Ah[2][128 * 32], Al[2][128 * 32];
    __shared__ __align__(16) unsigned short Bh[2][128 * 32], Bl[2][128 * 32];

    // ---- XCD-batch swizzle ----
    const unsigned npb = gridDim.x * gridDim.y;
    unsigned lin = blockIdx.x + gridDim.x * (blockIdx.y + gridDim.y * blockIdx.z);
    unsigned low = lin & 7u, rest = lin >> 3;
    unsigned high = (rest >= npb) ? 1u : 0u;
    unsigned idx = rest - high * npb;
    const int b = (int)(low + 8u * high);
    const int o0 = (int)(idx / gridDim.x) * 128, p0 = (int)(idx % gridDim.x) * 128;

    const int t = threadIdx.x;
    const int l = t & 63, w = t >> 6;
    const int wr = w >> 1, wc = w & 1;           // wave owns (wr*64, wc*64) of 128x128
    const int g = l >> 4, l15 = l & 15;
    const int slotl = (l & 3) ^ ((l >> 2) & 3);

    f32x4 acc[4][4];
    #pragma unroll
    for (int m = 0; m < 4; m++)
        #pragma unroll
        for (int n = 0; n < 4; n++) acc[m][n] = (f32x4){0.f, 0.f, 0.f, 0.f};

    // A-stage: 128 rows x 32 k, 16 elems/thread (two 8-elem windows)
    const int arow = t >> 1;
    const int ak16 = (t & 1) * 16;
    const int aslot = (arow & 3) ^ ((arow >> 2) & 3);
    // B-stage: 128 rows(p) x 32 k, 16 elems/thread (8 k-pairs)
    const int bp = t & 127;
    const int bhalfk = t >> 7;                   // 0 -> k 0..15, 1 -> k 16..31
    const int bslot = (bp & 3) ^ ((bp >> 2) & 3);

    float4 pa[4];
    unsigned pb[16];

    #define LOAD_TILE(K0)                                                                 \
    {                                                                                     \
        const float* wsrc = Wt + (size_t)(o0 + arow) * Ctot + (K0) + ak16;                \
        pa[0] = *(const float4*)(wsrc);                                                   \
        pa[1] = *(const float4*)(wsrc + 4);                                               \
        pa[2] = *(const float4*)(wsrc + 8);                                               \
        pa[3] = *(const float4*)(wsrc + 12);                                              \
        _Pragma("unroll")                                                                 \
        for (int q = 0; q < 8; q++) {                                                     \
            int c2 = bhalfk * 16 + q * 2;                                                 \
            int cc = (K0) + c2;                                                           \
            const float* srcp = (cc < C1) ? inA + ((size_t)b * sA + cc) * (size_t)NP      \
                                          : inB + ((size_t)b * sB + (cc - C1)) * (size_t)NP; \
            pb[2 * q]     = __float_as_uint(srcp[p0 + bp]);                               \
            pb[2 * q + 1] = __float_as_uint(srcp[(size_t)NP + p0 + bp]);                  \
        }                                                                                 \
    }

    #define STORE_LDS(BUF)                                                                \
    {                                                                                     \
        char* sAh = (char*)Ah[BUF]; char* sAl = (char*)Al[BUF];                           \
        char* sBh = (char*)Bh[BUF]; char* sBl = (char*)Bl[BUF];                           \
        _Pragma("unroll")                                                                 \
        for (int wnd = 0; wnd < 2; wnd++) {                                               \
            float4 f0 = pa[2 * wnd], f1 = pa[2 * wnd + 1];                                \
            ushort4 h0, l0, h1, l1;                                                       \
            split_rn(f0.x, h0.x, l0.x); split_rn(f0.y, h0.y, l0.y);                       \
            split_rn(f0.z, h0.z, l0.z); split_rn(f0.w, h0.w, l0.w);                       \
            split_rn(f1.x, h1.x, l1.x); split_rn(f1.y, h1.y, l1.y);                       \
            split_rn(f1.z, h1.z, l1.z); split_rn(f1.w, h1.w, l1.w);                       \
            int kk = ak16 + 8 * wnd;                                                      \
            int off = arow * 64 + ((((kk >> 3)) ^ aslot) << 4);                           \
            *(ushort4*)(sAh + off) = h0; *(ushort4*)(sAh + off + 8) = h1;                 \
            *(ushort4*)(sAl + off) = l0; *(ushort4*)(sAl + off + 8) = l1;                 \
        }                                                                                 \
        _Pragma("unroll")                                                                 \
        for (int q = 0; q < 8; q++) {                                                     \
            int c2 = bhalfk * 16 + q * 2;                                                 \
            unsigned u0 = pb[2 * q], u1 = pb[2 * q + 1];                                  \
            unsigned hp = __builtin_amdgcn_perm(u1, u0, 0x07060302u);                     \
            unsigned lp = __builtin_amdgcn_perm(u1, u0, 0x05040100u);                     \
            int off = bp * 64 + ((((c2 >> 3)) ^ bslot) << 4) + (c2 & 7) * 2;              \
            *(unsigned*)(sBh + off) = hp;                                                 \
            *(unsigned*)(sBl + off) = lp;                                                 \
        }                                                                                 \
    }

    LOAD_TILE(0)
    STORE_LDS(0)
    __syncthreads();

    int cb = 0;
    for (int k0 = 0; k0 < Ctot; k0 += 32) {
        const bool more = (k0 + 32 < Ctot);
        if (more) LOAD_TILE(k0 + 32)

        const char* fAh = (const char*)Ah[cb]; const char* fAl = (const char*)Al[cb];
        const char* fBh = (const char*)Bh[cb]; const char* fBl = (const char*)Bl[cb];
        s16x8 ah[4], al[4];
        #pragma unroll
        for (int m = 0; m < 4; m++) {
            int ao = (wr * 64 + m * 16 + l15) * 64 + ((g ^ slotl) << 4);
            ah[m] = *(const s16x8*)(fAh + ao);
            al[m] = *(const s16x8*)(fAl + ao);
        }
        #pragma unroll
        for (int n = 0; n < 4; n++) {
            int bo = (wc * 64 + n * 16 + l15) * 64 + ((g ^ slotl) << 4);
            s16x8 bh = *(const s16x8*)(fBh + bo);
            s16x8 bl = *(const s16x8*)(fBl + bo);
            #pragma unroll
            for (int m = 0; m < 4; m++) {
                acc[m][n] = __builtin_amdgcn_mfma_f32_16x16x32_bf16(ah[m], bh, acc[m][n], 0, 0, 0);
                acc[m][n] = __builtin_amdgcn_mfma_f32_16x16x32_bf16(ah[m], bl, acc[m][n], 0, 0, 0);
                acc[m][n] = __builtin_amdgcn_mfma_f32_16x16x32_bf16(al[m], bh, acc[m][n], 0, 0, 0);
            }
        }
        if (more) {
            STORE_LDS(cb ^ 1);
            __syncthreads();
        }
        cb ^= 1;
    }
    #undef LOAD_TILE
    #undef STORE_LDS

    // ---- epilogue: D[row=(l>>4)*4+r][col=l&15] ----
    #pragma unroll
    for (int m = 0; m < 4; m++) {
        #pragma unroll
        for (int r = 0; r < 4; r++) {
            int orow = o0 + wr * 64 + m * 16 + g * 4 + r;
            float bs = bias ? bias[orow] : 0.f;
            #pragma unroll
            for (int n = 0; n < 4; n++) {
                int pcol = p0 + wc * 64 + n * 16 + l15;
                float v = acc[m][n][r] + bs;
                if (resid) v += resid[((size_t)b * O + orow) * (size_t)NP + pcol];
                out[((size_t)b * sO + orow) * (size_t)NP + pcol] = PACKO ? packf(v) : v;
            }
        }
    }
}

// ---------------- l2norm along W for q and k rows; emit |row|-sums ----------------
__global__ __launch_bounds__(256) void l2norm_kernel(
    float* __restrict__ qkv, float* __restrict__ qrow, float* __restrict__ kheight)
{
    int r = blockIdx.x * 4 + (threadIdx.x >> 6);
    int lane = threadIdx.x & 63;
    int which = r >> 18;
    int rr = r & 262143;
    int bh = rr >> 11;
    int c = (rr >> 6) & 31;
    int h = rr & 63;
    int b = bh >> 3, head = bh & 7;
    int ch = which * 256 + head * 32 + c;
    float* p = qkv + ((size_t)b * 768 + ch) * NP + h * 64 + lane;
    float v = *p;
    float ss = v * v, as = fabsf(v);
    for (int off = 32; off; off >>= 1) { ss += __shfl_xor(ss, off); as += __shfl_xor(as, off); }
    float n = sqrtf(ss);
    float inv = 1.f / fmaxf(n, 1e-12f);
    *p = v * inv;
    if (lane == 0) {
        float s = as * inv;
        if (which == 0) qrow[rr] = s; else kheight[rr] = s;
    }
}

__global__ void qprobe_kernel(const float* __restrict__ qrow, float* __restrict__ qprobe)
{
    int i = blockIdx.x * 64 + threadIdx.x;
    double s = 0.0;
    for (int h = 0; h < 64; h++) s += qrow[(size_t)i * 64 + h];
    qprobe[i] = (float)s;
}

// ---------------- scores + top-k rows/cols + gather k/v ----------------
__global__ __launch_bounds__(64) void select_kernel(
    const float* __restrict__ qkv, const float* __restrict__ qprobe,
    const float* __restrict__ kheight,
    float* __restrict__ ksel, float* __restrict__ vsel)
{
    const int bh = blockIdx.x;
    const int b = bh >> 3, head = bh & 7;
    const int lane = threadIdx.x;
    __shared__ int hs[8], wsl[8];
    __shared__ float qp[32];
    if (lane < 32) qp[lane] = qprobe[bh * 32 + lane];
    __syncthreads();
    double scd = 0.0;
    for (int c = 0; c < 32; c++) scd += (double)qp[c] * kheight[((size_t)bh * 32 + c) * 64 + lane];
    float sc = (float)scd;
    for (int it = 0; it < 8; it++) {
        float v = sc; int id = lane;
        for (int off = 32; off; off >>= 1) {
            float ov = __shfl_xor(v, off); int oi = __shfl_xor(id, off);
            if (ov > v || (ov == v && oi < id)) { v = ov; id = oi; }
        }
        if (lane == 0) hs[it] = id;
        if (lane == id) sc = -3.4e38f;
    }
    __syncthreads();
    const float* kbase = qkv + ((size_t)b * 768 + 256 + head * 32) * NP;
    double sc2d = 0.0;
    for (int c = 0; c < 32; c++) {
        float kw = 0.f;
        for (int hi = 0; hi < 8; hi++)
            kw += fabsf(kbase[(size_t)c * NP + hs[hi] * 64 + lane]);
        sc2d += (double)qp[c] * kw;
    }
    float sc2 = (float)sc2d;
    for (int it = 0; it < 8; it++) {
        float v = sc2; int id = lane;
        for (int off = 32; off; off >>= 1) {
            float ov = __shfl_xor(v, off); int oi = __shfl_xor(id, off);
            if (ov > v || (ov == v && oi < id)) { v = ov; id = oi; }
        }
        if (lane == 0) wsl[it] = id;
        if (lane == id) sc2 = -3.4e38f;
    }
    __syncthreads();
    const float* vbase = qkv + ((size_t)b * 768 + 512 + head * 32) * NP;
    int hi = lane >> 3, wi = lane & 7;
    int hh = hs[hi], ww = wsl[wi];
    for (int d = 0; d < 32; d++) {
        ksel[((size_t)bh * 64 + lane) * 32 + d] = kbase[(size_t)d * NP + hh * 64 + ww];
        vsel[((size_t)bh * 64 + lane) * 32 + d] = vbase[(size_t)d * NP + hh * 64 + ww];
    }
}

// ---------------- attention: in-place over q slot; writes PACKED ctx ----------------
__global__ __launch_bounds__(256) void attn_kernel(
    float* __restrict__ qkv, const float* __restrict__ ksel, const float* __restrict__ vsel)
{
    __shared__ __align__(16) float ks[64][32];
    __shared__ __align__(16) float vs[64][32];
    int bh = blockIdx.y, b = bh >> 3, head = bh & 7;
    int t = threadIdx.x;
    const float* kb = ksel + (size_t)bh * 2048;
    const float* vb = vsel + (size_t)bh * 2048;
    for (int i = 0; i < 8; i++) {
        ((float*)ks)[t + i * 256] = kb[t + i * 256];
        ((float*)vs)[t + i * 256] = vb[t + i * 256];
    }
    __syncthreads();
    int p = blockIdx.x * 256 + t;
    float* qb = qkv + ((size_t)b * 768 + head * 32) * NP + p;
    float q[32];
    #pragma unroll
    for (int d = 0; d < 32; d++) q[d] = qb[(size_t)d * NP];
    float s[64], m = -3.4e38f;
    for (int j = 0; j < 64; j++) {
        float dot = 0.f;
        #pragma unroll
        for (int d = 0; d < 32; d++) dot += q[d] * ks[j][d];
        s[j] = dot; m = fmaxf(m, dot);
    }
    float den = 0.f;
    for (int j = 0; j < 64; j++) { float e = expf(s[j] - m); s[j] = e; den += e; }
    float o[32] = {};
    for (int j = 0; j < 64; j++) {
        float a = s[j];
        #pragma unroll
        for (int d = 0; d < 32; d++) o[d] += a * vs[j][d];
    }
    float r = 1.f / den;
    #pragma unroll
    for (int d = 0; d < 32; d++) qb[(size_t)d * NP] = packf(o[d] * r);
}

// ---------------- depthwise 3x3 on x; PACKED strided output planes ----------------
__global__ __launch_bounds__(256) void dwconv_kernel(
    const float* __restrict__ in, const float* __restrict__ w, const float* __restrict__ bias,
    float* __restrict__ out, int Cn, int sO)
{
    __shared__ __align__(16) float pl[64][64];
    int bcb = blockIdx.x;
    int b = bcb / Cn, c = bcb % Cn;
    const float* src = in + (size_t)bcb * NP;
    float* dst = out + ((size_t)b * sO + c) * NP;
    int t = threadIdx.x;
    for (int i = 0; i < 16; i++) { int pix = t + i * 256; pl[pix >> 6][pix & 63] = src[pix]; }
    float w9[9];
    #pragma unroll
    for (int k = 0; k < 9; k++) w9[k] = w[c * 9 + k];
    float bsv = bias[c];
    __syncthreads();
    for (int i = 0; i < 16; i++) {
        int pix = t + i * 256; int y = pix >> 6, xx = pix & 63;
        float acc = bsv;
        #pragma unroll
        for (int dy = 0; dy < 3; dy++) {
            int yy = y + dy - 1; if (yy < 0 || yy > 63) continue;
            #pragma unroll
            for (int dx = 0; dx < 3; dx++) {
                int x2 = xx + dx - 1; if (x2 < 0 || x2 > 63) continue;
                acc += w9[dy * 3 + dx] * pl[yy][x2];
            }
        }
        dst[pix] = packf(acc);
    }
}

// ---------------- fast gelu: A&S 7.1.26 erf (max abs err ~1.5e-7) ----------------
__device__ inline float gelu_fast(float x) {
    float z = x * 0.70710678118654752f;
    float a = fabsf(z);
    float t = 1.0f / (1.0f + 0.3275911f * a);
    float p = t * (0.254829592f + t * (-0.284496736f + t * (1.421413741f +
              t * (-1.453152027f + t * 1.061405429f))));
    float e = __expf(-a * a);
    float r = 1.0f - p * e;                 // erf(|z|)
    float erfz = copysignf(r, z);
    return 0.5f * x * (1.0f + erfz);
}

__device__ inline void block_reduce2(double& s, double& s2, double* red, int t)
{
    __syncthreads();
    red[t] = s; red[256 + t] = s2;
    __syncthreads();
    for (int st = 128; st; st >>= 1) {
        if (t < st) { red[t] += red[t + st]; red[256 + t] += red[256 + t + st]; }
        __syncthreads();
    }
    s = red[0]; s2 = red[256];
}

// ---------------- fused FF: h = gelu(IN(h)); h += gelu(IN(dwconv3(h))); PACKED out ----
__global__ __launch_bounds__(256) void ff_fused_kernel(
    float* __restrict__ h, const float* __restrict__ w, const float* __restrict__ bias)
{
    __shared__ __align__(16) float pl[64][64];
    __shared__ double red[512];
    int plane = blockIdx.x;
    int c = plane & (NFF - 1);
    size_t base = (size_t)plane * NP;
    int t = threadIdx.x;
    float v[16]; double s = 0.0, s2 = 0.0;
    for (int i = 0; i < 16; i++) { float x = h[base + t + i * 256]; v[i] = x; s += x; s2 += (double)x * x; }
    block_reduce2(s, s2, red, t);
    double mean = s * (1.0 / NP);
    double var = s2 * (1.0 / NP) - mean * mean;
    float rs = (float)(1.0 / sqrt(var + (double)CEPS));
    float mf = (float)mean;
    for (int i = 0; i < 16; i++) {
        float gx = gelu_fast((v[i] - mf) * rs);
        v[i] = gx;
        int pix = t + i * 256;
        pl[pix >> 6][pix & 63] = gx;
    }
    __syncthreads();
    float w9[9];
    #pragma unroll
    for (int k = 0; k < 9; k++) w9[k] = w[c * 9 + k];
    float bsv = bias[c];
    float tv[16]; s = 0.0; s2 = 0.0;
    for (int i = 0; i < 16; i++) {
        int pix = t + i * 256; int y = pix >> 6, xx = pix & 63;
        float acc = bsv;
        #pragma unroll
        for (int dy = 0; dy < 3; dy++) {
            int yy = y + dy - 1; if (yy < 0 || yy > 63) continue;
            #pragma unroll
            for (int dx = 0; dx < 3; dx++) {
                int x2 = xx + dx - 1; if (x2 < 0 || x2 > 63) continue;
                acc += w9[dy * 3 + dx] * pl[yy][x2];
            }
        }
        tv[i] = acc; s += acc; s2 += (double)acc * acc;
    }
    block_reduce2(s, s2, red, t);
    double mean2 = s * (1.0 / NP);
    double var2 = s2 * (1.0 / NP) - mean2 * mean2;
    float rs2 = (float)(1.0 / sqrt(var2 + (double)CEPS));
    float mf2 = (float)mean2;
    for (int i = 0; i < 16; i++) {
        int pix = t + i * 256;
        float o = v[i] + gelu_fast((tv[i] - mf2) * rs2);
        h[base + pix] = packf(o);
    }
}

// ---------------- final instance norm in place on d_out ----------------
__global__ __launch_bounds__(256) void in_final_kernel(float* __restrict__ y)
{
    __shared__ double red[512];
    size_t base = (size_t)blockIdx.x * NP;
    int t = threadIdx.x;
    float v[16]; double s = 0.0, s2 = 0.0;
    for (int i = 0; i < 16; i++) { float x = y[base + t + i * 256]; v[i] = x; s += x; s2 += (double)x * x; }
    block_reduce2(s, s2, red, t);
    double mean = s * (1.0 / NP);
    double var = s2 * (1.0 / NP) - mean * mean;
    float rs = (float)(1.0 / sqrt(var + (double)CEPS));
    float mf = (float)mean;
    for (int i = 0; i < 16; i++)
        y[base + t + i * 256] = (v[i] - mf) * rs;
}

extern "C" void kernel_launch(void* const* d_in, const int* in_sizes, int n_in,
                              void* d_out, int out_size, void* d_ws, size_t ws_size,
                              hipStream_t stream)
{
    const float* x      = (const float*)d_in[0];
    const float* g      = (const float*)d_in[1];
    const float* bc     = (const float*)d_in[2];
    const float* w_qkv  = (const float*)d_in[3];
    const float* w_out  = (const float*)d_in[4];
    const float* b_out  = (const float*)d_in[5];
    const float* w_dw   = (const float*)d_in[6];
    const float* b_dw   = (const float*)d_in[7];
    const float* w_comb = (const float*)d_in[8];
    const float* b_comb = (const float*)d_in[9];
    const float* w_ff1  = (const float*)d_in[10];
    const float* b_ff1  = (const float*)d_in[11];
    const float* w_ffdw = (const float*)d_in[12];
    const float* b_ffdw = (const float*)d_in[13];
    const float* w_ff2  = (const float*)d_in[14];
    const float* b_ff2  = (const float*)d_in[15];
    float* out = (float*)d_out;
    float* ws  = (float*)d_ws;

    const size_t S = (size_t)NB * NC * NP;   // 16,777,216 floats (64 MiB)
    float* xn    = ws;
    float* qkv   = ws + S;
    float* h1    = ws;
    float* Fbuf  = out;
    float* attnb = qkv + (size_t)256 * NP;
    float* convb = qkv + (size_t)512 * NP;
    float* qrow    = ws;
    float* qprobe  = qrow + 262144;
    float* kheight = qprobe + 4096;
    float* kselb   = kheight + 262144;
    float* vselb   = kselb + 262144;

    size_t need = 4 * S * sizeof(float);
    if (ws_size < need) {
        float val = 1024.0f + (float)(ws_size >> 20);
        diag_fill<<<(out_size + 255) / 256, 256, 0, stream>>>(out, val, out_size);
        return;
    }

    cln_kernel<<<256, 256, 0, stream>>>(x, g, bc, xn);
    gemm_mfma<false><<<dim3(32, 6, NB), 256, 0, stream>>>(xn, 256, 256, nullptr, 0, 256,
                                                          w_qkv, nullptr, nullptr, qkv, 768, 768);
    l2norm_kernel<<<131072, 256, 0, stream>>>(qkv, qrow, kheight);
    qprobe_kernel<<<64, 64, 0, stream>>>(qrow, qprobe);
    select_kernel<<<NBH, 64, 0, stream>>>(qkv, qprobe, kheight, kselb, vselb);
    attn_kernel<<<dim3(16, NBH), 256, 0, stream>>>(qkv, kselb, vselb);
    gemm_mfma<true><<<dim3(32, 2, NB), 256, 0, stream>>>(qkv, 768, 256, nullptr, 0, 256,
                                                         w_out, b_out, nullptr, attnb, 768, 256);
    dwconv_kernel<<<NB * NC, 256, 0, stream>>>(x, w_dw, b_dw, convb, NC, 768);
    gemm_mfma<true><<<dim3(32, 2, NB), 256, 0, stream>>>(attnb, 768, 256, convb, 768, 512,
                                                         w_comb, b_comb, x, Fbuf, 256, 256);
    gemm_mfma<false><<<dim3(32, 8, NB), 256, 0, stream>>>(Fbuf, 256, 256, nullptr, 0, 256,
                                                          w_ff1, b_ff1, nullptr, h1, 1024, 1024);
    ff_fused_kernel<<<NB * NFF, 256, 0, stream>>>(h1, w_ffdw, b_ffdw);
    gemm_mfma<false><<<dim3(32, 2, NB), 256, 0, stream>>>(h1, 1024, 1024, nullptr, 0, 1024,
                                                          w_ff2, b_ff2, nullptr, out, 256, 256);
    in_final_kernel<<<NB * NC, 256, 0, stream>>>(out);
}

// Round 12
// 1149.545 us; speedup vs baseline: 1.0441x; 1.0441x over previous
//
#include <hip/hip_runtime.h>
#include <math.h>

#define NB 16
#define NC 256
#define NP 4096      // 64*64
#define NHEADS 8
#define NDH 32
#define NBH 128
#define NFF 1024
#define CEPS 1e-5f

typedef short s16x8 __attribute__((ext_vector_type(8)));
typedef float f32x4 __attribute__((ext_vector_type(4)));

// ---------------- diagnostic fill (guard trip) ----------------
__global__ __launch_bounds__(256) void diag_fill(float* __restrict__ out, float val, int n)
{
    int i = blockIdx.x * 256 + threadIdx.x;
    if (i < n) out[i] = val;
}

// ---------------- bf16 split helpers ----------------
__device__ inline unsigned short f2bf(float f) {
    unsigned u = __float_as_uint(f);
    return (unsigned short)((u + 0x7FFFu + ((u >> 16) & 1u)) >> 16);
}
__device__ inline float bf2f(unsigned short h) { return __uint_as_float(((unsigned)h) << 16); }
__device__ inline void split2(float f, unsigned short& hi, unsigned short& lo) {
    hi = f2bf(f);
    lo = f2bf(f - bf2f(hi));
}
// fast round-to-nearest split (6 ops); same 2^-17 error class (round-11 validated)
__device__ inline void split_rn(float f, unsigned short& hi, unsigned short& lo) {
    unsigned u = __float_as_uint(f);
    unsigned tt = u + 0x8000u;
    hi = (unsigned short)(tt >> 16);
    float r = f - __uint_as_float(tt & 0xffff0000u);
    lo = (unsigned short)((__float_as_uint(r) + 0x8000u) >> 16);
}
// packed: (hi<<16)|lo
__device__ inline unsigned pack_hl(float f) {
    unsigned short h, lo; split2(f, h, lo);
    return ((unsigned)h << 16) | (unsigned)lo;
}
__device__ inline float packf(float f) { return __uint_as_float(pack_hl(f)); }

// ---------------- channel layer norm -> PACKED xn ----------------
__global__ __launch_bounds__(256) void cln_kernel(
    const float* __restrict__ x, const float* __restrict__ g, const float* __restrict__ bc,
    float* __restrict__ xn)
{
    int gp = blockIdx.x * 256 + threadIdx.x;
    int b = gp >> 12, p = gp & 4095;
    const float* src = x + (size_t)b * NC * NP + p;
    double s = 0.0, s2 = 0.0;
    for (int c = 0; c < NC; c++) { float v = src[(size_t)c * NP]; s += v; s2 += (double)v * v; }
    double mean = s * (1.0 / NC);
    double var = s2 * (1.0 / NC) - mean * mean;
    float rs = (float)(1.0 / sqrt(var + (double)CEPS));
    float mf = (float)mean;
    float* dst = xn + (size_t)b * NC * NP + p;
    for (int c = 0; c < NC; c++)
        dst[(size_t)c * NP] = packf((src[(size_t)c * NP] - mf) * rs * g[c] + bc[c]);
}

// ---------------- split-bf16 MFMA GEMM: 128o x 256p tile, 8 waves, K-step 32 ----------
// Single LDS buffer (48 KB), 2-deep register prefetch: STORE(set) consumes loads
// issued TWO MFMA phases earlier. Requires Ctot % 64 == 0.
template<bool PACKO>
__global__ __launch_bounds__(512) void gemm_mfma(
    const float* __restrict__ inA, int sA, int C1,
    const float* __restrict__ inB, int sB, int Ctot,
    const float* __restrict__ Wt, const float* __restrict__ bias,
    const float* __restrict__ resid, float* __restrict__ out, int sO, int O)
{
    __shared__ __align__(16) unsigned short Ah[128 * 32], Al[128 * 32];
    __shared__ __align__(16) unsigned short Bh[256 * 32], Bl[256 * 32];
    char* cAh = (char*)Ah; char* cAl = (char*)Al;
    char* cBh = (char*)Bh; char* cBl = (char*)Bl;

    // ---- XCD-batch swizzle ----
    const unsigned npb = gridDim.x * gridDim.y;
    unsigned lin = blockIdx.x + gridDim.x * (blockIdx.y + gridDim.y * blockIdx.z);
    unsigned low = lin & 7u, rest = lin >> 3;
    unsigned high = (rest >= npb) ? 1u : 0u;
    unsigned idx = rest - high * npb;
    const int b = (int)(low + 8u * high);
    const int o0 = (int)(idx / gridDim.x) * 128, p0 = (int)(idx % gridDim.x) * 256;

    const int t = threadIdx.x;
    const int l = t & 63, w = t >> 6;
    const int wr = w >> 2, wc = w & 3;
    const int g = l >> 4, l15 = l & 15;
    const int slotl = (l & 3) ^ ((l >> 2) & 3);

    f32x4 acc[4][4];
    #pragma unroll
    for (int m = 0; m < 4; m++)
        #pragma unroll
        for (int n = 0; n < 4; n++) acc[m][n] = (f32x4){0.f, 0.f, 0.f, 0.f};

    const int arow = t >> 2;
    const int ak8 = (t & 3) * 8;
    const int aslot = (arow & 3) ^ ((arow >> 2) & 3);
    const int aoff = arow * 64 + ((((ak8 >> 3)) ^ aslot) << 4);
    const int bp = t & 255;
    const int bhalfk = t >> 8;
    const int bslot = (bp & 3) ^ ((bp >> 2) & 3);

    // two prefetch register sets (2-deep pipeline)
    float4 paA0, paA1, paB0, paB1;
    unsigned pbA[16], pbB[16];

    #define LOAD_TILE(K0, PA0, PA1, PB)                                                   \
    {                                                                                     \
        const float* wsrc = Wt + (size_t)(o0 + arow) * Ctot + (K0) + ak8;                 \
        PA0 = *(const float4*)(wsrc);                                                     \
        PA1 = *(const float4*)(wsrc + 4);                                                 \
        _Pragma("unroll")                                                                 \
        for (int q = 0; q < 8; q++) {                                                     \
            int c2 = bhalfk * 16 + q * 2;                                                 \
            int cc = (K0) + c2;                                                           \
            const float* srcp = (cc < C1) ? inA + ((size_t)b * sA + cc) * (size_t)NP      \
                                          : inB + ((size_t)b * sB + (cc - C1)) * (size_t)NP; \
            PB[2 * q]     = __float_as_uint(srcp[p0 + bp]);                               \
            PB[2 * q + 1] = __float_as_uint(srcp[(size_t)NP + p0 + bp]);                  \
        }                                                                                 \
    }

    #define STORE_LDS(PA0, PA1, PB)                                                       \
    {                                                                                     \
        ushort4 h0, l0, h1, l1;                                                           \
        split_rn(PA0.x, h0.x, l0.x); split_rn(PA0.y, h0.y, l0.y);                         \
        split_rn(PA0.z, h0.z, l0.z); split_rn(PA0.w, h0.w, l0.w);                         \
        split_rn(PA1.x, h1.x, l1.x); split_rn(PA1.y, h1.y, l1.y);                         \
        split_rn(PA1.z, h1.z, l1.z); split_rn(PA1.w, h1.w, l1.w);                         \
        *(ushort4*)(cAh + aoff) = h0; *(ushort4*)(cAh + aoff + 8) = h1;                   \
        *(ushort4*)(cAl + aoff) = l0; *(ushort4*)(cAl + aoff + 8) = l1;                   \
        _Pragma("unroll")                                                                 \
        for (int q = 0; q < 8; q++) {                                                     \
            int c2 = bhalfk * 16 + q * 2;                                                 \
            unsigned u0 = PB[2 * q], u1 = PB[2 * q + 1];                                  \
            unsigned hp = __builtin_amdgcn_perm(u1, u0, 0x07060302u);                     \
            unsigned lp = __builtin_amdgcn_perm(u1, u0, 0x05040100u);                     \
            int off = bp * 64 + ((((c2 >> 3)) ^ bslot) << 4) + (c2 & 7) * 2;              \
            *(unsigned*)(cBh + off) = hp;                                                 \
            *(unsigned*)(cBl + off) = lp;                                                 \
        }                                                                                 \
    }

    #define MFMA_PHASE()                                                                  \
    {                                                                                     \
        s16x8 ah[4], al[4];                                                               \
        _Pragma("unroll")                                                                 \
        for (int m = 0; m < 4; m++) {                                                     \
            int ao = (wr * 64 + m * 16 + l15) * 64 + ((g ^ slotl) << 4);                  \
            ah[m] = *(const s16x8*)(cAh + ao);                                            \
            al[m] = *(const s16x8*)(cAl + ao);                                            \
        }                                                                                 \
        _Pragma("unroll")                                                                 \
        for (int n = 0; n < 4; n++) {                                                     \
            int bo = (wc * 64 + n * 16 + l15) * 64 + ((g ^ slotl) << 4);                  \
            s16x8 bh = *(const s16x8*)(cBh + bo);                                         \
            s16x8 bl = *(const s16x8*)(cBl + bo);                                         \
            _Pragma("unroll")                                                             \
            for (int m = 0; m < 4; m++) {                                                 \
                acc[m][n] = __builtin_amdgcn_mfma_f32_16x16x32_bf16(ah[m], bh, acc[m][n], 0, 0, 0); \
                acc[m][n] = __builtin_amdgcn_mfma_f32_16x16x32_bf16(ah[m], bl, acc[m][n], 0, 0, 0); \
                acc[m][n] = __builtin_amdgcn_mfma_f32_16x16x32_bf16(al[m], bh, acc[m][n], 0, 0, 0); \
            }                                                                             \
        }                                                                                 \
    }

    // prologue: fill both prefetch sets
    LOAD_TILE(0, paA0, paA1, pbA)
    LOAD_TILE(32, paB0, paB1, pbB)

    for (int k0 = 0; k0 < Ctot; k0 += 64) {
        if (k0) __syncthreads();
        STORE_LDS(paA0, paA1, pbA)            // tile k0 (loaded 2 phases ago)
        __syncthreads();
        if (k0 + 64 < Ctot) LOAD_TILE(k0 + 64, paA0, paA1, pbA)
        MFMA_PHASE()

        __syncthreads();
        STORE_LDS(paB0, paB1, pbB)            // tile k0+32
        __syncthreads();
        if (k0 + 96 < Ctot) LOAD_TILE(k0 + 96, paB0, paB1, pbB)
        MFMA_PHASE()
    }
    #undef LOAD_TILE
    #undef STORE_LDS
    #undef MFMA_PHASE

    // ---- epilogue: D[row=(l>>4)*4+r][col=l&15] ----
    #pragma unroll
    for (int m = 0; m < 4; m++) {
        #pragma unroll
        for (int r = 0; r < 4; r++) {
            int orow = o0 + wr * 64 + m * 16 + g * 4 + r;
            float bs = bias ? bias[orow] : 0.f;
            #pragma unroll
            for (int n = 0; n < 4; n++) {
                int pcol = p0 + wc * 64 + n * 16 + l15;
                float v = acc[m][n][r] + bs;
                if (resid) v += resid[((size_t)b * O + orow) * (size_t)NP + pcol];
                out[((size_t)b * sO + orow) * (size_t)NP + pcol] = PACKO ? packf(v) : v;
            }
        }
    }
}

// ---------------- l2norm along W for q and k rows; emit |row|-sums ----------------
__global__ __launch_bounds__(256) void l2norm_kernel(
    float* __restrict__ qkv, float* __restrict__ qrow, float* __restrict__ kheight)
{
    int r = blockIdx.x * 4 + (threadIdx.x >> 6);
    int lane = threadIdx.x & 63;
    int which = r >> 18;
    int rr = r & 262143;
    int bh = rr >> 11;
    int c = (rr >> 6) & 31;
    int h = rr & 63;
    int b = bh >> 3, head = bh & 7;
    int ch = which * 256 + head * 32 + c;
    float* p = qkv + ((size_t)b * 768 + ch) * NP + h * 64 + lane;
    float v = *p;
    float ss = v * v, as = fabsf(v);
    for (int off = 32; off; off >>= 1) { ss += __shfl_xor(ss, off); as += __shfl_xor(as, off); }
    float n = sqrtf(ss);
    float inv = 1.f / fmaxf(n, 1e-12f);
    *p = v * inv;
    if (lane == 0) {
        float s = as * inv;
        if (which == 0) qrow[rr] = s; else kheight[rr] = s;
    }
}

__global__ void qprobe_kernel(const float* __restrict__ qrow, float* __restrict__ qprobe)
{
    int i = blockIdx.x * 64 + threadIdx.x;
    double s = 0.0;
    for (int h = 0; h < 64; h++) s += qrow[(size_t)i * 64 + h];
    qprobe[i] = (float)s;
}

// ---------------- scores + top-k rows/cols + gather k/v ----------------
__global__ __launch_bounds__(64) void select_kernel(
    const float* __restrict__ qkv, const float* __restrict__ qprobe,
    const float* __restrict__ kheight,
    float* __restrict__ ksel, float* __restrict__ vsel)
{
    const int bh = blockIdx.x;
    const int b = bh >> 3, head = bh & 7;
    const int lane = threadIdx.x;
    __shared__ int hs[8], wsl[8];
    __shared__ float qp[32];
    if (lane < 32) qp[lane] = qprobe[bh * 32 + lane];
    __syncthreads();
    double scd = 0.0;
    for (int c = 0; c < 32; c++) scd += (double)qp[c] * kheight[((size_t)bh * 32 + c) * 64 + lane];
    float sc = (float)scd;
    for (int it = 0; it < 8; it++) {
        float v = sc; int id = lane;
        for (int off = 32; off; off >>= 1) {
            float ov = __shfl_xor(v, off); int oi = __shfl_xor(id, off);
            if (ov > v || (ov == v && oi < id)) { v = ov; id = oi; }
        }
        if (lane == 0) hs[it] = id;
        if (lane == id) sc = -3.4e38f;
    }
    __syncthreads();
    const float* kbase = qkv + ((size_t)b * 768 + 256 + head * 32) * NP;
    double sc2d = 0.0;
    for (int c = 0; c < 32; c++) {
        float kw = 0.f;
        for (int hi = 0; hi < 8; hi++)
            kw += fabsf(kbase[(size_t)c * NP + hs[hi] * 64 + lane]);
        sc2d += (double)qp[c] * kw;
    }
    float sc2 = (float)sc2d;
    for (int it = 0; it < 8; it++) {
        float v = sc2; int id = lane;
        for (int off = 32; off; off >>= 1) {
            float ov = __shfl_xor(v, off); int oi = __shfl_xor(id, off);
            if (ov > v || (ov == v && oi < id)) { v = ov; id = oi; }
        }
        if (lane == 0) wsl[it] = id;
        if (lane == id) sc2 = -3.4e38f;
    }
    __syncthreads();
    const float* vbase = qkv + ((size_t)b * 768 + 512 + head * 32) * NP;
    int hi = lane >> 3, wi = lane & 7;
    int hh = hs[hi], ww = wsl[wi];
    for (int d = 0; d < 32; d++) {
        ksel[((size_t)bh * 64 + lane) * 32 + d] = kbase[(size_t)d * NP + hh * 64 + ww];
        vsel[((size_t)bh * 64 + lane) * 32 + d] = vbase[(size_t)d * NP + hh * 64 + ww];
    }
}

// ---------------- attention: in-place over q slot; writes PACKED ctx ----------------
__global__ __launch_bounds__(256) void attn_kernel(
    float* __restrict__ qkv, const float* __restrict__ ksel, const float* __restrict__ vsel)
{
    __shared__ __align__(16) float ks[64][32];
    __shared__ __align__(16) float vs[64][32];
    int bh = blockIdx.y, b = bh >> 3, head = bh & 7;
    int t = threadIdx.x;
    const float* kb = ksel + (size_t)bh * 2048;
    const float* vb = vsel + (size_t)bh * 2048;
    for (int i = 0; i < 8; i++) {
        ((float*)ks)[t + i * 256] = kb[t + i * 256];
        ((float*)vs)[t + i * 256] = vb[t + i * 256];
    }
    __syncthreads();
    int p = blockIdx.x * 256 + t;
    float* qb = qkv + ((size_t)b * 768 + head * 32) * NP + p;
    float q[32];
    #pragma unroll
    for (int d = 0; d < 32; d++) q[d] = qb[(size_t)d * NP];
    float s[64], m = -3.4e38f;
    for (int j = 0; j < 64; j++) {
        float dot = 0.f;
        #pragma unroll
        for (int d = 0; d < 32; d++) dot += q[d] * ks[j][d];
        s[j] = dot; m = fmaxf(m, dot);
    }
    float den = 0.f;
    for (int j = 0; j < 64; j++) { float e = expf(s[j] - m); s[j] = e; den += e; }
    float o[32] = {};
    for (int j = 0; j < 64; j++) {
        float a = s[j];
        #pragma unroll
        for (int d = 0; d < 32; d++) o[d] += a * vs[j][d];
    }
    float r = 1.f / den;
    #pragma unroll
    for (int d = 0; d < 32; d++) qb[(size_t)d * NP] = packf(o[d] * r);
}

// ---------------- depthwise 3x3 on x; PACKED strided output planes ----------------
__global__ __launch_bounds__(256) void dwconv_kernel(
    const float* __restrict__ in, const float* __restrict__ w, const float* __restrict__ bias,
    float* __restrict__ out, int Cn, int sO)
{
    __shared__ __align__(16) float pl[64][64];
    int bcb = blockIdx.x;
    int b = bcb / Cn, c = bcb % Cn;
    const float* src = in + (size_t)bcb * NP;
    float* dst = out + ((size_t)b * sO + c) * NP;
    int t = threadIdx.x;
    for (int i = 0; i < 16; i++) { int pix = t + i * 256; pl[pix >> 6][pix & 63] = src[pix]; }
    float w9[9];
    #pragma unroll
    for (int k = 0; k < 9; k++) w9[k] = w[c * 9 + k];
    float bsv = bias[c];
    __syncthreads();
    for (int i = 0; i < 16; i++) {
        int pix = t + i * 256; int y = pix >> 6, xx = pix & 63;
        float acc = bsv;
        #pragma unroll
        for (int dy = 0; dy < 3; dy++) {
            int yy = y + dy - 1; if (yy < 0 || yy > 63) continue;
            #pragma unroll
            for (int dx = 0; dx < 3; dx++) {
                int x2 = xx + dx - 1; if (x2 < 0 || x2 > 63) continue;
                acc += w9[dy * 3 + dx] * pl[yy][x2];
            }
        }
        dst[pix] = packf(acc);
    }
}

// ---------------- fast gelu: A&S 7.1.26 erf (max abs err ~1.5e-7) ----------------
__device__ inline float gelu_fast(float x) {
    float z = x * 0.70710678118654752f;
    float a = fabsf(z);
    float t = 1.0f / (1.0f + 0.3275911f * a);
    float p = t * (0.254829592f + t * (-0.284496736f + t * (1.421413741f +
              t * (-1.453152027f + t * 1.061405429f))));
    float e = __expf(-a * a);
    float r = 1.0f - p * e;                 // erf(|z|)
    float erfz = copysignf(r, z);
    return 0.5f * x * (1.0f + erfz);
}

__device__ inline void block_reduce2(double& s, double& s2, double* red, int t)
{
    __syncthreads();
    red[t] = s; red[256 + t] = s2;
    __syncthreads();
    for (int st = 128; st; st >>= 1) {
        if (t < st) { red[t] += red[t + st]; red[256 + t] += red[256 + t + st]; }
        __syncthreads();
    }
    s = red[0]; s2 = red[256];
}

// ---------------- fused FF: h = gelu(IN(h)); h += gelu(IN(dwconv3(h))); PACKED out ----
__global__ __launch_bounds__(256) void ff_fused_kernel(
    float* __restrict__ h, const float* __restrict__ w, const float* __restrict__ bias)
{
    __shared__ __align__(16) float pl[64][64];
    __shared__ double red[512];
    int plane = blockIdx.x;
    int c = plane & (NFF - 1);
    size_t base = (size_t)plane * NP;
    int t = threadIdx.x;
    float v[16]; double s = 0.0, s2 = 0.0;
    for (int i = 0; i < 16; i++) { float x = h[base + t + i * 256]; v[i] = x; s += x; s2 += (double)x * x; }
    block_reduce2(s, s2, red, t);
    double mean = s * (1.0 / NP);
    double var = s2 * (1.0 / NP) - mean * mean;
    float rs = (float)(1.0 / sqrt(var + (double)CEPS));
    float mf = (float)mean;
    for (int i = 0; i < 16; i++) {
        float gx = gelu_fast((v[i] - mf) * rs);
        v[i] = gx;
        int pix = t + i * 256;
        pl[pix >> 6][pix & 63] = gx;
    }
    __syncthreads();
    float w9[9];
    #pragma unroll
    for (int k = 0; k < 9; k++) w9[k] = w[c * 9 + k];
    float bsv = bias[c];
    float tv[16]; s = 0.0; s2 = 0.0;
    for (int i = 0; i < 16; i++) {
        int pix = t + i * 256; int y = pix >> 6, xx = pix & 63;
        float acc = bsv;
        #pragma unroll
        for (int dy = 0; dy < 3; dy++) {
            int yy = y + dy - 1; if (yy < 0 || yy > 63) continue;
            #pragma unroll
            for (int dx = 0; dx < 3; dx++) {
                int x2 = xx + dx - 1; if (x2 < 0 || x2 > 63) continue;
                acc += w9[dy * 3 + dx] * pl[yy][x2];
            }
        }
        tv[i] = acc; s += acc; s2 += (double)acc * acc;
    }
    block_reduce2(s, s2, red, t);
    double mean2 = s * (1.0 / NP);
    double var2 = s2 * (1.0 / NP) - mean2 * mean2;
    float rs2 = (float)(1.0 / sqrt(var2 + (double)CEPS));
    float mf2 = (float)mean2;
    for (int i = 0; i < 16; i++) {
        int pix = t + i * 256;
        float o = v[i] + gelu_fast((tv[i] - mf2) * rs2);
        h[base + pix] = packf(o);
    }
}

// ---------------- final instance norm in place on d_out ----------------
__global__ __launch_bounds__(256) void in_final_kernel(float* __restrict__ y)
{
    __shared__ double red[512];
    size_t base = (size_t)blockIdx.x * NP;
    int t = threadIdx.x;
    float v[16]; double s = 0.0, s2 = 0.0;
    for (int i = 0; i < 16; i++) { float x = y[base + t + i * 256]; v[i] = x; s += x; s2 += (double)x * x; }
    block_reduce2(s, s2, red, t);
    double mean = s * (1.0 / NP);
    double var = s2 * (1.0 / NP) - mean * mean;
    float rs = (float)(1.0 / sqrt(var + (double)CEPS));
    float mf = (float)mean;
    for (int i = 0; i < 16; i++)
        y[base + t + i * 256] = (v[i] - mf) * rs;
}

extern "C" void kernel_launch(void* const* d_in, const int* in_sizes, int n_in,
                              void* d_out, int out_size, void* d_ws, size_t ws_size,
                              hipStream_t stream)
{
    const float* x      = (const float*)d_in[0];
    const float* g      = (const float*)d_in[1];
    const float* bc     = (const float*)d_in[2];
    const float* w_qkv  = (const float*)d_in[3];
    const float* w_out  = (const float*)d_in[4];
    const float* b_out  = (const float*)d_in[5];
    const float* w_dw   = (const float*)d_in[6];
    const float* b_dw   = (const float*)d_in[7];
    const float* w_comb = (const float*)d_in[8];
    const float* b_comb = (const float*)d_in[9];
    const float* w_ff1  = (const float*)d_in[10];
    const float* b_ff1  = (const float*)d_in[11];
    const float* w_ffdw = (const float*)d_in[12];
    const float* b_ffdw = (const float*)d_in[13];
    const float* w_ff2  = (const float*)d_in[14];
    const float* b_ff2  = (const float*)d_in[15];
    float* out = (float*)d_out;
    float* ws  = (float*)d_ws;

    const size_t S = (size_t)NB * NC * NP;   // 16,777,216 floats (64 MiB)
    float* xn    = ws;
    float* qkv   = ws + S;
    float* h1    = ws;
    float* Fbuf  = out;
    float* attnb = qkv + (size_t)256 * NP;
    float* convb = qkv + (size_t)512 * NP;
    float* qrow    = ws;
    float* qprobe  = qrow + 262144;
    float* kheight = qprobe + 4096;
    float* kselb   = kheight + 262144;
    float* vselb   = kselb + 262144;

    size_t need = 4 * S * sizeof(float);
    if (ws_size < need) {
        float val = 1024.0f + (float)(ws_size >> 20);
        diag_fill<<<(out_size + 255) / 256, 256, 0, stream>>>(out, val, out_size);
        return;
    }

    cln_kernel<<<256, 256, 0, stream>>>(x, g, bc, xn);
    gemm_mfma<false><<<dim3(16, 6, NB), 512, 0, stream>>>(xn, 256, 256, nullptr, 0, 256,
                                                          w_qkv, nullptr, nullptr, qkv, 768, 768);
    l2norm_kernel<<<131072, 256, 0, stream>>>(qkv, qrow, kheight);
    qprobe_kernel<<<64, 64, 0, stream>>>(qrow, qprobe);
    select_kernel<<<NBH, 64, 0, stream>>>(qkv, qprobe, kheight, kselb, vselb);
    attn_kernel<<<dim3(16, NBH), 256, 0, stream>>>(qkv, kselb, vselb);
    gemm_mfma<true><<<dim3(16, 2, NB), 512, 0, stream>>>(qkv, 768, 256, nullptr, 0, 256,
                                                         w_out, b_out, nullptr, attnb, 768, 256);
    dwconv_kernel<<<NB * NC, 256, 0, stream>>>(x, w_dw, b_dw, convb, NC, 768);
    gemm_mfma<true><<<dim3(16, 2, NB), 512, 0, stream>>>(attnb, 768, 256, convb, 768, 512,
                                                         w_comb, b_comb, x, Fbuf, 256, 256);
    gemm_mfma<false><<<dim3(16, 8, NB), 512, 0, stream>>>(Fbuf, 256, 256, nullptr, 0, 256,
                                                          w_ff1, b_ff1, nullptr, h1, 1024, 1024);
    ff_fused_kernel<<<NB * NFF, 256, 0, stream>>>(h1, w_ffdw, b_ffdw);
    gemm_mfma<false><<<dim3(16, 2, NB), 512, 0, stream>>>(h1, 1024, 1024, nullptr, 0, 1024,
                                                          w_ff2, b_ff2, nullptr, out, 256, 256);
    in_final_kernel<<<NB * NC, 256, 0, stream>>>(out);
}

// Round 13
// 1114.630 us; speedup vs baseline: 1.0768x; 1.0313x over previous
//
#include <hip/hip_runtime.h>
#include <math.h>

#define NB 16
#define NC 256
#define NP 4096      // 64*64
#define NHEADS 8
#define NDH 32
#define NBH 128
#define NFF 1024
#define CEPS 1e-5f

typedef short s16x8 __attribute__((ext_vector_type(8)));
typedef float f32x4 __attribute__((ext_vector_type(4)));

// ---------------- diagnostic fill (guard trip) ----------------
__global__ __launch_bounds__(256) void diag_fill(float* __restrict__ out, float val, int n)
{
    int i = blockIdx.x * 256 + threadIdx.x;
    if (i < n) out[i] = val;
}

// ---------------- bf16 split helpers ----------------
__device__ inline unsigned short f2bf(float f) {
    unsigned u = __float_as_uint(f);
    return (unsigned short)((u + 0x7FFFu + ((u >> 16) & 1u)) >> 16);
}
__device__ inline float bf2f(unsigned short h) { return __uint_as_float(((unsigned)h) << 16); }
__device__ inline void split2(float f, unsigned short& hi, unsigned short& lo) {
    hi = f2bf(f);
    lo = f2bf(f - bf2f(hi));
}
// fast round-to-nearest split (6 ops); same 2^-17 error class (round-11 validated)
__device__ inline void split_rn(float f, unsigned short& hi, unsigned short& lo) {
    unsigned u = __float_as_uint(f);
    unsigned tt = u + 0x8000u;
    hi = (unsigned short)(tt >> 16);
    float r = f - __uint_as_float(tt & 0xffff0000u);
    lo = (unsigned short)((__float_as_uint(r) + 0x8000u) >> 16);
}
// packed: (hi<<16)|lo
__device__ inline unsigned pack_hl(float f) {
    unsigned short h, lo; split2(f, h, lo);
    return ((unsigned)h << 16) | (unsigned)lo;
}
__device__ inline float packf(float f) { return __uint_as_float(pack_hl(f)); }

// ---------------- weight prepack: fp32 -> packed hi|lo uint32 ----------------
__global__ __launch_bounds__(256) void pack_w_kernel(
    const float* __restrict__ w, unsigned* __restrict__ pw, int n)
{
    int i = blockIdx.x * 256 + threadIdx.x;
    if (i < n) pw[i] = pack_hl(w[i]);
}

// ---------------- fused comb weight: W_fused = [W_comb_L @ W_out | W_comb_R] ----------
// pwF: 256x512 packed. bF[o] = sum_k W_comb[o][k]*b_out[k] + b_comb[o].
__global__ __launch_bounds__(256) void fuse_comb_kernel(
    const float* __restrict__ w_comb, const float* __restrict__ w_out,
    const float* __restrict__ b_out, const float* __restrict__ b_comb,
    unsigned* __restrict__ pwF, float* __restrict__ bF)
{
    int idx = blockIdx.x * 256 + threadIdx.x;   // 131072
    int o = idx >> 9, cc = idx & 511;
    float val;
    if (cc < 256) {
        double s = 0.0;
        for (int k = 0; k < 256; k++)
            s += (double)w_comb[o * 512 + k] * (double)w_out[k * 256 + cc];
        val = (float)s;
    } else {
        val = w_comb[o * 512 + cc];
    }
    pwF[idx] = pack_hl(val);
    if (idx < 256) {
        double s = 0.0;
        for (int k = 0; k < 256; k++)
            s += (double)w_comb[idx * 512 + k] * (double)b_out[k];
        bF[idx] = (float)(s + (double)b_comb[idx]);
    }
}

// ---------------- channel layer norm -> PACKED xn ----------------
__global__ __launch_bounds__(256) void cln_kernel(
    const float* __restrict__ x, const float* __restrict__ g, const float* __restrict__ bc,
    float* __restrict__ xn)
{
    int gp = blockIdx.x * 256 + threadIdx.x;
    int b = gp >> 12, p = gp & 4095;
    const float* src = x + (size_t)b * NC * NP + p;
    double s = 0.0, s2 = 0.0;
    for (int c = 0; c < NC; c++) { float v = src[(size_t)c * NP]; s += v; s2 += (double)v * v; }
    double mean = s * (1.0 / NC);
    double var = s2 * (1.0 / NC) - mean * mean;
    float rs = (float)(1.0 / sqrt(var + (double)CEPS));
    float mf = (float)mean;
    float* dst = xn + (size_t)b * NC * NP + p;
    for (int c = 0; c < NC; c++)
        dst[(size_t)c * NP] = packf((src[(size_t)c * NP] - mf) * rs * g[c] + bc[c]);
}

// ---------------- split-bf16 MFMA GEMM: 128o x 256p tile, 8 waves, K-step 32 ----------
// B-input PACKED hi/lo uint32. A (weights): PACKA ? packed uint32 : raw fp32.
template<bool PACKO, bool PACKA>
__global__ __launch_bounds__(512) void gemm_mfma(
    const float* __restrict__ inA, int sA, int C1,
    const float* __restrict__ inB, int sB, int Ctot,
    const float* __restrict__ Wt, const float* __restrict__ bias,
    const float* __restrict__ resid, float* __restrict__ out, int sO, int O)
{
    __shared__ __align__(16) unsigned short Ah[128 * 32], Al[128 * 32];
    __shared__ __align__(16) unsigned short Bh[256 * 32], Bl[256 * 32];
    char* cAh = (char*)Ah; char* cAl = (char*)Al;
    char* cBh = (char*)Bh; char* cBl = (char*)Bl;

    // ---- XCD-batch swizzle ----
    const unsigned npb = gridDim.x * gridDim.y;
    unsigned lin = blockIdx.x + gridDim.x * (blockIdx.y + gridDim.y * blockIdx.z);
    unsigned low = lin & 7u, rest = lin >> 3;
    unsigned high = (rest >= npb) ? 1u : 0u;
    unsigned idx = rest - high * npb;
    const int b = (int)(low + 8u * high);
    const int o0 = (int)(idx / gridDim.x) * 128, p0 = (int)(idx % gridDim.x) * 256;

    const int t = threadIdx.x;
    const int l = t & 63, w = t >> 6;
    const int wr = w >> 2, wc = w & 3;
    const int g = l >> 4, l15 = l & 15;
    const int slotl = (l & 3) ^ ((l >> 2) & 3);

    f32x4 acc[4][4];
    #pragma unroll
    for (int m = 0; m < 4; m++)
        #pragma unroll
        for (int n = 0; n < 4; n++) acc[m][n] = (f32x4){0.f, 0.f, 0.f, 0.f};

    const int arow = t >> 2;
    const int ak8 = (t & 3) * 8;
    const int aslot = (arow & 3) ^ ((arow >> 2) & 3);
    const int aoff = arow * 64 + ((((ak8 >> 3)) ^ aslot) << 4);
    const int bp = t & 255;
    const int bhalfk = t >> 8;
    const int bslot = (bp & 3) ^ ((bp >> 2) & 3);

    uint4 wa0, wa1;          // A prefetch (bitwise fp32 or packed)
    unsigned pb[16];         // B prefetch

    #define LOAD_TILE(K0)                                                                 \
    {                                                                                     \
        const unsigned* wsrc = (const unsigned*)Wt + (size_t)(o0 + arow) * Ctot + (K0) + ak8; \
        wa0 = *(const uint4*)(wsrc);                                                      \
        wa1 = *(const uint4*)(wsrc + 4);                                                  \
        _Pragma("unroll")                                                                 \
        for (int q = 0; q < 8; q++) {                                                     \
            int c2 = bhalfk * 16 + q * 2;                                                 \
            int cc = (K0) + c2;                                                           \
            const float* srcp = (cc < C1) ? inA + ((size_t)b * sA + cc) * (size_t)NP      \
                                          : inB + ((size_t)b * sB + (cc - C1)) * (size_t)NP; \
            pb[2 * q]     = __float_as_uint(srcp[p0 + bp]);                               \
            pb[2 * q + 1] = __float_as_uint(srcp[(size_t)NP + p0 + bp]);                  \
        }                                                                                 \
    }

    #define STORE_LDS()                                                                   \
    {                                                                                     \
        if constexpr (PACKA) {                                                            \
            uint4 hq, lq;                                                                 \
            hq.x = __builtin_amdgcn_perm(wa0.y, wa0.x, 0x07060302u);                      \
            lq.x = __builtin_amdgcn_perm(wa0.y, wa0.x, 0x05040100u);                      \
            hq.y = __builtin_amdgcn_perm(wa0.w, wa0.z, 0x07060302u);                      \
            lq.y = __builtin_amdgcn_perm(wa0.w, wa0.z, 0x05040100u);                      \
            hq.z = __builtin_amdgcn_perm(wa1.y, wa1.x, 0x07060302u);                      \
            lq.z = __builtin_amdgcn_perm(wa1.y, wa1.x, 0x05040100u);                      \
            hq.w = __builtin_amdgcn_perm(wa1.w, wa1.z, 0x07060302u);                      \
            lq.w = __builtin_amdgcn_perm(wa1.w, wa1.z, 0x05040100u);                      \
            *(uint4*)(cAh + aoff) = hq;                                                   \
            *(uint4*)(cAl + aoff) = lq;                                                   \
        } else {                                                                          \
            ushort4 h0, l0, h1, l1;                                                       \
            split_rn(__uint_as_float(wa0.x), h0.x, l0.x);                                 \
            split_rn(__uint_as_float(wa0.y), h0.y, l0.y);                                 \
            split_rn(__uint_as_float(wa0.z), h0.z, l0.z);                                 \
            split_rn(__uint_as_float(wa0.w), h0.w, l0.w);                                 \
            split_rn(__uint_as_float(wa1.x), h1.x, l1.x);                                 \
            split_rn(__uint_as_float(wa1.y), h1.y, l1.y);                                 \
            split_rn(__uint_as_float(wa1.z), h1.z, l1.z);                                 \
            split_rn(__uint_as_float(wa1.w), h1.w, l1.w);                                 \
            *(ushort4*)(cAh + aoff) = h0; *(ushort4*)(cAh + aoff + 8) = h1;               \
            *(ushort4*)(cAl + aoff) = l0; *(ushort4*)(cAl + aoff + 8) = l1;               \
        }                                                                                 \
        _Pragma("unroll")                                                                 \
        for (int q = 0; q < 8; q++) {                                                     \
            int c2 = bhalfk * 16 + q * 2;                                                 \
            unsigned u0 = pb[2 * q], u1 = pb[2 * q + 1];                                  \
            unsigned hp = __builtin_amdgcn_perm(u1, u0, 0x07060302u);                     \
            unsigned lp = __builtin_amdgcn_perm(u1, u0, 0x05040100u);                     \
            int off = bp * 64 + ((((c2 >> 3)) ^ bslot) << 4) + (c2 & 7) * 2;              \
            *(unsigned*)(cBh + off) = hp;                                                 \
            *(unsigned*)(cBl + off) = lp;                                                 \
        }                                                                                 \
    }

    LOAD_TILE(0)

    for (int k0 = 0; k0 < Ctot; k0 += 32) {
        if (k0) __syncthreads();
        STORE_LDS()
        __syncthreads();
        if (k0 + 32 < Ctot) LOAD_TILE(k0 + 32)

        s16x8 ah[4], al[4];
        #pragma unroll
        for (int m = 0; m < 4; m++) {
            int ao = (wr * 64 + m * 16 + l15) * 64 + ((g ^ slotl) << 4);
            ah[m] = *(const s16x8*)(cAh + ao);
            al[m] = *(const s16x8*)(cAl + ao);
        }
        #pragma unroll
        for (int n = 0; n < 4; n++) {
            int bo = (wc * 64 + n * 16 + l15) * 64 + ((g ^ slotl) << 4);
            s16x8 bh = *(const s16x8*)(cBh + bo);
            s16x8 bl = *(const s16x8*)(cBl + bo);
            #pragma unroll
            for (int m = 0; m < 4; m++) {
                acc[m][n] = __builtin_amdgcn_mfma_f32_16x16x32_bf16(ah[m], bh, acc[m][n], 0, 0, 0);
                acc[m][n] = __builtin_amdgcn_mfma_f32_16x16x32_bf16(ah[m], bl, acc[m][n], 0, 0, 0);
                acc[m][n] = __builtin_amdgcn_mfma_f32_16x16x32_bf16(al[m], bh, acc[m][n], 0, 0, 0);
            }
        }
    }
    #undef LOAD_TILE
    #undef STORE_LDS

    // ---- epilogue: D[row=(l>>4)*4+r][col=l&15] ----
    #pragma unroll
    for (int m = 0; m < 4; m++) {
        #pragma unroll
        for (int r = 0; r < 4; r++) {
            int orow = o0 + wr * 64 + m * 16 + g * 4 + r;
            float bs = bias ? bias[orow] : 0.f;
            #pragma unroll
            for (int n = 0; n < 4; n++) {
                int pcol = p0 + wc * 64 + n * 16 + l15;
                float v = acc[m][n][r] + bs;
                if (resid) v += resid[((size_t)b * O + orow) * (size_t)NP + pcol];
                out[((size_t)b * sO + orow) * (size_t)NP + pcol] = PACKO ? packf(v) : v;
            }
        }
    }
}

// ---------------- l2norm along W for q and k rows; emit |row|-sums ----------------
__global__ __launch_bounds__(256) void l2norm_kernel(
    float* __restrict__ qkv, float* __restrict__ qrow, float* __restrict__ kheight)
{
    int r = blockIdx.x * 4 + (threadIdx.x >> 6);
    int lane = threadIdx.x & 63;
    int which = r >> 18;
    int rr = r & 262143;
    int bh = rr >> 11;
    int c = (rr >> 6) & 31;
    int h = rr & 63;
    int b = bh >> 3, head = bh & 7;
    int ch = which * 256 + head * 32 + c;
    float* p = qkv + ((size_t)b * 768 + ch) * NP + h * 64 + lane;
    float v = *p;
    float ss = v * v, as = fabsf(v);
    for (int off = 32; off; off >>= 1) { ss += __shfl_xor(ss, off); as += __shfl_xor(as, off); }
    float n = sqrtf(ss);
    float inv = 1.f / fmaxf(n, 1e-12f);
    *p = v * inv;
    if (lane == 0) {
        float s = as * inv;
        if (which == 0) qrow[rr] = s; else kheight[rr] = s;
    }
}

__global__ void qprobe_kernel(const float* __restrict__ qrow, float* __restrict__ qprobe)
{
    int i = blockIdx.x * 64 + threadIdx.x;
    double s = 0.0;
    for (int h = 0; h < 64; h++) s += qrow[(size_t)i * 64 + h];
    qprobe[i] = (float)s;
}

// ---------------- scores + top-k rows/cols + gather k/v ----------------
__global__ __launch_bounds__(64) void select_kernel(
    const float* __restrict__ qkv, const float* __restrict__ qprobe,
    const float* __restrict__ kheight,
    float* __restrict__ ksel, float* __restrict__ vsel)
{
    const int bh = blockIdx.x;
    const int b = bh >> 3, head = bh & 7;
    const int lane = threadIdx.x;
    __shared__ int hs[8], wsl[8];
    __shared__ float qp[32];
    if (lane < 32) qp[lane] = qprobe[bh * 32 + lane];
    __syncthreads();
    double scd = 0.0;
    for (int c = 0; c < 32; c++) scd += (double)qp[c] * kheight[((size_t)bh * 32 + c) * 64 + lane];
    float sc = (float)scd;
    for (int it = 0; it < 8; it++) {
        float v = sc; int id = lane;
        for (int off = 32; off; off >>= 1) {
            float ov = __shfl_xor(v, off); int oi = __shfl_xor(id, off);
            if (ov > v || (ov == v && oi < id)) { v = ov; id = oi; }
        }
        if (lane == 0) hs[it] = id;
        if (lane == id) sc = -3.4e38f;
    }
    __syncthreads();
    const float* kbase = qkv + ((size_t)b * 768 + 256 + head * 32) * NP;
    double sc2d = 0.0;
    for (int c = 0; c < 32; c++) {
        float kw = 0.f;
        for (int hi = 0; hi < 8; hi++)
            kw += fabsf(kbase[(size_t)c * NP + hs[hi] * 64 + lane]);
        sc2d += (double)qp[c] * kw;
    }
    float sc2 = (float)sc2d;
    for (int it = 0; it < 8; it++) {
        float v = sc2; int id = lane;
        for (int off = 32; off; off >>= 1) {
            float ov = __shfl_xor(v, off); int oi = __shfl_xor(id, off);
            if (ov > v || (ov == v && oi < id)) { v = ov; id = oi; }
        }
        if (lane == 0) wsl[it] = id;
        if (lane == id) sc2 = -3.4e38f;
    }
    __syncthreads();
    const float* vbase = qkv + ((size_t)b * 768 + 512 + head * 32) * NP;
    int hi = lane >> 3, wi = lane & 7;
    int hh = hs[hi], ww = wsl[wi];
    for (int d = 0; d < 32; d++) {
        ksel[((size_t)bh * 64 + lane) * 32 + d] = kbase[(size_t)d * NP + hh * 64 + ww];
        vsel[((size_t)bh * 64 + lane) * 32 + d] = vbase[(size_t)d * NP + hh * 64 + ww];
    }
}

// ---------------- attention: in-place over q slot; writes PACKED ctx ----------------
__global__ __launch_bounds__(256) void attn_kernel(
    float* __restrict__ qkv, const float* __restrict__ ksel, const float* __restrict__ vsel)
{
    __shared__ __align__(16) float ks[64][32];
    __shared__ __align__(16) float vs[64][32];
    int bh = blockIdx.y, b = bh >> 3, head = bh & 7;
    int t = threadIdx.x;
    const float* kb = ksel + (size_t)bh * 2048;
    const float* vb = vsel + (size_t)bh * 2048;
    for (int i = 0; i < 8; i++) {
        ((float*)ks)[t + i * 256] = kb[t + i * 256];
        ((float*)vs)[t + i * 256] = vb[t + i * 256];
    }
    __syncthreads();
    int p = blockIdx.x * 256 + t;
    float* qb = qkv + ((size_t)b * 768 + head * 32) * NP + p;
    float q[32];
    #pragma unroll
    for (int d = 0; d < 32; d++) q[d] = qb[(size_t)d * NP];
    float s[64], m = -3.4e38f;
    for (int j = 0; j < 64; j++) {
        float dot = 0.f;
        #pragma unroll
        for (int d = 0; d < 32; d++) dot += q[d] * ks[j][d];
        s[j] = dot; m = fmaxf(m, dot);
    }
    float den = 0.f;
    for (int j = 0; j < 64; j++) { float e = expf(s[j] - m); s[j] = e; den += e; }
    float o[32] = {};
    for (int j = 0; j < 64; j++) {
        float a = s[j];
        #pragma unroll
        for (int d = 0; d < 32; d++) o[d] += a * vs[j][d];
    }
    float r = 1.f / den;
    #pragma unroll
    for (int d = 0; d < 32; d++) qb[(size_t)d * NP] = packf(o[d] * r);
}

// ---------------- depthwise 3x3 on x; PACKED strided output planes ----------------
__global__ __launch_bounds__(256) void dwconv_kernel(
    const float* __restrict__ in, const float* __restrict__ w, const float* __restrict__ bias,
    float* __restrict__ out, int Cn, int sO)
{
    __shared__ __align__(16) float pl[64][64];
    int bcb = blockIdx.x;
    int b = bcb / Cn, c = bcb % Cn;
    const float* src = in + (size_t)bcb * NP;
    float* dst = out + ((size_t)b * sO + c) * NP;
    int t = threadIdx.x;
    for (int i = 0; i < 16; i++) { int pix = t + i * 256; pl[pix >> 6][pix & 63] = src[pix]; }
    float w9[9];
    #pragma unroll
    for (int k = 0; k < 9; k++) w9[k] = w[c * 9 + k];
    float bsv = bias[c];
    __syncthreads();
    for (int i = 0; i < 16; i++) {
        int pix = t + i * 256; int y = pix >> 6, xx = pix & 63;
        float acc = bsv;
        #pragma unroll
        for (int dy = 0; dy < 3; dy++) {
            int yy = y + dy - 1; if (yy < 0 || yy > 63) continue;
            #pragma unroll
            for (int dx = 0; dx < 3; dx++) {
                int x2 = xx + dx - 1; if (x2 < 0 || x2 > 63) continue;
                acc += w9[dy * 3 + dx] * pl[yy][x2];
            }
        }
        dst[pix] = packf(acc);
    }
}

// ---------------- fast gelu: A&S 7.1.26 erf (max abs err ~1.5e-7) ----------------
__device__ inline float gelu_fast(float x) {
    float z = x * 0.70710678118654752f;
    float a = fabsf(z);
    float t = 1.0f / (1.0f + 0.3275911f * a);
    float p = t * (0.254829592f + t * (-0.284496736f + t * (1.421413741f +
              t * (-1.453152027f + t * 1.061405429f))));
    float e = __expf(-a * a);
    float r = 1.0f - p * e;                 // erf(|z|)
    float erfz = copysignf(r, z);
    return 0.5f * x * (1.0f + erfz);
}

__device__ inline void block_reduce2(double& s, double& s2, double* red, int t)
{
    __syncthreads();
    red[t] = s; red[256 + t] = s2;
    __syncthreads();
    for (int st = 128; st; st >>= 1) {
        if (t < st) { red[t] += red[t + st]; red[256 + t] += red[256 + t + st]; }
        __syncthreads();
    }
    s = red[0]; s2 = red[256];
}

// ---------------- fused FF: h = gelu(IN(h)); h += gelu(IN(dwconv3(h))); PACKED out ----
__global__ __launch_bounds__(256) void ff_fused_kernel(
    float* __restrict__ h, const float* __restrict__ w, const float* __restrict__ bias)
{
    __shared__ __align__(16) float pl[64][64];
    __shared__ double red[512];
    int plane = blockIdx.x;
    int c = plane & (NFF - 1);
    size_t base = (size_t)plane * NP;
    int t = threadIdx.x;
    float v[16]; double s = 0.0, s2 = 0.0;
    for (int i = 0; i < 16; i++) { float x = h[base + t + i * 256]; v[i] = x; s += x; s2 += (double)x * x; }
    block_reduce2(s, s2, red, t);
    double mean = s * (1.0 / NP);
    double var = s2 * (1.0 / NP) - mean * mean;
    float rs = (float)(1.0 / sqrt(var + (double)CEPS));
    float mf = (float)mean;
    for (int i = 0; i < 16; i++) {
        float gx = gelu_fast((v[i] - mf) * rs);
        v[i] = gx;
        int pix = t + i * 256;
        pl[pix >> 6][pix & 63] = gx;
    }
    __syncthreads();
    float w9[9];
    #pragma unroll
    for (int k = 0; k < 9; k++) w9[k] = w[c * 9 + k];
    float bsv = bias[c];
    float tv[16]; s = 0.0; s2 = 0.0;
    for (int i = 0; i < 16; i++) {
        int pix = t + i * 256; int y = pix >> 6, xx = pix & 63;
        float acc = bsv;
        #pragma unroll
        for (int dy = 0; dy < 3; dy++) {
            int yy = y + dy - 1; if (yy < 0 || yy > 63) continue;
            #pragma unroll
            for (int dx = 0; dx < 3; dx++) {
                int x2 = xx + dx - 1; if (x2 < 0 || x2 > 63) continue;
                acc += w9[dy * 3 + dx] * pl[yy][x2];
            }
        }
        tv[i] = acc; s += acc; s2 += (double)acc * acc;
    }
    block_reduce2(s, s2, red, t);
    double mean2 = s * (1.0 / NP);
    double var2 = s2 * (1.0 / NP) - mean2 * mean2;
    float rs2 = (float)(1.0 / sqrt(var2 + (double)CEPS));
    float mf2 = (float)mean2;
    for (int i = 0; i < 16; i++) {
        int pix = t + i * 256;
        float o = v[i] + gelu_fast((tv[i] - mf2) * rs2);
        h[base + pix] = packf(o);
    }
}

// ---------------- final instance norm in place on d_out ----------------
__global__ __launch_bounds__(256) void in_final_kernel(float* __restrict__ y)
{
    __shared__ double red[512];
    size_t base = (size_t)blockIdx.x * NP;
    int t = threadIdx.x;
    float v[16]; double s = 0.0, s2 = 0.0;
    for (int i = 0; i < 16; i++) { float x = y[base + t + i * 256]; v[i] = x; s += x; s2 += (double)x * x; }
    block_reduce2(s, s2, red, t);
    double mean = s * (1.0 / NP);
    double var = s2 * (1.0 / NP) - mean * mean;
    float rs = (float)(1.0 / sqrt(var + (double)CEPS));
    float mf = (float)mean;
    for (int i = 0; i < 16; i++)
        y[base + t + i * 256] = (v[i] - mf) * rs;
}

extern "C" void kernel_launch(void* const* d_in, const int* in_sizes, int n_in,
                              void* d_out, int out_size, void* d_ws, size_t ws_size,
                              hipStream_t stream)
{
    const float* x      = (const float*)d_in[0];
    const float* g      = (const float*)d_in[1];
    const float* bc     = (const float*)d_in[2];
    const float* w_qkv  = (const float*)d_in[3];
    const float* w_out  = (const float*)d_in[4];
    const float* b_out  = (const float*)d_in[5];
    const float* w_dw   = (const float*)d_in[6];
    const float* b_dw   = (const float*)d_in[7];
    const float* w_comb = (const float*)d_in[8];
    const float* b_comb = (const float*)d_in[9];
    const float* w_ff1  = (const float*)d_in[10];
    const float* b_ff1  = (const float*)d_in[11];
    const float* w_ffdw = (const float*)d_in[12];
    const float* b_ffdw = (const float*)d_in[13];
    const float* w_ff2  = (const float*)d_in[14];
    const float* b_ff2  = (const float*)d_in[15];
    float* out = (float*)d_out;
    float* ws  = (float*)d_ws;

    const size_t S = (size_t)NB * NC * NP;   // 16,777,216 floats (64 MiB)
    // Memory plan (ws = 4S exactly):
    //   d_out      : pw_qkv (packed qkv weights) until step 9; Fbuf (attn_out, steps 9-10);
    //                final output (12+)
    //   ws[0,S)    : xn packed (1-2) -> smalls (3-6) -> pwF+bF (7-9, dead smalls) -> dead
    //   ws[S,4S)   : qkv fp32; ctx packed in q-planes after attn; convb packed in v-planes;
    //                k-planes dead after select
    //   ws[0,4S)   : h1 fp32 (10+), packed in place by ff_fused (11)
    float* xn    = ws;
    float* qkv   = ws + S;
    float* h1    = ws;
    float* Fbuf  = out;
    float* convb = qkv + (size_t)512 * NP;
    float* qrow    = ws;
    float* qprobe  = qrow + 262144;
    float* kheight = qprobe + 4096;
    float* kselb   = kheight + 262144;
    float* vselb   = kselb + 262144;
    unsigned* pw_qkv = (unsigned*)out;        // 196608 u32 in d_out (free until step 9)
    unsigned* pwF    = (unsigned*)ws;         // 131072 u32 (dead smalls, after attn)
    float*    bF     = ws + 131072;           // 256 floats

    size_t need = 4 * S * sizeof(float);
    if (ws_size < need) {
        float val = 1024.0f + (float)(ws_size >> 20);
        diag_fill<<<(out_size + 255) / 256, 256, 0, stream>>>(out, val, out_size);
        return;
    }

    // 0. prepack qkv weights -> d_out
    pack_w_kernel<<<768, 256, 0, stream>>>(w_qkv, pw_qkv, 768 * 256);
    // 1. channel layer norm -> packed xn
    cln_kernel<<<256, 256, 0, stream>>>(x, g, bc, xn);
    // 2. qkv = W_qkv * xn (packed A)
    gemm_mfma<false, true><<<dim3(16, 6, NB), 512, 0, stream>>>(
        xn, 256, 256, nullptr, 0, 256, (const float*)pw_qkv, nullptr, nullptr, qkv, 768, 768);
    // 3-6. l2norm, qprobe, select, attention (packed ctx -> q-planes)
    l2norm_kernel<<<131072, 256, 0, stream>>>(qkv, qrow, kheight);
    qprobe_kernel<<<64, 64, 0, stream>>>(qrow, qprobe);
    select_kernel<<<NBH, 64, 0, stream>>>(qkv, qprobe, kheight, kselb, vselb);
    attn_kernel<<<dim3(16, NBH), 256, 0, stream>>>(qkv, kselb, vselb);
    // 7. fused comb weight (W_comb_L @ W_out | W_comb_R) -> packed, into dead smalls
    fuse_comb_kernel<<<512, 256, 0, stream>>>(w_comb, w_out, b_out, b_comb, pwF, bF);
    // 8. conv branch -> v-planes (packed)
    dwconv_kernel<<<NB * NC, 256, 0, stream>>>(x, w_dw, b_dw, convb, NC, 768);
    // 9. attn_out = W_fused * [ctx; convb] + b_fused + x -> d_out (packed)
    //    (out-projection algebraically folded in; k-planes/out-proj GEMM eliminated)
    gemm_mfma<true, true><<<dim3(16, 2, NB), 512, 0, stream>>>(
        qkv, 768, 256, convb, 768, 512, (const float*)pwF, bF, x, Fbuf, 256, 256);
    // 10. h1 = W_ff1 * attn_out + b_ff1 -> ws[0,4S) fp32
    gemm_mfma<false, false><<<dim3(16, 8, NB), 512, 0, stream>>>(
        Fbuf, 256, 256, nullptr, 0, 256, w_ff1, b_ff1, nullptr, h1, 1024, 1024);
    // 11. fused FF (packed in place)
    ff_fused_kernel<<<NB * NFF, 256, 0, stream>>>(h1, w_ffdw, b_ffdw);
    // 12. y = W_ff2 * h1 + b_ff2 -> d_out fp32
    gemm_mfma<false, false><<<dim3(16, 2, NB), 512, 0, stream>>>(
        h1, 1024, 1024, nullptr, 0, 1024, w_ff2, b_ff2, nullptr, out, 256, 256);
    // 13. final instance norm
    in_final_kernel<<<NB * NC, 256, 0, stream>>>(out);
}

// Round 14
// 1073.951 us; speedup vs baseline: 1.1176x; 1.0379x over previous
//
#include <hip/hip_runtime.h>
#include <math.h>

#define NB 16
#define NC 256
#define NP 4096      // 64*64
#define NHEADS 8
#define NDH 32
#define NBH 128
#define NFF 1024
#define CEPS 1e-5f

typedef short s16x8 __attribute__((ext_vector_type(8)));
typedef float f32x4 __attribute__((ext_vector_type(4)));

// ---------------- diagnostic fill (guard trip) ----------------
__global__ __launch_bounds__(256) void diag_fill(float* __restrict__ out, float val, int n)
{
    int i = blockIdx.x * 256 + threadIdx.x;
    if (i < n) out[i] = val;
}

// ---------------- bf16 split helpers ----------------
__device__ inline unsigned short f2bf(float f) {
    unsigned u = __float_as_uint(f);
    return (unsigned short)((u + 0x7FFFu + ((u >> 16) & 1u)) >> 16);
}
__device__ inline float bf2f(unsigned short h) { return __uint_as_float(((unsigned)h) << 16); }
__device__ inline void split2(float f, unsigned short& hi, unsigned short& lo) {
    hi = f2bf(f);
    lo = f2bf(f - bf2f(hi));
}
// fast round-to-nearest split (6 ops); same 2^-17 error class (round-11 validated)
__device__ inline void split_rn(float f, unsigned short& hi, unsigned short& lo) {
    unsigned u = __float_as_uint(f);
    unsigned tt = u + 0x8000u;
    hi = (unsigned short)(tt >> 16);
    float r = f - __uint_as_float(tt & 0xffff0000u);
    lo = (unsigned short)((__float_as_uint(r) + 0x8000u) >> 16);
}
// packed: (hi<<16)|lo
__device__ inline unsigned pack_hl(float f) {
    unsigned short h, lo; split2(f, h, lo);
    return ((unsigned)h << 16) | (unsigned)lo;
}
__device__ inline float packf(float f) { return __uint_as_float(pack_hl(f)); }

// ---------------- weight prepack with channel gain: pw = pack(w[o,c]*g[c]) ----------
__global__ __launch_bounds__(256) void pack_wg_kernel(
    const float* __restrict__ w, const float* __restrict__ g,
    unsigned* __restrict__ pw, int n)
{
    int i = blockIdx.x * 256 + threadIdx.x;
    if (i < n) pw[i] = pack_hl(w[i] * g[i & 255]);
}

// ---------------- cln stats: per (b,p) mean/rsqrt over 256 channels (4-way split) ----
__global__ __launch_bounds__(256) void cln_stats_kernel(
    const float* __restrict__ x, float* __restrict__ rs, float* __restrict__ mrs)
{
    __shared__ double red[512];
    int t = threadIdx.x;
    int i = t & 63, q = t >> 6;
    int col = blockIdx.x * 64 + i;           // 0..65535 (b*4096+p)
    int b = col >> 12, p = col & 4095;
    const float* src = x + (size_t)b * NC * NP + (size_t)(q * 64) * NP + p;
    double s = 0.0, s2 = 0.0;
    #pragma unroll 8
    for (int c = 0; c < 64; c++) { float v = src[(size_t)c * NP]; s += v; s2 += (double)v * v; }
    red[q * 64 + i] = s; red[256 + q * 64 + i] = s2;
    __syncthreads();
    if (q == 0) {
        double S  = red[i] + red[64 + i] + red[128 + i] + red[192 + i];
        double S2 = red[256 + i] + red[320 + i] + red[384 + i] + red[448 + i];
        double mean = S * (1.0 / 256.0);
        double var = S2 * (1.0 / 256.0) - mean * mean;
        double r = 1.0 / sqrt(var + (double)CEPS);
        rs[col]  = (float)r;
        mrs[col] = (float)(mean * r);
    }
}

// ---------------- A/B fold constants: A[o]=sum W[o,c]g[c], B[o]=sum W[o,c]bc[c] ------
__global__ __launch_bounds__(256) void ab_kernel(
    const float* __restrict__ wq, const float* __restrict__ g, const float* __restrict__ bc,
    float* __restrict__ Aab, float* __restrict__ Bab)
{
    int o = blockIdx.x * 256 + threadIdx.x;
    if (o >= 768) return;
    double a = 0.0, bsum = 0.0;
    for (int c = 0; c < 256; c++) {
        double w = wq[o * 256 + c];
        a += w * (double)g[c];
        bsum += w * (double)bc[c];
    }
    Aab[o] = (float)a; Bab[o] = (float)bsum;
}

// ---------------- fused comb weight: W_fused = [W_comb_L @ W_out | W_comb_R] ----------
__global__ __launch_bounds__(256) void fuse_comb_kernel(
    const float* __restrict__ w_comb, const float* __restrict__ w_out,
    const float* __restrict__ b_out, const float* __restrict__ b_comb,
    unsigned* __restrict__ pwF, float* __restrict__ bF)
{
    int idx = blockIdx.x * 256 + threadIdx.x;   // 131072
    int o = idx >> 9, cc = idx & 511;
    float val;
    if (cc < 256) {
        double s = 0.0;
        for (int k = 0; k < 256; k++)
            s += (double)w_comb[o * 512 + k] * (double)w_out[k * 256 + cc];
        val = (float)s;
    } else {
        val = w_comb[o * 512 + cc];
    }
    pwF[idx] = pack_hl(val);
    if (idx < 256) {
        double s = 0.0;
        for (int k = 0; k < 256; k++)
            s += (double)w_comb[idx * 512 + k] * (double)b_out[k];
        bF[idx] = (float)(s + (double)b_comb[idx]);
    }
}

// ---------------- split-bf16 MFMA GEMM: 128o x 256p tile, 8 waves, K-step 32 ----------
// B-input: CLN ? raw fp32 (split in-stage) : PACKED hi/lo uint32.
// A: PACKA ? packed uint32 : raw fp32. CLN epilogue: v = rs*acc - mrs*A[o] + B[o].
template<bool PACKO, bool PACKA, bool CLN>
__global__ __launch_bounds__(512) void gemm_mfma(
    const float* __restrict__ inA, int sA, int C1,
    const float* __restrict__ inB, int sB, int Ctot,
    const float* __restrict__ Wt, const float* __restrict__ bias,
    const float* __restrict__ resid, float* __restrict__ out, int sO, int O,
    const float* __restrict__ rs, const float* __restrict__ mrs,
    const float* __restrict__ Aab, const float* __restrict__ Bab)
{
    __shared__ __align__(16) unsigned short Ah[128 * 32], Al[128 * 32];
    __shared__ __align__(16) unsigned short Bh[256 * 32], Bl[256 * 32];
    char* cAh = (char*)Ah; char* cAl = (char*)Al;
    char* cBh = (char*)Bh; char* cBl = (char*)Bl;

    // ---- XCD-batch swizzle ----
    const unsigned npb = gridDim.x * gridDim.y;
    unsigned lin = blockIdx.x + gridDim.x * (blockIdx.y + gridDim.y * blockIdx.z);
    unsigned low = lin & 7u, rest = lin >> 3;
    unsigned high = (rest >= npb) ? 1u : 0u;
    unsigned idx = rest - high * npb;
    const int b = (int)(low + 8u * high);
    const int o0 = (int)(idx / gridDim.x) * 128, p0 = (int)(idx % gridDim.x) * 256;

    const int t = threadIdx.x;
    const int l = t & 63, w = t >> 6;
    const int wr = w >> 2, wc = w & 3;
    const int g = l >> 4, l15 = l & 15;
    const int slotl = (l & 3) ^ ((l >> 2) & 3);

    f32x4 acc[4][4];
    #pragma unroll
    for (int m = 0; m < 4; m++)
        #pragma unroll
        for (int n = 0; n < 4; n++) acc[m][n] = (f32x4){0.f, 0.f, 0.f, 0.f};

    const int arow = t >> 2;
    const int ak8 = (t & 3) * 8;
    const int aslot = (arow & 3) ^ ((arow >> 2) & 3);
    const int aoff = arow * 64 + ((((ak8 >> 3)) ^ aslot) << 4);
    const int bp = t & 255;
    const int bhalfk = t >> 8;
    const int bslot = (bp & 3) ^ ((bp >> 2) & 3);

    uint4 wa0, wa1;          // A prefetch (bitwise fp32 or packed)
    unsigned pb[16];         // B prefetch (packed or raw fp32 bits)

    #define LOAD_TILE(K0)                                                                 \
    {                                                                                     \
        const unsigned* wsrc = (const unsigned*)Wt + (size_t)(o0 + arow) * Ctot + (K0) + ak8; \
        wa0 = *(const uint4*)(wsrc);                                                      \
        wa1 = *(const uint4*)(wsrc + 4);                                                  \
        _Pragma("unroll")                                                                 \
        for (int q = 0; q < 8; q++) {                                                     \
            int c2 = bhalfk * 16 + q * 2;                                                 \
            int cc = (K0) + c2;                                                           \
            const float* srcp = (cc < C1) ? inA + ((size_t)b * sA + cc) * (size_t)NP      \
                                          : inB + ((size_t)b * sB + (cc - C1)) * (size_t)NP; \
            pb[2 * q]     = __float_as_uint(srcp[p0 + bp]);                               \
            pb[2 * q + 1] = __float_as_uint(srcp[(size_t)NP + p0 + bp]);                  \
        }                                                                                 \
    }

    #define STORE_LDS()                                                                   \
    {                                                                                     \
        if constexpr (PACKA) {                                                            \
            uint4 hq, lq;                                                                 \
            hq.x = __builtin_amdgcn_perm(wa0.y, wa0.x, 0x07060302u);                      \
            lq.x = __builtin_amdgcn_perm(wa0.y, wa0.x, 0x05040100u);                      \
            hq.y = __builtin_amdgcn_perm(wa0.w, wa0.z, 0x07060302u);                      \
            lq.y = __builtin_amdgcn_perm(wa0.w, wa0.z, 0x05040100u);                      \
            hq.z = __builtin_amdgcn_perm(wa1.y, wa1.x, 0x07060302u);                      \
            lq.z = __builtin_amdgcn_perm(wa1.y, wa1.x, 0x05040100u);                      \
            hq.w = __builtin_amdgcn_perm(wa1.w, wa1.z, 0x07060302u);                      \
            lq.w = __builtin_amdgcn_perm(wa1.w, wa1.z, 0x05040100u);                      \
            *(uint4*)(cAh + aoff) = hq;                                                   \
            *(uint4*)(cAl + aoff) = lq;                                                   \
        } else {                                                                          \
            ushort4 h0, l0, h1, l1;                                                       \
            split_rn(__uint_as_float(wa0.x), h0.x, l0.x);                                 \
            split_rn(__uint_as_float(wa0.y), h0.y, l0.y);                                 \
            split_rn(__uint_as_float(wa0.z), h0.z, l0.z);                                 \
            split_rn(__uint_as_float(wa0.w), h0.w, l0.w);                                 \
            split_rn(__uint_as_float(wa1.x), h1.x, l1.x);                                 \
            split_rn(__uint_as_float(wa1.y), h1.y, l1.y);                                 \
            split_rn(__uint_as_float(wa1.z), h1.z, l1.z);                                 \
            split_rn(__uint_as_float(wa1.w), h1.w, l1.w);                                 \
            *(ushort4*)(cAh + aoff) = h0; *(ushort4*)(cAh + aoff + 8) = h1;               \
            *(ushort4*)(cAl + aoff) = l0; *(ushort4*)(cAl + aoff + 8) = l1;               \
        }                                                                                 \
        _Pragma("unroll")                                                                 \
        for (int q = 0; q < 8; q++) {                                                     \
            int c2 = bhalfk * 16 + q * 2;                                                 \
            unsigned u0 = pb[2 * q], u1 = pb[2 * q + 1];                                  \
            unsigned hp, lp;                                                              \
            if constexpr (CLN) {                                                          \
                unsigned short sh0, sl0, sh1, sl1;                                        \
                split_rn(__uint_as_float(u0), sh0, sl0);                                  \
                split_rn(__uint_as_float(u1), sh1, sl1);                                  \
                hp = (unsigned)sh0 | ((unsigned)sh1 << 16);                               \
                lp = (unsigned)sl0 | ((unsigned)sl1 << 16);                               \
            } else {                                                                      \
                hp = __builtin_amdgcn_perm(u1, u0, 0x07060302u);                          \
                lp = __builtin_amdgcn_perm(u1, u0, 0x05040100u);                          \
            }                                                                             \
            int off = bp * 64 + ((((c2 >> 3)) ^ bslot) << 4) + (c2 & 7) * 2;              \
            *(unsigned*)(cBh + off) = hp;                                                 \
            *(unsigned*)(cBl + off) = lp;                                                 \
        }                                                                                 \
    }

    LOAD_TILE(0)

    for (int k0 = 0; k0 < Ctot; k0 += 32) {
        if (k0) __syncthreads();
        STORE_LDS()
        __syncthreads();
        if (k0 + 32 < Ctot) LOAD_TILE(k0 + 32)

        s16x8 ah[4], al[4];
        #pragma unroll
        for (int m = 0; m < 4; m++) {
            int ao = (wr * 64 + m * 16 + l15) * 64 + ((g ^ slotl) << 4);
            ah[m] = *(const s16x8*)(cAh + ao);
            al[m] = *(const s16x8*)(cAl + ao);
        }
        #pragma unroll
        for (int n = 0; n < 4; n++) {
            int bo = (wc * 64 + n * 16 + l15) * 64 + ((g ^ slotl) << 4);
            s16x8 bh = *(const s16x8*)(cBh + bo);
            s16x8 bl = *(const s16x8*)(cBl + bo);
            #pragma unroll
            for (int m = 0; m < 4; m++) {
                acc[m][n] = __builtin_amdgcn_mfma_f32_16x16x32_bf16(ah[m], bh, acc[m][n], 0, 0, 0);
                acc[m][n] = __builtin_amdgcn_mfma_f32_16x16x32_bf16(ah[m], bl, acc[m][n], 0, 0, 0);
                acc[m][n] = __builtin_amdgcn_mfma_f32_16x16x32_bf16(al[m], bh, acc[m][n], 0, 0, 0);
            }
        }
    }
    #undef LOAD_TILE
    #undef STORE_LDS

    // ---- epilogue: D[row=(l>>4)*4+r][col=l&15] ----
    #pragma unroll
    for (int m = 0; m < 4; m++) {
        #pragma unroll
        for (int r = 0; r < 4; r++) {
            int orow = o0 + wr * 64 + m * 16 + g * 4 + r;
            float bs = (!CLN && bias) ? bias[orow] : 0.f;
            float Ao = CLN ? Aab[orow] : 0.f;
            float Bo = CLN ? Bab[orow] : 0.f;
            #pragma unroll
            for (int n = 0; n < 4; n++) {
                int pcol = p0 + wc * 64 + n * 16 + l15;
                float v;
                if constexpr (CLN) {
                    size_t cidx = (size_t)b * NP + pcol;
                    v = rs[cidx] * acc[m][n][r] - mrs[cidx] * Ao + Bo;
                } else {
                    v = acc[m][n][r] + bs;
                    if (resid) v += resid[((size_t)b * O + orow) * (size_t)NP + pcol];
                }
                out[((size_t)b * sO + orow) * (size_t)NP + pcol] = PACKO ? packf(v) : v;
            }
        }
    }
}

// ---------------- l2norm along W for q and k rows; emit |row|-sums ----------------
__global__ __launch_bounds__(256) void l2norm_kernel(
    float* __restrict__ qkv, float* __restrict__ qrow, float* __restrict__ kheight)
{
    int r = blockIdx.x * 4 + (threadIdx.x >> 6);
    int lane = threadIdx.x & 63;
    int which = r >> 18;
    int rr = r & 262143;
    int bh = rr >> 11;
    int c = (rr >> 6) & 31;
    int h = rr & 63;
    int b = bh >> 3, head = bh & 7;
    int ch = which * 256 + head * 32 + c;
    float* p = qkv + ((size_t)b * 768 + ch) * NP + h * 64 + lane;
    float v = *p;
    float ss = v * v, as = fabsf(v);
    for (int off = 32; off; off >>= 1) { ss += __shfl_xor(ss, off); as += __shfl_xor(as, off); }
    float n = sqrtf(ss);
    float inv = 1.f / fmaxf(n, 1e-12f);
    *p = v * inv;
    if (lane == 0) {
        float s = as * inv;
        if (which == 0) qrow[rr] = s; else kheight[rr] = s;
    }
}

__global__ void qprobe_kernel(const float* __restrict__ qrow, float* __restrict__ qprobe)
{
    int i = blockIdx.x * 64 + threadIdx.x;
    double s = 0.0;
    for (int h = 0; h < 64; h++) s += qrow[(size_t)i * 64 + h];
    qprobe[i] = (float)s;
}

// ---------------- scores + top-k rows/cols + gather k/v ----------------
__global__ __launch_bounds__(64) void select_kernel(
    const float* __restrict__ qkv, const float* __restrict__ qprobe,
    const float* __restrict__ kheight,
    float* __restrict__ ksel, float* __restrict__ vsel)
{
    const int bh = blockIdx.x;
    const int b = bh >> 3, head = bh & 7;
    const int lane = threadIdx.x;
    __shared__ int hs[8], wsl[8];
    __shared__ float qp[32];
    if (lane < 32) qp[lane] = qprobe[bh * 32 + lane];
    __syncthreads();
    double scd = 0.0;
    for (int c = 0; c < 32; c++) scd += (double)qp[c] * kheight[((size_t)bh * 32 + c) * 64 + lane];
    float sc = (float)scd;
    for (int it = 0; it < 8; it++) {
        float v = sc; int id = lane;
        for (int off = 32; off; off >>= 1) {
            float ov = __shfl_xor(v, off); int oi = __shfl_xor(id, off);
            if (ov > v || (ov == v && oi < id)) { v = ov; id = oi; }
        }
        if (lane == 0) hs[it] = id;
        if (lane == id) sc = -3.4e38f;
    }
    __syncthreads();
    const float* kbase = qkv + ((size_t)b * 768 + 256 + head * 32) * NP;
    double sc2d = 0.0;
    for (int c = 0; c < 32; c++) {
        float kw = 0.f;
        for (int hi = 0; hi < 8; hi++)
            kw += fabsf(kbase[(size_t)c * NP + hs[hi] * 64 + lane]);
        sc2d += (double)qp[c] * kw;
    }
    float sc2 = (float)sc2d;
    for (int it = 0; it < 8; it++) {
        float v = sc2; int id = lane;
        for (int off = 32; off; off >>= 1) {
            float ov = __shfl_xor(v, off); int oi = __shfl_xor(id, off);
            if (ov > v || (ov == v && oi < id)) { v = ov; id = oi; }
        }
        if (lane == 0) wsl[it] = id;
        if (lane == id) sc2 = -3.4e38f;
    }
    __syncthreads();
    const float* vbase = qkv + ((size_t)b * 768 + 512 + head * 32) * NP;
    int hi = lane >> 3, wi = lane & 7;
    int hh = hs[hi], ww = wsl[wi];
    for (int d = 0; d < 32; d++) {
        ksel[((size_t)bh * 64 + lane) * 32 + d] = kbase[(size_t)d * NP + hh * 64 + ww];
        vsel[((size_t)bh * 64 + lane) * 32 + d] = vbase[(size_t)d * NP + hh * 64 + ww];
    }
}

// ---------------- attention: in-place over q slot; writes PACKED ctx ----------------
__global__ __launch_bounds__(256) void attn_kernel(
    float* __restrict__ qkv, const float* __restrict__ ksel, const float* __restrict__ vsel)
{
    __shared__ __align__(16) float ks[64][32];
    __shared__ __align__(16) float vs[64][32];
    int bh = blockIdx.y, b = bh >> 3, head = bh & 7;
    int t = threadIdx.x;
    const float* kb = ksel + (size_t)bh * 2048;
    const float* vb = vsel + (size_t)bh * 2048;
    for (int i = 0; i < 8; i++) {
        ((float*)ks)[t + i * 256] = kb[t + i * 256];
        ((float*)vs)[t + i * 256] = vb[t + i * 256];
    }
    __syncthreads();
    int p = blockIdx.x * 256 + t;
    float* qb = qkv + ((size_t)b * 768 + head * 32) * NP + p;
    float q[32];
    #pragma unroll
    for (int d = 0; d < 32; d++) q[d] = qb[(size_t)d * NP];
    float s[64], m = -3.4e38f;
    for (int j = 0; j < 64; j++) {
        float dot = 0.f;
        #pragma unroll
        for (int d = 0; d < 32; d++) dot += q[d] * ks[j][d];
        s[j] = dot; m = fmaxf(m, dot);
    }
    float den = 0.f;
    for (int j = 0; j < 64; j++) { float e = expf(s[j] - m); s[j] = e; den += e; }
    float o[32] = {};
    for (int j = 0; j < 64; j++) {
        float a = s[j];
        #pragma unroll
        for (int d = 0; d < 32; d++) o[d] += a * vs[j][d];
    }
    float r = 1.f / den;
    #pragma unroll
    for (int d = 0; d < 32; d++) qb[(size_t)d * NP] = packf(o[d] * r);
}

// ---------------- depthwise 3x3 on x; PACKED strided output planes ----------------
__global__ __launch_bounds__(256) void dwconv_kernel(
    const float* __restrict__ in, const float* __restrict__ w, const float* __restrict__ bias,
    float* __restrict__ out, int Cn, int sO)
{
    __shared__ __align__(16) float pl[64][64];
    int bcb = blockIdx.x;
    int b = bcb / Cn, c = bcb % Cn;
    const float* src = in + (size_t)bcb * NP;
    float* dst = out + ((size_t)b * sO + c) * NP;
    int t = threadIdx.x;
    for (int i = 0; i < 16; i++) { int pix = t + i * 256; pl[pix >> 6][pix & 63] = src[pix]; }
    float w9[9];
    #pragma unroll
    for (int k = 0; k < 9; k++) w9[k] = w[c * 9 + k];
    float bsv = bias[c];
    __syncthreads();
    for (int i = 0; i < 16; i++) {
        int pix = t + i * 256; int y = pix >> 6, xx = pix & 63;
        float acc = bsv;
        #pragma unroll
        for (int dy = 0; dy < 3; dy++) {
            int yy = y + dy - 1; if (yy < 0 || yy > 63) continue;
            #pragma unroll
            for (int dx = 0; dx < 3; dx++) {
                int x2 = xx + dx - 1; if (x2 < 0 || x2 > 63) continue;
                acc += w9[dy * 3 + dx] * pl[yy][x2];
            }
        }
        dst[pix] = packf(acc);
    }
}

// ---------------- fast gelu: A&S 7.1.26 erf (max abs err ~1.5e-7) ----------------
__device__ inline float gelu_fast(float x) {
    float z = x * 0.70710678118654752f;
    float a = fabsf(z);
    float t = 1.0f / (1.0f + 0.3275911f * a);
    float p = t * (0.254829592f + t * (-0.284496736f + t * (1.421413741f +
              t * (-1.453152027f + t * 1.061405429f))));
    float e = __expf(-a * a);
    float r = 1.0f - p * e;                 // erf(|z|)
    float erfz = copysignf(r, z);
    return 0.5f * x * (1.0f + erfz);
}

__device__ inline void block_reduce2(double& s, double& s2, double* red, int t)
{
    __syncthreads();
    red[t] = s; red[256 + t] = s2;
    __syncthreads();
    for (int st = 128; st; st >>= 1) {
        if (t < st) { red[t] += red[t + st]; red[256 + t] += red[256 + t + st]; }
        __syncthreads();
    }
    s = red[0]; s2 = red[256];
}

// ---------------- fused FF: h = gelu(IN(h)); h += gelu(IN(dwconv3(h))); PACKED out ----
__global__ __launch_bounds__(256) void ff_fused_kernel(
    float* __restrict__ h, const float* __restrict__ w, const float* __restrict__ bias)
{
    __shared__ __align__(16) float pl[64][64];
    __shared__ double red[512];
    int plane = blockIdx.x;
    int c = plane & (NFF - 1);
    size_t base = (size_t)plane * NP;
    int t = threadIdx.x;
    float v[16]; double s = 0.0, s2 = 0.0;
    for (int i = 0; i < 16; i++) { float x = h[base + t + i * 256]; v[i] = x; s += x; s2 += (double)x * x; }
    block_reduce2(s, s2, red, t);
    double mean = s * (1.0 / NP);
    double var = s2 * (1.0 / NP) - mean * mean;
    float rs = (float)(1.0 / sqrt(var + (double)CEPS));
    float mf = (float)mean;
    for (int i = 0; i < 16; i++) {
        float gx = gelu_fast((v[i] - mf) * rs);
        v[i] = gx;
        int pix = t + i * 256;
        pl[pix >> 6][pix & 63] = gx;
    }
    __syncthreads();
    float w9[9];
    #pragma unroll
    for (int k = 0; k < 9; k++) w9[k] = w[c * 9 + k];
    float bsv = bias[c];
    float tv[16]; s = 0.0; s2 = 0.0;
    for (int i = 0; i < 16; i++) {
        int pix = t + i * 256; int y = pix >> 6, xx = pix & 63;
        float acc = bsv;
        #pragma unroll
        for (int dy = 0; dy < 3; dy++) {
            int yy = y + dy - 1; if (yy < 0 || yy > 63) continue;
            #pragma unroll
            for (int dx = 0; dx < 3; dx++) {
                int x2 = xx + dx - 1; if (x2 < 0 || x2 > 63) continue;
                acc += w9[dy * 3 + dx] * pl[yy][x2];
            }
        }
        tv[i] = acc; s += acc; s2 += (double)acc * acc;
    }
    block_reduce2(s, s2, red, t);
    double mean2 = s * (1.0 / NP);
    double var2 = s2 * (1.0 / NP) - mean2 * mean2;
    float rs2 = (float)(1.0 / sqrt(var2 + (double)CEPS));
    float mf2 = (float)mean2;
    for (int i = 0; i < 16; i++) {
        int pix = t + i * 256;
        float o = v[i] + gelu_fast((tv[i] - mf2) * rs2);
        h[base + pix] = packf(o);
    }
}

// ---------------- final instance norm in place on d_out ----------------
__global__ __launch_bounds__(256) void in_final_kernel(float* __restrict__ y)
{
    __shared__ double red[512];
    size_t base = (size_t)blockIdx.x * NP;
    int t = threadIdx.x;
    float v[16]; double s = 0.0, s2 = 0.0;
    for (int i = 0; i < 16; i++) { float x = y[base + t + i * 256]; v[i] = x; s += x; s2 += (double)x * x; }
    block_reduce2(s, s2, red, t);
    double mean = s * (1.0 / NP);
    double var = s2 * (1.0 / NP) - mean * mean;
    float rs = (float)(1.0 / sqrt(var + (double)CEPS));
    float mf = (float)mean;
    for (int i = 0; i < 16; i++)
        y[base + t + i * 256] = (v[i] - mf) * rs;
}

extern "C" void kernel_launch(void* const* d_in, const int* in_sizes, int n_in,
                              void* d_out, int out_size, void* d_ws, size_t ws_size,
                              hipStream_t stream)
{
    const float* x      = (const float*)d_in[0];
    const float* g      = (const float*)d_in[1];
    const float* bc     = (const float*)d_in[2];
    const float* w_qkv  = (const float*)d_in[3];
    const float* w_out  = (const float*)d_in[4];
    const float* b_out  = (const float*)d_in[5];
    const float* w_dw   = (const float*)d_in[6];
    const float* b_dw   = (const float*)d_in[7];
    const float* w_comb = (const float*)d_in[8];
    const float* b_comb = (const float*)d_in[9];
    const float* w_ff1  = (const float*)d_in[10];
    const float* b_ff1  = (const float*)d_in[11];
    const float* w_ffdw = (const float*)d_in[12];
    const float* b_ffdw = (const float*)d_in[13];
    const float* w_ff2  = (const float*)d_in[14];
    const float* b_ff2  = (const float*)d_in[15];
    float* out = (float*)d_out;
    float* ws  = (float*)d_ws;

    const size_t S = (size_t)NB * NC * NP;   // 16,777,216 floats (64 MiB)
    // Memory plan (ws = 4S exactly):
    //   d_out      : pw_qkv (packed W_qkv*g) until step 9; Fbuf (attn_out, 9-10);
    //                final output (12+)
    //   ws[0,S)    : smalls: qrow/qprobe/kheight/kselb/vselb [0,1052672);
    //                cln stats rs/mrs + Aab/Bab at [1052672, ~1.19M) (live through step 2);
    //                pwF+bF (step 7+, overwrites [0,131329)) -> dead
    //   ws[S,4S)   : qkv fp32; ctx packed in q-planes after attn; convb packed in v-planes
    //   ws[0,4S)   : h1 fp32 (10+), packed in place by ff_fused (11)
    float* qkv   = ws + S;
    float* h1    = ws;
    float* Fbuf  = out;
    float* convb = qkv + (size_t)512 * NP;
    float* qrow    = ws;
    float* qprobe  = qrow + 262144;
    float* kheight = qprobe + 4096;
    float* kselb   = kheight + 262144;
    float* vselb   = kselb + 262144;           // ends at 1052672
    float* rs_a    = ws + 1052672;             // 65536
    float* mrs_a   = rs_a + 65536;             // 65536
    float* Aab     = mrs_a + 65536;            // 768
    float* Bab     = Aab + 768;                // 768
    unsigned* pw_qkv = (unsigned*)out;         // 196608 u32 in d_out (free until step 9)
    unsigned* pwF    = (unsigned*)ws;          // 131072 u32 (dead smalls, after attn)
    float*    bF     = ws + 131072;            // 256 floats

    size_t need = 4 * S * sizeof(float);
    if (ws_size < need) {
        float val = 1024.0f + (float)(ws_size >> 20);
        diag_fill<<<(out_size + 255) / 256, 256, 0, stream>>>(out, val, out_size);
        return;
    }

    // 0. prepack W_qkv*diag(g) -> d_out; cln stats; fold constants
    pack_wg_kernel<<<768, 256, 0, stream>>>(w_qkv, g, pw_qkv, 768 * 256);
    cln_stats_kernel<<<1024, 256, 0, stream>>>(x, rs_a, mrs_a);
    ab_kernel<<<3, 256, 0, stream>>>(w_qkv, g, bc, Aab, Bab);
    // 2. qkv = fold( (W_qkv g) * x ) : rs*acc - mrs*A + B   (cln eliminated)
    gemm_mfma<false, true, true><<<dim3(16, 6, NB), 512, 0, stream>>>(
        x, 256, 256, nullptr, 0, 256, (const float*)pw_qkv, nullptr, nullptr, qkv, 768, 768,
        rs_a, mrs_a, Aab, Bab);
    // 3-6. l2norm, qprobe, select, attention (packed ctx -> q-planes)
    l2norm_kernel<<<131072, 256, 0, stream>>>(qkv, qrow, kheight);
    qprobe_kernel<<<64, 64, 0, stream>>>(qrow, qprobe);
    select_kernel<<<NBH, 64, 0, stream>>>(qkv, qprobe, kheight, kselb, vselb);
    attn_kernel<<<dim3(16, NBH), 256, 0, stream>>>(qkv, kselb, vselb);
    // 7. fused comb weight -> packed, into dead smalls
    fuse_comb_kernel<<<512, 256, 0, stream>>>(w_comb, w_out, b_out, b_comb, pwF, bF);
    // 8. conv branch -> v-planes (packed)
    dwconv_kernel<<<NB * NC, 256, 0, stream>>>(x, w_dw, b_dw, convb, NC, 768);
    // 9. attn_out = W_fused * [ctx; convb] + b_fused + x -> d_out (packed)
    gemm_mfma<true, true, false><<<dim3(16, 2, NB), 512, 0, stream>>>(
        qkv, 768, 256, convb, 768, 512, (const float*)pwF, bF, x, Fbuf, 256, 256,
        nullptr, nullptr, nullptr, nullptr);
    // 10. h1 = W_ff1 * attn_out + b_ff1 -> ws[0,4S) fp32
    gemm_mfma<false, false, false><<<dim3(16, 8, NB), 512, 0, stream>>>(
        Fbuf, 256, 256, nullptr, 0, 256, w_ff1, b_ff1, nullptr, h1, 1024, 1024,
        nullptr, nullptr, nullptr, nullptr);
    // 11. fused FF (packed in place)
    ff_fused_kernel<<<NB * NFF, 256, 0, stream>>>(h1, w_ffdw, b_ffdw);
    // 12. y = W_ff2 * h1 + b_ff2 -> d_out fp32
    gemm_mfma<false, false, false><<<dim3(16, 2, NB), 512, 0, stream>>>(
        h1, 1024, 1024, nullptr, 0, 1024, w_ff2, b_ff2, nullptr, out, 256, 256,
        nullptr, nullptr, nullptr, nullptr);
    // 13. final instance norm
    in_final_kernel<<<NB * NC, 256, 0, stream>>>(out);
}

// Round 15
// 999.498 us; speedup vs baseline: 1.2008x; 1.0745x over previous
//
#include <hip/hip_runtime.h>
#include <math.h>

#define NB 16
#define NC 256
#define NP 4096      // 64*64
#define NHEADS 8
#define NDH 32
#define NBH 128
#define NFF 1024
#define CEPS 1e-5f

typedef short s16x8 __attribute__((ext_vector_type(8)));
typedef float f32x4 __attribute__((ext_vector_type(4)));

// ---------------- diagnostic fill (guard trip) ----------------
__global__ __launch_bounds__(256) void diag_fill(float* __restrict__ out, float val, int n)
{
    int i = blockIdx.x * 256 + threadIdx.x;
    if (i < n) out[i] = val;
}

// ---------------- bf16 split helpers ----------------
__device__ inline unsigned short f2bf(float f) {
    unsigned u = __float_as_uint(f);
    return (unsigned short)((u + 0x7FFFu + ((u >> 16) & 1u)) >> 16);
}
__device__ inline float bf2f(unsigned short h) { return __uint_as_float(((unsigned)h) << 16); }
__device__ inline void split2(float f, unsigned short& hi, unsigned short& lo) {
    hi = f2bf(f);
    lo = f2bf(f - bf2f(hi));
}
// fast round-to-nearest split (6 ops); same 2^-17 error class (round-11 validated)
__device__ inline void split_rn(float f, unsigned short& hi, unsigned short& lo) {
    unsigned u = __float_as_uint(f);
    unsigned tt = u + 0x8000u;
    hi = (unsigned short)(tt >> 16);
    float r = f - __uint_as_float(tt & 0xffff0000u);
    lo = (unsigned short)((__float_as_uint(r) + 0x8000u) >> 16);
}
// packed: (hi<<16)|lo
__device__ inline unsigned pack_hl(float f) {
    unsigned short h, lo; split2(f, h, lo);
    return ((unsigned)h << 16) | (unsigned)lo;
}
__device__ inline float packf(float f) { return __uint_as_float(pack_hl(f)); }

// ---------------- weight prepack with channel gain: pw = pack(w[o,c]*g[c]) ----------
__global__ __launch_bounds__(256) void pack_wg_kernel(
    const float* __restrict__ w, const float* __restrict__ g,
    unsigned* __restrict__ pw, int n)
{
    int i = blockIdx.x * 256 + threadIdx.x;
    if (i < n) pw[i] = pack_hl(w[i] * g[i & 255]);
}

// ---------------- cln stats: per (b,p) mean/rsqrt over 256 channels (4-way split) ----
__global__ __launch_bounds__(256) void cln_stats_kernel(
    const float* __restrict__ x, float* __restrict__ rs, float* __restrict__ mrs)
{
    __shared__ double red[512];
    int t = threadIdx.x;
    int i = t & 63, q = t >> 6;
    int col = blockIdx.x * 64 + i;           // 0..65535 (b*4096+p)
    int b = col >> 12, p = col & 4095;
    const float* src = x + (size_t)b * NC * NP + (size_t)(q * 64) * NP + p;
    double s = 0.0, s2 = 0.0;
    #pragma unroll 8
    for (int c = 0; c < 64; c++) { float v = src[(size_t)c * NP]; s += v; s2 += (double)v * v; }
    red[q * 64 + i] = s; red[256 + q * 64 + i] = s2;
    __syncthreads();
    if (q == 0) {
        double S  = red[i] + red[64 + i] + red[128 + i] + red[192 + i];
        double S2 = red[256 + i] + red[320 + i] + red[384 + i] + red[448 + i];
        double mean = S * (1.0 / 256.0);
        double var = S2 * (1.0 / 256.0) - mean * mean;
        double r = 1.0 / sqrt(var + (double)CEPS);
        rs[col]  = (float)r;
        mrs[col] = (float)(mean * r);
    }
}

// ---------------- A/B fold constants: A[o]=sum W[o,c]g[c], B[o]=sum W[o,c]bc[c] ------
__global__ __launch_bounds__(256) void ab_kernel(
    const float* __restrict__ wq, const float* __restrict__ g, const float* __restrict__ bc,
    float* __restrict__ Aab, float* __restrict__ Bab)
{
    int o = blockIdx.x * 256 + threadIdx.x;
    if (o >= 768) return;
    double a = 0.0, bsum = 0.0;
    for (int c = 0; c < 256; c++) {
        double w = wq[o * 256 + c];
        a += w * (double)g[c];
        bsum += w * (double)bc[c];
    }
    Aab[o] = (float)a; Bab[o] = (float)bsum;
}

// ---------------- fused comb weight: W_fused = [W_comb_L @ W_out | W_comb_R] ----------
__global__ __launch_bounds__(256) void fuse_comb_kernel(
    const float* __restrict__ w_comb, const float* __restrict__ w_out,
    const float* __restrict__ b_out, const float* __restrict__ b_comb,
    unsigned* __restrict__ pwF, float* __restrict__ bF)
{
    int idx = blockIdx.x * 256 + threadIdx.x;   // 131072
    int o = idx >> 9, cc = idx & 511;
    float val;
    if (cc < 256) {
        double s = 0.0;
        for (int k = 0; k < 256; k++)
            s += (double)w_comb[o * 512 + k] * (double)w_out[k * 256 + cc];
        val = (float)s;
    } else {
        val = w_comb[o * 512 + cc];
    }
    pwF[idx] = pack_hl(val);
    if (idx < 256) {
        double s = 0.0;
        for (int k = 0; k < 256; k++)
            s += (double)w_comb[idx * 512 + k] * (double)b_out[k];
        bF[idx] = (float)(s + (double)b_comb[idx]);
    }
}

// ---------------- split-bf16 MFMA GEMM: 128o x 256p tile, 8 waves, K-step 32 ----------
// B-input: CLN ? raw fp32 (split in-stage) : PACKED hi/lo uint32.
// A: PACKA ? packed uint32 : raw fp32.
// CLN epilogue: v = rs*acc - mrs*A[o] + B[o]; then fused l2norm along width rows for
// q/k channels (orow<512) + qrow/kheight row-sums.
template<bool PACKO, bool PACKA, bool CLN>
__global__ __launch_bounds__(512) void gemm_mfma(
    const float* __restrict__ inA, int sA, int C1,
    const float* __restrict__ inB, int sB, int Ctot,
    const float* __restrict__ Wt, const float* __restrict__ bias,
    const float* __restrict__ resid, float* __restrict__ out, int sO, int O,
    const float* __restrict__ rs, const float* __restrict__ mrs,
    const float* __restrict__ Aab, const float* __restrict__ Bab,
    float* __restrict__ qrow, float* __restrict__ kheight)
{
    __shared__ __align__(16) unsigned short Ah[128 * 32], Al[128 * 32];
    __shared__ __align__(16) unsigned short Bh[256 * 32], Bl[256 * 32];
    char* cAh = (char*)Ah; char* cAl = (char*)Al;
    char* cBh = (char*)Bh; char* cBl = (char*)Bl;

    // ---- XCD-batch swizzle ----
    const unsigned npb = gridDim.x * gridDim.y;
    unsigned lin = blockIdx.x + gridDim.x * (blockIdx.y + gridDim.y * blockIdx.z);
    unsigned low = lin & 7u, rest = lin >> 3;
    unsigned high = (rest >= npb) ? 1u : 0u;
    unsigned idx = rest - high * npb;
    const int b = (int)(low + 8u * high);
    const int o0 = (int)(idx / gridDim.x) * 128, p0 = (int)(idx % gridDim.x) * 256;

    const int t = threadIdx.x;
    const int l = t & 63, w = t >> 6;
    const int wr = w >> 2, wc = w & 3;
    const int g = l >> 4, l15 = l & 15;
    const int slotl = (l & 3) ^ ((l >> 2) & 3);

    f32x4 acc[4][4];
    #pragma unroll
    for (int m = 0; m < 4; m++)
        #pragma unroll
        for (int n = 0; n < 4; n++) acc[m][n] = (f32x4){0.f, 0.f, 0.f, 0.f};

    const int arow = t >> 2;
    const int ak8 = (t & 3) * 8;
    const int aslot = (arow & 3) ^ ((arow >> 2) & 3);
    const int aoff = arow * 64 + ((((ak8 >> 3)) ^ aslot) << 4);
    const int bp = t & 255;
    const int bhalfk = t >> 8;
    const int bslot = (bp & 3) ^ ((bp >> 2) & 3);

    uint4 wa0, wa1;          // A prefetch (bitwise fp32 or packed)
    unsigned pb[16];         // B prefetch (packed or raw fp32 bits)

    #define LOAD_TILE(K0)                                                                 \
    {                                                                                     \
        const unsigned* wsrc = (const unsigned*)Wt + (size_t)(o0 + arow) * Ctot + (K0) + ak8; \
        wa0 = *(const uint4*)(wsrc);                                                      \
        wa1 = *(const uint4*)(wsrc + 4);                                                  \
        _Pragma("unroll")                                                                 \
        for (int q = 0; q < 8; q++) {                                                     \
            int c2 = bhalfk * 16 + q * 2;                                                 \
            int cc = (K0) + c2;                                                           \
            const float* srcp = (cc < C1) ? inA + ((size_t)b * sA + cc) * (size_t)NP      \
                                          : inB + ((size_t)b * sB + (cc - C1)) * (size_t)NP; \
            pb[2 * q]     = __float_as_uint(srcp[p0 + bp]);                               \
            pb[2 * q + 1] = __float_as_uint(srcp[(size_t)NP + p0 + bp]);                  \
        }                                                                                 \
    }

    #define STORE_LDS()                                                                   \
    {                                                                                     \
        if constexpr (PACKA) {                                                            \
            uint4 hq, lq;                                                                 \
            hq.x = __builtin_amdgcn_perm(wa0.y, wa0.x, 0x07060302u);                      \
            lq.x = __builtin_amdgcn_perm(wa0.y, wa0.x, 0x05040100u);                      \
            hq.y = __builtin_amdgcn_perm(wa0.w, wa0.z, 0x07060302u);                      \
            lq.y = __builtin_amdgcn_perm(wa0.w, wa0.z, 0x05040100u);                      \
            hq.z = __builtin_amdgcn_perm(wa1.y, wa1.x, 0x07060302u);                      \
            lq.z = __builtin_amdgcn_perm(wa1.y, wa1.x, 0x05040100u);                      \
            hq.w = __builtin_amdgcn_perm(wa1.w, wa1.z, 0x07060302u);                      \
            lq.w = __builtin_amdgcn_perm(wa1.w, wa1.z, 0x05040100u);                      \
            *(uint4*)(cAh + aoff) = hq;                                                   \
            *(uint4*)(cAl + aoff) = lq;                                                   \
        } else {                                                                          \
            ushort4 h0, l0, h1, l1;                                                       \
            split_rn(__uint_as_float(wa0.x), h0.x, l0.x);                                 \
            split_rn(__uint_as_float(wa0.y), h0.y, l0.y);                                 \
            split_rn(__uint_as_float(wa0.z), h0.z, l0.z);                                 \
            split_rn(__uint_as_float(wa0.w), h0.w, l0.w);                                 \
            split_rn(__uint_as_float(wa1.x), h1.x, l1.x);                                 \
            split_rn(__uint_as_float(wa1.y), h1.y, l1.y);                                 \
            split_rn(__uint_as_float(wa1.z), h1.z, l1.z);                                 \
            split_rn(__uint_as_float(wa1.w), h1.w, l1.w);                                 \
            *(ushort4*)(cAh + aoff) = h0; *(ushort4*)(cAh + aoff + 8) = h1;               \
            *(ushort4*)(cAl + aoff) = l0; *(ushort4*)(cAl + aoff + 8) = l1;               \
        }                                                                                 \
        _Pragma("unroll")                                                                 \
        for (int q = 0; q < 8; q++) {                                                     \
            int c2 = bhalfk * 16 + q * 2;                                                 \
            unsigned u0 = pb[2 * q], u1 = pb[2 * q + 1];                                  \
            unsigned hp, lp;                                                              \
            if constexpr (CLN) {                                                          \
                unsigned short sh0, sl0, sh1, sl1;                                        \
                split_rn(__uint_as_float(u0), sh0, sl0);                                  \
                split_rn(__uint_as_float(u1), sh1, sl1);                                  \
                hp = (unsigned)sh0 | ((unsigned)sh1 << 16);                               \
                lp = (unsigned)sl0 | ((unsigned)sl1 << 16);                               \
            } else {                                                                      \
                hp = __builtin_amdgcn_perm(u1, u0, 0x07060302u);                          \
                lp = __builtin_amdgcn_perm(u1, u0, 0x05040100u);                          \
            }                                                                             \
            int off = bp * 64 + ((((c2 >> 3)) ^ bslot) << 4) + (c2 & 7) * 2;              \
            *(unsigned*)(cBh + off) = hp;                                                 \
            *(unsigned*)(cBl + off) = lp;                                                 \
        }                                                                                 \
    }

    LOAD_TILE(0)

    for (int k0 = 0; k0 < Ctot; k0 += 32) {
        if (k0) __syncthreads();
        STORE_LDS()
        __syncthreads();
        if (k0 + 32 < Ctot) LOAD_TILE(k0 + 32)

        s16x8 ah[4], al[4];
        #pragma unroll
        for (int m = 0; m < 4; m++) {
            int ao = (wr * 64 + m * 16 + l15) * 64 + ((g ^ slotl) << 4);
            ah[m] = *(const s16x8*)(cAh + ao);
            al[m] = *(const s16x8*)(cAl + ao);
        }
        #pragma unroll
        for (int n = 0; n < 4; n++) {
            int bo = (wc * 64 + n * 16 + l15) * 64 + ((g ^ slotl) << 4);
            s16x8 bh = *(const s16x8*)(cBh + bo);
            s16x8 bl = *(const s16x8*)(cBl + bo);
            #pragma unroll
            for (int m = 0; m < 4; m++) {
                acc[m][n] = __builtin_amdgcn_mfma_f32_16x16x32_bf16(ah[m], bh, acc[m][n], 0, 0, 0);
                acc[m][n] = __builtin_amdgcn_mfma_f32_16x16x32_bf16(ah[m], bl, acc[m][n], 0, 0, 0);
                acc[m][n] = __builtin_amdgcn_mfma_f32_16x16x32_bf16(al[m], bh, acc[m][n], 0, 0, 0);
            }
        }
    }
    #undef LOAD_TILE
    #undef STORE_LDS

    // ---- epilogue: D[row=(l>>4)*4+r][col=l&15] ----
    #pragma unroll
    for (int m = 0; m < 4; m++) {
        #pragma unroll
        for (int r = 0; r < 4; r++) {
            int orow = o0 + wr * 64 + m * 16 + g * 4 + r;
            float bs = (!CLN && bias) ? bias[orow] : 0.f;
            float Ao = CLN ? Aab[orow] : 0.f;
            float Bo = CLN ? Bab[orow] : 0.f;
            if constexpr (CLN) {
                // values for this output row: w = n*16 + l15 (full width row per wave)
                float vv[4];
                #pragma unroll
                for (int n = 0; n < 4; n++) {
                    int pcol = p0 + wc * 64 + n * 16 + l15;
                    size_t cidx = (size_t)b * NP + pcol;
                    vv[n] = rs[cidx] * acc[m][n][r] - mrs[cidx] * Ao + Bo;
                }
                int which = orow >> 8;           // 0=q, 1=k, 2=v
                if (which < 2) {
                    // fused l2norm over the 64-wide row (16 lanes x 4 values)
                    float ss = vv[0] * vv[0] + vv[1] * vv[1] + vv[2] * vv[2] + vv[3] * vv[3];
                    ss += __shfl_xor(ss, 1); ss += __shfl_xor(ss, 2);
                    ss += __shfl_xor(ss, 4); ss += __shfl_xor(ss, 8);
                    float inv = 1.f / fmaxf(sqrtf(ss), 1e-12f);
                    float as = 0.f;
                    #pragma unroll
                    for (int n = 0; n < 4; n++) { vv[n] *= inv; as += fabsf(vv[n]); }
                    as += __shfl_xor(as, 1); as += __shfl_xor(as, 2);
                    as += __shfl_xor(as, 4); as += __shfl_xor(as, 8);
                    if (l15 == 0) {
                        int idx2 = orow & 255;
                        int head = idx2 >> 5, c = idx2 & 31;
                        int h = (p0 >> 6) + wc;
                        int rr = ((b << 3) + head) * 2048 + c * 64 + h;
                        (which == 0 ? qrow : kheight)[rr] = as;
                    }
                }
                #pragma unroll
                for (int n = 0; n < 4; n++) {
                    int pcol = p0 + wc * 64 + n * 16 + l15;
                    out[((size_t)b * sO + orow) * (size_t)NP + pcol] = vv[n];
                }
            } else {
                #pragma unroll
                for (int n = 0; n < 4; n++) {
                    int pcol = p0 + wc * 64 + n * 16 + l15;
                    float v = acc[m][n][r] + bs;
                    if (resid) v += resid[((size_t)b * O + orow) * (size_t)NP + pcol];
                    out[((size_t)b * sO + orow) * (size_t)NP + pcol] = PACKO ? packf(v) : v;
                }
            }
        }
    }
}

// ---------------- scores + top-k rows/cols + gather k/v (qprobe folded in) ----------
__global__ __launch_bounds__(64) void select_kernel(
    const float* __restrict__ qkv, const float* __restrict__ qrow,
    const float* __restrict__ kheight,
    float* __restrict__ ksel, float* __restrict__ vsel)
{
    const int bh = blockIdx.x;
    const int b = bh >> 3, head = bh & 7;
    const int lane = threadIdx.x;
    __shared__ int hs[8], wsl[8];
    __shared__ float qp[32];
    if (lane < 32) {
        double s = 0.0;
        const float* qr = qrow + (size_t)bh * 2048 + lane * 64;
        for (int h = 0; h < 64; h++) s += qr[h];
        qp[lane] = (float)s;
    }
    __syncthreads();
    double scd = 0.0;
    for (int c = 0; c < 32; c++) scd += (double)qp[c] * kheight[((size_t)bh * 32 + c) * 64 + lane];
    float sc = (float)scd;
    for (int it = 0; it < 8; it++) {
        float v = sc; int id = lane;
        for (int off = 32; off; off >>= 1) {
            float ov = __shfl_xor(v, off); int oi = __shfl_xor(id, off);
            if (ov > v || (ov == v && oi < id)) { v = ov; id = oi; }
        }
        if (lane == 0) hs[it] = id;
        if (lane == id) sc = -3.4e38f;
    }
    __syncthreads();
    const float* kbase = qkv + ((size_t)b * 768 + 256 + head * 32) * NP;
    double sc2d = 0.0;
    for (int c = 0; c < 32; c++) {
        float kw = 0.f;
        for (int hi = 0; hi < 8; hi++)
            kw += fabsf(kbase[(size_t)c * NP + hs[hi] * 64 + lane]);
        sc2d += (double)qp[c] * kw;
    }
    float sc2 = (float)sc2d;
    for (int it = 0; it < 8; it++) {
        float v = sc2; int id = lane;
        for (int off = 32; off; off >>= 1) {
            float ov = __shfl_xor(v, off); int oi = __shfl_xor(id, off);
            if (ov > v || (ov == v && oi < id)) { v = ov; id = oi; }
        }
        if (lane == 0) wsl[it] = id;
        if (lane == id) sc2 = -3.4e38f;
    }
    __syncthreads();
    const float* vbase = qkv + ((size_t)b * 768 + 512 + head * 32) * NP;
    int hi = lane >> 3, wi = lane & 7;
    int hh = hs[hi], ww = wsl[wi];
    for (int d = 0; d < 32; d++) {
        ksel[((size_t)bh * 64 + lane) * 32 + d] = kbase[(size_t)d * NP + hh * 64 + ww];
        vsel[((size_t)bh * 64 + lane) * 32 + d] = vbase[(size_t)d * NP + hh * 64 + ww];
    }
}

// ---------------- attention: in-place over q slot; writes PACKED ctx ----------------
__global__ __launch_bounds__(256) void attn_kernel(
    float* __restrict__ qkv, const float* __restrict__ ksel, const float* __restrict__ vsel)
{
    __shared__ __align__(16) float ks[64][32];
    __shared__ __align__(16) float vs[64][32];
    int bh = blockIdx.y, b = bh >> 3, head = bh & 7;
    int t = threadIdx.x;
    const float* kb = ksel + (size_t)bh * 2048;
    const float* vb = vsel + (size_t)bh * 2048;
    for (int i = 0; i < 8; i++) {
        ((float*)ks)[t + i * 256] = kb[t + i * 256];
        ((float*)vs)[t + i * 256] = vb[t + i * 256];
    }
    __syncthreads();
    int p = blockIdx.x * 256 + t;
    float* qb = qkv + ((size_t)b * 768 + head * 32) * NP + p;
    float q[32];
    #pragma unroll
    for (int d = 0; d < 32; d++) q[d] = qb[(size_t)d * NP];
    float s[64], m = -3.4e38f;
    for (int j = 0; j < 64; j++) {
        float dot = 0.f;
        #pragma unroll
        for (int d = 0; d < 32; d++) dot += q[d] * ks[j][d];
        s[j] = dot; m = fmaxf(m, dot);
    }
    float den = 0.f;
    for (int j = 0; j < 64; j++) { float e = expf(s[j] - m); s[j] = e; den += e; }
    float o[32] = {};
    for (int j = 0; j < 64; j++) {
        float a = s[j];
        #pragma unroll
        for (int d = 0; d < 32; d++) o[d] += a * vs[j][d];
    }
    float r = 1.f / den;
    #pragma unroll
    for (int d = 0; d < 32; d++) qb[(size_t)d * NP] = packf(o[d] * r);
}

// ---------------- depthwise 3x3 on x; PACKED strided output planes ----------------
__global__ __launch_bounds__(256) void dwconv_kernel(
    const float* __restrict__ in, const float* __restrict__ w, const float* __restrict__ bias,
    float* __restrict__ out, int Cn, int sO)
{
    __shared__ __align__(16) float pl[64][64];
    int bcb = blockIdx.x;
    int b = bcb / Cn, c = bcb % Cn;
    const float* src = in + (size_t)bcb * NP;
    float* dst = out + ((size_t)b * sO + c) * NP;
    int t = threadIdx.x;
    for (int i = 0; i < 16; i++) { int pix = t + i * 256; pl[pix >> 6][pix & 63] = src[pix]; }
    float w9[9];
    #pragma unroll
    for (int k = 0; k < 9; k++) w9[k] = w[c * 9 + k];
    float bsv = bias[c];
    __syncthreads();
    for (int i = 0; i < 16; i++) {
        int pix = t + i * 256; int y = pix >> 6, xx = pix & 63;
        float acc = bsv;
        #pragma unroll
        for (int dy = 0; dy < 3; dy++) {
            int yy = y + dy - 1; if (yy < 0 || yy > 63) continue;
            #pragma unroll
            for (int dx = 0; dx < 3; dx++) {
                int x2 = xx + dx - 1; if (x2 < 0 || x2 > 63) continue;
                acc += w9[dy * 3 + dx] * pl[yy][x2];
            }
        }
        dst[pix] = packf(acc);
    }
}

// ---------------- fast gelu: A&S 7.1.26 erf (max abs err ~1.5e-7) ----------------
__device__ inline float gelu_fast(float x) {
    float z = x * 0.70710678118654752f;
    float a = fabsf(z);
    float t = 1.0f / (1.0f + 0.3275911f * a);
    float p = t * (0.254829592f + t * (-0.284496736f + t * (1.421413741f +
              t * (-1.453152027f + t * 1.061405429f))));
    float e = __expf(-a * a);
    float r = 1.0f - p * e;                 // erf(|z|)
    float erfz = copysignf(r, z);
    return 0.5f * x * (1.0f + erfz);
}

__device__ inline void block_reduce2(double& s, double& s2, double* red, int t)
{
    __syncthreads();
    red[t] = s; red[256 + t] = s2;
    __syncthreads();
    for (int st = 128; st; st >>= 1) {
        if (t < st) { red[t] += red[t + st]; red[256 + t] += red[256 + t + st]; }
        __syncthreads();
    }
    s = red[0]; s2 = red[256];
}

// ---------------- fused FF: h = gelu(IN(h)); h += gelu(IN(dwconv3(h))); PACKED out ----
__global__ __launch_bounds__(256) void ff_fused_kernel(
    float* __restrict__ h, const float* __restrict__ w, const float* __restrict__ bias)
{
    __shared__ __align__(16) float pl[64][64];
    __shared__ double red[512];
    int plane = blockIdx.x;
    int c = plane & (NFF - 1);
    size_t base = (size_t)plane * NP;
    int t = threadIdx.x;
    float v[16]; double s = 0.0, s2 = 0.0;
    for (int i = 0; i < 16; i++) { float x = h[base + t + i * 256]; v[i] = x; s += x; s2 += (double)x * x; }
    block_reduce2(s, s2, red, t);
    double mean = s * (1.0 / NP);
    double var = s2 * (1.0 / NP) - mean * mean;
    float rs = (float)(1.0 / sqrt(var + (double)CEPS));
    float mf = (float)mean;
    for (int i = 0; i < 16; i++) {
        float gx = gelu_fast((v[i] - mf) * rs);
        v[i] = gx;
        int pix = t + i * 256;
        pl[pix >> 6][pix & 63] = gx;
    }
    __syncthreads();
    float w9[9];
    #pragma unroll
    for (int k = 0; k < 9; k++) w9[k] = w[c * 9 + k];
    float bsv = bias[c];
    float tv[16]; s = 0.0; s2 = 0.0;
    for (int i = 0; i < 16; i++) {
        int pix = t + i * 256; int y = pix >> 6, xx = pix & 63;
        float acc = bsv;
        #pragma unroll
        for (int dy = 0; dy < 3; dy++) {
            int yy = y + dy - 1; if (yy < 0 || yy > 63) continue;
            #pragma unroll
            for (int dx = 0; dx < 3; dx++) {
                int x2 = xx + dx - 1; if (x2 < 0 || x2 > 63) continue;
                acc += w9[dy * 3 + dx] * pl[yy][x2];
            }
        }
        tv[i] = acc; s += acc; s2 += (double)acc * acc;
    }
    block_reduce2(s, s2, red, t);
    double mean2 = s * (1.0 / NP);
    double var2 = s2 * (1.0 / NP) - mean2 * mean2;
    float rs2 = (float)(1.0 / sqrt(var2 + (double)CEPS));
    float mf2 = (float)mean2;
    for (int i = 0; i < 16; i++) {
        int pix = t + i * 256;
        float o = v[i] + gelu_fast((tv[i] - mf2) * rs2);
        h[base + pix] = packf(o);
    }
}

// ---------------- final instance norm in place on d_out ----------------
__global__ __launch_bounds__(256) void in_final_kernel(float* __restrict__ y)
{
    __shared__ double red[512];
    size_t base = (size_t)blockIdx.x * NP;
    int t = threadIdx.x;
    float v[16]; double s = 0.0, s2 = 0.0;
    for (int i = 0; i < 16; i++) { float x = y[base + t + i * 256]; v[i] = x; s += x; s2 += (double)x * x; }
    block_reduce2(s, s2, red, t);
    double mean = s * (1.0 / NP);
    double var = s2 * (1.0 / NP) - mean * mean;
    float rs = (float)(1.0 / sqrt(var + (double)CEPS));
    float mf = (float)mean;
    for (int i = 0; i < 16; i++)
        y[base + t + i * 256] = (v[i] - mf) * rs;
}

extern "C" void kernel_launch(void* const* d_in, const int* in_sizes, int n_in,
                              void* d_out, int out_size, void* d_ws, size_t ws_size,
                              hipStream_t stream)
{
    const float* x      = (const float*)d_in[0];
    const float* g      = (const float*)d_in[1];
    const float* bc     = (const float*)d_in[2];
    const float* w_qkv  = (const float*)d_in[3];
    const float* w_out  = (const float*)d_in[4];
    const float* b_out  = (const float*)d_in[5];
    const float* w_dw   = (const float*)d_in[6];
    const float* b_dw   = (const float*)d_in[7];
    const float* w_comb = (const float*)d_in[8];
    const float* b_comb = (const float*)d_in[9];
    const float* w_ff1  = (const float*)d_in[10];
    const float* b_ff1  = (const float*)d_in[11];
    const float* w_ffdw = (const float*)d_in[12];
    const float* b_ffdw = (const float*)d_in[13];
    const float* w_ff2  = (const float*)d_in[14];
    const float* b_ff2  = (const float*)d_in[15];
    float* out = (float*)d_out;
    float* ws  = (float*)d_ws;

    const size_t S = (size_t)NB * NC * NP;   // 16,777,216 floats (64 MiB)
    // Memory plan (ws = 4S exactly):
    //   d_out      : pw_qkv (packed W_qkv*g) until step 9; Fbuf (attn_out, 9-10);
    //                final output (12+)
    //   ws[0,S)    : smalls: qrow/kheight/kselb/vselb [0,1048576);
    //                cln stats rs/mrs + Aab/Bab at [1052672, ~1.19M) (live through step 2);
    //                pwF+bF (step 7+, overwrites [0,131329)) -> dead
    //   ws[S,4S)   : qkv fp32; ctx packed in q-planes after attn; convb packed in v-planes
    //   ws[0,4S)   : h1 fp32 (10+), packed in place by ff_fused (11)
    float* qkv   = ws + S;
    float* h1    = ws;
    float* Fbuf  = out;
    float* convb = qkv + (size_t)512 * NP;
    float* qrow    = ws;                       // 262144
    float* kheight = qrow + 262144;            // 262144
    float* kselb   = kheight + 262144;         // 262144
    float* vselb   = kselb + 262144;           // ends at 1048576
    float* rs_a    = ws + 1052672;             // 65536
    float* mrs_a   = rs_a + 65536;             // 65536
    float* Aab     = mrs_a + 65536;            // 768
    float* Bab     = Aab + 768;                // 768
    unsigned* pw_qkv = (unsigned*)out;         // 196608 u32 in d_out (free until step 9)
    unsigned* pwF    = (unsigned*)ws;          // 131072 u32 (dead smalls, after attn)
    float*    bF     = ws + 131072;            // 256 floats

    size_t need = 4 * S * sizeof(float);
    if (ws_size < need) {
        float val = 1024.0f + (float)(ws_size >> 20);
        diag_fill<<<(out_size + 255) / 256, 256, 0, stream>>>(out, val, out_size);
        return;
    }

    // 0. prepack W_qkv*diag(g) -> d_out; cln stats; fold constants
    pack_wg_kernel<<<768, 256, 0, stream>>>(w_qkv, g, pw_qkv, 768 * 256);
    cln_stats_kernel<<<1024, 256, 0, stream>>>(x, rs_a, mrs_a);
    ab_kernel<<<3, 256, 0, stream>>>(w_qkv, g, bc, Aab, Bab);
    // 2. qkv = fold( (W_qkv g) * x ) with fused l2norm + qrow/kheight (cln + l2norm eliminated)
    gemm_mfma<false, true, true><<<dim3(16, 6, NB), 512, 0, stream>>>(
        x, 256, 256, nullptr, 0, 256, (const float*)pw_qkv, nullptr, nullptr, qkv, 768, 768,
        rs_a, mrs_a, Aab, Bab, qrow, kheight);
    // 5-6. select (qprobe folded), attention (packed ctx -> q-planes)
    select_kernel<<<NBH, 64, 0, stream>>>(qkv, qrow, kheight, kselb, vselb);
    attn_kernel<<<dim3(16, NBH), 256, 0, stream>>>(qkv, kselb, vselb);
    // 7. fused comb weight -> packed, into dead smalls
    fuse_comb_kernel<<<512, 256, 0, stream>>>(w_comb, w_out, b_out, b_comb, pwF, bF);
    // 8. conv branch -> v-planes (packed)
    dwconv_kernel<<<NB * NC, 256, 0, stream>>>(x, w_dw, b_dw, convb, NC, 768);
    // 9. attn_out = W_fused * [ctx; convb] + b_fused + x -> d_out (packed)
    gemm_mfma<true, true, false><<<dim3(16, 2, NB), 512, 0, stream>>>(
        qkv, 768, 256, convb, 768, 512, (const float*)pwF, bF, x, Fbuf, 256, 256,
        nullptr, nullptr, nullptr, nullptr, nullptr, nullptr);
    // 10. h1 = W_ff1 * attn_out + b_ff1 -> ws[0,4S) fp32
    gemm_mfma<false, false, false><<<dim3(16, 8, NB), 512, 0, stream>>>(
        Fbuf, 256, 256, nullptr, 0, 256, w_ff1, b_ff1, nullptr, h1, 1024, 1024,
        nullptr, nullptr, nullptr, nullptr, nullptr, nullptr);
    // 11. fused FF (packed in place)
    ff_fused_kernel<<<NB * NFF, 256, 0, stream>>>(h1, w_ffdw, b_ffdw);
    // 12. y = W_ff2 * h1 + b_ff2 -> d_out fp32
    gemm_mfma<false, false, false><<<dim3(16, 2, NB), 512, 0, stream>>>(
        h1, 1024, 1024, nullptr, 0, 1024, w_ff2, b_ff2, nullptr, out, 256, 256,
        nullptr, nullptr, nullptr, nullptr, nullptr, nullptr);
    // 13. final instance norm
    in_final_kernel<<<NB * NC, 256, 0, stream>>>(out);
}

// Round 16
// 970.804 us; speedup vs baseline: 1.2363x; 1.0296x over previous
//
#include <hip/hip_runtime.h>
#include <math.h>

#define NB 16
#define NC 256
#define NP 4096      // 64*64
#define NHEADS 8
#define NDH 32
#define NBH 128
#define NFF 1024
#define CEPS 1e-5f

typedef short s16x8 __attribute__((ext_vector_type(8)));
typedef float f32x4 __attribute__((ext_vector_type(4)));

// ---------------- diagnostic fill (guard trip) ----------------
__global__ __launch_bounds__(256) void diag_fill(float* __restrict__ out, float val, int n)
{
    int i = blockIdx.x * 256 + threadIdx.x;
    if (i < n) out[i] = val;
}

// ---------------- bf16 split helpers ----------------
__device__ inline unsigned short f2bf(float f) {
    unsigned u = __float_as_uint(f);
    return (unsigned short)((u + 0x7FFFu + ((u >> 16) & 1u)) >> 16);
}
__device__ inline float bf2f(unsigned short h) { return __uint_as_float(((unsigned)h) << 16); }
__device__ inline void split2(float f, unsigned short& hi, unsigned short& lo) {
    hi = f2bf(f);
    lo = f2bf(f - bf2f(hi));
}
// fast round-to-nearest split (6 ops); same 2^-17 error class (round-11 validated)
__device__ inline void split_rn(float f, unsigned short& hi, unsigned short& lo) {
    unsigned u = __float_as_uint(f);
    unsigned tt = u + 0x8000u;
    hi = (unsigned short)(tt >> 16);
    float r = f - __uint_as_float(tt & 0xffff0000u);
    lo = (unsigned short)((__float_as_uint(r) + 0x8000u) >> 16);
}
// packed: (hi<<16)|lo
__device__ inline unsigned pack_hl(float f) {
    unsigned short h, lo; split2(f, h, lo);
    return ((unsigned)h << 16) | (unsigned)lo;
}
__device__ inline float packf(float f) { return __uint_as_float(pack_hl(f)); }

// ---------------- weight prepack with channel gain: pw = pack(w[o,c]*g[c]) ----------
__global__ __launch_bounds__(256) void pack_wg_kernel(
    const float* __restrict__ w, const float* __restrict__ g,
    unsigned* __restrict__ pw, int n)
{
    int i = blockIdx.x * 256 + threadIdx.x;
    if (i < n) pw[i] = pack_hl(w[i] * g[i & 255]);
}

// ---------------- cln stats: per (b,p) mean/rsqrt over 256 channels (4-way split) ----
__global__ __launch_bounds__(256) void cln_stats_kernel(
    const float* __restrict__ x, float* __restrict__ rs, float* __restrict__ mrs)
{
    __shared__ double red[512];
    int t = threadIdx.x;
    int i = t & 63, q = t >> 6;
    int col = blockIdx.x * 64 + i;           // 0..65535 (b*4096+p)
    int b = col >> 12, p = col & 4095;
    const float* src = x + (size_t)b * NC * NP + (size_t)(q * 64) * NP + p;
    double s = 0.0, s2 = 0.0;
    #pragma unroll 8
    for (int c = 0; c < 64; c++) { float v = src[(size_t)c * NP]; s += v; s2 += (double)v * v; }
    red[q * 64 + i] = s; red[256 + q * 64 + i] = s2;
    __syncthreads();
    if (q == 0) {
        double S  = red[i] + red[64 + i] + red[128 + i] + red[192 + i];
        double S2 = red[256 + i] + red[320 + i] + red[384 + i] + red[448 + i];
        double mean = S * (1.0 / 256.0);
        double var = S2 * (1.0 / 256.0) - mean * mean;
        double r = 1.0 / sqrt(var + (double)CEPS);
        rs[col]  = (float)r;
        mrs[col] = (float)(mean * r);
    }
}

// ---------------- A/B fold constants: A[o]=sum W[o,c]g[c], B[o]=sum W[o,c]bc[c] ------
__global__ __launch_bounds__(256) void ab_kernel(
    const float* __restrict__ wq, const float* __restrict__ g, const float* __restrict__ bc,
    float* __restrict__ Aab, float* __restrict__ Bab)
{
    int o = blockIdx.x * 256 + threadIdx.x;
    if (o >= 768) return;
    double a = 0.0, bsum = 0.0;
    for (int c = 0; c < 256; c++) {
        double w = wq[o * 256 + c];
        a += w * (double)g[c];
        bsum += w * (double)bc[c];
    }
    Aab[o] = (float)a; Bab[o] = (float)bsum;
}

// ---------------- fused comb weight: W_fused = [W_comb_L @ W_out | W_comb_R] ----------
__global__ __launch_bounds__(256) void fuse_comb_kernel(
    const float* __restrict__ w_comb, const float* __restrict__ w_out,
    const float* __restrict__ b_out, const float* __restrict__ b_comb,
    unsigned* __restrict__ pwF, float* __restrict__ bF)
{
    int idx = blockIdx.x * 256 + threadIdx.x;   // 131072
    int o = idx >> 9, cc = idx & 511;
    float val;
    if (cc < 256) {
        double s = 0.0;
        for (int k = 0; k < 256; k++)
            s += (double)w_comb[o * 512 + k] * (double)w_out[k * 256 + cc];
        val = (float)s;
    } else {
        val = w_comb[o * 512 + cc];
    }
    pwF[idx] = pack_hl(val);
    if (idx < 256) {
        double s = 0.0;
        for (int k = 0; k < 256; k++)
            s += (double)w_comb[idx * 512 + k] * (double)b_out[k];
        bF[idx] = (float)(s + (double)b_comb[idx]);
    }
}

// ---------------- split-bf16 MFMA GEMM: 128o x 256p tile, 8 waves, K-step 32 ----------
// B-input: CLN ? raw fp32 (split in-stage) : BBF16 ? bf16 planes : PACKED hi/lo u32.
// A: PACKA ? packed u32 : raw fp32. OBF16: write bf16 output.
// CLN epilogue: v = rs*acc - mrs*A[o] + B[o], plus fused l2norm + qrow/kheight.
template<bool PACKO, bool PACKA, bool CLN, bool OBF16, bool BBF16>
__global__ __launch_bounds__(512) void gemm_mfma(
    const float* __restrict__ inA, int sA, int C1,
    const float* __restrict__ inB, int sB, int Ctot,
    const float* __restrict__ Wt, const float* __restrict__ bias,
    const float* __restrict__ resid, float* __restrict__ out, int sO, int O,
    const float* __restrict__ rs, const float* __restrict__ mrs,
    const float* __restrict__ Aab, const float* __restrict__ Bab,
    float* __restrict__ qrow, float* __restrict__ kheight)
{
    __shared__ __align__(16) unsigned short Ah[128 * 32], Al[128 * 32];
    __shared__ __align__(16) unsigned short Bh[256 * 32];
    __shared__ __align__(16) unsigned short Bl[BBF16 ? 16 : 256 * 32];
    char* cAh = (char*)Ah; char* cAl = (char*)Al;
    char* cBh = (char*)Bh; char* cBl = (char*)Bl;

    // ---- XCD-batch swizzle ----
    const unsigned npb = gridDim.x * gridDim.y;
    unsigned lin = blockIdx.x + gridDim.x * (blockIdx.y + gridDim.y * blockIdx.z);
    unsigned low = lin & 7u, rest = lin >> 3;
    unsigned high = (rest >= npb) ? 1u : 0u;
    unsigned idx = rest - high * npb;
    const int b = (int)(low + 8u * high);
    const int o0 = (int)(idx / gridDim.x) * 128, p0 = (int)(idx % gridDim.x) * 256;

    const int t = threadIdx.x;
    const int l = t & 63, w = t >> 6;
    const int wr = w >> 2, wc = w & 3;
    const int g = l >> 4, l15 = l & 15;
    const int slotl = (l & 3) ^ ((l >> 2) & 3);

    f32x4 acc[4][4];
    #pragma unroll
    for (int m = 0; m < 4; m++)
        #pragma unroll
        for (int n = 0; n < 4; n++) acc[m][n] = (f32x4){0.f, 0.f, 0.f, 0.f};

    const int arow = t >> 2;
    const int ak8 = (t & 3) * 8;
    const int aslot = (arow & 3) ^ ((arow >> 2) & 3);
    const int aoff = arow * 64 + ((((ak8 >> 3)) ^ aslot) << 4);
    const int bp = t & 255;
    const int bhalfk = t >> 8;
    const int bslot = (bp & 3) ^ ((bp >> 2) & 3);

    uint4 wa0, wa1;          // A prefetch (bitwise fp32 or packed)
    unsigned pb[16];         // B prefetch

    #define LOAD_TILE(K0)                                                                 \
    {                                                                                     \
        const unsigned* wsrc = (const unsigned*)Wt + (size_t)(o0 + arow) * Ctot + (K0) + ak8; \
        wa0 = *(const uint4*)(wsrc);                                                      \
        wa1 = *(const uint4*)(wsrc + 4);                                                  \
        _Pragma("unroll")                                                                 \
        for (int q = 0; q < 8; q++) {                                                     \
            int c2 = bhalfk * 16 + q * 2;                                                 \
            int cc = (K0) + c2;                                                           \
            if constexpr (BBF16) {                                                        \
                const unsigned short* s16 = (const unsigned short*)inA                    \
                    + ((size_t)b * sA + cc) * (size_t)NP + p0 + bp;                       \
                unsigned short v0 = s16[0];                                               \
                unsigned short v1 = s16[NP];                                              \
                pb[q] = (unsigned)v0 | ((unsigned)v1 << 16);                              \
            } else {                                                                      \
                const float* srcp = (cc < C1) ? inA + ((size_t)b * sA + cc) * (size_t)NP  \
                                              : inB + ((size_t)b * sB + (cc - C1)) * (size_t)NP; \
                pb[2 * q]     = __float_as_uint(srcp[p0 + bp]);                           \
                pb[2 * q + 1] = __float_as_uint(srcp[(size_t)NP + p0 + bp]);              \
            }                                                                             \
        }                                                                                 \
    }

    #define STORE_LDS()                                                                   \
    {                                                                                     \
        if constexpr (PACKA) {                                                            \
            uint4 hq, lq;                                                                 \
            hq.x = __builtin_amdgcn_perm(wa0.y, wa0.x, 0x07060302u);                      \
            lq.x = __builtin_amdgcn_perm(wa0.y, wa0.x, 0x05040100u);                      \
            hq.y = __builtin_amdgcn_perm(wa0.w, wa0.z, 0x07060302u);                      \
            lq.y = __builtin_amdgcn_perm(wa0.w, wa0.z, 0x05040100u);                      \
            hq.z = __builtin_amdgcn_perm(wa1.y, wa1.x, 0x07060302u);                      \
            lq.z = __builtin_amdgcn_perm(wa1.y, wa1.x, 0x05040100u);                      \
            hq.w = __builtin_amdgcn_perm(wa1.w, wa1.z, 0x07060302u);                      \
            lq.w = __builtin_amdgcn_perm(wa1.w, wa1.z, 0x05040100u);                      \
            *(uint4*)(cAh + aoff) = hq;                                                   \
            *(uint4*)(cAl + aoff) = lq;                                                   \
        } else {                                                                          \
            ushort4 h0, l0, h1, l1;                                                       \
            split_rn(__uint_as_float(wa0.x), h0.x, l0.x);                                 \
            split_rn(__uint_as_float(wa0.y), h0.y, l0.y);                                 \
            split_rn(__uint_as_float(wa0.z), h0.z, l0.z);                                 \
            split_rn(__uint_as_float(wa0.w), h0.w, l0.w);                                 \
            split_rn(__uint_as_float(wa1.x), h1.x, l1.x);                                 \
            split_rn(__uint_as_float(wa1.y), h1.y, l1.y);                                 \
            split_rn(__uint_as_float(wa1.z), h1.z, l1.z);                                 \
            split_rn(__uint_as_float(wa1.w), h1.w, l1.w);                                 \
            *(ushort4*)(cAh + aoff) = h0; *(ushort4*)(cAh + aoff + 8) = h1;               \
            *(ushort4*)(cAl + aoff) = l0; *(ushort4*)(cAl + aoff + 8) = l1;               \
        }                                                                                 \
        _Pragma("unroll")                                                                 \
        for (int q = 0; q < 8; q++) {                                                     \
            int c2 = bhalfk * 16 + q * 2;                                                 \
            int off = bp * 64 + ((((c2 >> 3)) ^ bslot) << 4) + (c2 & 7) * 2;              \
            if constexpr (BBF16) {                                                        \
                *(unsigned*)(cBh + off) = pb[q];                                          \
            } else {                                                                      \
                unsigned u0 = pb[2 * q], u1 = pb[2 * q + 1];                              \
                unsigned hp, lp;                                                          \
                if constexpr (CLN) {                                                      \
                    unsigned short sh0, sl0, sh1, sl1;                                    \
                    split_rn(__uint_as_float(u0), sh0, sl0);                              \
                    split_rn(__uint_as_float(u1), sh1, sl1);                              \
                    hp = (unsigned)sh0 | ((unsigned)sh1 << 16);                           \
                    lp = (unsigned)sl0 | ((unsigned)sl1 << 16);                           \
                } else {                                                                  \
                    hp = __builtin_amdgcn_perm(u1, u0, 0x07060302u);                      \
                    lp = __builtin_amdgcn_perm(u1, u0, 0x05040100u);                      \
                }                                                                         \
                *(unsigned*)(cBh + off) = hp;                                             \
                *(unsigned*)(cBl + off) = lp;                                             \
            }                                                                             \
        }                                                                                 \
    }

    LOAD_TILE(0)

    for (int k0 = 0; k0 < Ctot; k0 += 32) {
        if (k0) __syncthreads();
        STORE_LDS()
        __syncthreads();
        if (k0 + 32 < Ctot) LOAD_TILE(k0 + 32)

        s16x8 ah[4], al[4];
        #pragma unroll
        for (int m = 0; m < 4; m++) {
            int ao = (wr * 64 + m * 16 + l15) * 64 + ((g ^ slotl) << 4);
            ah[m] = *(const s16x8*)(cAh + ao);
            al[m] = *(const s16x8*)(cAl + ao);
        }
        #pragma unroll
        for (int n = 0; n < 4; n++) {
            int bo = (wc * 64 + n * 16 + l15) * 64 + ((g ^ slotl) << 4);
            s16x8 bh = *(const s16x8*)(cBh + bo);
            if constexpr (BBF16) {
                #pragma unroll
                for (int m = 0; m < 4; m++) {
                    acc[m][n] = __builtin_amdgcn_mfma_f32_16x16x32_bf16(ah[m], bh, acc[m][n], 0, 0, 0);
                    acc[m][n] = __builtin_amdgcn_mfma_f32_16x16x32_bf16(al[m], bh, acc[m][n], 0, 0, 0);
                }
            } else {
                s16x8 bl = *(const s16x8*)(cBl + bo);
                #pragma unroll
                for (int m = 0; m < 4; m++) {
                    acc[m][n] = __builtin_amdgcn_mfma_f32_16x16x32_bf16(ah[m], bh, acc[m][n], 0, 0, 0);
                    acc[m][n] = __builtin_amdgcn_mfma_f32_16x16x32_bf16(ah[m], bl, acc[m][n], 0, 0, 0);
                    acc[m][n] = __builtin_amdgcn_mfma_f32_16x16x32_bf16(al[m], bh, acc[m][n], 0, 0, 0);
                }
            }
        }
    }
    #undef LOAD_TILE
    #undef STORE_LDS

    // ---- epilogue: D[row=(l>>4)*4+r][col=l&15] ----
    #pragma unroll
    for (int m = 0; m < 4; m++) {
        #pragma unroll
        for (int r = 0; r < 4; r++) {
            int orow = o0 + wr * 64 + m * 16 + g * 4 + r;
            float bs = (!CLN && bias) ? bias[orow] : 0.f;
            float Ao = CLN ? Aab[orow] : 0.f;
            float Bo = CLN ? Bab[orow] : 0.f;
            if constexpr (CLN) {
                float vv[4];
                #pragma unroll
                for (int n = 0; n < 4; n++) {
                    int pcol = p0 + wc * 64 + n * 16 + l15;
                    size_t cidx = (size_t)b * NP + pcol;
                    vv[n] = rs[cidx] * acc[m][n][r] - mrs[cidx] * Ao + Bo;
                }
                int which = orow >> 8;           // 0=q, 1=k, 2=v
                if (which < 2) {
                    float ss = vv[0] * vv[0] + vv[1] * vv[1] + vv[2] * vv[2] + vv[3] * vv[3];
                    ss += __shfl_xor(ss, 1); ss += __shfl_xor(ss, 2);
                    ss += __shfl_xor(ss, 4); ss += __shfl_xor(ss, 8);
                    float inv = 1.f / fmaxf(sqrtf(ss), 1e-12f);
                    float as = 0.f;
                    #pragma unroll
                    for (int n = 0; n < 4; n++) { vv[n] *= inv; as += fabsf(vv[n]); }
                    as += __shfl_xor(as, 1); as += __shfl_xor(as, 2);
                    as += __shfl_xor(as, 4); as += __shfl_xor(as, 8);
                    if (l15 == 0) {
                        int idx2 = orow & 255;
                        int head = idx2 >> 5, c = idx2 & 31;
                        int h = (p0 >> 6) + wc;
                        int rr = ((b << 3) + head) * 2048 + c * 64 + h;
                        (which == 0 ? qrow : kheight)[rr] = as;
                    }
                }
                #pragma unroll
                for (int n = 0; n < 4; n++) {
                    int pcol = p0 + wc * 64 + n * 16 + l15;
                    out[((size_t)b * sO + orow) * (size_t)NP + pcol] = vv[n];
                }
            } else {
                #pragma unroll
                for (int n = 0; n < 4; n++) {
                    int pcol = p0 + wc * 64 + n * 16 + l15;
                    float v = acc[m][n][r] + bs;
                    if (resid) v += resid[((size_t)b * O + orow) * (size_t)NP + pcol];
                    size_t oidx = ((size_t)b * sO + orow) * (size_t)NP + pcol;
                    if constexpr (OBF16)
                        ((unsigned short*)out)[oidx] = f2bf(v);
                    else
                        out[oidx] = PACKO ? packf(v) : v;
                }
            }
        }
    }
}

// ---------------- scores + top-k rows/cols + gather k/v (qprobe folded in) ----------
__global__ __launch_bounds__(64) void select_kernel(
    const float* __restrict__ qkv, const float* __restrict__ qrow,
    const float* __restrict__ kheight,
    float* __restrict__ ksel, float* __restrict__ vsel)
{
    const int bh = blockIdx.x;
    const int b = bh >> 3, head = bh & 7;
    const int lane = threadIdx.x;
    __shared__ int hs[8], wsl[8];
    __shared__ float qp[32];
    if (lane < 32) {
        double s = 0.0;
        const float* qr = qrow + (size_t)bh * 2048 + lane * 64;
        for (int h = 0; h < 64; h++) s += qr[h];
        qp[lane] = (float)s;
    }
    __syncthreads();
    double scd = 0.0;
    for (int c = 0; c < 32; c++) scd += (double)qp[c] * kheight[((size_t)bh * 32 + c) * 64 + lane];
    float sc = (float)scd;
    for (int it = 0; it < 8; it++) {
        float v = sc; int id = lane;
        for (int off = 32; off; off >>= 1) {
            float ov = __shfl_xor(v, off); int oi = __shfl_xor(id, off);
            if (ov > v || (ov == v && oi < id)) { v = ov; id = oi; }
        }
        if (lane == 0) hs[it] = id;
        if (lane == id) sc = -3.4e38f;
    }
    __syncthreads();
    const float* kbase = qkv + ((size_t)b * 768 + 256 + head * 32) * NP;
    double sc2d = 0.0;
    for (int c = 0; c < 32; c++) {
        float kw = 0.f;
        for (int hi = 0; hi < 8; hi++)
            kw += fabsf(kbase[(size_t)c * NP + hs[hi] * 64 + lane]);
        sc2d += (double)qp[c] * kw;
    }
    float sc2 = (float)sc2d;
    for (int it = 0; it < 8; it++) {
        float v = sc2; int id = lane;
        for (int off = 32; off; off >>= 1) {
            float ov = __shfl_xor(v, off); int oi = __shfl_xor(id, off);
            if (ov > v || (ov == v && oi < id)) { v = ov; id = oi; }
        }
        if (lane == 0) wsl[it] = id;
        if (lane == id) sc2 = -3.4e38f;
    }
    __syncthreads();
    const float* vbase = qkv + ((size_t)b * 768 + 512 + head * 32) * NP;
    int hi = lane >> 3, wi = lane & 7;
    int hh = hs[hi], ww = wsl[wi];
    for (int d = 0; d < 32; d++) {
        ksel[((size_t)bh * 64 + lane) * 32 + d] = kbase[(size_t)d * NP + hh * 64 + ww];
        vsel[((size_t)bh * 64 + lane) * 32 + d] = vbase[(size_t)d * NP + hh * 64 + ww];
    }
}

// ---------------- attention: in-place over q slot; writes PACKED ctx ----------------
__global__ __launch_bounds__(256) void attn_kernel(
    float* __restrict__ qkv, const float* __restrict__ ksel, const float* __restrict__ vsel)
{
    __shared__ __align__(16) float ks[64][32];
    __shared__ __align__(16) float vs[64][32];
    int bh = blockIdx.y, b = bh >> 3, head = bh & 7;
    int t = threadIdx.x;
    const float* kb = ksel + (size_t)bh * 2048;
    const float* vb = vsel + (size_t)bh * 2048;
    for (int i = 0; i < 8; i++) {
        ((float*)ks)[t + i * 256] = kb[t + i * 256];
        ((float*)vs)[t + i * 256] = vb[t + i * 256];
    }
    __syncthreads();
    int p = blockIdx.x * 256 + t;
    float* qb = qkv + ((size_t)b * 768 + head * 32) * NP + p;
    float q[32];
    #pragma unroll
    for (int d = 0; d < 32; d++) q[d] = qb[(size_t)d * NP];
    float s[64], m = -3.4e38f;
    for (int j = 0; j < 64; j++) {
        float dot = 0.f;
        #pragma unroll
        for (int d = 0; d < 32; d++) dot += q[d] * ks[j][d];
        s[j] = dot; m = fmaxf(m, dot);
    }
    float den = 0.f;
    for (int j = 0; j < 64; j++) { float e = expf(s[j] - m); s[j] = e; den += e; }
    float o[32] = {};
    for (int j = 0; j < 64; j++) {
        float a = s[j];
        #pragma unroll
        for (int d = 0; d < 32; d++) o[d] += a * vs[j][d];
    }
    float r = 1.f / den;
    #pragma unroll
    for (int d = 0; d < 32; d++) qb[(size_t)d * NP] = packf(o[d] * r);
}

// ---------------- depthwise 3x3 on x; PACKED strided output planes ----------------
__global__ __launch_bounds__(256) void dwconv_kernel(
    const float* __restrict__ in, const float* __restrict__ w, const float* __restrict__ bias,
    float* __restrict__ out, int Cn, int sO)
{
    __shared__ __align__(16) float pl[64][64];
    int bcb = blockIdx.x;
    int b = bcb / Cn, c = bcb % Cn;
    const float* src = in + (size_t)bcb * NP;
    float* dst = out + ((size_t)b * sO + c) * NP;
    int t = threadIdx.x;
    for (int i = 0; i < 16; i++) { int pix = t + i * 256; pl[pix >> 6][pix & 63] = src[pix]; }
    float w9[9];
    #pragma unroll
    for (int k = 0; k < 9; k++) w9[k] = w[c * 9 + k];
    float bsv = bias[c];
    __syncthreads();
    for (int i = 0; i < 16; i++) {
        int pix = t + i * 256; int y = pix >> 6, xx = pix & 63;
        float acc = bsv;
        #pragma unroll
        for (int dy = 0; dy < 3; dy++) {
            int yy = y + dy - 1; if (yy < 0 || yy > 63) continue;
            #pragma unroll
            for (int dx = 0; dx < 3; dx++) {
                int x2 = xx + dx - 1; if (x2 < 0 || x2 > 63) continue;
                acc += w9[dy * 3 + dx] * pl[yy][x2];
            }
        }
        dst[pix] = packf(acc);
    }
}

// ---------------- fast gelu: A&S 7.1.26 erf (max abs err ~1.5e-7) ----------------
__device__ inline float gelu_fast(float x) {
    float z = x * 0.70710678118654752f;
    float a = fabsf(z);
    float t = 1.0f / (1.0f + 0.3275911f * a);
    float p = t * (0.254829592f + t * (-0.284496736f + t * (1.421413741f +
              t * (-1.453152027f + t * 1.061405429f))));
    float e = __expf(-a * a);
    float r = 1.0f - p * e;                 // erf(|z|)
    float erfz = copysignf(r, z);
    return 0.5f * x * (1.0f + erfz);
}

__device__ inline void block_reduce2(double& s, double& s2, double* red, int t)
{
    __syncthreads();
    red[t] = s; red[256 + t] = s2;
    __syncthreads();
    for (int st = 128; st; st >>= 1) {
        if (t < st) { red[t] += red[t + st]; red[256 + t] += red[256 + t + st]; }
        __syncthreads();
    }
    s = red[0]; s2 = red[256];
}

// ---------------- fused FF on bf16 h: gelu(IN(h)) + residual dwconv path; bf16 out ----
__global__ __launch_bounds__(256) void ff_fused_kernel(
    unsigned short* __restrict__ h, const float* __restrict__ w, const float* __restrict__ bias)
{
    __shared__ __align__(16) float pl[64][64];
    __shared__ double red[512];
    int plane = blockIdx.x;
    int c = plane & (NFF - 1);
    size_t base = (size_t)plane * NP;
    int t = threadIdx.x;
    float v[16]; double s = 0.0, s2 = 0.0;
    for (int i = 0; i < 16; i++) {
        float x = bf2f(h[base + t + i * 256]);
        v[i] = x; s += x; s2 += (double)x * x;
    }
    block_reduce2(s, s2, red, t);
    double mean = s * (1.0 / NP);
    double var = s2 * (1.0 / NP) - mean * mean;
    float rs = (float)(1.0 / sqrt(var + (double)CEPS));
    float mf = (float)mean;
    for (int i = 0; i < 16; i++) {
        float gx = gelu_fast((v[i] - mf) * rs);
        v[i] = gx;
        int pix = t + i * 256;
        pl[pix >> 6][pix & 63] = gx;
    }
    __syncthreads();
    float w9[9];
    #pragma unroll
    for (int k = 0; k < 9; k++) w9[k] = w[c * 9 + k];
    float bsv = bias[c];
    float tv[16]; s = 0.0; s2 = 0.0;
    for (int i = 0; i < 16; i++) {
        int pix = t + i * 256; int y = pix >> 6, xx = pix & 63;
        float acc = bsv;
        #pragma unroll
        for (int dy = 0; dy < 3; dy++) {
            int yy = y + dy - 1; if (yy < 0 || yy > 63) continue;
            #pragma unroll
            for (int dx = 0; dx < 3; dx++) {
                int x2 = xx + dx - 1; if (x2 < 0 || x2 > 63) continue;
                acc += w9[dy * 3 + dx] * pl[yy][x2];
            }
        }
        tv[i] = acc; s += acc; s2 += (double)acc * acc;
    }
    block_reduce2(s, s2, red, t);
    double mean2 = s * (1.0 / NP);
    double var2 = s2 * (1.0 / NP) - mean2 * mean2;
    float rs2 = (float)(1.0 / sqrt(var2 + (double)CEPS));
    float mf2 = (float)mean2;
    for (int i = 0; i < 16; i++) {
        int pix = t + i * 256;
        float o = v[i] + gelu_fast((tv[i] - mf2) * rs2);
        h[base + pix] = f2bf(o);
    }
}

// ---------------- final instance norm in place on d_out ----------------
__global__ __launch_bounds__(256) void in_final_kernel(float* __restrict__ y)
{
    __shared__ double red[512];
    size_t base = (size_t)blockIdx.x * NP;
    int t = threadIdx.x;
    float v[16]; double s = 0.0, s2 = 0.0;
    for (int i = 0; i < 16; i++) { float x = y[base + t + i * 256]; v[i] = x; s += x; s2 += (double)x * x; }
    block_reduce2(s, s2, red, t);
    double mean = s * (1.0 / NP);
    double var = s2 * (1.0 / NP) - mean * mean;
    float rs = (float)(1.0 / sqrt(var + (double)CEPS));
    float mf = (float)mean;
    for (int i = 0; i < 16; i++)
        y[base + t + i * 256] = (v[i] - mf) * rs;
}

extern "C" void kernel_launch(void* const* d_in, const int* in_sizes, int n_in,
                              void* d_out, int out_size, void* d_ws, size_t ws_size,
                              hipStream_t stream)
{
    const float* x      = (const float*)d_in[0];
    const float* g      = (const float*)d_in[1];
    const float* bc     = (const float*)d_in[2];
    const float* w_qkv  = (const float*)d_in[3];
    const float* w_out  = (const float*)d_in[4];
    const float* b_out  = (const float*)d_in[5];
    const float* w_dw   = (const float*)d_in[6];
    const float* b_dw   = (const float*)d_in[7];
    const float* w_comb = (const float*)d_in[8];
    const float* b_comb = (const float*)d_in[9];
    const float* w_ff1  = (const float*)d_in[10];
    const float* b_ff1  = (const float*)d_in[11];
    const float* w_ffdw = (const float*)d_in[12];
    const float* b_ffdw = (const float*)d_in[13];
    const float* w_ff2  = (const float*)d_in[14];
    const float* b_ff2  = (const float*)d_in[15];
    float* out = (float*)d_out;
    float* ws  = (float*)d_ws;

    const size_t S = (size_t)NB * NC * NP;   // 16,777,216 floats (64 MiB)
    // Memory plan (ws = 4S exactly):
    //   d_out      : pw_qkv until step 9; Fbuf (attn_out packed, 9-10); final output (12+)
    //   ws[0,S)    : smalls [0,1048576); cln stats at [1052672,...); pwF+bF (7-9) -> dead
    //   ws[S,4S)   : qkv fp32; ctx packed in q-planes; convb packed in v-planes
    //   ws[0,2S)   : h1 as bf16 (128 MiB, 67.1M ushorts), written step 10 (qkv dead),
    //                processed in place by ff_fused (11), read by ff2 (12)
    float* qkv   = ws + S;
    unsigned short* h1u = (unsigned short*)ws;
    float* Fbuf  = out;
    float* convb = qkv + (size_t)512 * NP;
    float* qrow    = ws;                       // 262144
    float* kheight = qrow + 262144;            // 262144
    float* kselb   = kheight + 262144;         // 262144
    float* vselb   = kselb + 262144;           // ends at 1048576
    float* rs_a    = ws + 1052672;             // 65536
    float* mrs_a   = rs_a + 65536;             // 65536
    float* Aab     = mrs_a + 65536;            // 768
    float* Bab     = Aab + 768;                // 768
    unsigned* pw_qkv = (unsigned*)out;         // 196608 u32 in d_out (free until step 9)
    unsigned* pwF    = (unsigned*)ws;          // 131072 u32 (dead smalls, after attn)
    float*    bF     = ws + 131072;            // 256 floats

    size_t need = 4 * S * sizeof(float);
    if (ws_size < need) {
        float val = 1024.0f + (float)(ws_size >> 20);
        diag_fill<<<(out_size + 255) / 256, 256, 0, stream>>>(out, val, out_size);
        return;
    }

    // 0. prepack W_qkv*diag(g); cln stats; fold constants
    pack_wg_kernel<<<768, 256, 0, stream>>>(w_qkv, g, pw_qkv, 768 * 256);
    cln_stats_kernel<<<1024, 256, 0, stream>>>(x, rs_a, mrs_a);
    ab_kernel<<<3, 256, 0, stream>>>(w_qkv, g, bc, Aab, Bab);
    // 2. qkv = fold( (W_qkv g) * x ) with fused l2norm + qrow/kheight
    gemm_mfma<false, true, true, false, false><<<dim3(16, 6, NB), 512, 0, stream>>>(
        x, 256, 256, nullptr, 0, 256, (const float*)pw_qkv, nullptr, nullptr, qkv, 768, 768,
        rs_a, mrs_a, Aab, Bab, qrow, kheight);
    // 5-6. select (qprobe folded), attention (packed ctx -> q-planes)
    select_kernel<<<NBH, 64, 0, stream>>>(qkv, qrow, kheight, kselb, vselb);
    attn_kernel<<<dim3(16, NBH), 256, 0, stream>>>(qkv, kselb, vselb);
    // 7. fused comb weight -> packed, into dead smalls
    fuse_comb_kernel<<<512, 256, 0, stream>>>(w_comb, w_out, b_out, b_comb, pwF, bF);
    // 8. conv branch -> v-planes (packed)
    dwconv_kernel<<<NB * NC, 256, 0, stream>>>(x, w_dw, b_dw, convb, NC, 768);
    // 9. attn_out = W_fused * [ctx; convb] + b_fused + x -> d_out (packed)
    gemm_mfma<true, true, false, false, false><<<dim3(16, 2, NB), 512, 0, stream>>>(
        qkv, 768, 256, convb, 768, 512, (const float*)pwF, bF, x, Fbuf, 256, 256,
        nullptr, nullptr, nullptr, nullptr, nullptr, nullptr);
    // 10. h1 = W_ff1 * attn_out + b_ff1 -> bf16 at ws[0,2S)  (qkv + smalls dead)
    gemm_mfma<false, false, false, true, false><<<dim3(16, 8, NB), 512, 0, stream>>>(
        Fbuf, 256, 256, nullptr, 0, 256, w_ff1, b_ff1, nullptr, (float*)h1u, 1024, 1024,
        nullptr, nullptr, nullptr, nullptr, nullptr, nullptr);
    // 11. fused FF on bf16 h1 (in place)
    ff_fused_kernel<<<NB * NFF, 256, 0, stream>>>(h1u, w_ffdw, b_ffdw);
    // 12. y = W_ff2 * h1(bf16 B, 2-MFMA) + b_ff2 -> d_out fp32
    gemm_mfma<false, false, false, false, true><<<dim3(16, 2, NB), 512, 0, stream>>>(
        (const float*)h1u, 1024, 1024, nullptr, 0, 1024, w_ff2, b_ff2, nullptr, out, 256, 256,
        nullptr, nullptr, nullptr, nullptr, nullptr, nullptr);
    // 13. final instance norm
    in_final_kernel<<<NB * NC, 256, 0, stream>>>(out);
}

// Round 17
// 935.472 us; speedup vs baseline: 1.2830x; 1.0378x over previous
//
#include <hip/hip_runtime.h>
#include <math.h>

#define NB 16
#define NC 256
#define NP 4096      // 64*64
#define NHEADS 8
#define NDH 32
#define NBH 128
#define NFF 1024
#define CEPS 1e-5f

typedef short s16x8 __attribute__((ext_vector_type(8)));
typedef float f32x4 __attribute__((ext_vector_type(4)));

// ---------------- diagnostic fill (guard trip) ----------------
__global__ __launch_bounds__(256) void diag_fill(float* __restrict__ out, float val, int n)
{
    int i = blockIdx.x * 256 + threadIdx.x;
    if (i < n) out[i] = val;
}

// ---------------- bf16 split helpers ----------------
__device__ inline unsigned short f2bf(float f) {
    unsigned u = __float_as_uint(f);
    return (unsigned short)((u + 0x7FFFu + ((u >> 16) & 1u)) >> 16);
}
__device__ inline float bf2f(unsigned short h) { return __uint_as_float(((unsigned)h) << 16); }
__device__ inline void split2(float f, unsigned short& hi, unsigned short& lo) {
    hi = f2bf(f);
    lo = f2bf(f - bf2f(hi));
}
// fast round-to-nearest split (6 ops)
__device__ inline void split_rn(float f, unsigned short& hi, unsigned short& lo) {
    unsigned u = __float_as_uint(f);
    unsigned tt = u + 0x8000u;
    hi = (unsigned short)(tt >> 16);
    float r = f - __uint_as_float(tt & 0xffff0000u);
    lo = (unsigned short)((__float_as_uint(r) + 0x8000u) >> 16);
}
// packed: (hi<<16)|lo
__device__ inline unsigned pack_hl(float f) {
    unsigned short h, lo; split2(f, h, lo);
    return ((unsigned)h << 16) | (unsigned)lo;
}
__device__ inline float packf(float f) { return __uint_as_float(pack_hl(f)); }

// ---------------- weight prepack with channel gain: pw = pack(w[o,c]*g[c]) ----------
__global__ __launch_bounds__(256) void pack_wg_kernel(
    const float* __restrict__ w, const float* __restrict__ g,
    unsigned* __restrict__ pw, int n)
{
    int i = blockIdx.x * 256 + threadIdx.x;
    if (i < n) pw[i] = pack_hl(w[i] * g[i & 255]);
}

// ---------------- cln stats: per (b,p) mean/rsqrt over 256 channels ----------------
__global__ __launch_bounds__(256) void cln_stats_kernel(
    const float* __restrict__ x, float* __restrict__ rs, float* __restrict__ mrs)
{
    __shared__ double red[512];
    int t = threadIdx.x;
    int i = t & 63, q = t >> 6;
    int col = blockIdx.x * 64 + i;
    int b = col >> 12, p = col & 4095;
    const float* src = x + (size_t)b * NC * NP + (size_t)(q * 64) * NP + p;
    double s = 0.0, s2 = 0.0;
    #pragma unroll 8
    for (int c = 0; c < 64; c++) { float v = src[(size_t)c * NP]; s += v; s2 += (double)v * v; }
    red[q * 64 + i] = s; red[256 + q * 64 + i] = s2;
    __syncthreads();
    if (q == 0) {
        double S  = red[i] + red[64 + i] + red[128 + i] + red[192 + i];
        double S2 = red[256 + i] + red[320 + i] + red[384 + i] + red[448 + i];
        double mean = S * (1.0 / 256.0);
        double var = S2 * (1.0 / 256.0) - mean * mean;
        double r = 1.0 / sqrt(var + (double)CEPS);
        rs[col]  = (float)r;
        mrs[col] = (float)(mean * r);
    }
}

// ---------------- A/B fold constants ----------------
__global__ __launch_bounds__(256) void ab_kernel(
    const float* __restrict__ wq, const float* __restrict__ g, const float* __restrict__ bc,
    float* __restrict__ Aab, float* __restrict__ Bab)
{
    int o = blockIdx.x * 256 + threadIdx.x;
    if (o >= 768) return;
    double a = 0.0, bsum = 0.0;
    for (int c = 0; c < 256; c++) {
        double w = wq[o * 256 + c];
        a += w * (double)g[c];
        bsum += w * (double)bc[c];
    }
    Aab[o] = (float)a; Bab[o] = (float)bsum;
}

// ---------------- fused comb weight: W_fused = [W_comb_L @ W_out | W_comb_R] ----------
__global__ __launch_bounds__(256) void fuse_comb_kernel(
    const float* __restrict__ w_comb, const float* __restrict__ w_out,
    const float* __restrict__ b_out, const float* __restrict__ b_comb,
    unsigned* __restrict__ pwF, float* __restrict__ bF)
{
    int idx = blockIdx.x * 256 + threadIdx.x;   // 131072
    int o = idx >> 9, cc = idx & 511;
    float val;
    if (cc < 256) {
        double s = 0.0;
        for (int k = 0; k < 256; k++)
            s += (double)w_comb[o * 512 + k] * (double)w_out[k * 256 + cc];
        val = (float)s;
    } else {
        val = w_comb[o * 512 + cc];
    }
    pwF[idx] = pack_hl(val);
    if (idx < 256) {
        double s = 0.0;
        for (int k = 0; k < 256; k++)
            s += (double)w_comb[idx * 512 + k] * (double)b_out[k];
        bF[idx] = (float)(s + (double)b_comb[idx]);
    }
}

// ---------------- split-bf16 MFMA GEMM: 128o x 256p tile, 8 waves, K-step 32 ----------
// B-input: CLN ? raw fp32 (split in-stage) : BBF16 ? bf16 planes (C1-split) : packed u32.
// A: PACKA ? packed u32 : raw fp32. OBF16: bf16 output.
template<bool PACKO, bool PACKA, bool CLN, bool OBF16, bool BBF16>
__global__ __launch_bounds__(512) void gemm_mfma(
    const float* __restrict__ inA, int sA, int C1,
    const float* __restrict__ inB, int sB, int Ctot,
    const float* __restrict__ Wt, const float* __restrict__ bias,
    const float* __restrict__ resid, float* __restrict__ out, int sO, int O,
    const float* __restrict__ rs, const float* __restrict__ mrs,
    const float* __restrict__ Aab, const float* __restrict__ Bab,
    float* __restrict__ qrow, float* __restrict__ kheight)
{
    __shared__ __align__(16) unsigned short Ah[128 * 32], Al[128 * 32];
    __shared__ __align__(16) unsigned short Bh[256 * 32];
    __shared__ __align__(16) unsigned short Bl[BBF16 ? 16 : 256 * 32];
    char* cAh = (char*)Ah; char* cAl = (char*)Al;
    char* cBh = (char*)Bh; char* cBl = (char*)Bl;

    // ---- XCD-batch swizzle ----
    const unsigned npb = gridDim.x * gridDim.y;
    unsigned lin = blockIdx.x + gridDim.x * (blockIdx.y + gridDim.y * blockIdx.z);
    unsigned low = lin & 7u, rest = lin >> 3;
    unsigned high = (rest >= npb) ? 1u : 0u;
    unsigned idx = rest - high * npb;
    const int b = (int)(low + 8u * high);
    const int o0 = (int)(idx / gridDim.x) * 128, p0 = (int)(idx % gridDim.x) * 256;

    const int t = threadIdx.x;
    const int l = t & 63, w = t >> 6;
    const int wr = w >> 2, wc = w & 3;
    const int g = l >> 4, l15 = l & 15;
    const int slotl = (l & 3) ^ ((l >> 2) & 3);

    f32x4 acc[4][4];
    #pragma unroll
    for (int m = 0; m < 4; m++)
        #pragma unroll
        for (int n = 0; n < 4; n++) acc[m][n] = (f32x4){0.f, 0.f, 0.f, 0.f};

    const int arow = t >> 2;
    const int ak8 = (t & 3) * 8;
    const int aslot = (arow & 3) ^ ((arow >> 2) & 3);
    const int aoff = arow * 64 + ((((ak8 >> 3)) ^ aslot) << 4);
    const int bp = t & 255;
    const int bhalfk = t >> 8;
    const int bslot = (bp & 3) ^ ((bp >> 2) & 3);

    uint4 wa0, wa1;          // A prefetch
    unsigned pb[16];         // B prefetch

    #define LOAD_TILE(K0)                                                                 \
    {                                                                                     \
        const unsigned* wsrc = (const unsigned*)Wt + (size_t)(o0 + arow) * Ctot + (K0) + ak8; \
        wa0 = *(const uint4*)(wsrc);                                                      \
        wa1 = *(const uint4*)(wsrc + 4);                                                  \
        _Pragma("unroll")                                                                 \
        for (int q = 0; q < 8; q++) {                                                     \
            int c2 = bhalfk * 16 + q * 2;                                                 \
            int cc = (K0) + c2;                                                           \
            if constexpr (BBF16) {                                                        \
                const unsigned short* s16 = (cc < C1)                                     \
                    ? (const unsigned short*)inA + ((size_t)b * sA + cc) * (size_t)NP + p0 + bp \
                    : (const unsigned short*)inB + ((size_t)b * sB + (cc - C1)) * (size_t)NP + p0 + bp; \
                unsigned short v0 = s16[0];                                               \
                unsigned short v1 = s16[NP];                                              \
                pb[q] = (unsigned)v0 | ((unsigned)v1 << 16);                              \
            } else {                                                                      \
                const float* srcp = (cc < C1) ? inA + ((size_t)b * sA + cc) * (size_t)NP  \
                                              : inB + ((size_t)b * sB + (cc - C1)) * (size_t)NP; \
                pb[2 * q]     = __float_as_uint(srcp[p0 + bp]);                           \
                pb[2 * q + 1] = __float_as_uint(srcp[(size_t)NP + p0 + bp]);              \
            }                                                                             \
        }                                                                                 \
    }

    #define STORE_LDS()                                                                   \
    {                                                                                     \
        if constexpr (PACKA) {                                                            \
            uint4 hq, lq;                                                                 \
            hq.x = __builtin_amdgcn_perm(wa0.y, wa0.x, 0x07060302u);                      \
            lq.x = __builtin_amdgcn_perm(wa0.y, wa0.x, 0x05040100u);                      \
            hq.y = __builtin_amdgcn_perm(wa0.w, wa0.z, 0x07060302u);                      \
            lq.y = __builtin_amdgcn_perm(wa0.w, wa0.z, 0x05040100u);                      \
            hq.z = __builtin_amdgcn_perm(wa1.y, wa1.x, 0x07060302u);                      \
            lq.z = __builtin_amdgcn_perm(wa1.y, wa1.x, 0x05040100u);                      \
            hq.w = __builtin_amdgcn_perm(wa1.w, wa1.z, 0x07060302u);                      \
            lq.w = __builtin_amdgcn_perm(wa1.w, wa1.z, 0x05040100u);                      \
            *(uint4*)(cAh + aoff) = hq;                                                   \
            *(uint4*)(cAl + aoff) = lq;                                                   \
        } else {                                                                          \
            ushort4 h0, l0, h1, l1;                                                       \
            split_rn(__uint_as_float(wa0.x), h0.x, l0.x);                                 \
            split_rn(__uint_as_float(wa0.y), h0.y, l0.y);                                 \
            split_rn(__uint_as_float(wa0.z), h0.z, l0.z);                                 \
            split_rn(__uint_as_float(wa0.w), h0.w, l0.w);                                 \
            split_rn(__uint_as_float(wa1.x), h1.x, l1.x);                                 \
            split_rn(__uint_as_float(wa1.y), h1.y, l1.y);                                 \
            split_rn(__uint_as_float(wa1.z), h1.z, l1.z);                                 \
            split_rn(__uint_as_float(wa1.w), h1.w, l1.w);                                 \
            *(ushort4*)(cAh + aoff) = h0; *(ushort4*)(cAh + aoff + 8) = h1;               \
            *(ushort4*)(cAl + aoff) = l0; *(ushort4*)(cAl + aoff + 8) = l1;               \
        }                                                                                 \
        _Pragma("unroll")                                                                 \
        for (int q = 0; q < 8; q++) {                                                     \
            int c2 = bhalfk * 16 + q * 2;                                                 \
            int off = bp * 64 + ((((c2 >> 3)) ^ bslot) << 4) + (c2 & 7) * 2;              \
            if constexpr (BBF16) {                                                        \
                *(unsigned*)(cBh + off) = pb[q];                                          \
            } else {                                                                      \
                unsigned u0 = pb[2 * q], u1 = pb[2 * q + 1];                              \
                unsigned hp, lp;                                                          \
                if constexpr (CLN) {                                                      \
                    unsigned short sh0, sl0, sh1, sl1;                                    \
                    split_rn(__uint_as_float(u0), sh0, sl0);                              \
                    split_rn(__uint_as_float(u1), sh1, sl1);                              \
                    hp = (unsigned)sh0 | ((unsigned)sh1 << 16);                           \
                    lp = (unsigned)sl0 | ((unsigned)sl1 << 16);                           \
                } else {                                                                  \
                    hp = __builtin_amdgcn_perm(u1, u0, 0x07060302u);                      \
                    lp = __builtin_amdgcn_perm(u1, u0, 0x05040100u);                      \
                }                                                                         \
                *(unsigned*)(cBh + off) = hp;                                             \
                *(unsigned*)(cBl + off) = lp;                                             \
            }                                                                             \
        }                                                                                 \
    }

    LOAD_TILE(0)

    for (int k0 = 0; k0 < Ctot; k0 += 32) {
        if (k0) __syncthreads();
        STORE_LDS()
        __syncthreads();
        if (k0 + 32 < Ctot) LOAD_TILE(k0 + 32)

        s16x8 ah[4], al[4];
        #pragma unroll
        for (int m = 0; m < 4; m++) {
            int ao = (wr * 64 + m * 16 + l15) * 64 + ((g ^ slotl) << 4);
            ah[m] = *(const s16x8*)(cAh + ao);
            al[m] = *(const s16x8*)(cAl + ao);
        }
        #pragma unroll
        for (int n = 0; n < 4; n++) {
            int bo = (wc * 64 + n * 16 + l15) * 64 + ((g ^ slotl) << 4);
            s16x8 bh = *(const s16x8*)(cBh + bo);
            if constexpr (BBF16) {
                #pragma unroll
                for (int m = 0; m < 4; m++) {
                    acc[m][n] = __builtin_amdgcn_mfma_f32_16x16x32_bf16(ah[m], bh, acc[m][n], 0, 0, 0);
                    acc[m][n] = __builtin_amdgcn_mfma_f32_16x16x32_bf16(al[m], bh, acc[m][n], 0, 0, 0);
                }
            } else {
                s16x8 bl = *(const s16x8*)(cBl + bo);
                #pragma unroll
                for (int m = 0; m < 4; m++) {
                    acc[m][n] = __builtin_amdgcn_mfma_f32_16x16x32_bf16(ah[m], bh, acc[m][n], 0, 0, 0);
                    acc[m][n] = __builtin_amdgcn_mfma_f32_16x16x32_bf16(ah[m], bl, acc[m][n], 0, 0, 0);
                    acc[m][n] = __builtin_amdgcn_mfma_f32_16x16x32_bf16(al[m], bh, acc[m][n], 0, 0, 0);
                }
            }
        }
    }
    #undef LOAD_TILE
    #undef STORE_LDS

    // ---- epilogue: D[row=(l>>4)*4+r][col=l&15] ----
    #pragma unroll
    for (int m = 0; m < 4; m++) {
        #pragma unroll
        for (int r = 0; r < 4; r++) {
            int orow = o0 + wr * 64 + m * 16 + g * 4 + r;
            float bs = (!CLN && bias) ? bias[orow] : 0.f;
            float Ao = CLN ? Aab[orow] : 0.f;
            float Bo = CLN ? Bab[orow] : 0.f;
            if constexpr (CLN) {
                float vv[4];
                #pragma unroll
                for (int n = 0; n < 4; n++) {
                    int pcol = p0 + wc * 64 + n * 16 + l15;
                    size_t cidx = (size_t)b * NP + pcol;
                    vv[n] = rs[cidx] * acc[m][n][r] - mrs[cidx] * Ao + Bo;
                }
                int which = orow >> 8;           // 0=q, 1=k, 2=v
                if (which < 2) {
                    float ss = vv[0] * vv[0] + vv[1] * vv[1] + vv[2] * vv[2] + vv[3] * vv[3];
                    ss += __shfl_xor(ss, 1); ss += __shfl_xor(ss, 2);
                    ss += __shfl_xor(ss, 4); ss += __shfl_xor(ss, 8);
                    float inv = 1.f / fmaxf(sqrtf(ss), 1e-12f);
                    float as = 0.f;
                    #pragma unroll
                    for (int n = 0; n < 4; n++) { vv[n] *= inv; as += fabsf(vv[n]); }
                    as += __shfl_xor(as, 1); as += __shfl_xor(as, 2);
                    as += __shfl_xor(as, 4); as += __shfl_xor(as, 8);
                    if (l15 == 0) {
                        int idx2 = orow & 255;
                        int head = idx2 >> 5, c = idx2 & 31;
                        int h = (p0 >> 6) + wc;
                        int rr = ((b << 3) + head) * 2048 + c * 64 + h;
                        (which == 0 ? qrow : kheight)[rr] = as;
                    }
                }
                #pragma unroll
                for (int n = 0; n < 4; n++) {
                    int pcol = p0 + wc * 64 + n * 16 + l15;
                    out[((size_t)b * sO + orow) * (size_t)NP + pcol] = vv[n];
                }
            } else {
                #pragma unroll
                for (int n = 0; n < 4; n++) {
                    int pcol = p0 + wc * 64 + n * 16 + l15;
                    float v = acc[m][n][r] + bs;
                    if (resid) v += resid[((size_t)b * O + orow) * (size_t)NP + pcol];
                    size_t oidx = ((size_t)b * sO + orow) * (size_t)NP + pcol;
                    if constexpr (OBF16)
                        ((unsigned short*)out)[oidx] = f2bf(v);
                    else
                        out[oidx] = PACKO ? packf(v) : v;
                }
            }
        }
    }
}

// ---------------- scores + top-k rows/cols + gather k/v (qprobe folded in) ----------
__global__ __launch_bounds__(64) void select_kernel(
    const float* __restrict__ qkv, const float* __restrict__ qrow,
    const float* __restrict__ kheight,
    float* __restrict__ ksel, float* __restrict__ vsel)
{
    const int bh = blockIdx.x;
    const int b = bh >> 3, head = bh & 7;
    const int lane = threadIdx.x;
    __shared__ int hs[8], wsl[8];
    __shared__ float qp[32];
    if (lane < 32) {
        double s = 0.0;
        const float* qr = qrow + (size_t)bh * 2048 + lane * 64;
        for (int h = 0; h < 64; h++) s += qr[h];
        qp[lane] = (float)s;
    }
    __syncthreads();
    double scd = 0.0;
    for (int c = 0; c < 32; c++) scd += (double)qp[c] * kheight[((size_t)bh * 32 + c) * 64 + lane];
    float sc = (float)scd;
    for (int it = 0; it < 8; it++) {
        float v = sc; int id = lane;
        for (int off = 32; off; off >>= 1) {
            float ov = __shfl_xor(v, off); int oi = __shfl_xor(id, off);
            if (ov > v || (ov == v && oi < id)) { v = ov; id = oi; }
        }
        if (lane == 0) hs[it] = id;
        if (lane == id) sc = -3.4e38f;
    }
    __syncthreads();
    const float* kbase = qkv + ((size_t)b * 768 + 256 + head * 32) * NP;
    double sc2d = 0.0;
    for (int c = 0; c < 32; c++) {
        float kw = 0.f;
        for (int hi = 0; hi < 8; hi++)
            kw += fabsf(kbase[(size_t)c * NP + hs[hi] * 64 + lane]);
        sc2d += (double)qp[c] * kw;
    }
    float sc2 = (float)sc2d;
    for (int it = 0; it < 8; it++) {
        float v = sc2; int id = lane;
        for (int off = 32; off; off >>= 1) {
            float ov = __shfl_xor(v, off); int oi = __shfl_xor(id, off);
            if (ov > v || (ov == v && oi < id)) { v = ov; id = oi; }
        }
        if (lane == 0) wsl[it] = id;
        if (lane == id) sc2 = -3.4e38f;
    }
    __syncthreads();
    const float* vbase = qkv + ((size_t)b * 768 + 512 + head * 32) * NP;
    int hi = lane >> 3, wi = lane & 7;
    int hh = hs[hi], ww = wsl[wi];
    for (int d = 0; d < 32; d++) {
        ksel[((size_t)bh * 64 + lane) * 32 + d] = kbase[(size_t)d * NP + hh * 64 + ww];
        vsel[((size_t)bh * 64 + lane) * 32 + d] = vbase[(size_t)d * NP + hh * 64 + ww];
    }
}

// ---------------- attention: writes compact bf16 ctx [b][256][NP] ----------------
__global__ __launch_bounds__(256) void attn_kernel(
    const float* __restrict__ qkv, const float* __restrict__ ksel, const float* __restrict__ vsel,
    unsigned short* __restrict__ ctxu)
{
    __shared__ __align__(16) float ks[64][32];
    __shared__ __align__(16) float vs[64][32];
    int bh = blockIdx.y, b = bh >> 3, head = bh & 7;
    int t = threadIdx.x;
    const float* kb = ksel + (size_t)bh * 2048;
    const float* vb = vsel + (size_t)bh * 2048;
    for (int i = 0; i < 8; i++) {
        ((float*)ks)[t + i * 256] = kb[t + i * 256];
        ((float*)vs)[t + i * 256] = vb[t + i * 256];
    }
    __syncthreads();
    int p = blockIdx.x * 256 + t;
    const float* qb = qkv + ((size_t)b * 768 + head * 32) * NP + p;
    unsigned short* ob = ctxu + ((size_t)b * 256 + head * 32) * NP + p;
    float q[32];
    #pragma unroll
    for (int d = 0; d < 32; d++) q[d] = qb[(size_t)d * NP];
    float s[64], m = -3.4e38f;
    for (int j = 0; j < 64; j++) {
        float dot = 0.f;
        #pragma unroll
        for (int d = 0; d < 32; d++) dot += q[d] * ks[j][d];
        s[j] = dot; m = fmaxf(m, dot);
    }
    float den = 0.f;
    for (int j = 0; j < 64; j++) { float e = expf(s[j] - m); s[j] = e; den += e; }
    float o[32] = {};
    for (int j = 0; j < 64; j++) {
        float a = s[j];
        #pragma unroll
        for (int d = 0; d < 32; d++) o[d] += a * vs[j][d];
    }
    float r = 1.f / den;
    #pragma unroll
    for (int d = 0; d < 32; d++) ob[(size_t)d * NP] = f2bf(o[d] * r);
}

// ---------------- depthwise 3x3 on x; compact bf16 output [b][256][NP] ----------------
__global__ __launch_bounds__(256) void dwconv_kernel(
    const float* __restrict__ in, const float* __restrict__ w, const float* __restrict__ bias,
    unsigned short* __restrict__ out, int Cn)
{
    __shared__ __align__(16) float pl[64][64];
    int bcb = blockIdx.x;
    int c = bcb % Cn;
    const float* src = in + (size_t)bcb * NP;
    unsigned short* dst = out + (size_t)bcb * NP;
    int t = threadIdx.x;
    for (int i = 0; i < 16; i++) { int pix = t + i * 256; pl[pix >> 6][pix & 63] = src[pix]; }
    float w9[9];
    #pragma unroll
    for (int k = 0; k < 9; k++) w9[k] = w[c * 9 + k];
    float bsv = bias[c];
    __syncthreads();
    for (int i = 0; i < 16; i++) {
        int pix = t + i * 256; int y = pix >> 6, xx = pix & 63;
        float acc = bsv;
        #pragma unroll
        for (int dy = 0; dy < 3; dy++) {
            int yy = y + dy - 1; if (yy < 0 || yy > 63) continue;
            #pragma unroll
            for (int dx = 0; dx < 3; dx++) {
                int x2 = xx + dx - 1; if (x2 < 0 || x2 > 63) continue;
                acc += w9[dy * 3 + dx] * pl[yy][x2];
            }
        }
        dst[pix] = f2bf(acc);
    }
}

// ---------------- fast gelu: A&S 7.1.26 erf ----------------
__device__ inline float gelu_fast(float x) {
    float z = x * 0.70710678118654752f;
    float a = fabsf(z);
    float t = 1.0f / (1.0f + 0.3275911f * a);
    float p = t * (0.254829592f + t * (-0.284496736f + t * (1.421413741f +
              t * (-1.453152027f + t * 1.061405429f))));
    float e = __expf(-a * a);
    float r = 1.0f - p * e;
    float erfz = copysignf(r, z);
    return 0.5f * x * (1.0f + erfz);
}

__device__ inline void block_reduce2(double& s, double& s2, double* red, int t)
{
    __syncthreads();
    red[t] = s; red[256 + t] = s2;
    __syncthreads();
    for (int st = 128; st; st >>= 1) {
        if (t < st) { red[t] += red[t + st]; red[256 + t] += red[256 + t + st]; }
        __syncthreads();
    }
    s = red[0]; s2 = red[256];
}

// ---------------- fused FF on bf16 h; bf16 out ----------------
__global__ __launch_bounds__(256) void ff_fused_kernel(
    unsigned short* __restrict__ h, const float* __restrict__ w, const float* __restrict__ bias)
{
    __shared__ __align__(16) float pl[64][64];
    __shared__ double red[512];
    int plane = blockIdx.x;
    int c = plane & (NFF - 1);
    size_t base = (size_t)plane * NP;
    int t = threadIdx.x;
    float v[16]; double s = 0.0, s2 = 0.0;
    for (int i = 0; i < 16; i++) {
        float x = bf2f(h[base + t + i * 256]);
        v[i] = x; s += x; s2 += (double)x * x;
    }
    block_reduce2(s, s2, red, t);
    double mean = s * (1.0 / NP);
    double var = s2 * (1.0 / NP) - mean * mean;
    float rs = (float)(1.0 / sqrt(var + (double)CEPS));
    float mf = (float)mean;
    for (int i = 0; i < 16; i++) {
        float gx = gelu_fast((v[i] - mf) * rs);
        v[i] = gx;
        int pix = t + i * 256;
        pl[pix >> 6][pix & 63] = gx;
    }
    __syncthreads();
    float w9[9];
    #pragma unroll
    for (int k = 0; k < 9; k++) w9[k] = w[c * 9 + k];
    float bsv = bias[c];
    float tv[16]; s = 0.0; s2 = 0.0;
    for (int i = 0; i < 16; i++) {
        int pix = t + i * 256; int y = pix >> 6, xx = pix & 63;
        float acc = bsv;
        #pragma unroll
        for (int dy = 0; dy < 3; dy++) {
            int yy = y + dy - 1; if (yy < 0 || yy > 63) continue;
            #pragma unroll
            for (int dx = 0; dx < 3; dx++) {
                int x2 = xx + dx - 1; if (x2 < 0 || x2 > 63) continue;
                acc += w9[dy * 3 + dx] * pl[yy][x2];
            }
        }
        tv[i] = acc; s += acc; s2 += (double)acc * acc;
    }
    block_reduce2(s, s2, red, t);
    double mean2 = s * (1.0 / NP);
    double var2 = s2 * (1.0 / NP) - mean2 * mean2;
    float rs2 = (float)(1.0 / sqrt(var2 + (double)CEPS));
    float mf2 = (float)mean2;
    for (int i = 0; i < 16; i++) {
        int pix = t + i * 256;
        float o = v[i] + gelu_fast((tv[i] - mf2) * rs2);
        h[base + pix] = f2bf(o);
    }
}

// ---------------- final instance norm in place on d_out ----------------
__global__ __launch_bounds__(256) void in_final_kernel(float* __restrict__ y)
{
    __shared__ double red[512];
    size_t base = (size_t)blockIdx.x * NP;
    int t = threadIdx.x;
    float v[16]; double s = 0.0, s2 = 0.0;
    for (int i = 0; i < 16; i++) { float x = y[base + t + i * 256]; v[i] = x; s += x; s2 += (double)x * x; }
    block_reduce2(s, s2, red, t);
    double mean = s * (1.0 / NP);
    double var = s2 * (1.0 / NP) - mean * mean;
    float rs = (float)(1.0 / sqrt(var + (double)CEPS));
    float mf = (float)mean;
    for (int i = 0; i < 16; i++)
        y[base + t + i * 256] = (v[i] - mf) * rs;
}

extern "C" void kernel_launch(void* const* d_in, const int* in_sizes, int n_in,
                              void* d_out, int out_size, void* d_ws, size_t ws_size,
                              hipStream_t stream)
{
    const float* x      = (const float*)d_in[0];
    const float* g      = (const float*)d_in[1];
    const float* bc     = (const float*)d_in[2];
    const float* w_qkv  = (const float*)d_in[3];
    const float* w_out  = (const float*)d_in[4];
    const float* b_out  = (const float*)d_in[5];
    const float* w_dw   = (const float*)d_in[6];
    const float* b_dw   = (const float*)d_in[7];
    const float* w_comb = (const float*)d_in[8];
    const float* b_comb = (const float*)d_in[9];
    const float* w_ff1  = (const float*)d_in[10];
    const float* b_ff1  = (const float*)d_in[11];
    const float* w_ffdw = (const float*)d_in[12];
    const float* b_ffdw = (const float*)d_in[13];
    const float* w_ff2  = (const float*)d_in[14];
    const float* b_ff2  = (const float*)d_in[15];
    float* out = (float*)d_out;
    float* ws  = (float*)d_ws;

    const size_t S = (size_t)NB * NC * NP;   // 16,777,216 floats (64 MiB)
    // Memory plan (ws = 4S exactly):
    //   d_out      : pw_qkv (until step 2); Fbuf bf16 attn_out (step 9-10); final output (12+)
    //   ws[0,S)    : smalls [0,1048576); cln stats [1052672..); ctxu bf16 [2M,10M) floats
    //                (step 6-9); pwF+bF [0,131329) (7-9); all dead by step 10
    //   ws[S,4S)   : qkv fp32 (dead after attn); convu bf16 at ws+S (step 8-9)
    //   ws[0,2S)   : h1 bf16 (step 10+), in-place ff_fused (11), read by ff2 (12)
    float* qkv   = ws + S;
    unsigned short* h1u   = (unsigned short*)ws;
    unsigned short* ctxu  = (unsigned short*)(ws + 2097152);   // 32 MiB, [2M,10M) floats
    unsigned short* convu = (unsigned short*)(ws + S);         // 32 MiB in dead qkv space
    unsigned short* Fbufu = (unsigned short*)out;
    float* qrow    = ws;                       // 262144
    float* kheight = qrow + 262144;            // 262144
    float* kselb   = kheight + 262144;         // 262144
    float* vselb   = kselb + 262144;           // ends at 1048576
    float* rs_a    = ws + 1052672;             // 65536
    float* mrs_a   = rs_a + 65536;             // 65536
    float* Aab     = mrs_a + 65536;            // 768
    float* Bab     = Aab + 768;                // 768
    unsigned* pw_qkv = (unsigned*)out;         // 196608 u32 (free until step 9)
    unsigned* pwF    = (unsigned*)ws;          // 131072 u32 (dead smalls, after attn)
    float*    bF     = ws + 131072;            // 256 floats

    size_t need = 4 * S * sizeof(float);
    if (ws_size < need) {
        float val = 1024.0f + (float)(ws_size >> 20);
        diag_fill<<<(out_size + 255) / 256, 256, 0, stream>>>(out, val, out_size);
        return;
    }

    // 0. prepack W_qkv*diag(g); cln stats; fold constants
    pack_wg_kernel<<<768, 256, 0, stream>>>(w_qkv, g, pw_qkv, 768 * 256);
    cln_stats_kernel<<<1024, 256, 0, stream>>>(x, rs_a, mrs_a);
    ab_kernel<<<3, 256, 0, stream>>>(w_qkv, g, bc, Aab, Bab);
    // 2. qkv = fold( (W_qkv g) * x ) with fused l2norm + qrow/kheight
    gemm_mfma<false, true, true, false, false><<<dim3(16, 6, NB), 512, 0, stream>>>(
        x, 256, 256, nullptr, 0, 256, (const float*)pw_qkv, nullptr, nullptr, qkv, 768, 768,
        rs_a, mrs_a, Aab, Bab, qrow, kheight);
    // 5-6. select (qprobe folded); attention -> compact bf16 ctx
    select_kernel<<<NBH, 64, 0, stream>>>(qkv, qrow, kheight, kselb, vselb);
    attn_kernel<<<dim3(16, NBH), 256, 0, stream>>>(qkv, kselb, vselb, ctxu);
    // 7. fused comb weight -> packed, into dead smalls
    fuse_comb_kernel<<<512, 256, 0, stream>>>(w_comb, w_out, b_out, b_comb, pwF, bF);
    // 8. conv branch -> compact bf16 (dead qkv space)
    dwconv_kernel<<<NB * NC, 256, 0, stream>>>(x, w_dw, b_dw, convu, NC);
    // 9. attn_out = W_fused * [ctx; conv] (bf16 B, 2-MFMA) + b_fused + x -> bf16 d_out
    gemm_mfma<false, true, false, true, true><<<dim3(16, 2, NB), 512, 0, stream>>>(
        (const float*)ctxu, 256, 256, (const float*)convu, 256, 512,
        (const float*)pwF, bF, x, (float*)Fbufu, 256, 256,
        nullptr, nullptr, nullptr, nullptr, nullptr, nullptr);
    // 10. h1 = W_ff1 * attn_out (bf16 B, 2-MFMA) + b_ff1 -> bf16 ws[0,2S)
    gemm_mfma<false, false, false, true, true><<<dim3(16, 8, NB), 512, 0, stream>>>(
        (const float*)Fbufu, 256, 256, nullptr, 0, 256, w_ff1, b_ff1, nullptr, (float*)h1u,
        1024, 1024, nullptr, nullptr, nullptr, nullptr, nullptr, nullptr);
    // 11. fused FF on bf16 h1 (in place)
    ff_fused_kernel<<<NB * NFF, 256, 0, stream>>>(h1u, w_ffdw, b_ffdw);
    // 12. y = W_ff2 * h1 (bf16 B, 2-MFMA) + b_ff2 -> d_out fp32
    gemm_mfma<false, false, false, false, true><<<dim3(16, 2, NB), 512, 0, stream>>>(
        (const float*)h1u, 1024, 1024, nullptr, 0, 1024, w_ff2, b_ff2, nullptr, out, 256, 256,
        nullptr, nullptr, nullptr, nullptr, nullptr, nullptr);
    // 13. final instance norm
    in_final_kernel<<<NB * NC, 256, 0, stream>>>(out);
}

// Round 18
// 795.227 us; speedup vs baseline: 1.5093x; 1.1764x over previous
//
#include <hip/hip_runtime.h>
#include <math.h>

#define NB 16
#define NC 256
#define NP 4096      // 64*64
#define NHEADS 8
#define NDH 32
#define NBH 128
#define NFF 1024
#define CEPS 1e-5f

typedef short s16x8 __attribute__((ext_vector_type(8)));
typedef float f32x4 __attribute__((ext_vector_type(4)));

// ---------------- diagnostic fill (guard trip) ----------------
__global__ __launch_bounds__(256) void diag_fill(float* __restrict__ out, float val, int n)
{
    int i = blockIdx.x * 256 + threadIdx.x;
    if (i < n) out[i] = val;
}

// ---------------- bf16 split helpers ----------------
__device__ inline unsigned short f2bf(float f) {
    unsigned u = __float_as_uint(f);
    return (unsigned short)((u + 0x7FFFu + ((u >> 16) & 1u)) >> 16);
}
__device__ inline float bf2f(unsigned short h) { return __uint_as_float(((unsigned)h) << 16); }
__device__ inline void split2(float f, unsigned short& hi, unsigned short& lo) {
    hi = f2bf(f);
    lo = f2bf(f - bf2f(hi));
}
// fast round-to-nearest split (6 ops)
__device__ inline void split_rn(float f, unsigned short& hi, unsigned short& lo) {
    unsigned u = __float_as_uint(f);
    unsigned tt = u + 0x8000u;
    hi = (unsigned short)(tt >> 16);
    float r = f - __uint_as_float(tt & 0xffff0000u);
    lo = (unsigned short)((__float_as_uint(r) + 0x8000u) >> 16);
}
// packed: (hi<<16)|lo
__device__ inline unsigned pack_hl(float f) {
    unsigned short h, lo; split2(f, h, lo);
    return ((unsigned)h << 16) | (unsigned)lo;
}
__device__ inline float packf(float f) { return __uint_as_float(pack_hl(f)); }

// ---------------- weight prepack with channel gain: pw = pack(w[o,c]*g[c]) ----------
__global__ __launch_bounds__(256) void pack_wg_kernel(
    const float* __restrict__ w, const float* __restrict__ g,
    unsigned* __restrict__ pw, int n)
{
    int i = blockIdx.x * 256 + threadIdx.x;
    if (i < n) pw[i] = pack_hl(w[i] * g[i & 255]);
}

// ---------------- cln stats: per (b,p) mean/rsqrt over 256 channels ----------------
__global__ __launch_bounds__(256) void cln_stats_kernel(
    const float* __restrict__ x, float* __restrict__ rs, float* __restrict__ mrs)
{
    __shared__ double red[512];
    int t = threadIdx.x;
    int i = t & 63, q = t >> 6;
    int col = blockIdx.x * 64 + i;
    int b = col >> 12, p = col & 4095;
    const float* src = x + (size_t)b * NC * NP + (size_t)(q * 64) * NP + p;
    double s = 0.0, s2 = 0.0;
    #pragma unroll 8
    for (int c = 0; c < 64; c++) { float v = src[(size_t)c * NP]; s += v; s2 += (double)v * v; }
    red[q * 64 + i] = s; red[256 + q * 64 + i] = s2;
    __syncthreads();
    if (q == 0) {
        double S  = red[i] + red[64 + i] + red[128 + i] + red[192 + i];
        double S2 = red[256 + i] + red[320 + i] + red[384 + i] + red[448 + i];
        double mean = S * (1.0 / 256.0);
        double var = S2 * (1.0 / 256.0) - mean * mean;
        double r = 1.0 / sqrt(var + (double)CEPS);
        rs[col]  = (float)r;
        mrs[col] = (float)(mean * r);
    }
}

// ---------------- A/B fold constants ----------------
__global__ __launch_bounds__(256) void ab_kernel(
    const float* __restrict__ wq, const float* __restrict__ g, const float* __restrict__ bc,
    float* __restrict__ Aab, float* __restrict__ Bab)
{
    int o = blockIdx.x * 256 + threadIdx.x;
    if (o >= 768) return;
    double a = 0.0, bsum = 0.0;
    for (int c = 0; c < 256; c++) {
        double w = wq[o * 256 + c];
        a += w * (double)g[c];
        bsum += w * (double)bc[c];
    }
    Aab[o] = (float)a; Bab[o] = (float)bsum;
}

// ---------------- fused comb weight: W_fused = [W_comb_L @ W_out | W_comb_R] ----------
__global__ __launch_bounds__(256) void fuse_comb_kernel(
    const float* __restrict__ w_comb, const float* __restrict__ w_out,
    const float* __restrict__ b_out, const float* __restrict__ b_comb,
    unsigned* __restrict__ pwF, float* __restrict__ bF)
{
    int idx = blockIdx.x * 256 + threadIdx.x;   // 131072
    int o = idx >> 9, cc = idx & 511;
    float val;
    if (cc < 256) {
        double s = 0.0;
        for (int k = 0; k < 256; k++)
            s += (double)w_comb[o * 512 + k] * (double)w_out[k * 256 + cc];
        val = (float)s;
    } else {
        val = w_comb[o * 512 + cc];
    }
    pwF[idx] = pack_hl(val);
    if (idx < 256) {
        double s = 0.0;
        for (int k = 0; k < 256; k++)
            s += (double)w_comb[idx * 512 + k] * (double)b_out[k];
        bF[idx] = (float)(s + (double)b_comb[idx]);
    }
}

// ---------------- split-bf16 MFMA GEMM: 128o x 128p tile, 8 waves (32x64/wave) --------
// acc[2][4] = 32 AGPR/thread -> 2-3 blocks/CU resident (vs 1 before).
// B-input: CLN ? raw fp32 (split in-stage) : BBF16 ? bf16 planes (C1-split) : packed u32.
// A: PACKA ? packed u32 : raw fp32. OBF16: bf16 output.
template<bool PACKO, bool PACKA, bool CLN, bool OBF16, bool BBF16>
__global__ __launch_bounds__(512) void gemm_mfma(
    const float* __restrict__ inA, int sA, int C1,
    const float* __restrict__ inB, int sB, int Ctot,
    const float* __restrict__ Wt, const float* __restrict__ bias,
    const float* __restrict__ resid, float* __restrict__ out, int sO, int O,
    const float* __restrict__ rs, const float* __restrict__ mrs,
    const float* __restrict__ Aab, const float* __restrict__ Bab,
    float* __restrict__ qrow, float* __restrict__ kheight)
{
    __shared__ __align__(16) unsigned short Ah[128 * 32], Al[128 * 32];
    __shared__ __align__(16) unsigned short Bh[128 * 32];
    __shared__ __align__(16) unsigned short Bl[BBF16 ? 16 : 128 * 32];
    char* cAh = (char*)Ah; char* cAl = (char*)Al;
    char* cBh = (char*)Bh; char* cBl = (char*)Bl;

    // ---- XCD-batch swizzle ----
    const unsigned npb = gridDim.x * gridDim.y;
    unsigned lin = blockIdx.x + gridDim.x * (blockIdx.y + gridDim.y * blockIdx.z);
    unsigned low = lin & 7u, rest = lin >> 3;
    unsigned high = (rest >= npb) ? 1u : 0u;
    unsigned idx = rest - high * npb;
    const int b = (int)(low + 8u * high);
    const int o0 = (int)(idx / gridDim.x) * 128, p0 = (int)(idx % gridDim.x) * 128;

    const int t = threadIdx.x;
    const int l = t & 63, w = t >> 6;
    const int wr = w & 3, wc = w >> 2;       // wave tile: o strip wr*32, p strip wc*64
    const int g = l >> 4, l15 = l & 15;
    const int slotl = (l & 3) ^ ((l >> 2) & 3);

    f32x4 acc[2][4];
    #pragma unroll
    for (int m = 0; m < 2; m++)
        #pragma unroll
        for (int n = 0; n < 4; n++) acc[m][n] = (f32x4){0.f, 0.f, 0.f, 0.f};

    // A staging: 128 rows x 32 k, 8 elems/thread
    const int arow = t >> 2;
    const int ak8 = (t & 3) * 8;
    const int aslot = (arow & 3) ^ ((arow >> 2) & 3);
    const int aoff = arow * 64 + ((((ak8 >> 3)) ^ aslot) << 4);
    // B staging: 128 p x 32 k, 8 elems/thread (4 k-pairs, one 16B window)
    const int bp = t & 127;
    const int bhk = t >> 7;                  // 0..3: k window bhk*8..+8
    const int bslot = (bp & 3) ^ ((bp >> 2) & 3);
    const int boffst = bp * 64 + ((bhk ^ bslot) << 4);

    uint4 wa0, wa1;          // A prefetch
    unsigned pb[8];          // B prefetch (split: 8 u32; bf16: 4 u32 used)

    #define LOAD_TILE(K0)                                                                 \
    {                                                                                     \
        const unsigned* wsrc = (const unsigned*)Wt + (size_t)(o0 + arow) * Ctot + (K0) + ak8; \
        wa0 = *(const uint4*)(wsrc);                                                      \
        wa1 = *(const uint4*)(wsrc + 4);                                                  \
        _Pragma("unroll")                                                                 \
        for (int q = 0; q < 4; q++) {                                                     \
            int c2 = bhk * 8 + q * 2;                                                     \
            int cc = (K0) + c2;                                                           \
            if constexpr (BBF16) {                                                        \
                const unsigned short* s16 = (cc < C1)                                     \
                    ? (const unsigned short*)inA + ((size_t)b * sA + cc) * (size_t)NP + p0 + bp \
                    : (const unsigned short*)inB + ((size_t)b * sB + (cc - C1)) * (size_t)NP + p0 + bp; \
                unsigned short v0 = s16[0];                                               \
                unsigned short v1 = s16[NP];                                              \
                pb[q] = (unsigned)v0 | ((unsigned)v1 << 16);                              \
            } else {                                                                      \
                const float* srcp = (cc < C1) ? inA + ((size_t)b * sA + cc) * (size_t)NP  \
                                              : inB + ((size_t)b * sB + (cc - C1)) * (size_t)NP; \
                pb[2 * q]     = __float_as_uint(srcp[p0 + bp]);                           \
                pb[2 * q + 1] = __float_as_uint(srcp[(size_t)NP + p0 + bp]);              \
            }                                                                             \
        }                                                                                 \
    }

    #define STORE_LDS()                                                                   \
    {                                                                                     \
        if constexpr (PACKA) {                                                            \
            uint4 hq, lq;                                                                 \
            hq.x = __builtin_amdgcn_perm(wa0.y, wa0.x, 0x07060302u);                      \
            lq.x = __builtin_amdgcn_perm(wa0.y, wa0.x, 0x05040100u);                      \
            hq.y = __builtin_amdgcn_perm(wa0.w, wa0.z, 0x07060302u);                      \
            lq.y = __builtin_amdgcn_perm(wa0.w, wa0.z, 0x05040100u);                      \
            hq.z = __builtin_amdgcn_perm(wa1.y, wa1.x, 0x07060302u);                      \
            lq.z = __builtin_amdgcn_perm(wa1.y, wa1.x, 0x05040100u);                      \
            hq.w = __builtin_amdgcn_perm(wa1.w, wa1.z, 0x07060302u);                      \
            lq.w = __builtin_amdgcn_perm(wa1.w, wa1.z, 0x05040100u);                      \
            *(uint4*)(cAh + aoff) = hq;                                                   \
            *(uint4*)(cAl + aoff) = lq;                                                   \
        } else {                                                                          \
            ushort4 h0, l0, h1, l1;                                                       \
            split_rn(__uint_as_float(wa0.x), h0.x, l0.x);                                 \
            split_rn(__uint_as_float(wa0.y), h0.y, l0.y);                                 \
            split_rn(__uint_as_float(wa0.z), h0.z, l0.z);                                 \
            split_rn(__uint_as_float(wa0.w), h0.w, l0.w);                                 \
            split_rn(__uint_as_float(wa1.x), h1.x, l1.x);                                 \
            split_rn(__uint_as_float(wa1.y), h1.y, l1.y);                                 \
            split_rn(__uint_as_float(wa1.z), h1.z, l1.z);                                 \
            split_rn(__uint_as_float(wa1.w), h1.w, l1.w);                                 \
            *(ushort4*)(cAh + aoff) = h0; *(ushort4*)(cAh + aoff + 8) = h1;               \
            *(ushort4*)(cAl + aoff) = l0; *(ushort4*)(cAl + aoff + 8) = l1;               \
        }                                                                                 \
        if constexpr (BBF16) {                                                            \
            *(uint4*)(cBh + boffst) = (uint4){pb[0], pb[1], pb[2], pb[3]};                \
        } else {                                                                          \
            unsigned hp[4], lp[4];                                                        \
            _Pragma("unroll")                                                             \
            for (int q = 0; q < 4; q++) {                                                 \
                unsigned u0 = pb[2 * q], u1 = pb[2 * q + 1];                              \
                if constexpr (CLN) {                                                      \
                    unsigned short sh0, sl0, sh1, sl1;                                    \
                    split_rn(__uint_as_float(u0), sh0, sl0);                              \
                    split_rn(__uint_as_float(u1), sh1, sl1);                              \
                    hp[q] = (unsigned)sh0 | ((unsigned)sh1 << 16);                        \
                    lp[q] = (unsigned)sl0 | ((unsigned)sl1 << 16);                        \
                } else {                                                                  \
                    hp[q] = __builtin_amdgcn_perm(u1, u0, 0x07060302u);                   \
                    lp[q] = __builtin_amdgcn_perm(u1, u0, 0x05040100u);                   \
                }                                                                         \
            }                                                                             \
            *(uint4*)(cBh + boffst) = (uint4){hp[0], hp[1], hp[2], hp[3]};                \
            *(uint4*)(cBl + boffst) = (uint4){lp[0], lp[1], lp[2], lp[3]};                \
        }                                                                                 \
    }

    LOAD_TILE(0)

    for (int k0 = 0; k0 < Ctot; k0 += 32) {
        if (k0) __syncthreads();
        STORE_LDS()
        __syncthreads();
        if (k0 + 32 < Ctot) LOAD_TILE(k0 + 32)

        s16x8 ah[2], al[2];
        #pragma unroll
        for (int m = 0; m < 2; m++) {
            int ao = (wr * 32 + m * 16 + l15) * 64 + ((g ^ slotl) << 4);
            ah[m] = *(const s16x8*)(cAh + ao);
            al[m] = *(const s16x8*)(cAl + ao);
        }
        #pragma unroll
        for (int n = 0; n < 4; n++) {
            int bo = (wc * 64 + n * 16 + l15) * 64 + ((g ^ slotl) << 4);
            s16x8 bh = *(const s16x8*)(cBh + bo);
            if constexpr (BBF16) {
                #pragma unroll
                for (int m = 0; m < 2; m++) {
                    acc[m][n] = __builtin_amdgcn_mfma_f32_16x16x32_bf16(ah[m], bh, acc[m][n], 0, 0, 0);
                    acc[m][n] = __builtin_amdgcn_mfma_f32_16x16x32_bf16(al[m], bh, acc[m][n], 0, 0, 0);
                }
            } else {
                s16x8 bl = *(const s16x8*)(cBl + bo);
                #pragma unroll
                for (int m = 0; m < 2; m++) {
                    acc[m][n] = __builtin_amdgcn_mfma_f32_16x16x32_bf16(ah[m], bh, acc[m][n], 0, 0, 0);
                    acc[m][n] = __builtin_amdgcn_mfma_f32_16x16x32_bf16(ah[m], bl, acc[m][n], 0, 0, 0);
                    acc[m][n] = __builtin_amdgcn_mfma_f32_16x16x32_bf16(al[m], bh, acc[m][n], 0, 0, 0);
                }
            }
        }
    }
    #undef LOAD_TILE
    #undef STORE_LDS

    // ---- epilogue: D[row=(l>>4)*4+r][col=l&15] ----
    #pragma unroll
    for (int m = 0; m < 2; m++) {
        #pragma unroll
        for (int r = 0; r < 4; r++) {
            int orow = o0 + wr * 32 + m * 16 + g * 4 + r;
            float bs = (!CLN && bias) ? bias[orow] : 0.f;
            float Ao = CLN ? Aab[orow] : 0.f;
            float Bo = CLN ? Bab[orow] : 0.f;
            if constexpr (CLN) {
                float vv[4];
                #pragma unroll
                for (int n = 0; n < 4; n++) {
                    int pcol = p0 + wc * 64 + n * 16 + l15;
                    size_t cidx = (size_t)b * NP + pcol;
                    vv[n] = rs[cidx] * acc[m][n][r] - mrs[cidx] * Ao + Bo;
                }
                int which = orow >> 8;           // 0=q, 1=k, 2=v
                if (which < 2) {
                    float ss = vv[0] * vv[0] + vv[1] * vv[1] + vv[2] * vv[2] + vv[3] * vv[3];
                    ss += __shfl_xor(ss, 1); ss += __shfl_xor(ss, 2);
                    ss += __shfl_xor(ss, 4); ss += __shfl_xor(ss, 8);
                    float inv = 1.f / fmaxf(sqrtf(ss), 1e-12f);
                    float as = 0.f;
                    #pragma unroll
                    for (int n = 0; n < 4; n++) { vv[n] *= inv; as += fabsf(vv[n]); }
                    as += __shfl_xor(as, 1); as += __shfl_xor(as, 2);
                    as += __shfl_xor(as, 4); as += __shfl_xor(as, 8);
                    if (l15 == 0) {
                        int idx2 = orow & 255;
                        int head = idx2 >> 5, c = idx2 & 31;
                        int h = (p0 >> 6) + wc;
                        int rr = ((b << 3) + head) * 2048 + c * 64 + h;
                        (which == 0 ? qrow : kheight)[rr] = as;
                    }
                }
                #pragma unroll
                for (int n = 0; n < 4; n++) {
                    int pcol = p0 + wc * 64 + n * 16 + l15;
                    out[((size_t)b * sO + orow) * (size_t)NP + pcol] = vv[n];
                }
            } else {
                #pragma unroll
                for (int n = 0; n < 4; n++) {
                    int pcol = p0 + wc * 64 + n * 16 + l15;
                    float v = acc[m][n][r] + bs;
                    if (resid) v += resid[((size_t)b * O + orow) * (size_t)NP + pcol];
                    size_t oidx = ((size_t)b * sO + orow) * (size_t)NP + pcol;
                    if constexpr (OBF16)
                        ((unsigned short*)out)[oidx] = f2bf(v);
                    else
                        out[oidx] = PACKO ? packf(v) : v;
                }
            }
        }
    }
}

// ---------------- scores + top-k rows/cols + gather k/v (qprobe folded in) ----------
__global__ __launch_bounds__(64) void select_kernel(
    const float* __restrict__ qkv, const float* __restrict__ qrow,
    const float* __restrict__ kheight,
    float* __restrict__ ksel, float* __restrict__ vsel)
{
    const int bh = blockIdx.x;
    const int b = bh >> 3, head = bh & 7;
    const int lane = threadIdx.x;
    __shared__ int hs[8], wsl[8];
    __shared__ float qp[32];
    if (lane < 32) {
        double s = 0.0;
        const float* qr = qrow + (size_t)bh * 2048 + lane * 64;
        for (int h = 0; h < 64; h++) s += qr[h];
        qp[lane] = (float)s;
    }
    __syncthreads();
    double scd = 0.0;
    for (int c = 0; c < 32; c++) scd += (double)qp[c] * kheight[((size_t)bh * 32 + c) * 64 + lane];
    float sc = (float)scd;
    for (int it = 0; it < 8; it++) {
        float v = sc; int id = lane;
        for (int off = 32; off; off >>= 1) {
            float ov = __shfl_xor(v, off); int oi = __shfl_xor(id, off);
            if (ov > v || (ov == v && oi < id)) { v = ov; id = oi; }
        }
        if (lane == 0) hs[it] = id;
        if (lane == id) sc = -3.4e38f;
    }
    __syncthreads();
    const float* kbase = qkv + ((size_t)b * 768 + 256 + head * 32) * NP;
    double sc2d = 0.0;
    for (int c = 0; c < 32; c++) {
        float kw = 0.f;
        for (int hi = 0; hi < 8; hi++)
            kw += fabsf(kbase[(size_t)c * NP + hs[hi] * 64 + lane]);
        sc2d += (double)qp[c] * kw;
    }
    float sc2 = (float)sc2d;
    for (int it = 0; it < 8; it++) {
        float v = sc2; int id = lane;
        for (int off = 32; off; off >>= 1) {
            float ov = __shfl_xor(v, off); int oi = __shfl_xor(id, off);
            if (ov > v || (ov == v && oi < id)) { v = ov; id = oi; }
        }
        if (lane == 0) wsl[it] = id;
        if (lane == id) sc2 = -3.4e38f;
    }
    __syncthreads();
    const float* vbase = qkv + ((size_t)b * 768 + 512 + head * 32) * NP;
    int hi = lane >> 3, wi = lane & 7;
    int hh = hs[hi], ww = wsl[wi];
    for (int d = 0; d < 32; d++) {
        ksel[((size_t)bh * 64 + lane) * 32 + d] = kbase[(size_t)d * NP + hh * 64 + ww];
        vsel[((size_t)bh * 64 + lane) * 32 + d] = vbase[(size_t)d * NP + hh * 64 + ww];
    }
}

// ---------------- attention: writes compact bf16 ctx [b][256][NP] ----------------
__global__ __launch_bounds__(256) void attn_kernel(
    const float* __restrict__ qkv, const float* __restrict__ ksel, const float* __restrict__ vsel,
    unsigned short* __restrict__ ctxu)
{
    __shared__ __align__(16) float ks[64][32];
    __shared__ __align__(16) float vs[64][32];
    int bh = blockIdx.y, b = bh >> 3, head = bh & 7;
    int t = threadIdx.x;
    const float* kb = ksel + (size_t)bh * 2048;
    const float* vb = vsel + (size_t)bh * 2048;
    for (int i = 0; i < 8; i++) {
        ((float*)ks)[t + i * 256] = kb[t + i * 256];
        ((float*)vs)[t + i * 256] = vb[t + i * 256];
    }
    __syncthreads();
    int p = blockIdx.x * 256 + t;
    const float* qb = qkv + ((size_t)b * 768 + head * 32) * NP + p;
    unsigned short* ob = ctxu + ((size_t)b * 256 + head * 32) * NP + p;
    float q[32];
    #pragma unroll
    for (int d = 0; d < 32; d++) q[d] = qb[(size_t)d * NP];
    float s[64], m = -3.4e38f;
    for (int j = 0; j < 64; j++) {
        float dot = 0.f;
        #pragma unroll
        for (int d = 0; d < 32; d++) dot += q[d] * ks[j][d];
        s[j] = dot; m = fmaxf(m, dot);
    }
    float den = 0.f;
    for (int j = 0; j < 64; j++) { float e = expf(s[j] - m); s[j] = e; den += e; }
    float o[32] = {};
    for (int j = 0; j < 64; j++) {
        float a = s[j];
        #pragma unroll
        for (int d = 0; d < 32; d++) o[d] += a * vs[j][d];
    }
    float r = 1.f / den;
    #pragma unroll
    for (int d = 0; d < 32; d++) ob[(size_t)d * NP] = f2bf(o[d] * r);
}

// ---------------- depthwise 3x3 on x; compact bf16 output [b][256][NP] ----------------
__global__ __launch_bounds__(256) void dwconv_kernel(
    const float* __restrict__ in, const float* __restrict__ w, const float* __restrict__ bias,
    unsigned short* __restrict__ out, int Cn)
{
    __shared__ __align__(16) float pl[64][64];
    int bcb = blockIdx.x;
    int c = bcb % Cn;
    const float* src = in + (size_t)bcb * NP;
    unsigned short* dst = out + (size_t)bcb * NP;
    int t = threadIdx.x;
    for (int i = 0; i < 16; i++) { int pix = t + i * 256; pl[pix >> 6][pix & 63] = src[pix]; }
    float w9[9];
    #pragma unroll
    for (int k = 0; k < 9; k++) w9[k] = w[c * 9 + k];
    float bsv = bias[c];
    __syncthreads();
    for (int i = 0; i < 16; i++) {
        int pix = t + i * 256; int y = pix >> 6, xx = pix & 63;
        float acc = bsv;
        #pragma unroll
        for (int dy = 0; dy < 3; dy++) {
            int yy = y + dy - 1; if (yy < 0 || yy > 63) continue;
            #pragma unroll
            for (int dx = 0; dx < 3; dx++) {
                int x2 = xx + dx - 1; if (x2 < 0 || x2 > 63) continue;
                acc += w9[dy * 3 + dx] * pl[yy][x2];
            }
        }
        dst[pix] = f2bf(acc);
    }
}

// ---------------- fast gelu: A&S 7.1.26 erf ----------------
__device__ inline float gelu_fast(float x) {
    float z = x * 0.70710678118654752f;
    float a = fabsf(z);
    float t = 1.0f / (1.0f + 0.3275911f * a);
    float p = t * (0.254829592f + t * (-0.284496736f + t * (1.421413741f +
              t * (-1.453152027f + t * 1.061405429f))));
    float e = __expf(-a * a);
    float r = 1.0f - p * e;
    float erfz = copysignf(r, z);
    return 0.5f * x * (1.0f + erfz);
}

__device__ inline void block_reduce2(double& s, double& s2, double* red, int t)
{
    __syncthreads();
    red[t] = s; red[256 + t] = s2;
    __syncthreads();
    for (int st = 128; st; st >>= 1) {
        if (t < st) { red[t] += red[t + st]; red[256 + t] += red[256 + t + st]; }
        __syncthreads();
    }
    s = red[0]; s2 = red[256];
}

// ---------------- fused FF on bf16 h; bf16 out ----------------
__global__ __launch_bounds__(256) void ff_fused_kernel(
    unsigned short* __restrict__ h, const float* __restrict__ w, const float* __restrict__ bias)
{
    __shared__ __align__(16) float pl[64][64];
    __shared__ double red[512];
    int plane = blockIdx.x;
    int c = plane & (NFF - 1);
    size_t base = (size_t)plane * NP;
    int t = threadIdx.x;
    float v[16]; double s = 0.0, s2 = 0.0;
    for (int i = 0; i < 16; i++) {
        float x = bf2f(h[base + t + i * 256]);
        v[i] = x; s += x; s2 += (double)x * x;
    }
    block_reduce2(s, s2, red, t);
    double mean = s * (1.0 / NP);
    double var = s2 * (1.0 / NP) - mean * mean;
    float rs = (float)(1.0 / sqrt(var + (double)CEPS));
    float mf = (float)mean;
    for (int i = 0; i < 16; i++) {
        float gx = gelu_fast((v[i] - mf) * rs);
        v[i] = gx;
        int pix = t + i * 256;
        pl[pix >> 6][pix & 63] = gx;
    }
    __syncthreads();
    float w9[9];
    #pragma unroll
    for (int k = 0; k < 9; k++) w9[k] = w[c * 9 + k];
    float bsv = bias[c];
    float tv[16]; s = 0.0; s2 = 0.0;
    for (int i = 0; i < 16; i++) {
        int pix = t + i * 256; int y = pix >> 6, xx = pix & 63;
        float acc = bsv;
        #pragma unroll
        for (int dy = 0; dy < 3; dy++) {
            int yy = y + dy - 1; if (yy < 0 || yy > 63) continue;
            #pragma unroll
            for (int dx = 0; dx < 3; dx++) {
                int x2 = xx + dx - 1; if (x2 < 0 || x2 > 63) continue;
                acc += w9[dy * 3 + dx] * pl[yy][x2];
            }
        }
        tv[i] = acc; s += acc; s2 += (double)acc * acc;
    }
    block_reduce2(s, s2, red, t);
    double mean2 = s * (1.0 / NP);
    double var2 = s2 * (1.0 / NP) - mean2 * mean2;
    float rs2 = (float)(1.0 / sqrt(var2 + (double)CEPS));
    float mf2 = (float)mean2;
    for (int i = 0; i < 16; i++) {
        int pix = t + i * 256;
        float o = v[i] + gelu_fast((tv[i] - mf2) * rs2);
        h[base + pix] = f2bf(o);
    }
}

// ---------------- final instance norm in place on d_out ----------------
__global__ __launch_bounds__(256) void in_final_kernel(float* __restrict__ y)
{
    __shared__ double red[512];
    size_t base = (size_t)blockIdx.x * NP;
    int t = threadIdx.x;
    float v[16]; double s = 0.0, s2 = 0.0;
    for (int i = 0; i < 16; i++) { float x = y[base + t + i * 256]; v[i] = x; s += x; s2 += (double)x * x; }
    block_reduce2(s, s2, red, t);
    double mean = s * (1.0 / NP);
    double var = s2 * (1.0 / NP) - mean * mean;
    float rs = (float)(1.0 / sqrt(var + (double)CEPS));
    float mf = (float)mean;
    for (int i = 0; i < 16; i++)
        y[base + t + i * 256] = (v[i] - mf) * rs;
}

extern "C" void kernel_launch(void* const* d_in, const int* in_sizes, int n_in,
                              void* d_out, int out_size, void* d_ws, size_t ws_size,
                              hipStream_t stream)
{
    const float* x      = (const float*)d_in[0];
    const float* g      = (const float*)d_in[1];
    const float* bc     = (const float*)d_in[2];
    const float* w_qkv  = (const float*)d_in[3];
    const float* w_out  = (const float*)d_in[4];
    const float* b_out  = (const float*)d_in[5];
    const float* w_dw   = (const float*)d_in[6];
    const float* b_dw   = (const float*)d_in[7];
    const float* w_comb = (const float*)d_in[8];
    const float* b_comb = (const float*)d_in[9];
    const float* w_ff1  = (const float*)d_in[10];
    const float* b_ff1  = (const float*)d_in[11];
    const float* w_ffdw = (const float*)d_in[12];
    const float* b_ffdw = (const float*)d_in[13];
    const float* w_ff2  = (const float*)d_in[14];
    const float* b_ff2  = (const float*)d_in[15];
    float* out = (float*)d_out;
    float* ws  = (float*)d_ws;

    const size_t S = (size_t)NB * NC * NP;   // 16,777,216 floats (64 MiB)
    // Memory plan (ws = 4S exactly):
    //   d_out      : pw_qkv (until step 2); Fbuf bf16 attn_out (9-10); final output (12+)
    //   ws[0,S)    : smalls [0,1048576); cln stats [1052672..); ctxu bf16 [2M,10M) floats;
    //                pwF+bF [0,131329) (7-9); all dead by step 10
    //   ws[S,4S)   : qkv fp32 (dead after attn); convu bf16 at ws+S (8-9)
    //   ws[0,2S)   : h1 bf16 (10+), in-place ff_fused (11), read by ff2 (12)
    float* qkv   = ws + S;
    unsigned short* h1u   = (unsigned short*)ws;
    unsigned short* ctxu  = (unsigned short*)(ws + 2097152);   // [2M,10M) floats
    unsigned short* convu = (unsigned short*)(ws + S);
    unsigned short* Fbufu = (unsigned short*)out;
    float* qrow    = ws;                       // 262144
    float* kheight = qrow + 262144;            // 262144
    float* kselb   = kheight + 262144;         // 262144
    float* vselb   = kselb + 262144;           // ends at 1048576
    float* rs_a    = ws + 1052672;             // 65536
    float* mrs_a   = rs_a + 65536;             // 65536
    float* Aab     = mrs_a + 65536;            // 768
    float* Bab     = Aab + 768;                // 768
    unsigned* pw_qkv = (unsigned*)out;         // 196608 u32 (free until step 9)
    unsigned* pwF    = (unsigned*)ws;          // 131072 u32 (dead smalls, after attn)
    float*    bF     = ws + 131072;            // 256 floats

    size_t need = 4 * S * sizeof(float);
    if (ws_size < need) {
        float val = 1024.0f + (float)(ws_size >> 20);
        diag_fill<<<(out_size + 255) / 256, 256, 0, stream>>>(out, val, out_size);
        return;
    }

    // 0. prepack W_qkv*diag(g); cln stats; fold constants
    pack_wg_kernel<<<768, 256, 0, stream>>>(w_qkv, g, pw_qkv, 768 * 256);
    cln_stats_kernel<<<1024, 256, 0, stream>>>(x, rs_a, mrs_a);
    ab_kernel<<<3, 256, 0, stream>>>(w_qkv, g, bc, Aab, Bab);
    // 2. qkv = fold( (W_qkv g) * x ) with fused l2norm + qrow/kheight
    gemm_mfma<false, true, true, false, false><<<dim3(32, 6, NB), 512, 0, stream>>>(
        x, 256, 256, nullptr, 0, 256, (const float*)pw_qkv, nullptr, nullptr, qkv, 768, 768,
        rs_a, mrs_a, Aab, Bab, qrow, kheight);
    // 5-6. select (qprobe folded); attention -> compact bf16 ctx
    select_kernel<<<NBH, 64, 0, stream>>>(qkv, qrow, kheight, kselb, vselb);
    attn_kernel<<<dim3(16, NBH), 256, 0, stream>>>(qkv, kselb, vselb, ctxu);
    // 7. fused comb weight -> packed, into dead smalls
    fuse_comb_kernel<<<512, 256, 0, stream>>>(w_comb, w_out, b_out, b_comb, pwF, bF);
    // 8. conv branch -> compact bf16 (dead qkv space)
    dwconv_kernel<<<NB * NC, 256, 0, stream>>>(x, w_dw, b_dw, convu, NC);
    // 9. attn_out = W_fused * [ctx; conv] (bf16 B, 2-MFMA) + b_fused + x -> bf16 d_out
    gemm_mfma<false, true, false, true, true><<<dim3(32, 2, NB), 512, 0, stream>>>(
        (const float*)ctxu, 256, 256, (const float*)convu, 256, 512,
        (const float*)pwF, bF, x, (float*)Fbufu, 256, 256,
        nullptr, nullptr, nullptr, nullptr, nullptr, nullptr);
    // 10. h1 = W_ff1 * attn_out (bf16 B, 2-MFMA) + b_ff1 -> bf16 ws[0,2S)
    gemm_mfma<false, false, false, true, true><<<dim3(32, 8, NB), 512, 0, stream>>>(
        (const float*)Fbufu, 256, 256, nullptr, 0, 256, w_ff1, b_ff1, nullptr, (float*)h1u,
        1024, 1024, nullptr, nullptr, nullptr, nullptr, nullptr, nullptr);
    // 11. fused FF on bf16 h1 (in place)
    ff_fused_kernel<<<NB * NFF, 256, 0, stream>>>(h1u, w_ffdw, b_ffdw);
    // 12. y = W_ff2 * h1 (bf16 B, 2-MFMA) + b_ff2 -> d_out fp32
    gemm_mfma<false, false, false, false, true><<<dim3(32, 2, NB), 512, 0, stream>>>(
        (const float*)h1u, 1024, 1024, nullptr, 0, 1024, w_ff2, b_ff2, nullptr, out, 256, 256,
        nullptr, nullptr, nullptr, nullptr, nullptr, nullptr);
    // 13. final instance norm
    in_final_kernel<<<NB * NC, 256, 0, stream>>>(out);
}

// Round 19
// 783.769 us; speedup vs baseline: 1.5313x; 1.0146x over previous
//
#include <hip/hip_runtime.h>
#include <math.h>

#define NB 16
#define NC 256
#define NP 4096      // 64*64
#define NHEADS 8
#define NDH 32
#define NBH 128
#define NFF 1024
#define CEPS 1e-5f

typedef short s16x8 __attribute__((ext_vector_type(8)));
typedef float f32x4 __attribute__((ext_vector_type(4)));

// ---------------- diagnostic fill (guard trip) ----------------
__global__ __launch_bounds__(256) void diag_fill(float* __restrict__ out, float val, int n)
{
    int i = blockIdx.x * 256 + threadIdx.x;
    if (i < n) out[i] = val;
}

// ---------------- bf16 split helpers ----------------
__device__ inline unsigned short f2bf(float f) {
    unsigned u = __float_as_uint(f);
    return (unsigned short)((u + 0x7FFFu + ((u >> 16) & 1u)) >> 16);
}
__device__ inline float bf2f(unsigned short h) { return __uint_as_float(((unsigned)h) << 16); }
__device__ inline void split2(float f, unsigned short& hi, unsigned short& lo) {
    hi = f2bf(f);
    lo = f2bf(f - bf2f(hi));
}
// fast round-to-nearest split (6 ops)
__device__ inline void split_rn(float f, unsigned short& hi, unsigned short& lo) {
    unsigned u = __float_as_uint(f);
    unsigned tt = u + 0x8000u;
    hi = (unsigned short)(tt >> 16);
    float r = f - __uint_as_float(tt & 0xffff0000u);
    lo = (unsigned short)((__float_as_uint(r) + 0x8000u) >> 16);
}
// packed: (hi<<16)|lo
__device__ inline unsigned pack_hl(float f) {
    unsigned short h, lo; split2(f, h, lo);
    return ((unsigned)h << 16) | (unsigned)lo;
}
__device__ inline float packf(float f) { return __uint_as_float(pack_hl(f)); }

// ---------------- weight prepack with channel gain: pw = pack(w[o,c]*g[c]) ----------
__global__ __launch_bounds__(256) void pack_wg_kernel(
    const float* __restrict__ w, const float* __restrict__ g,
    unsigned* __restrict__ pw, int n)
{
    int i = blockIdx.x * 256 + threadIdx.x;
    if (i < n) pw[i] = pack_hl(w[i] * g[i & 255]);
}

// ---------------- cln stats: per (b,p) mean/rsqrt over 256 channels ----------------
__global__ __launch_bounds__(256) void cln_stats_kernel(
    const float* __restrict__ x, float* __restrict__ rs, float* __restrict__ mrs)
{
    __shared__ double red[512];
    int t = threadIdx.x;
    int i = t & 63, q = t >> 6;
    int col = blockIdx.x * 64 + i;
    int b = col >> 12, p = col & 4095;
    const float* src = x + (size_t)b * NC * NP + (size_t)(q * 64) * NP + p;
    double s = 0.0, s2 = 0.0;
    #pragma unroll 8
    for (int c = 0; c < 64; c++) { float v = src[(size_t)c * NP]; s += v; s2 += (double)v * v; }
    red[q * 64 + i] = s; red[256 + q * 64 + i] = s2;
    __syncthreads();
    if (q == 0) {
        double S  = red[i] + red[64 + i] + red[128 + i] + red[192 + i];
        double S2 = red[256 + i] + red[320 + i] + red[384 + i] + red[448 + i];
        double mean = S * (1.0 / 256.0);
        double var = S2 * (1.0 / 256.0) - mean * mean;
        double r = 1.0 / sqrt(var + (double)CEPS);
        rs[col]  = (float)r;
        mrs[col] = (float)(mean * r);
    }
}

// ---------------- A/B fold constants ----------------
__global__ __launch_bounds__(256) void ab_kernel(
    const float* __restrict__ wq, const float* __restrict__ g, const float* __restrict__ bc,
    float* __restrict__ Aab, float* __restrict__ Bab)
{
    int o = blockIdx.x * 256 + threadIdx.x;
    if (o >= 768) return;
    double a = 0.0, bsum = 0.0;
    for (int c = 0; c < 256; c++) {
        double w = wq[o * 256 + c];
        a += w * (double)g[c];
        bsum += w * (double)bc[c];
    }
    Aab[o] = (float)a; Bab[o] = (float)bsum;
}

// ---------------- fused comb weight: W_fused = [W_comb_L @ W_out | W_comb_R] ----------
__global__ __launch_bounds__(256) void fuse_comb_kernel(
    const float* __restrict__ w_comb, const float* __restrict__ w_out,
    const float* __restrict__ b_out, const float* __restrict__ b_comb,
    unsigned* __restrict__ pwF, float* __restrict__ bF)
{
    int idx = blockIdx.x * 256 + threadIdx.x;   // 131072
    int o = idx >> 9, cc = idx & 511;
    float val;
    if (cc < 256) {
        double s = 0.0;
        for (int k = 0; k < 256; k++)
            s += (double)w_comb[o * 512 + k] * (double)w_out[k * 256 + cc];
        val = (float)s;
    } else {
        val = w_comb[o * 512 + cc];
    }
    pwF[idx] = pack_hl(val);
    if (idx < 256) {
        double s = 0.0;
        for (int k = 0; k < 256; k++)
            s += (double)w_comb[idx * 512 + k] * (double)b_out[k];
        bF[idx] = (float)(s + (double)b_comb[idx]);
    }
}

// ---------------- split-bf16 MFMA GEMM: 128o x 128p tile, 8 waves (32x64/wave) --------
template<bool PACKO, bool PACKA, bool CLN, bool OBF16, bool BBF16>
__global__ __launch_bounds__(512) void gemm_mfma(
    const float* __restrict__ inA, int sA, int C1,
    const float* __restrict__ inB, int sB, int Ctot,
    const float* __restrict__ Wt, const float* __restrict__ bias,
    const float* __restrict__ resid, float* __restrict__ out, int sO, int O,
    const float* __restrict__ rs, const float* __restrict__ mrs,
    const float* __restrict__ Aab, const float* __restrict__ Bab,
    float* __restrict__ qrow, float* __restrict__ kheight)
{
    __shared__ __align__(16) unsigned short Ah[128 * 32], Al[128 * 32];
    __shared__ __align__(16) unsigned short Bh[128 * 32];
    __shared__ __align__(16) unsigned short Bl[BBF16 ? 16 : 128 * 32];
    char* cAh = (char*)Ah; char* cAl = (char*)Al;
    char* cBh = (char*)Bh; char* cBl = (char*)Bl;

    // ---- XCD-batch swizzle ----
    const unsigned npb = gridDim.x * gridDim.y;
    unsigned lin = blockIdx.x + gridDim.x * (blockIdx.y + gridDim.y * blockIdx.z);
    unsigned low = lin & 7u, rest = lin >> 3;
    unsigned high = (rest >= npb) ? 1u : 0u;
    unsigned idx = rest - high * npb;
    const int b = (int)(low + 8u * high);
    const int o0 = (int)(idx / gridDim.x) * 128, p0 = (int)(idx % gridDim.x) * 128;

    const int t = threadIdx.x;
    const int l = t & 63, w = t >> 6;
    const int wr = w & 3, wc = w >> 2;
    const int g = l >> 4, l15 = l & 15;
    const int slotl = (l & 3) ^ ((l >> 2) & 3);

    f32x4 acc[2][4];
    #pragma unroll
    for (int m = 0; m < 2; m++)
        #pragma unroll
        for (int n = 0; n < 4; n++) acc[m][n] = (f32x4){0.f, 0.f, 0.f, 0.f};

    const int arow = t >> 2;
    const int ak8 = (t & 3) * 8;
    const int aslot = (arow & 3) ^ ((arow >> 2) & 3);
    const int aoff = arow * 64 + ((((ak8 >> 3)) ^ aslot) << 4);
    const int bp = t & 127;
    const int bhk = t >> 7;
    const int bslot = (bp & 3) ^ ((bp >> 2) & 3);
    const int boffst = bp * 64 + ((bhk ^ bslot) << 4);

    uint4 wa0, wa1;
    unsigned pb[8];

    #define LOAD_TILE(K0)                                                                 \
    {                                                                                     \
        const unsigned* wsrc = (const unsigned*)Wt + (size_t)(o0 + arow) * Ctot + (K0) + ak8; \
        wa0 = *(const uint4*)(wsrc);                                                      \
        wa1 = *(const uint4*)(wsrc + 4);                                                  \
        _Pragma("unroll")                                                                 \
        for (int q = 0; q < 4; q++) {                                                     \
            int c2 = bhk * 8 + q * 2;                                                     \
            int cc = (K0) + c2;                                                           \
            if constexpr (BBF16) {                                                        \
                const unsigned short* s16 = (cc < C1)                                     \
                    ? (const unsigned short*)inA + ((size_t)b * sA + cc) * (size_t)NP + p0 + bp \
                    : (const unsigned short*)inB + ((size_t)b * sB + (cc - C1)) * (size_t)NP + p0 + bp; \
                unsigned short v0 = s16[0];                                               \
                unsigned short v1 = s16[NP];                                              \
                pb[q] = (unsigned)v0 | ((unsigned)v1 << 16);                              \
            } else {                                                                      \
                const float* srcp = (cc < C1) ? inA + ((size_t)b * sA + cc) * (size_t)NP  \
                                              : inB + ((size_t)b * sB + (cc - C1)) * (size_t)NP; \
                pb[2 * q]     = __float_as_uint(srcp[p0 + bp]);                           \
                pb[2 * q + 1] = __float_as_uint(srcp[(size_t)NP + p0 + bp]);              \
            }                                                                             \
        }                                                                                 \
    }

    #define STORE_LDS()                                                                   \
    {                                                                                     \
        if constexpr (PACKA) {                                                            \
            uint4 hq, lq;                                                                 \
            hq.x = __builtin_amdgcn_perm(wa0.y, wa0.x, 0x07060302u);                      \
            lq.x = __builtin_amdgcn_perm(wa0.y, wa0.x, 0x05040100u);                      \
            hq.y = __builtin_amdgcn_perm(wa0.w, wa0.z, 0x07060302u);                      \
            lq.y = __builtin_amdgcn_perm(wa0.w, wa0.z, 0x05040100u);                      \
            hq.z = __builtin_amdgcn_perm(wa1.y, wa1.x, 0x07060302u);                      \
            lq.z = __builtin_amdgcn_perm(wa1.y, wa1.x, 0x05040100u);                      \
            hq.w = __builtin_amdgcn_perm(wa1.w, wa1.z, 0x07060302u);                      \
            lq.w = __builtin_amdgcn_perm(wa1.w, wa1.z, 0x05040100u);                      \
            *(uint4*)(cAh + aoff) = hq;                                                   \
            *(uint4*)(cAl + aoff) = lq;                                                   \
        } else {                                                                          \
            ushort4 h0, l0, h1, l1;                                                       \
            split_rn(__uint_as_float(wa0.x), h0.x, l0.x);                                 \
            split_rn(__uint_as_float(wa0.y), h0.y, l0.y);                                 \
            split_rn(__uint_as_float(wa0.z), h0.z, l0.z);                                 \
            split_rn(__uint_as_float(wa0.w), h0.w, l0.w);                                 \
            split_rn(__uint_as_float(wa1.x), h1.x, l1.x);                                 \
            split_rn(__uint_as_float(wa1.y), h1.y, l1.y);                                 \
            split_rn(__uint_as_float(wa1.z), h1.z, l1.z);                                 \
            split_rn(__uint_as_float(wa1.w), h1.w, l1.w);                                 \
            *(ushort4*)(cAh + aoff) = h0; *(ushort4*)(cAh + aoff + 8) = h1;               \
            *(ushort4*)(cAl + aoff) = l0; *(ushort4*)(cAl + aoff + 8) = l1;               \
        }                                                                                 \
        if constexpr (BBF16) {                                                            \
            *(uint4*)(cBh + boffst) = (uint4){pb[0], pb[1], pb[2], pb[3]};                \
        } else {                                                                          \
            unsigned hp[4], lp[4];                                                        \
            _Pragma("unroll")                                                             \
            for (int q = 0; q < 4; q++) {                                                 \
                unsigned u0 = pb[2 * q], u1 = pb[2 * q + 1];                              \
                if constexpr (CLN) {                                                      \
                    unsigned short sh0, sl0, sh1, sl1;                                    \
                    split_rn(__uint_as_float(u0), sh0, sl0);                              \
                    split_rn(__uint_as_float(u1), sh1, sl1);                              \
                    hp[q] = (unsigned)sh0 | ((unsigned)sh1 << 16);                        \
                    lp[q] = (unsigned)sl0 | ((unsigned)sl1 << 16);                        \
                } else {                                                                  \
                    hp[q] = __builtin_amdgcn_perm(u1, u0, 0x07060302u);                   \
                    lp[q] = __builtin_amdgcn_perm(u1, u0, 0x05040100u);                   \
                }                                                                         \
            }                                                                             \
            *(uint4*)(cBh + boffst) = (uint4){hp[0], hp[1], hp[2], hp[3]};                \
            *(uint4*)(cBl + boffst) = (uint4){lp[0], lp[1], lp[2], lp[3]};                \
        }                                                                                 \
    }

    LOAD_TILE(0)

    for (int k0 = 0; k0 < Ctot; k0 += 32) {
        if (k0) __syncthreads();
        STORE_LDS()
        __syncthreads();
        if (k0 + 32 < Ctot) LOAD_TILE(k0 + 32)

        s16x8 ah[2], al[2];
        #pragma unroll
        for (int m = 0; m < 2; m++) {
            int ao = (wr * 32 + m * 16 + l15) * 64 + ((g ^ slotl) << 4);
            ah[m] = *(const s16x8*)(cAh + ao);
            al[m] = *(const s16x8*)(cAl + ao);
        }
        #pragma unroll
        for (int n = 0; n < 4; n++) {
            int bo = (wc * 64 + n * 16 + l15) * 64 + ((g ^ slotl) << 4);
            s16x8 bh = *(const s16x8*)(cBh + bo);
            if constexpr (BBF16) {
                #pragma unroll
                for (int m = 0; m < 2; m++) {
                    acc[m][n] = __builtin_amdgcn_mfma_f32_16x16x32_bf16(ah[m], bh, acc[m][n], 0, 0, 0);
                    acc[m][n] = __builtin_amdgcn_mfma_f32_16x16x32_bf16(al[m], bh, acc[m][n], 0, 0, 0);
                }
            } else {
                s16x8 bl = *(const s16x8*)(cBl + bo);
                #pragma unroll
                for (int m = 0; m < 2; m++) {
                    acc[m][n] = __builtin_amdgcn_mfma_f32_16x16x32_bf16(ah[m], bh, acc[m][n], 0, 0, 0);
                    acc[m][n] = __builtin_amdgcn_mfma_f32_16x16x32_bf16(ah[m], bl, acc[m][n], 0, 0, 0);
                    acc[m][n] = __builtin_amdgcn_mfma_f32_16x16x32_bf16(al[m], bh, acc[m][n], 0, 0, 0);
                }
            }
        }
    }
    #undef LOAD_TILE
    #undef STORE_LDS

    // ---- epilogue: D[row=(l>>4)*4+r][col=l&15] ----
    #pragma unroll
    for (int m = 0; m < 2; m++) {
        #pragma unroll
        for (int r = 0; r < 4; r++) {
            int orow = o0 + wr * 32 + m * 16 + g * 4 + r;
            float bs = (!CLN && bias) ? bias[orow] : 0.f;
            float Ao = CLN ? Aab[orow] : 0.f;
            float Bo = CLN ? Bab[orow] : 0.f;
            if constexpr (CLN) {
                float vv[4];
                #pragma unroll
                for (int n = 0; n < 4; n++) {
                    int pcol = p0 + wc * 64 + n * 16 + l15;
                    size_t cidx = (size_t)b * NP + pcol;
                    vv[n] = rs[cidx] * acc[m][n][r] - mrs[cidx] * Ao + Bo;
                }
                int which = orow >> 8;
                if (which < 2) {
                    float ss = vv[0] * vv[0] + vv[1] * vv[1] + vv[2] * vv[2] + vv[3] * vv[3];
                    ss += __shfl_xor(ss, 1); ss += __shfl_xor(ss, 2);
                    ss += __shfl_xor(ss, 4); ss += __shfl_xor(ss, 8);
                    float inv = 1.f / fmaxf(sqrtf(ss), 1e-12f);
                    float as = 0.f;
                    #pragma unroll
                    for (int n = 0; n < 4; n++) { vv[n] *= inv; as += fabsf(vv[n]); }
                    as += __shfl_xor(as, 1); as += __shfl_xor(as, 2);
                    as += __shfl_xor(as, 4); as += __shfl_xor(as, 8);
                    if (l15 == 0) {
                        int idx2 = orow & 255;
                        int head = idx2 >> 5, c = idx2 & 31;
                        int h = (p0 >> 6) + wc;
                        int rr = ((b << 3) + head) * 2048 + c * 64 + h;
                        (which == 0 ? qrow : kheight)[rr] = as;
                    }
                }
                #pragma unroll
                for (int n = 0; n < 4; n++) {
                    int pcol = p0 + wc * 64 + n * 16 + l15;
                    out[((size_t)b * sO + orow) * (size_t)NP + pcol] = vv[n];
                }
            } else {
                #pragma unroll
                for (int n = 0; n < 4; n++) {
                    int pcol = p0 + wc * 64 + n * 16 + l15;
                    float v = acc[m][n][r] + bs;
                    if (resid) v += resid[((size_t)b * O + orow) * (size_t)NP + pcol];
                    size_t oidx = ((size_t)b * sO + orow) * (size_t)NP + pcol;
                    if constexpr (OBF16)
                        ((unsigned short*)out)[oidx] = f2bf(v);
                    else
                        out[oidx] = PACKO ? packf(v) : v;
                }
            }
        }
    }
}

// ---------------- scores + top-k rows/cols + gather k/v (qprobe folded in) ----------
__global__ __launch_bounds__(64) void select_kernel(
    const float* __restrict__ qkv, const float* __restrict__ qrow,
    const float* __restrict__ kheight,
    float* __restrict__ ksel, float* __restrict__ vsel)
{
    const int bh = blockIdx.x;
    const int b = bh >> 3, head = bh & 7;
    const int lane = threadIdx.x;
    __shared__ int hs[8], wsl[8];
    __shared__ float qp[32];
    if (lane < 32) {
        double s = 0.0;
        const float* qr = qrow + (size_t)bh * 2048 + lane * 64;
        for (int h = 0; h < 64; h++) s += qr[h];
        qp[lane] = (float)s;
    }
    __syncthreads();
    double scd = 0.0;
    for (int c = 0; c < 32; c++) scd += (double)qp[c] * kheight[((size_t)bh * 32 + c) * 64 + lane];
    float sc = (float)scd;
    for (int it = 0; it < 8; it++) {
        float v = sc; int id = lane;
        for (int off = 32; off; off >>= 1) {
            float ov = __shfl_xor(v, off); int oi = __shfl_xor(id, off);
            if (ov > v || (ov == v && oi < id)) { v = ov; id = oi; }
        }
        if (lane == 0) hs[it] = id;
        if (lane == id) sc = -3.4e38f;
    }
    __syncthreads();
    const float* kbase = qkv + ((size_t)b * 768 + 256 + head * 32) * NP;
    double sc2d = 0.0;
    for (int c = 0; c < 32; c++) {
        float kw = 0.f;
        for (int hi = 0; hi < 8; hi++)
            kw += fabsf(kbase[(size_t)c * NP + hs[hi] * 64 + lane]);
        sc2d += (double)qp[c] * kw;
    }
    float sc2 = (float)sc2d;
    for (int it = 0; it < 8; it++) {
        float v = sc2; int id = lane;
        for (int off = 32; off; off >>= 1) {
            float ov = __shfl_xor(v, off); int oi = __shfl_xor(id, off);
            if (ov > v || (ov == v && oi < id)) { v = ov; id = oi; }
        }
        if (lane == 0) wsl[it] = id;
        if (lane == id) sc2 = -3.4e38f;
    }
    __syncthreads();
    const float* vbase = qkv + ((size_t)b * 768 + 512 + head * 32) * NP;
    int hi = lane >> 3, wi = lane & 7;
    int hh = hs[hi], ww = wsl[wi];
    for (int d = 0; d < 32; d++) {
        ksel[((size_t)bh * 64 + lane) * 32 + d] = kbase[(size_t)d * NP + hh * 64 + ww];
        vsel[((size_t)bh * 64 + lane) * 32 + d] = vbase[(size_t)d * NP + hh * 64 + ww];
    }
}

// ---------------- attention: writes compact bf16 ctx [b][256][NP] ----------------
__global__ __launch_bounds__(256) void attn_kernel(
    const float* __restrict__ qkv, const float* __restrict__ ksel, const float* __restrict__ vsel,
    unsigned short* __restrict__ ctxu)
{
    __shared__ __align__(16) float ks[64][32];
    __shared__ __align__(16) float vs[64][32];
    int bh = blockIdx.y, b = bh >> 3, head = bh & 7;
    int t = threadIdx.x;
    const float* kb = ksel + (size_t)bh * 2048;
    const float* vb = vsel + (size_t)bh * 2048;
    for (int i = 0; i < 8; i++) {
        ((float*)ks)[t + i * 256] = kb[t + i * 256];
        ((float*)vs)[t + i * 256] = vb[t + i * 256];
    }
    __syncthreads();
    int p = blockIdx.x * 256 + t;
    const float* qb = qkv + ((size_t)b * 768 + head * 32) * NP + p;
    unsigned short* ob = ctxu + ((size_t)b * 256 + head * 32) * NP + p;
    float q[32];
    #pragma unroll
    for (int d = 0; d < 32; d++) q[d] = qb[(size_t)d * NP];
    float s[64], m = -3.4e38f;
    for (int j = 0; j < 64; j++) {
        float dot = 0.f;
        #pragma unroll
        for (int d = 0; d < 32; d++) dot += q[d] * ks[j][d];
        s[j] = dot; m = fmaxf(m, dot);
    }
    float den = 0.f;
    for (int j = 0; j < 64; j++) { float e = expf(s[j] - m); s[j] = e; den += e; }
    float o[32] = {};
    for (int j = 0; j < 64; j++) {
        float a = s[j];
        #pragma unroll
        for (int d = 0; d < 32; d++) o[d] += a * vs[j][d];
    }
    float r = 1.f / den;
    #pragma unroll
    for (int d = 0; d < 32; d++) ob[(size_t)d * NP] = f2bf(o[d] * r);
}

// ---------------- depthwise 3x3 on x; padded LDS, branch-free; bf16 pair output -------
__global__ __launch_bounds__(256) void dwconv_kernel(
    const float* __restrict__ in, const float* __restrict__ w, const float* __restrict__ bias,
    unsigned short* __restrict__ out, int Cn)
{
    __shared__ __align__(16) float pl[66][66];
    int bcb = blockIdx.x;
    int c = bcb % Cn;
    const float2* src2 = (const float2*)(in + (size_t)bcb * NP);
    unsigned* dst2 = (unsigned*)(out + (size_t)bcb * NP);
    int t = threadIdx.x;
    if (t < 66) { pl[0][t] = 0.f; pl[65][t] = 0.f; }
    if (t >= 66 && t < 130) { int rr = t - 65; pl[rr][0] = 0.f; pl[rr][65] = 0.f; }
    float w9[9];
    #pragma unroll
    for (int k = 0; k < 9; k++) w9[k] = w[c * 9 + k];
    float bsv = bias[c];
    #pragma unroll
    for (int i = 0; i < 8; i++) {
        float2 f = src2[i * 256 + t];
        int pix = i * 512 + 2 * t;
        int y = pix >> 6, xx = pix & 63;
        pl[y + 1][xx + 1] = f.x;
        pl[y + 1][xx + 2] = f.y;
    }
    __syncthreads();
    float vv[16];
    #pragma unroll
    for (int j = 0; j < 16; j++) {
        int pix = (j >> 1) * 512 + 2 * t + (j & 1);
        int y = pix >> 6, xx = pix & 63;
        float acc = bsv;
        #pragma unroll
        for (int dy = 0; dy < 3; dy++)
            #pragma unroll
            for (int dx = 0; dx < 3; dx++)
                acc += w9[dy * 3 + dx] * pl[y + dy][xx + dx];
        vv[j] = acc;
    }
    #pragma unroll
    for (int i = 0; i < 8; i++) {
        unsigned u = (unsigned)f2bf(vv[2 * i]) | ((unsigned)f2bf(vv[2 * i + 1]) << 16);
        dst2[i * 256 + t] = u;
    }
}

// ---------------- fast gelu: A&S 7.1.26 erf ----------------
__device__ inline float gelu_fast(float x) {
    float z = x * 0.70710678118654752f;
    float a = fabsf(z);
    float t = 1.0f / (1.0f + 0.3275911f * a);
    float p = t * (0.254829592f + t * (-0.284496736f + t * (1.421413741f +
              t * (-1.453152027f + t * 1.061405429f))));
    float e = __expf(-a * a);
    float r = 1.0f - p * e;
    float erfz = copysignf(r, z);
    return 0.5f * x * (1.0f + erfz);
}

// single-value fp32-partial -> fp64 tree block reduction (256 threads)
__device__ inline double block_reduce1(float s, double* red, int t)
{
    __syncthreads();
    red[t] = (double)s;
    __syncthreads();
    for (int st = 128; st; st >>= 1) {
        if (t < st) red[t] += red[t + st];
        __syncthreads();
    }
    return red[0];
}

// ---------------- fused FF on bf16 h; centered fp32 stats; padded conv; pair IO -------
__global__ __launch_bounds__(256) void ff_fused_kernel(
    unsigned short* __restrict__ h, const float* __restrict__ w, const float* __restrict__ bias)
{
    __shared__ __align__(16) float pl[66][66];
    __shared__ double red[256];
    int plane = blockIdx.x;
    int c = plane & (NFF - 1);
    const unsigned* h2 = (const unsigned*)(h + (size_t)plane * NP);
    unsigned* h2w = (unsigned*)(h + (size_t)plane * NP);
    int t = threadIdx.x;
    if (t < 66) { pl[0][t] = 0.f; pl[65][t] = 0.f; }
    if (t >= 66 && t < 130) { int rr = t - 65; pl[rr][0] = 0.f; pl[rr][65] = 0.f; }

    float v[16]; float sf = 0.f;
    #pragma unroll
    for (int i = 0; i < 8; i++) {
        unsigned u = h2[i * 256 + t];
        float x0 = bf2f((unsigned short)(u & 0xffffu));
        float x1 = bf2f((unsigned short)(u >> 16));
        v[2 * i] = x0; v[2 * i + 1] = x1;
        sf += x0 + x1;
    }
    double S = block_reduce1(sf, red, t);
    float mf = (float)(S * (1.0 / NP));
    float s2f = 0.f;
    #pragma unroll
    for (int j = 0; j < 16; j++) { float d = v[j] - mf; v[j] = d; s2f += d * d; }
    double S2 = block_reduce1(s2f, red, t);
    float rs = (float)(1.0 / sqrt(S2 * (1.0 / NP) + (double)CEPS));

    float w9[9];
    #pragma unroll
    for (int k = 0; k < 9; k++) w9[k] = w[c * 9 + k];
    float bsv = bias[c];

    #pragma unroll
    for (int j = 0; j < 16; j++) {
        int pix = (j >> 1) * 512 + 2 * t + (j & 1);
        float gx = gelu_fast(v[j] * rs);
        v[j] = gx;
        pl[(pix >> 6) + 1][(pix & 63) + 1] = gx;
    }
    __syncthreads();

    float tv[16]; float sg = 0.f;
    #pragma unroll
    for (int j = 0; j < 16; j++) {
        int pix = (j >> 1) * 512 + 2 * t + (j & 1);
        int y = pix >> 6, xx = pix & 63;
        float acc = bsv;
        #pragma unroll
        for (int dy = 0; dy < 3; dy++)
            #pragma unroll
            for (int dx = 0; dx < 3; dx++)
                acc += w9[dy * 3 + dx] * pl[y + dy][xx + dx];
        tv[j] = acc; sg += acc;
    }
    double Sb = block_reduce1(sg, red, t);
    float mf2 = (float)(Sb * (1.0 / NP));
    float s2g = 0.f;
    #pragma unroll
    for (int j = 0; j < 16; j++) { float d = tv[j] - mf2; tv[j] = d; s2g += d * d; }
    double S2b = block_reduce1(s2g, red, t);
    float rs2 = (float)(1.0 / sqrt(S2b * (1.0 / NP) + (double)CEPS));

    #pragma unroll
    for (int i = 0; i < 8; i++) {
        float o0 = v[2 * i]     + gelu_fast(tv[2 * i] * rs2);
        float o1 = v[2 * i + 1] + gelu_fast(tv[2 * i + 1] * rs2);
        unsigned u = (unsigned)f2bf(o0) | ((unsigned)f2bf(o1) << 16);
        h2w[i * 256 + t] = u;
    }
}

// ---------------- final instance norm in place on d_out (centered fp32 stats) ---------
__global__ __launch_bounds__(256) void in_final_kernel(float* __restrict__ y)
{
    __shared__ double red[256];
    size_t base = (size_t)blockIdx.x * NP;
    int t = threadIdx.x;
    float v[16]; float sf = 0.f;
    #pragma unroll
    for (int i = 0; i < 16; i++) { float x = y[base + t + i * 256]; v[i] = x; sf += x; }
    double S = block_reduce1(sf, red, t);
    float mf = (float)(S * (1.0 / NP));
    float s2f = 0.f;
    #pragma unroll
    for (int i = 0; i < 16; i++) { float d = v[i] - mf; v[i] = d; s2f += d * d; }
    double S2 = block_reduce1(s2f, red, t);
    float rs = (float)(1.0 / sqrt(S2 * (1.0 / NP) + (double)CEPS));
    #pragma unroll
    for (int i = 0; i < 16; i++)
        y[base + t + i * 256] = v[i] * rs;
}

extern "C" void kernel_launch(void* const* d_in, const int* in_sizes, int n_in,
                              void* d_out, int out_size, void* d_ws, size_t ws_size,
                              hipStream_t stream)
{
    const float* x      = (const float*)d_in[0];
    const float* g      = (const float*)d_in[1];
    const float* bc     = (const float*)d_in[2];
    const float* w_qkv  = (const float*)d_in[3];
    const float* w_out  = (const float*)d_in[4];
    const float* b_out  = (const float*)d_in[5];
    const float* w_dw   = (const float*)d_in[6];
    const float* b_dw   = (const float*)d_in[7];
    const float* w_comb = (const float*)d_in[8];
    const float* b_comb = (const float*)d_in[9];
    const float* w_ff1  = (const float*)d_in[10];
    const float* b_ff1  = (const float*)d_in[11];
    const float* w_ffdw = (const float*)d_in[12];
    const float* b_ffdw = (const float*)d_in[13];
    const float* w_ff2  = (const float*)d_in[14];
    const float* b_ff2  = (const float*)d_in[15];
    float* out = (float*)d_out;
    float* ws  = (float*)d_ws;

    const size_t S = (size_t)NB * NC * NP;   // 16,777,216 floats (64 MiB)
    float* qkv   = ws + S;
    unsigned short* h1u   = (unsigned short*)ws;
    unsigned short* ctxu  = (unsigned short*)(ws + 2097152);
    unsigned short* convu = (unsigned short*)(ws + S);
    unsigned short* Fbufu = (unsigned short*)out;
    float* qrow    = ws;                       // 262144
    float* kheight = qrow + 262144;            // 262144
    float* kselb   = kheight + 262144;         // 262144
    float* vselb   = kselb + 262144;           // ends at 1048576
    float* rs_a    = ws + 1052672;             // 65536
    float* mrs_a   = rs_a + 65536;             // 65536
    float* Aab     = mrs_a + 65536;            // 768
    float* Bab     = Aab + 768;                // 768
    unsigned* pw_qkv = (unsigned*)out;
    unsigned* pwF    = (unsigned*)ws;
    float*    bF     = ws + 131072;

    size_t need = 4 * S * sizeof(float);
    if (ws_size < need) {
        float val = 1024.0f + (float)(ws_size >> 20);
        diag_fill<<<(out_size + 255) / 256, 256, 0, stream>>>(out, val, out_size);
        return;
    }

    // 0. prepack W_qkv*diag(g); cln stats; fold constants
    pack_wg_kernel<<<768, 256, 0, stream>>>(w_qkv, g, pw_qkv, 768 * 256);
    cln_stats_kernel<<<1024, 256, 0, stream>>>(x, rs_a, mrs_a);
    ab_kernel<<<3, 256, 0, stream>>>(w_qkv, g, bc, Aab, Bab);
    // 2. qkv = fold( (W_qkv g) * x ) with fused l2norm + qrow/kheight
    gemm_mfma<false, true, true, false, false><<<dim3(32, 6, NB), 512, 0, stream>>>(
        x, 256, 256, nullptr, 0, 256, (const float*)pw_qkv, nullptr, nullptr, qkv, 768, 768,
        rs_a, mrs_a, Aab, Bab, qrow, kheight);
    // 5-6. select (qprobe folded); attention -> compact bf16 ctx
    select_kernel<<<NBH, 64, 0, stream>>>(qkv, qrow, kheight, kselb, vselb);
    attn_kernel<<<dim3(16, NBH), 256, 0, stream>>>(qkv, kselb, vselb, ctxu);
    // 7. fused comb weight -> packed, into dead smalls
    fuse_comb_kernel<<<512, 256, 0, stream>>>(w_comb, w_out, b_out, b_comb, pwF, bF);
    // 8. conv branch -> compact bf16 (dead qkv space)
    dwconv_kernel<<<NB * NC, 256, 0, stream>>>(x, w_dw, b_dw, convu, NC);
    // 9. attn_out = W_fused * [ctx; conv] (bf16 B, 2-MFMA) + b_fused + x -> bf16 d_out
    gemm_mfma<false, true, false, true, true><<<dim3(32, 2, NB), 512, 0, stream>>>(
        (const float*)ctxu, 256, 256, (const float*)convu, 256, 512,
        (const float*)pwF, bF, x, (float*)Fbufu, 256, 256,
        nullptr, nullptr, nullptr, nullptr, nullptr, nullptr);
    // 10. h1 = W_ff1 * attn_out (bf16 B, 2-MFMA) + b_ff1 -> bf16 ws[0,2S)
    gemm_mfma<false, false, false, true, true><<<dim3(32, 8, NB), 512, 0, stream>>>(
        (const float*)Fbufu, 256, 256, nullptr, 0, 256, w_ff1, b_ff1, nullptr, (float*)h1u,
        1024, 1024, nullptr, nullptr, nullptr, nullptr, nullptr, nullptr);
    // 11. fused FF on bf16 h1 (in place)
    ff_fused_kernel<<<NB * NFF, 256, 0, stream>>>(h1u, w_ffdw, b_ffdw);
    // 12. y = W_ff2 * h1 (bf16 B, 2-MFMA) + b_ff2 -> d_out fp32
    gemm_mfma<false, false, false, false, true><<<dim3(32, 2, NB), 512, 0, stream>>>(
        (const float*)h1u, 1024, 1024, nullptr, 0, 1024, w_ff2, b_ff2, nullptr, out, 256, 256,
        nullptr, nullptr, nullptr, nullptr, nullptr, nullptr);
    // 13. final instance norm
    in_final_kernel<<<NB * NC, 256, 0, stream>>>(out);
}

// Round 20
// 778.996 us; speedup vs baseline: 1.5407x; 1.0061x over previous
//
#include <hip/hip_runtime.h>
#include <math.h>

#define NB 16
#define NC 256
#define NP 4096      // 64*64
#define NHEADS 8
#define NDH 32
#define NBH 128
#define NFF 1024
#define CEPS 1e-5f

typedef short s16x8 __attribute__((ext_vector_type(8)));
typedef float f32x4 __attribute__((ext_vector_type(4)));

// ---------------- diagnostic fill (guard trip) ----------------
__global__ __launch_bounds__(256) void diag_fill(float* __restrict__ out, float val, int n)
{
    int i = blockIdx.x * 256 + threadIdx.x;
    if (i < n) out[i] = val;
}

// ---------------- bf16 split helpers ----------------
__device__ inline unsigned short f2bf(float f) {
    unsigned u = __float_as_uint(f);
    return (unsigned short)((u + 0x7FFFu + ((u >> 16) & 1u)) >> 16);
}
__device__ inline float bf2f(unsigned short h) { return __uint_as_float(((unsigned)h) << 16); }
__device__ inline void split2(float f, unsigned short& hi, unsigned short& lo) {
    hi = f2bf(f);
    lo = f2bf(f - bf2f(hi));
}
// fast round-to-nearest split (6 ops)
__device__ inline void split_rn(float f, unsigned short& hi, unsigned short& lo) {
    unsigned u = __float_as_uint(f);
    unsigned tt = u + 0x8000u;
    hi = (unsigned short)(tt >> 16);
    float r = f - __uint_as_float(tt & 0xffff0000u);
    lo = (unsigned short)((__float_as_uint(r) + 0x8000u) >> 16);
}
// packed: (hi<<16)|lo
__device__ inline unsigned pack_hl(float f) {
    unsigned short h, lo; split2(f, h, lo);
    return ((unsigned)h << 16) | (unsigned)lo;
}
__device__ inline float packf(float f) { return __uint_as_float(pack_hl(f)); }

// ---------------- weight prepack with channel gain: pw = pack(w[o,c]*g[c]) ----------
__global__ __launch_bounds__(256) void pack_wg_kernel(
    const float* __restrict__ w, const float* __restrict__ g,
    unsigned* __restrict__ pw, int n)
{
    int i = blockIdx.x * 256 + threadIdx.x;
    if (i < n) pw[i] = pack_hl(w[i] * g[i & 255]);
}

// ---------------- cln stats: per (b,p) mean/rsqrt over 256 channels ----------------
__global__ __launch_bounds__(256) void cln_stats_kernel(
    const float* __restrict__ x, float* __restrict__ rs, float* __restrict__ mrs)
{
    __shared__ double red[512];
    int t = threadIdx.x;
    int i = t & 63, q = t >> 6;
    int col = blockIdx.x * 64 + i;
    int b = col >> 12, p = col & 4095;
    const float* src = x + (size_t)b * NC * NP + (size_t)(q * 64) * NP + p;
    double s = 0.0, s2 = 0.0;
    #pragma unroll 8
    for (int c = 0; c < 64; c++) { float v = src[(size_t)c * NP]; s += v; s2 += (double)v * v; }
    red[q * 64 + i] = s; red[256 + q * 64 + i] = s2;
    __syncthreads();
    if (q == 0) {
        double S  = red[i] + red[64 + i] + red[128 + i] + red[192 + i];
        double S2 = red[256 + i] + red[320 + i] + red[384 + i] + red[448 + i];
        double mean = S * (1.0 / 256.0);
        double var = S2 * (1.0 / 256.0) - mean * mean;
        double r = 1.0 / sqrt(var + (double)CEPS);
        rs[col]  = (float)r;
        mrs[col] = (float)(mean * r);
    }
}

// ---------------- A/B fold constants ----------------
__global__ __launch_bounds__(256) void ab_kernel(
    const float* __restrict__ wq, const float* __restrict__ g, const float* __restrict__ bc,
    float* __restrict__ Aab, float* __restrict__ Bab)
{
    int o = blockIdx.x * 256 + threadIdx.x;
    if (o >= 768) return;
    double a = 0.0, bsum = 0.0;
    for (int c = 0; c < 256; c++) {
        double w = wq[o * 256 + c];
        a += w * (double)g[c];
        bsum += w * (double)bc[c];
    }
    Aab[o] = (float)a; Bab[o] = (float)bsum;
}

// ---------------- fused comb weight: W_fused = [W_comb_L @ W_out | W_comb_R] ----------
__global__ __launch_bounds__(256) void fuse_comb_kernel(
    const float* __restrict__ w_comb, const float* __restrict__ w_out,
    const float* __restrict__ b_out, const float* __restrict__ b_comb,
    unsigned* __restrict__ pwF, float* __restrict__ bF)
{
    int idx = blockIdx.x * 256 + threadIdx.x;   // 131072
    int o = idx >> 9, cc = idx & 511;
    float val;
    if (cc < 256) {
        double s = 0.0;
        for (int k = 0; k < 256; k++)
            s += (double)w_comb[o * 512 + k] * (double)w_out[k * 256 + cc];
        val = (float)s;
    } else {
        val = w_comb[o * 512 + cc];
    }
    pwF[idx] = pack_hl(val);
    if (idx < 256) {
        double s = 0.0;
        for (int k = 0; k < 256; k++)
            s += (double)w_comb[idx * 512 + k] * (double)b_out[k];
        bF[idx] = (float)(s + (double)b_comb[idx]);
    }
}

// ---------------- split-bf16 MFMA GEMM: 128o x 128p tile, 8 waves (32x64/wave) --------
template<bool PACKO, bool PACKA, bool CLN, bool OBF16, bool BBF16>
__global__ __launch_bounds__(512) void gemm_mfma(
    const float* __restrict__ inA, int sA, int C1,
    const float* __restrict__ inB, int sB, int Ctot,
    const float* __restrict__ Wt, const float* __restrict__ bias,
    const float* __restrict__ resid, float* __restrict__ out, int sO, int O,
    const float* __restrict__ rs, const float* __restrict__ mrs,
    const float* __restrict__ Aab, const float* __restrict__ Bab,
    float* __restrict__ qrow, float* __restrict__ kheight)
{
    __shared__ __align__(16) unsigned short Ah[128 * 32], Al[128 * 32];
    __shared__ __align__(16) unsigned short Bh[128 * 32];
    __shared__ __align__(16) unsigned short Bl[BBF16 ? 16 : 128 * 32];
    char* cAh = (char*)Ah; char* cAl = (char*)Al;
    char* cBh = (char*)Bh; char* cBl = (char*)Bl;

    // ---- XCD-batch swizzle ----
    const unsigned npb = gridDim.x * gridDim.y;
    unsigned lin = blockIdx.x + gridDim.x * (blockIdx.y + gridDim.y * blockIdx.z);
    unsigned low = lin & 7u, rest = lin >> 3;
    unsigned high = (rest >= npb) ? 1u : 0u;
    unsigned idx = rest - high * npb;
    const int b = (int)(low + 8u * high);
    const int o0 = (int)(idx / gridDim.x) * 128, p0 = (int)(idx % gridDim.x) * 128;

    const int t = threadIdx.x;
    const int l = t & 63, w = t >> 6;
    const int wr = w & 3, wc = w >> 2;
    const int g = l >> 4, l15 = l & 15;
    const int slotl = (l & 3) ^ ((l >> 2) & 3);

    f32x4 acc[2][4];
    #pragma unroll
    for (int m = 0; m < 2; m++)
        #pragma unroll
        for (int n = 0; n < 4; n++) acc[m][n] = (f32x4){0.f, 0.f, 0.f, 0.f};

    const int arow = t >> 2;
    const int ak8 = (t & 3) * 8;
    const int aslot = (arow & 3) ^ ((arow >> 2) & 3);
    const int aoff = arow * 64 + ((((ak8 >> 3)) ^ aslot) << 4);
    const int bp = t & 127;
    const int bhk = t >> 7;
    const int bslot = (bp & 3) ^ ((bp >> 2) & 3);
    const int boffst = bp * 64 + ((bhk ^ bslot) << 4);

    uint4 wa0, wa1;
    unsigned pb[8];

    #define LOAD_TILE(K0)                                                                 \
    {                                                                                     \
        const unsigned* wsrc = (const unsigned*)Wt + (size_t)(o0 + arow) * Ctot + (K0) + ak8; \
        wa0 = *(const uint4*)(wsrc);                                                      \
        wa1 = *(const uint4*)(wsrc + 4);                                                  \
        _Pragma("unroll")                                                                 \
        for (int q = 0; q < 4; q++) {                                                     \
            int c2 = bhk * 8 + q * 2;                                                     \
            int cc = (K0) + c2;                                                           \
            if constexpr (BBF16) {                                                        \
                const unsigned short* s16 = (cc < C1)                                     \
                    ? (const unsigned short*)inA + ((size_t)b * sA + cc) * (size_t)NP + p0 + bp \
                    : (const unsigned short*)inB + ((size_t)b * sB + (cc - C1)) * (size_t)NP + p0 + bp; \
                unsigned short v0 = s16[0];                                               \
                unsigned short v1 = s16[NP];                                              \
                pb[q] = (unsigned)v0 | ((unsigned)v1 << 16);                              \
            } else {                                                                      \
                const float* srcp = (cc < C1) ? inA + ((size_t)b * sA + cc) * (size_t)NP  \
                                              : inB + ((size_t)b * sB + (cc - C1)) * (size_t)NP; \
                pb[2 * q]     = __float_as_uint(srcp[p0 + bp]);                           \
                pb[2 * q + 1] = __float_as_uint(srcp[(size_t)NP + p0 + bp]);              \
            }                                                                             \
        }                                                                                 \
    }

    #define STORE_LDS()                                                                   \
    {                                                                                     \
        if constexpr (PACKA) {                                                            \
            uint4 hq, lq;                                                                 \
            hq.x = __builtin_amdgcn_perm(wa0.y, wa0.x, 0x07060302u);                      \
            lq.x = __builtin_amdgcn_perm(wa0.y, wa0.x, 0x05040100u);                      \
            hq.y = __builtin_amdgcn_perm(wa0.w, wa0.z, 0x07060302u);                      \
            lq.y = __builtin_amdgcn_perm(wa0.w, wa0.z, 0x05040100u);                      \
            hq.z = __builtin_amdgcn_perm(wa1.y, wa1.x, 0x07060302u);                      \
            lq.z = __builtin_amdgcn_perm(wa1.y, wa1.x, 0x05040100u);                      \
            hq.w = __builtin_amdgcn_perm(wa1.w, wa1.z, 0x07060302u);                      \
            lq.w = __builtin_amdgcn_perm(wa1.w, wa1.z, 0x05040100u);                      \
            *(uint4*)(cAh + aoff) = hq;                                                   \
            *(uint4*)(cAl + aoff) = lq;                                                   \
        } else {                                                                          \
            ushort4 h0, l0, h1, l1;                                                       \
            split_rn(__uint_as_float(wa0.x), h0.x, l0.x);                                 \
            split_rn(__uint_as_float(wa0.y), h0.y, l0.y);                                 \
            split_rn(__uint_as_float(wa0.z), h0.z, l0.z);                                 \
            split_rn(__uint_as_float(wa0.w), h0.w, l0.w);                                 \
            split_rn(__uint_as_float(wa1.x), h1.x, l1.x);                                 \
            split_rn(__uint_as_float(wa1.y), h1.y, l1.y);                                 \
            split_rn(__uint_as_float(wa1.z), h1.z, l1.z);                                 \
            split_rn(__uint_as_float(wa1.w), h1.w, l1.w);                                 \
            *(ushort4*)(cAh + aoff) = h0; *(ushort4*)(cAh + aoff + 8) = h1;               \
            *(ushort4*)(cAl + aoff) = l0; *(ushort4*)(cAl + aoff + 8) = l1;               \
        }                                                                                 \
        if constexpr (BBF16) {                                                            \
            *(uint4*)(cBh + boffst) = (uint4){pb[0], pb[1], pb[2], pb[3]};                \
        } else {                                                                          \
            unsigned hp[4], lp[4];                                                        \
            _Pragma("unroll")                                                             \
            for (int q = 0; q < 4; q++) {                                                 \
                unsigned u0 = pb[2 * q], u1 = pb[2 * q + 1];                              \
                if constexpr (CLN) {                                                      \
                    unsigned short sh0, sl0, sh1, sl1;                                    \
                    split_rn(__uint_as_float(u0), sh0, sl0);                              \
                    split_rn(__uint_as_float(u1), sh1, sl1);                              \
                    hp[q] = (unsigned)sh0 | ((unsigned)sh1 << 16);                        \
                    lp[q] = (unsigned)sl0 | ((unsigned)sl1 << 16);                        \
                } else {                                                                  \
                    hp[q] = __builtin_amdgcn_perm(u1, u0, 0x07060302u);                   \
                    lp[q] = __builtin_amdgcn_perm(u1, u0, 0x05040100u);                   \
                }                                                                         \
            }                                                                             \
            *(uint4*)(cBh + boffst) = (uint4){hp[0], hp[1], hp[2], hp[3]};                \
            *(uint4*)(cBl + boffst) = (uint4){lp[0], lp[1], lp[2], lp[3]};                \
        }                                                                                 \
    }

    LOAD_TILE(0)

    for (int k0 = 0; k0 < Ctot; k0 += 32) {
        if (k0) __syncthreads();
        STORE_LDS()
        __syncthreads();
        if (k0 + 32 < Ctot) LOAD_TILE(k0 + 32)

        s16x8 ah[2], al[2];
        #pragma unroll
        for (int m = 0; m < 2; m++) {
            int ao = (wr * 32 + m * 16 + l15) * 64 + ((g ^ slotl) << 4);
            ah[m] = *(const s16x8*)(cAh + ao);
            al[m] = *(const s16x8*)(cAl + ao);
        }
        #pragma unroll
        for (int n = 0; n < 4; n++) {
            int bo = (wc * 64 + n * 16 + l15) * 64 + ((g ^ slotl) << 4);
            s16x8 bh = *(const s16x8*)(cBh + bo);
            if constexpr (BBF16) {
                #pragma unroll
                for (int m = 0; m < 2; m++) {
                    acc[m][n] = __builtin_amdgcn_mfma_f32_16x16x32_bf16(ah[m], bh, acc[m][n], 0, 0, 0);
                    acc[m][n] = __builtin_amdgcn_mfma_f32_16x16x32_bf16(al[m], bh, acc[m][n], 0, 0, 0);
                }
            } else {
                s16x8 bl = *(const s16x8*)(cBl + bo);
                #pragma unroll
                for (int m = 0; m < 2; m++) {
                    acc[m][n] = __builtin_amdgcn_mfma_f32_16x16x32_bf16(ah[m], bh, acc[m][n], 0, 0, 0);
                    acc[m][n] = __builtin_amdgcn_mfma_f32_16x16x32_bf16(ah[m], bl, acc[m][n], 0, 0, 0);
                    acc[m][n] = __builtin_amdgcn_mfma_f32_16x16x32_bf16(al[m], bh, acc[m][n], 0, 0, 0);
                }
            }
        }
    }
    #undef LOAD_TILE
    #undef STORE_LDS

    // ---- epilogue: D[row=(l>>4)*4+r][col=l&15] ----
    #pragma unroll
    for (int m = 0; m < 2; m++) {
        #pragma unroll
        for (int r = 0; r < 4; r++) {
            int orow = o0 + wr * 32 + m * 16 + g * 4 + r;
            float bs = (!CLN && bias) ? bias[orow] : 0.f;
            float Ao = CLN ? Aab[orow] : 0.f;
            float Bo = CLN ? Bab[orow] : 0.f;
            if constexpr (CLN) {
                float vv[4];
                #pragma unroll
                for (int n = 0; n < 4; n++) {
                    int pcol = p0 + wc * 64 + n * 16 + l15;
                    size_t cidx = (size_t)b * NP + pcol;
                    vv[n] = rs[cidx] * acc[m][n][r] - mrs[cidx] * Ao + Bo;
                }
                int which = orow >> 8;
                if (which < 2) {
                    float ss = vv[0] * vv[0] + vv[1] * vv[1] + vv[2] * vv[2] + vv[3] * vv[3];
                    ss += __shfl_xor(ss, 1); ss += __shfl_xor(ss, 2);
                    ss += __shfl_xor(ss, 4); ss += __shfl_xor(ss, 8);
                    float inv = 1.f / fmaxf(sqrtf(ss), 1e-12f);
                    float as = 0.f;
                    #pragma unroll
                    for (int n = 0; n < 4; n++) { vv[n] *= inv; as += fabsf(vv[n]); }
                    as += __shfl_xor(as, 1); as += __shfl_xor(as, 2);
                    as += __shfl_xor(as, 4); as += __shfl_xor(as, 8);
                    if (l15 == 0) {
                        int idx2 = orow & 255;
                        int head = idx2 >> 5, c = idx2 & 31;
                        int h = (p0 >> 6) + wc;
                        int rr = ((b << 3) + head) * 2048 + c * 64 + h;
                        (which == 0 ? qrow : kheight)[rr] = as;
                    }
                }
                #pragma unroll
                for (int n = 0; n < 4; n++) {
                    int pcol = p0 + wc * 64 + n * 16 + l15;
                    out[((size_t)b * sO + orow) * (size_t)NP + pcol] = vv[n];
                }
            } else {
                #pragma unroll
                for (int n = 0; n < 4; n++) {
                    int pcol = p0 + wc * 64 + n * 16 + l15;
                    float v = acc[m][n][r] + bs;
                    if (resid) v += resid[((size_t)b * O + orow) * (size_t)NP + pcol];
                    size_t oidx = ((size_t)b * sO + orow) * (size_t)NP + pcol;
                    if constexpr (OBF16)
                        ((unsigned short*)out)[oidx] = f2bf(v);
                    else
                        out[oidx] = PACKO ? packf(v) : v;
                }
            }
        }
    }
}

// ---------------- scores + top-k rows/cols + gather k/v (qprobe folded in) ----------
__global__ __launch_bounds__(64) void select_kernel(
    const float* __restrict__ qkv, const float* __restrict__ qrow,
    const float* __restrict__ kheight,
    float* __restrict__ ksel, float* __restrict__ vsel)
{
    const int bh = blockIdx.x;
    const int b = bh >> 3, head = bh & 7;
    const int lane = threadIdx.x;
    __shared__ int hs[8], wsl[8];
    __shared__ float qp[32];
    if (lane < 32) {
        double s = 0.0;
        const float* qr = qrow + (size_t)bh * 2048 + lane * 64;
        for (int h = 0; h < 64; h++) s += qr[h];
        qp[lane] = (float)s;
    }
    __syncthreads();
    double scd = 0.0;
    for (int c = 0; c < 32; c++) scd += (double)qp[c] * kheight[((size_t)bh * 32 + c) * 64 + lane];
    float sc = (float)scd;
    for (int it = 0; it < 8; it++) {
        float v = sc; int id = lane;
        for (int off = 32; off; off >>= 1) {
            float ov = __shfl_xor(v, off); int oi = __shfl_xor(id, off);
            if (ov > v || (ov == v && oi < id)) { v = ov; id = oi; }
        }
        if (lane == 0) hs[it] = id;
        if (lane == id) sc = -3.4e38f;
    }
    __syncthreads();
    const float* kbase = qkv + ((size_t)b * 768 + 256 + head * 32) * NP;
    double sc2d = 0.0;
    for (int c = 0; c < 32; c++) {
        float kw = 0.f;
        for (int hi = 0; hi < 8; hi++)
            kw += fabsf(kbase[(size_t)c * NP + hs[hi] * 64 + lane]);
        sc2d += (double)qp[c] * kw;
    }
    float sc2 = (float)sc2d;
    for (int it = 0; it < 8; it++) {
        float v = sc2; int id = lane;
        for (int off = 32; off; off >>= 1) {
            float ov = __shfl_xor(v, off); int oi = __shfl_xor(id, off);
            if (ov > v || (ov == v && oi < id)) { v = ov; id = oi; }
        }
        if (lane == 0) wsl[it] = id;
        if (lane == id) sc2 = -3.4e38f;
    }
    __syncthreads();
    const float* vbase = qkv + ((size_t)b * 768 + 512 + head * 32) * NP;
    int hi = lane >> 3, wi = lane & 7;
    int hh = hs[hi], ww = wsl[wi];
    for (int d = 0; d < 32; d++) {
        ksel[((size_t)bh * 64 + lane) * 32 + d] = kbase[(size_t)d * NP + hh * 64 + ww];
        vsel[((size_t)bh * 64 + lane) * 32 + d] = vbase[(size_t)d * NP + hh * 64 + ww];
    }
}

// ---------------- attention: writes compact bf16 ctx [b][256][NP] ----------------
__global__ __launch_bounds__(256) void attn_kernel(
    const float* __restrict__ qkv, const float* __restrict__ ksel, const float* __restrict__ vsel,
    unsigned short* __restrict__ ctxu)
{
    __shared__ __align__(16) float ks[64][32];
    __shared__ __align__(16) float vs[64][32];
    int bh = blockIdx.y, b = bh >> 3, head = bh & 7;
    int t = threadIdx.x;
    const float* kb = ksel + (size_t)bh * 2048;
    const float* vb = vsel + (size_t)bh * 2048;
    for (int i = 0; i < 8; i++) {
        ((float*)ks)[t + i * 256] = kb[t + i * 256];
        ((float*)vs)[t + i * 256] = vb[t + i * 256];
    }
    __syncthreads();
    int p = blockIdx.x * 256 + t;
    const float* qb = qkv + ((size_t)b * 768 + head * 32) * NP + p;
    unsigned short* ob = ctxu + ((size_t)b * 256 + head * 32) * NP + p;
    float q[32];
    #pragma unroll
    for (int d = 0; d < 32; d++) q[d] = qb[(size_t)d * NP];
    float s[64], m = -3.4e38f;
    for (int j = 0; j < 64; j++) {
        float dot = 0.f;
        #pragma unroll
        for (int d = 0; d < 32; d++) dot += q[d] * ks[j][d];
        s[j] = dot; m = fmaxf(m, dot);
    }
    float den = 0.f;
    for (int j = 0; j < 64; j++) { float e = expf(s[j] - m); s[j] = e; den += e; }
    float o[32] = {};
    for (int j = 0; j < 64; j++) {
        float a = s[j];
        #pragma unroll
        for (int d = 0; d < 32; d++) o[d] += a * vs[j][d];
    }
    float r = 1.f / den;
    #pragma unroll
    for (int d = 0; d < 32; d++) ob[(size_t)d * NP] = f2bf(o[d] * r);
}

// ---------------- depthwise 3x3 on x; padded LDS (67 stride), branch-free -------------
__global__ __launch_bounds__(256) void dwconv_kernel(
    const float* __restrict__ in, const float* __restrict__ w, const float* __restrict__ bias,
    unsigned short* __restrict__ out, int Cn)
{
    __shared__ __align__(16) float pl[66][67];
    int bcb = blockIdx.x;
    int c = bcb % Cn;
    const float2* src2 = (const float2*)(in + (size_t)bcb * NP);
    unsigned* dst2 = (unsigned*)(out + (size_t)bcb * NP);
    int t = threadIdx.x;
    if (t < 66) { pl[0][t] = 0.f; pl[65][t] = 0.f; }
    if (t >= 66 && t < 130) { int rr = t - 65; pl[rr][0] = 0.f; pl[rr][65] = 0.f; }
    float w9[9];
    #pragma unroll
    for (int k = 0; k < 9; k++) w9[k] = w[c * 9 + k];
    float bsv = bias[c];
    #pragma unroll
    for (int i = 0; i < 8; i++) {
        float2 f = src2[i * 256 + t];
        int pix = i * 512 + 2 * t;
        int y = pix >> 6, xx = pix & 63;
        pl[y + 1][xx + 1] = f.x;
        pl[y + 1][xx + 2] = f.y;
    }
    __syncthreads();
    float vv[16];
    #pragma unroll
    for (int j = 0; j < 16; j++) {
        int pix = (j >> 1) * 512 + 2 * t + (j & 1);
        int y = pix >> 6, xx = pix & 63;
        float acc = bsv;
        #pragma unroll
        for (int dy = 0; dy < 3; dy++)
            #pragma unroll
            for (int dx = 0; dx < 3; dx++)
                acc += w9[dy * 3 + dx] * pl[y + dy][xx + dx];
        vv[j] = acc;
    }
    #pragma unroll
    for (int i = 0; i < 8; i++) {
        unsigned u = (unsigned)f2bf(vv[2 * i]) | ((unsigned)f2bf(vv[2 * i + 1]) << 16);
        dst2[i * 256 + t] = u;
    }
}

// ---------------- fast gelu: A&S 7.1.26 erf ----------------
__device__ inline float gelu_fast(float x) {
    float z = x * 0.70710678118654752f;
    float a = fabsf(z);
    float t = 1.0f / (1.0f + 0.3275911f * a);
    float p = t * (0.254829592f + t * (-0.284496736f + t * (1.421413741f +
              t * (-1.453152027f + t * 1.061405429f))));
    float e = __expf(-a * a);
    float r = 1.0f - p * e;
    float erfz = copysignf(r, z);
    return 0.5f * x * (1.0f + erfz);
}

// paired fp32-partial -> fp64 tree reduction (256 threads, one barrier sequence)
__device__ inline void block_reduceP(float a, float b, double* red, int t,
                                     double& A, double& B)
{
    __syncthreads();
    red[t] = (double)a; red[256 + t] = (double)b;
    __syncthreads();
    for (int st = 128; st; st >>= 1) {
        if (t < st) { red[t] += red[t + st]; red[256 + t] += red[256 + t + st]; }
        __syncthreads();
    }
    A = red[0]; B = red[256];
}

// single-value fp32-partial -> fp64 tree block reduction
__device__ inline double block_reduce1(float s, double* red, int t)
{
    __syncthreads();
    red[t] = (double)s;
    __syncthreads();
    for (int st = 128; st; st >>= 1) {
        if (t < st) red[t] += red[t + st];
        __syncthreads();
    }
    return red[0];
}

// ---------------- fused FF on bf16 h; 1-pass paired stats; padded conv ----------------
__global__ __launch_bounds__(256) void ff_fused_kernel(
    unsigned short* __restrict__ h, const float* __restrict__ w, const float* __restrict__ bias)
{
    __shared__ __align__(16) float pl[66][67];
    __shared__ double red[512];
    int plane = blockIdx.x;
    int c = plane & (NFF - 1);
    const unsigned* h2 = (const unsigned*)(h + (size_t)plane * NP);
    unsigned* h2w = (unsigned*)(h + (size_t)plane * NP);
    int t = threadIdx.x;
    if (t < 66) { pl[0][t] = 0.f; pl[65][t] = 0.f; }
    if (t >= 66 && t < 130) { int rr = t - 65; pl[rr][0] = 0.f; pl[rr][65] = 0.f; }

    float v[16]; float sf = 0.f, s2f = 0.f;
    #pragma unroll
    for (int i = 0; i < 8; i++) {
        unsigned u = h2[i * 256 + t];
        float x0 = bf2f((unsigned short)(u & 0xffffu));
        float x1 = bf2f((unsigned short)(u >> 16));
        v[2 * i] = x0; v[2 * i + 1] = x1;
        sf += x0 + x1;
        s2f += x0 * x0 + x1 * x1;
    }
    double S, S2;
    block_reduceP(sf, s2f, red, t, S, S2);
    double mean = S * (1.0 / NP);
    double var = S2 * (1.0 / NP) - mean * mean;
    float rs = (float)(1.0 / sqrt(var + (double)CEPS));
    float mf = (float)mean;

    float w9[9];
    #pragma unroll
    for (int k = 0; k < 9; k++) w9[k] = w[c * 9 + k];
    float bsv = bias[c];

    #pragma unroll
    for (int j = 0; j < 16; j++) {
        int pix = (j >> 1) * 512 + 2 * t + (j & 1);
        float gx = gelu_fast((v[j] - mf) * rs);
        v[j] = gx;
        pl[(pix >> 6) + 1][(pix & 63) + 1] = gx;
    }
    __syncthreads();

    float tv[16]; float sg = 0.f, s2g = 0.f;
    #pragma unroll
    for (int j = 0; j < 16; j++) {
        int pix = (j >> 1) * 512 + 2 * t + (j & 1);
        int y = pix >> 6, xx = pix & 63;
        float acc = bsv;
        #pragma unroll
        for (int dy = 0; dy < 3; dy++)
            #pragma unroll
            for (int dx = 0; dx < 3; dx++)
                acc += w9[dy * 3 + dx] * pl[y + dy][xx + dx];
        tv[j] = acc; sg += acc; s2g += acc * acc;
    }
    double Sb, S2b;
    block_reduceP(sg, s2g, red, t, Sb, S2b);
    double mean2 = Sb * (1.0 / NP);
    double var2 = S2b * (1.0 / NP) - mean2 * mean2;
    float rs2 = (float)(1.0 / sqrt(var2 + (double)CEPS));
    float mf2 = (float)mean2;

    #pragma unroll
    for (int i = 0; i < 8; i++) {
        float o0 = v[2 * i]     + gelu_fast((tv[2 * i] - mf2) * rs2);
        float o1 = v[2 * i + 1] + gelu_fast((tv[2 * i + 1] - mf2) * rs2);
        unsigned u = (unsigned)f2bf(o0) | ((unsigned)f2bf(o1) << 16);
        h2w[i * 256 + t] = u;
    }
}

// ---------------- final instance norm in place on d_out (2-pass centered) -------------
__global__ __launch_bounds__(256) void in_final_kernel(float* __restrict__ y)
{
    __shared__ double red[256];
    size_t base = (size_t)blockIdx.x * NP;
    int t = threadIdx.x;
    float v[16]; float sf = 0.f;
    #pragma unroll
    for (int i = 0; i < 16; i++) { float x = y[base + t + i * 256]; v[i] = x; sf += x; }
    double S = block_reduce1(sf, red, t);
    float mf = (float)(S * (1.0 / NP));
    float s2f = 0.f;
    #pragma unroll
    for (int i = 0; i < 16; i++) { float d = v[i] - mf; v[i] = d; s2f += d * d; }
    double S2 = block_reduce1(s2f, red, t);
    float rs = (float)(1.0 / sqrt(S2 * (1.0 / NP) + (double)CEPS));
    #pragma unroll
    for (int i = 0; i < 16; i++)
        y[base + t + i * 256] = v[i] * rs;
}

extern "C" void kernel_launch(void* const* d_in, const int* in_sizes, int n_in,
                              void* d_out, int out_size, void* d_ws, size_t ws_size,
                              hipStream_t stream)
{
    const float* x      = (const float*)d_in[0];
    const float* g      = (const float*)d_in[1];
    const float* bc     = (const float*)d_in[2];
    const float* w_qkv  = (const float*)d_in[3];
    const float* w_out  = (const float*)d_in[4];
    const float* b_out  = (const float*)d_in[5];
    const float* w_dw   = (const float*)d_in[6];
    const float* b_dw   = (const float*)d_in[7];
    const float* w_comb = (const float*)d_in[8];
    const float* b_comb = (const float*)d_in[9];
    const float* w_ff1  = (const float*)d_in[10];
    const float* b_ff1  = (const float*)d_in[11];
    const float* w_ffdw = (const float*)d_in[12];
    const float* b_ffdw = (const float*)d_in[13];
    const float* w_ff2  = (const float*)d_in[14];
    const float* b_ff2  = (const float*)d_in[15];
    float* out = (float*)d_out;
    float* ws  = (float*)d_ws;

    const size_t S = (size_t)NB * NC * NP;   // 16,777,216 floats (64 MiB)
    float* qkv   = ws + S;
    unsigned short* h1u   = (unsigned short*)ws;
    unsigned short* ctxu  = (unsigned short*)(ws + 2097152);
    unsigned short* convu = (unsigned short*)(ws + S);
    unsigned short* Fbufu = (unsigned short*)out;
    float* qrow    = ws;                       // 262144
    float* kheight = qrow + 262144;            // 262144
    float* kselb   = kheight + 262144;         // 262144
    float* vselb   = kselb + 262144;           // ends at 1048576
    float* rs_a    = ws + 1052672;             // 65536
    float* mrs_a   = rs_a + 65536;             // 65536
    float* Aab     = mrs_a + 65536;            // 768
    float* Bab     = Aab + 768;                // 768
    unsigned* pw_qkv = (unsigned*)out;
    unsigned* pwF    = (unsigned*)ws;
    float*    bF     = ws + 131072;

    size_t need = 4 * S * sizeof(float);
    if (ws_size < need) {
        float val = 1024.0f + (float)(ws_size >> 20);
        diag_fill<<<(out_size + 255) / 256, 256, 0, stream>>>(out, val, out_size);
        return;
    }

    // 0. prepack W_qkv*diag(g); cln stats; fold constants
    pack_wg_kernel<<<768, 256, 0, stream>>>(w_qkv, g, pw_qkv, 768 * 256);
    cln_stats_kernel<<<1024, 256, 0, stream>>>(x, rs_a, mrs_a);
    ab_kernel<<<3, 256, 0, stream>>>(w_qkv, g, bc, Aab, Bab);
    // 2. qkv = fold( (W_qkv g) * x ) with fused l2norm + qrow/kheight
    gemm_mfma<false, true, true, false, false><<<dim3(32, 6, NB), 512, 0, stream>>>(
        x, 256, 256, nullptr, 0, 256, (const float*)pw_qkv, nullptr, nullptr, qkv, 768, 768,
        rs_a, mrs_a, Aab, Bab, qrow, kheight);
    // 5-6. select (qprobe folded); attention -> compact bf16 ctx
    select_kernel<<<NBH, 64, 0, stream>>>(qkv, qrow, kheight, kselb, vselb);
    attn_kernel<<<dim3(16, NBH), 256, 0, stream>>>(qkv, kselb, vselb, ctxu);
    // 7. fused comb weight -> packed, into dead smalls
    fuse_comb_kernel<<<512, 256, 0, stream>>>(w_comb, w_out, b_out, b_comb, pwF, bF);
    // 8. conv branch -> compact bf16 (dead qkv space)
    dwconv_kernel<<<NB * NC, 256, 0, stream>>>(x, w_dw, b_dw, convu, NC);
    // 9. attn_out = W_fused * [ctx; conv] (bf16 B, 2-MFMA) + b_fused + x -> bf16 d_out
    gemm_mfma<false, true, false, true, true><<<dim3(32, 2, NB), 512, 0, stream>>>(
        (const float*)ctxu, 256, 256, (const float*)convu, 256, 512,
        (const float*)pwF, bF, x, (float*)Fbufu, 256, 256,
        nullptr, nullptr, nullptr, nullptr, nullptr, nullptr);
    // 10. h1 = W_ff1 * attn_out (bf16 B, 2-MFMA) + b_ff1 -> bf16 ws[0,2S)
    gemm_mfma<false, false, false, true, true><<<dim3(32, 8, NB), 512, 0, stream>>>(
        (const float*)Fbufu, 256, 256, nullptr, 0, 256, w_ff1, b_ff1, nullptr, (float*)h1u,
        1024, 1024, nullptr, nullptr, nullptr, nullptr, nullptr, nullptr);
    // 11. fused FF on bf16 h1 (in place)
    ff_fused_kernel<<<NB * NFF, 256, 0, stream>>>(h1u, w_ffdw, b_ffdw);
    // 12. y = W_ff2 * h1 (bf16 B, 2-MFMA) + b_ff2 -> d_out fp32
    gemm_mfma<false, false, false, false, true><<<dim3(32, 2, NB), 512, 0, stream>>>(
        (const float*)h1u, 1024, 1024, nullptr, 0, 1024, w_ff2, b_ff2, nullptr, out, 256, 256,
        nullptr, nullptr, nullptr, nullptr, nullptr, nullptr);
    // 13. final instance norm
    in_final_kernel<<<NB * NC, 256, 0, stream>>>(out);
}

// Round 21
// 772.617 us; speedup vs baseline: 1.5534x; 1.0083x over previous
//
#include <hip/hip_runtime.h>
#include <math.h>

#define NB 16
#define NC 256
#define NP 4096      // 64*64
#define NHEADS 8
#define NDH 32
#define NBH 128
#define NFF 1024
#define CEPS 1e-5f

typedef short s16x8 __attribute__((ext_vector_type(8)));
typedef float f32x4 __attribute__((ext_vector_type(4)));

// ---------------- diagnostic fill (guard trip) ----------------
__global__ __launch_bounds__(256) void diag_fill(float* __restrict__ out, float val, int n)
{
    int i = blockIdx.x * 256 + threadIdx.x;
    if (i < n) out[i] = val;
}

// ---------------- bf16 split helpers ----------------
__device__ inline unsigned short f2bf(float f) {
    unsigned u = __float_as_uint(f);
    return (unsigned short)((u + 0x7FFFu + ((u >> 16) & 1u)) >> 16);
}
__device__ inline float bf2f(unsigned short h) { return __uint_as_float(((unsigned)h) << 16); }
__device__ inline void split2(float f, unsigned short& hi, unsigned short& lo) {
    hi = f2bf(f);
    lo = f2bf(f - bf2f(hi));
}
// fast round-to-nearest split (6 ops)
__device__ inline void split_rn(float f, unsigned short& hi, unsigned short& lo) {
    unsigned u = __float_as_uint(f);
    unsigned tt = u + 0x8000u;
    hi = (unsigned short)(tt >> 16);
    float r = f - __uint_as_float(tt & 0xffff0000u);
    lo = (unsigned short)((__float_as_uint(r) + 0x8000u) >> 16);
}
// packed: (hi<<16)|lo
__device__ inline unsigned pack_hl(float f) {
    unsigned short h, lo; split2(f, h, lo);
    return ((unsigned)h << 16) | (unsigned)lo;
}
__device__ inline float packf(float f) { return __uint_as_float(pack_hl(f)); }

// ---------------- weight prepack with channel gain: pw = pack(w[o,c]*g[c]) ----------
__global__ __launch_bounds__(256) void pack_wg_kernel(
    const float* __restrict__ w, const float* __restrict__ g,
    unsigned* __restrict__ pw, int n)
{
    int i = blockIdx.x * 256 + threadIdx.x;
    if (i < n) pw[i] = pack_hl(w[i] * g[i & 255]);
}

// ---------------- cln stats: per (b,p) mean/rsqrt over 256 channels ----------------
__global__ __launch_bounds__(256) void cln_stats_kernel(
    const float* __restrict__ x, float* __restrict__ rs, float* __restrict__ mrs)
{
    __shared__ double red[512];
    int t = threadIdx.x;
    int i = t & 63, q = t >> 6;
    int col = blockIdx.x * 64 + i;
    int b = col >> 12, p = col & 4095;
    const float* src = x + (size_t)b * NC * NP + (size_t)(q * 64) * NP + p;
    double s = 0.0, s2 = 0.0;
    #pragma unroll 8
    for (int c = 0; c < 64; c++) { float v = src[(size_t)c * NP]; s += v; s2 += (double)v * v; }
    red[q * 64 + i] = s; red[256 + q * 64 + i] = s2;
    __syncthreads();
    if (q == 0) {
        double S  = red[i] + red[64 + i] + red[128 + i] + red[192 + i];
        double S2 = red[256 + i] + red[320 + i] + red[384 + i] + red[448 + i];
        double mean = S * (1.0 / 256.0);
        double var = S2 * (1.0 / 256.0) - mean * mean;
        double r = 1.0 / sqrt(var + (double)CEPS);
        rs[col]  = (float)r;
        mrs[col] = (float)(mean * r);
    }
}

// ---------------- A/B fold constants ----------------
__global__ __launch_bounds__(256) void ab_kernel(
    const float* __restrict__ wq, const float* __restrict__ g, const float* __restrict__ bc,
    float* __restrict__ Aab, float* __restrict__ Bab)
{
    int o = blockIdx.x * 256 + threadIdx.x;
    if (o >= 768) return;
    double a = 0.0, bsum = 0.0;
    for (int c = 0; c < 256; c++) {
        double w = wq[o * 256 + c];
        a += w * (double)g[c];
        bsum += w * (double)bc[c];
    }
    Aab[o] = (float)a; Bab[o] = (float)bsum;
}

// ---------------- fused comb weight: W_fused = [W_comb_L @ W_out | W_comb_R] ----------
__global__ __launch_bounds__(256) void fuse_comb_kernel(
    const float* __restrict__ w_comb, const float* __restrict__ w_out,
    const float* __restrict__ b_out, const float* __restrict__ b_comb,
    unsigned* __restrict__ pwF, float* __restrict__ bF)
{
    int idx = blockIdx.x * 256 + threadIdx.x;   // 131072
    int o = idx >> 9, cc = idx & 511;
    float val;
    if (cc < 256) {
        double s = 0.0;
        for (int k = 0; k < 256; k++)
            s += (double)w_comb[o * 512 + k] * (double)w_out[k * 256 + cc];
        val = (float)s;
    } else {
        val = w_comb[o * 512 + cc];
    }
    pwF[idx] = pack_hl(val);
    if (idx < 256) {
        double s = 0.0;
        for (int k = 0; k < 256; k++)
            s += (double)w_comb[idx * 512 + k] * (double)b_out[k];
        bF[idx] = (float)(s + (double)b_comb[idx]);
    }
}

// ---------------- split-bf16 MFMA GEMM: 128o x 128p tile, 8 waves (32x64/wave) --------
template<bool PACKO, bool PACKA, bool CLN, bool OBF16, bool BBF16>
__global__ __launch_bounds__(512) void gemm_mfma(
    const float* __restrict__ inA, int sA, int C1,
    const float* __restrict__ inB, int sB, int Ctot,
    const float* __restrict__ Wt, const float* __restrict__ bias,
    const float* __restrict__ resid, float* __restrict__ out, int sO, int O,
    const float* __restrict__ rs, const float* __restrict__ mrs,
    const float* __restrict__ Aab, const float* __restrict__ Bab,
    float* __restrict__ qrow, float* __restrict__ kheight)
{
    __shared__ __align__(16) unsigned short Ah[128 * 32], Al[128 * 32];
    __shared__ __align__(16) unsigned short Bh[128 * 32];
    __shared__ __align__(16) unsigned short Bl[BBF16 ? 16 : 128 * 32];
    char* cAh = (char*)Ah; char* cAl = (char*)Al;
    char* cBh = (char*)Bh; char* cBl = (char*)Bl;

    // ---- XCD-batch swizzle ----
    const unsigned npb = gridDim.x * gridDim.y;
    unsigned lin = blockIdx.x + gridDim.x * (blockIdx.y + gridDim.y * blockIdx.z);
    unsigned low = lin & 7u, rest = lin >> 3;
    unsigned high = (rest >= npb) ? 1u : 0u;
    unsigned idx = rest - high * npb;
    const int b = (int)(low + 8u * high);
    const int o0 = (int)(idx / gridDim.x) * 128, p0 = (int)(idx % gridDim.x) * 128;

    const int t = threadIdx.x;
    const int l = t & 63, w = t >> 6;
    const int wr = w & 3, wc = w >> 2;
    const int g = l >> 4, l15 = l & 15;
    const int slotl = (l & 3) ^ ((l >> 2) & 3);

    f32x4 acc[2][4];
    #pragma unroll
    for (int m = 0; m < 2; m++)
        #pragma unroll
        for (int n = 0; n < 4; n++) acc[m][n] = (f32x4){0.f, 0.f, 0.f, 0.f};

    const int arow = t >> 2;
    const int ak8 = (t & 3) * 8;
    const int aslot = (arow & 3) ^ ((arow >> 2) & 3);
    const int aoff = arow * 64 + ((((ak8 >> 3)) ^ aslot) << 4);
    const int bp = t & 127;
    const int bhk = t >> 7;
    const int bslot = (bp & 3) ^ ((bp >> 2) & 3);
    const int boffst = bp * 64 + ((bhk ^ bslot) << 4);

    uint4 wa0, wa1;
    unsigned pb[8];

    #define LOAD_TILE(K0)                                                                 \
    {                                                                                     \
        const unsigned* wsrc = (const unsigned*)Wt + (size_t)(o0 + arow) * Ctot + (K0) + ak8; \
        wa0 = *(const uint4*)(wsrc);                                                      \
        wa1 = *(const uint4*)(wsrc + 4);                                                  \
        _Pragma("unroll")                                                                 \
        for (int q = 0; q < 4; q++) {                                                     \
            int c2 = bhk * 8 + q * 2;                                                     \
            int cc = (K0) + c2;                                                           \
            if constexpr (BBF16) {                                                        \
                const unsigned short* s16 = (cc < C1)                                     \
                    ? (const unsigned short*)inA + ((size_t)b * sA + cc) * (size_t)NP + p0 + bp \
                    : (const unsigned short*)inB + ((size_t)b * sB + (cc - C1)) * (size_t)NP + p0 + bp; \
                unsigned short v0 = s16[0];                                               \
                unsigned short v1 = s16[NP];                                              \
                pb[q] = (unsigned)v0 | ((unsigned)v1 << 16);                              \
            } else {                                                                      \
                const float* srcp = (cc < C1) ? inA + ((size_t)b * sA + cc) * (size_t)NP  \
                                              : inB + ((size_t)b * sB + (cc - C1)) * (size_t)NP; \
                pb[2 * q]     = __float_as_uint(srcp[p0 + bp]);                           \
                pb[2 * q + 1] = __float_as_uint(srcp[(size_t)NP + p0 + bp]);              \
            }                                                                             \
        }                                                                                 \
    }

    #define STORE_LDS()                                                                   \
    {                                                                                     \
        if constexpr (PACKA) {                                                            \
            uint4 hq, lq;                                                                 \
            hq.x = __builtin_amdgcn_perm(wa0.y, wa0.x, 0x07060302u);                      \
            lq.x = __builtin_amdgcn_perm(wa0.y, wa0.x, 0x05040100u);                      \
            hq.y = __builtin_amdgcn_perm(wa0.w, wa0.z, 0x07060302u);                      \
            lq.y = __builtin_amdgcn_perm(wa0.w, wa0.z, 0x05040100u);                      \
            hq.z = __builtin_amdgcn_perm(wa1.y, wa1.x, 0x07060302u);                      \
            lq.z = __builtin_amdgcn_perm(wa1.y, wa1.x, 0x05040100u);                      \
            hq.w = __builtin_amdgcn_perm(wa1.w, wa1.z, 0x07060302u);                      \
            lq.w = __builtin_amdgcn_perm(wa1.w, wa1.z, 0x05040100u);                      \
            *(uint4*)(cAh + aoff) = hq;                                                   \
            *(uint4*)(cAl + aoff) = lq;                                                   \
        } else {                                                                          \
            ushort4 h0, l0, h1, l1;                                                       \
            split_rn(__uint_as_float(wa0.x), h0.x, l0.x);                                 \
            split_rn(__uint_as_float(wa0.y), h0.y, l0.y);                                 \
            split_rn(__uint_as_float(wa0.z), h0.z, l0.z);                                 \
            split_rn(__uint_as_float(wa0.w), h0.w, l0.w);                                 \
            split_rn(__uint_as_float(wa1.x), h1.x, l1.x);                                 \
            split_rn(__uint_as_float(wa1.y), h1.y, l1.y);                                 \
            split_rn(__uint_as_float(wa1.z), h1.z, l1.z);                                 \
            split_rn(__uint_as_float(wa1.w), h1.w, l1.w);                                 \
            *(ushort4*)(cAh + aoff) = h0; *(ushort4*)(cAh + aoff + 8) = h1;               \
            *(ushort4*)(cAl + aoff) = l0; *(ushort4*)(cAl + aoff + 8) = l1;               \
        }                                                                                 \
        if constexpr (BBF16) {                                                            \
            *(uint4*)(cBh + boffst) = (uint4){pb[0], pb[1], pb[2], pb[3]};                \
        } else {                                                                          \
            unsigned hp[4], lp[4];                                                        \
            _Pragma("unroll")                                                             \
            for (int q = 0; q < 4; q++) {                                                 \
                unsigned u0 = pb[2 * q], u1 = pb[2 * q + 1];                              \
                if constexpr (CLN) {                                                      \
                    unsigned short sh0, sl0, sh1, sl1;                                    \
                    split_rn(__uint_as_float(u0), sh0, sl0);                              \
                    split_rn(__uint_as_float(u1), sh1, sl1);                              \
                    hp[q] = (unsigned)sh0 | ((unsigned)sh1 << 16);                        \
                    lp[q] = (unsigned)sl0 | ((unsigned)sl1 << 16);                        \
                } else {                                                                  \
                    hp[q] = __builtin_amdgcn_perm(u1, u0, 0x07060302u);                   \
                    lp[q] = __builtin_amdgcn_perm(u1, u0, 0x05040100u);                   \
                }                                                                         \
            }                                                                             \
            *(uint4*)(cBh + boffst) = (uint4){hp[0], hp[1], hp[2], hp[3]};                \
            *(uint4*)(cBl + boffst) = (uint4){lp[0], lp[1], lp[2], lp[3]};                \
        }                                                                                 \
    }

    LOAD_TILE(0)

    for (int k0 = 0; k0 < Ctot; k0 += 32) {
        if (k0) __syncthreads();
        STORE_LDS()
        __syncthreads();
        if (k0 + 32 < Ctot) LOAD_TILE(k0 + 32)

        s16x8 ah[2], al[2];
        #pragma unroll
        for (int m = 0; m < 2; m++) {
            int ao = (wr * 32 + m * 16 + l15) * 64 + ((g ^ slotl) << 4);
            ah[m] = *(const s16x8*)(cAh + ao);
            al[m] = *(const s16x8*)(cAl + ao);
        }
        #pragma unroll
        for (int n = 0; n < 4; n++) {
            int bo = (wc * 64 + n * 16 + l15) * 64 + ((g ^ slotl) << 4);
            s16x8 bh = *(const s16x8*)(cBh + bo);
            if constexpr (BBF16) {
                #pragma unroll
                for (int m = 0; m < 2; m++) {
                    acc[m][n] = __builtin_amdgcn_mfma_f32_16x16x32_bf16(ah[m], bh, acc[m][n], 0, 0, 0);
                    acc[m][n] = __builtin_amdgcn_mfma_f32_16x16x32_bf16(al[m], bh, acc[m][n], 0, 0, 0);
                }
            } else {
                s16x8 bl = *(const s16x8*)(cBl + bo);
                #pragma unroll
                for (int m = 0; m < 2; m++) {
                    acc[m][n] = __builtin_amdgcn_mfma_f32_16x16x32_bf16(ah[m], bh, acc[m][n], 0, 0, 0);
                    acc[m][n] = __builtin_amdgcn_mfma_f32_16x16x32_bf16(ah[m], bl, acc[m][n], 0, 0, 0);
                    acc[m][n] = __builtin_amdgcn_mfma_f32_16x16x32_bf16(al[m], bh, acc[m][n], 0, 0, 0);
                }
            }
        }
    }
    #undef LOAD_TILE
    #undef STORE_LDS

    // ---- epilogue: D[row=(l>>4)*4+r][col=l&15] ----
    #pragma unroll
    for (int m = 0; m < 2; m++) {
        #pragma unroll
        for (int r = 0; r < 4; r++) {
            int orow = o0 + wr * 32 + m * 16 + g * 4 + r;
            float bs = (!CLN && bias) ? bias[orow] : 0.f;
            float Ao = CLN ? Aab[orow] : 0.f;
            float Bo = CLN ? Bab[orow] : 0.f;
            if constexpr (CLN) {
                float vv[4];
                #pragma unroll
                for (int n = 0; n < 4; n++) {
                    int pcol = p0 + wc * 64 + n * 16 + l15;
                    size_t cidx = (size_t)b * NP + pcol;
                    vv[n] = rs[cidx] * acc[m][n][r] - mrs[cidx] * Ao + Bo;
                }
                int which = orow >> 8;
                if (which < 2) {
                    float ss = vv[0] * vv[0] + vv[1] * vv[1] + vv[2] * vv[2] + vv[3] * vv[3];
                    ss += __shfl_xor(ss, 1); ss += __shfl_xor(ss, 2);
                    ss += __shfl_xor(ss, 4); ss += __shfl_xor(ss, 8);
                    float inv = 1.f / fmaxf(sqrtf(ss), 1e-12f);
                    float as = 0.f;
                    #pragma unroll
                    for (int n = 0; n < 4; n++) { vv[n] *= inv; as += fabsf(vv[n]); }
                    as += __shfl_xor(as, 1); as += __shfl_xor(as, 2);
                    as += __shfl_xor(as, 4); as += __shfl_xor(as, 8);
                    if (l15 == 0) {
                        int idx2 = orow & 255;
                        int head = idx2 >> 5, c = idx2 & 31;
                        int h = (p0 >> 6) + wc;
                        int rr = ((b << 3) + head) * 2048 + c * 64 + h;
                        (which == 0 ? qrow : kheight)[rr] = as;
                    }
                }
                #pragma unroll
                for (int n = 0; n < 4; n++) {
                    int pcol = p0 + wc * 64 + n * 16 + l15;
                    out[((size_t)b * sO + orow) * (size_t)NP + pcol] = vv[n];
                }
            } else {
                #pragma unroll
                for (int n = 0; n < 4; n++) {
                    int pcol = p0 + wc * 64 + n * 16 + l15;
                    float v = acc[m][n][r] + bs;
                    if (resid) v += resid[((size_t)b * O + orow) * (size_t)NP + pcol];
                    size_t oidx = ((size_t)b * sO + orow) * (size_t)NP + pcol;
                    if constexpr (OBF16)
                        ((unsigned short*)out)[oidx] = f2bf(v);
                    else
                        out[oidx] = PACKO ? packf(v) : v;
                }
            }
        }
    }
}

// ---------------- scores + top-k rows/cols + gather k (qprobe folded); exports idx ----
__global__ __launch_bounds__(64) void select_kernel(
    const float* __restrict__ qkv, const float* __restrict__ qrow,
    const float* __restrict__ kheight,
    float* __restrict__ ksel, int* __restrict__ hswsl)
{
    const int bh = blockIdx.x;
    const int b = bh >> 3, head = bh & 7;
    const int lane = threadIdx.x;
    __shared__ int hs[8], wsl[8];
    __shared__ float qp[32];
    if (lane < 32) {
        double s = 0.0;
        const float* qr = qrow + (size_t)bh * 2048 + lane * 64;
        for (int h = 0; h < 64; h++) s += qr[h];
        qp[lane] = (float)s;
    }
    __syncthreads();
    double scd = 0.0;
    for (int c = 0; c < 32; c++) scd += (double)qp[c] * kheight[((size_t)bh * 32 + c) * 64 + lane];
    float sc = (float)scd;
    for (int it = 0; it < 8; it++) {
        float v = sc; int id = lane;
        for (int off = 32; off; off >>= 1) {
            float ov = __shfl_xor(v, off); int oi = __shfl_xor(id, off);
            if (ov > v || (ov == v && oi < id)) { v = ov; id = oi; }
        }
        if (lane == 0) hs[it] = id;
        if (lane == id) sc = -3.4e38f;
    }
    __syncthreads();
    const float* kbase = qkv + ((size_t)b * 768 + 256 + head * 32) * NP;
    double sc2d = 0.0;
    for (int c = 0; c < 32; c++) {
        float kw = 0.f;
        for (int hi = 0; hi < 8; hi++)
            kw += fabsf(kbase[(size_t)c * NP + hs[hi] * 64 + lane]);
        sc2d += (double)qp[c] * kw;
    }
    float sc2 = (float)sc2d;
    for (int it = 0; it < 8; it++) {
        float v = sc2; int id = lane;
        for (int off = 32; off; off >>= 1) {
            float ov = __shfl_xor(v, off); int oi = __shfl_xor(id, off);
            if (ov > v || (ov == v && oi < id)) { v = ov; id = oi; }
        }
        if (lane == 0) wsl[it] = id;
        if (lane == id) sc2 = -3.4e38f;
    }
    __syncthreads();
    // export indices for vsel_kernel
    if (lane < 8) hswsl[bh * 16 + lane] = hs[lane];
    else if (lane < 16) hswsl[bh * 16 + lane] = wsl[lane - 8];
    // gather k only
    int hi = lane >> 3, wi = lane & 7;
    int hh = hs[hi], ww = wsl[wi];
    for (int d = 0; d < 32; d++)
        ksel[((size_t)bh * 64 + lane) * 32 + d] = kbase[(size_t)d * NP + hh * 64 + ww];
}

// ---------------- lazy v: vsel[j][d] = rs*( (Wv g) . x[:,pos] ) - mrs*Av + Bv --------
// grid (4, NBH), 256 threads. Each block: one bh, 16 j's.
__global__ __launch_bounds__(256) void vsel_kernel(
    const float* __restrict__ x, const float* __restrict__ w_qkv, const float* __restrict__ g,
    const int* __restrict__ hswsl, const float* __restrict__ rs, const float* __restrict__ mrs,
    const float* __restrict__ Aab, const float* __restrict__ Bab,
    float* __restrict__ vsel)
{
    __shared__ float Wg[32][257];
    __shared__ float xcol[16][257];
    __shared__ int pos_s[16];
    const int bh = blockIdx.y, b = bh >> 3, head = bh & 7;
    const int t = threadIdx.x;
    // stage Wv*g (32 x 256)
    for (int i = t; i < 8192; i += 256) {
        int d = i >> 8, c = i & 255;
        Wg[d][c] = w_qkv[(size_t)(512 + head * 32 + d) * 256 + c] * g[c];
    }
    if (t < 16) {
        int j = blockIdx.x * 16 + t;
        int hh = hswsl[bh * 16 + (j >> 3)];
        int ww = hswsl[bh * 16 + 8 + (j & 7)];
        pos_s[t] = hh * 64 + ww;
    }
    __syncthreads();
    // stage x columns (16 j x 256 c); scattered reads
    for (int i = t; i < 4096; i += 256) {
        int jj = i >> 8, c = i & 255;
        xcol[jj][c] = x[((size_t)b * 256 + c) * (size_t)NP + pos_s[jj]];
    }
    __syncthreads();
    // compute: wave w handles jj = w*4..w*4+3; lane: d = l&31, ch = l>>5
    const int l = t & 63, w = t >> 6;
    const int d = l & 31, ch = l >> 5;
    const float Av = Aab[512 + head * 32 + d];
    const float Bv = Bab[512 + head * 32 + d];
    for (int q = 0; q < 4; q++) {
        int jj = w * 4 + q;
        float s = 0.f;
        #pragma unroll
        for (int c = 0; c < 128; c++) s += Wg[d][ch * 128 + c] * xcol[jj][ch * 128 + c];
        s += __shfl_xor(s, 32);
        if (ch == 0) {
            int j = blockIdx.x * 16 + jj;
            size_t cidx = (size_t)b * NP + pos_s[jj];
            float val = rs[cidx] * s - mrs[cidx] * Av + Bv;
            vsel[((size_t)bh * 64 + j) * 32 + d] = val;
        }
    }
}

// ---------------- attention: writes compact bf16 ctx [b][256][NP] ----------------
__global__ __launch_bounds__(256) void attn_kernel(
    const float* __restrict__ qkv, const float* __restrict__ ksel, const float* __restrict__ vsel,
    unsigned short* __restrict__ ctxu)
{
    __shared__ __align__(16) float ks[64][32];
    __shared__ __align__(16) float vs[64][32];
    int bh = blockIdx.y, b = bh >> 3, head = bh & 7;
    int t = threadIdx.x;
    const float* kb = ksel + (size_t)bh * 2048;
    const float* vb = vsel + (size_t)bh * 2048;
    for (int i = 0; i < 8; i++) {
        ((float*)ks)[t + i * 256] = kb[t + i * 256];
        ((float*)vs)[t + i * 256] = vb[t + i * 256];
    }
    __syncthreads();
    int p = blockIdx.x * 256 + t;
    const float* qb = qkv + ((size_t)b * 768 + head * 32) * NP + p;
    unsigned short* ob = ctxu + ((size_t)b * 256 + head * 32) * NP + p;
    float q[32];
    #pragma unroll
    for (int d = 0; d < 32; d++) q[d] = qb[(size_t)d * NP];
    float s[64], m = -3.4e38f;
    for (int j = 0; j < 64; j++) {
        float dot = 0.f;
        #pragma unroll
        for (int d = 0; d < 32; d++) dot += q[d] * ks[j][d];
        s[j] = dot; m = fmaxf(m, dot);
    }
    float den = 0.f;
    for (int j = 0; j < 64; j++) { float e = expf(s[j] - m); s[j] = e; den += e; }
    float o[32] = {};
    for (int j = 0; j < 64; j++) {
        float a = s[j];
        #pragma unroll
        for (int d = 0; d < 32; d++) o[d] += a * vs[j][d];
    }
    float r = 1.f / den;
    #pragma unroll
    for (int d = 0; d < 32; d++) ob[(size_t)d * NP] = f2bf(o[d] * r);
}

// ---------------- depthwise 3x3 on x; padded LDS, branch-free -------------
__global__ __launch_bounds__(256) void dwconv_kernel(
    const float* __restrict__ in, const float* __restrict__ w, const float* __restrict__ bias,
    unsigned short* __restrict__ out, int Cn)
{
    __shared__ __align__(16) float pl[66][67];
    int bcb = blockIdx.x;
    int c = bcb % Cn;
    const float2* src2 = (const float2*)(in + (size_t)bcb * NP);
    unsigned* dst2 = (unsigned*)(out + (size_t)bcb * NP);
    int t = threadIdx.x;
    if (t < 66) { pl[0][t] = 0.f; pl[65][t] = 0.f; }
    if (t >= 66 && t < 130) { int rr = t - 65; pl[rr][0] = 0.f; pl[rr][65] = 0.f; }
    float w9[9];
    #pragma unroll
    for (int k = 0; k < 9; k++) w9[k] = w[c * 9 + k];
    float bsv = bias[c];
    #pragma unroll
    for (int i = 0; i < 8; i++) {
        float2 f = src2[i * 256 + t];
        int pix = i * 512 + 2 * t;
        int y = pix >> 6, xx = pix & 63;
        pl[y + 1][xx + 1] = f.x;
        pl[y + 1][xx + 2] = f.y;
    }
    __syncthreads();
    float vv[16];
    #pragma unroll
    for (int j = 0; j < 16; j++) {
        int pix = (j >> 1) * 512 + 2 * t + (j & 1);
        int y = pix >> 6, xx = pix & 63;
        float acc = bsv;
        #pragma unroll
        for (int dy = 0; dy < 3; dy++)
            #pragma unroll
            for (int dx = 0; dx < 3; dx++)
                acc += w9[dy * 3 + dx] * pl[y + dy][xx + dx];
        vv[j] = acc;
    }
    #pragma unroll
    for (int i = 0; i < 8; i++) {
        unsigned u = (unsigned)f2bf(vv[2 * i]) | ((unsigned)f2bf(vv[2 * i + 1]) << 16);
        dst2[i * 256 + t] = u;
    }
}

// ---------------- fast gelu: A&S 7.1.26 erf ----------------
__device__ inline float gelu_fast(float x) {
    float z = x * 0.70710678118654752f;
    float a = fabsf(z);
    float t = 1.0f / (1.0f + 0.3275911f * a);
    float p = t * (0.254829592f + t * (-0.284496736f + t * (1.421413741f +
              t * (-1.453152027f + t * 1.061405429f))));
    float e = __expf(-a * a);
    float r = 1.0f - p * e;
    float erfz = copysignf(r, z);
    return 0.5f * x * (1.0f + erfz);
}

// paired fp32-partial -> fp64 tree reduction
__device__ inline void block_reduceP(float a, float b, double* red, int t,
                                     double& A, double& B)
{
    __syncthreads();
    red[t] = (double)a; red[256 + t] = (double)b;
    __syncthreads();
    for (int st = 128; st; st >>= 1) {
        if (t < st) { red[t] += red[t + st]; red[256 + t] += red[256 + t + st]; }
        __syncthreads();
    }
    A = red[0]; B = red[256];
}

__device__ inline double block_reduce1(float s, double* red, int t)
{
    __syncthreads();
    red[t] = (double)s;
    __syncthreads();
    for (int st = 128; st; st >>= 1) {
        if (t < st) red[t] += red[t + st];
        __syncthreads();
    }
    return red[0];
}

// ---------------- fused FF on bf16 h; 1-pass paired stats; padded conv ----------------
__global__ __launch_bounds__(256) void ff_fused_kernel(
    unsigned short* __restrict__ h, const float* __restrict__ w, const float* __restrict__ bias)
{
    __shared__ __align__(16) float pl[66][67];
    __shared__ double red[512];
    int plane = blockIdx.x;
    int c = plane & (NFF - 1);
    const unsigned* h2 = (const unsigned*)(h + (size_t)plane * NP);
    unsigned* h2w = (unsigned*)(h + (size_t)plane * NP);
    int t = threadIdx.x;
    if (t < 66) { pl[0][t] = 0.f; pl[65][t] = 0.f; }
    if (t >= 66 && t < 130) { int rr = t - 65; pl[rr][0] = 0.f; pl[rr][65] = 0.f; }

    float v[16]; float sf = 0.f, s2f = 0.f;
    #pragma unroll
    for (int i = 0; i < 8; i++) {
        unsigned u = h2[i * 256 + t];
        float x0 = bf2f((unsigned short)(u & 0xffffu));
        float x1 = bf2f((unsigned short)(u >> 16));
        v[2 * i] = x0; v[2 * i + 1] = x1;
        sf += x0 + x1;
        s2f += x0 * x0 + x1 * x1;
    }
    double S, S2;
    block_reduceP(sf, s2f, red, t, S, S2);
    double mean = S * (1.0 / NP);
    double var = S2 * (1.0 / NP) - mean * mean;
    float rs = (float)(1.0 / sqrt(var + (double)CEPS));
    float mf = (float)mean;

    float w9[9];
    #pragma unroll
    for (int k = 0; k < 9; k++) w9[k] = w[c * 9 + k];
    float bsv = bias[c];

    #pragma unroll
    for (int j = 0; j < 16; j++) {
        int pix = (j >> 1) * 512 + 2 * t + (j & 1);
        float gx = gelu_fast((v[j] - mf) * rs);
        v[j] = gx;
        pl[(pix >> 6) + 1][(pix & 63) + 1] = gx;
    }
    __syncthreads();

    float tv[16]; float sg = 0.f, s2g = 0.f;
    #pragma unroll
    for (int j = 0; j < 16; j++) {
        int pix = (j >> 1) * 512 + 2 * t + (j & 1);
        int y = pix >> 6, xx = pix & 63;
        float acc = bsv;
        #pragma unroll
        for (int dy = 0; dy < 3; dy++)
            #pragma unroll
            for (int dx = 0; dx < 3; dx++)
                acc += w9[dy * 3 + dx] * pl[y + dy][xx + dx];
        tv[j] = acc; sg += acc; s2g += acc * acc;
    }
    double Sb, S2b;
    block_reduceP(sg, s2g, red, t, Sb, S2b);
    double mean2 = Sb * (1.0 / NP);
    double var2 = S2b * (1.0 / NP) - mean2 * mean2;
    float rs2 = (float)(1.0 / sqrt(var2 + (double)CEPS));
    float mf2 = (float)mean2;

    #pragma unroll
    for (int i = 0; i < 8; i++) {
        float o0 = v[2 * i]     + gelu_fast((tv[2 * i] - mf2) * rs2);
        float o1 = v[2 * i + 1] + gelu_fast((tv[2 * i + 1] - mf2) * rs2);
        unsigned u = (unsigned)f2bf(o0) | ((unsigned)f2bf(o1) << 16);
        h2w[i * 256 + t] = u;
    }
}

// ---------------- final instance norm in place on d_out (2-pass centered) -------------
__global__ __launch_bounds__(256) void in_final_kernel(float* __restrict__ y)
{
    __shared__ double red[256];
    size_t base = (size_t)blockIdx.x * NP;
    int t = threadIdx.x;
    float v[16]; float sf = 0.f;
    #pragma unroll
    for (int i = 0; i < 16; i++) { float x = y[base + t + i * 256]; v[i] = x; sf += x; }
    double S = block_reduce1(sf, red, t);
    float mf = (float)(S * (1.0 / NP));
    float s2f = 0.f;
    #pragma unroll
    for (int i = 0; i < 16; i++) { float d = v[i] - mf; v[i] = d; s2f += d * d; }
    double S2 = block_reduce1(s2f, red, t);
    float rs = (float)(1.0 / sqrt(S2 * (1.0 / NP) + (double)CEPS));
    #pragma unroll
    for (int i = 0; i < 16; i++)
        y[base + t + i * 256] = v[i] * rs;
}

extern "C" void kernel_launch(void* const* d_in, const int* in_sizes, int n_in,
                              void* d_out, int out_size, void* d_ws, size_t ws_size,
                              hipStream_t stream)
{
    const float* x      = (const float*)d_in[0];
    const float* g      = (const float*)d_in[1];
    const float* bc     = (const float*)d_in[2];
    const float* w_qkv  = (const float*)d_in[3];
    const float* w_out  = (const float*)d_in[4];
    const float* b_out  = (const float*)d_in[5];
    const float* w_dw   = (const float*)d_in[6];
    const float* b_dw   = (const float*)d_in[7];
    const float* w_comb = (const float*)d_in[8];
    const float* b_comb = (const float*)d_in[9];
    const float* w_ff1  = (const float*)d_in[10];
    const float* b_ff1  = (const float*)d_in[11];
    const float* w_ffdw = (const float*)d_in[12];
    const float* b_ffdw = (const float*)d_in[13];
    const float* w_ff2  = (const float*)d_in[14];
    const float* b_ff2  = (const float*)d_in[15];
    float* out = (float*)d_out;
    float* ws  = (float*)d_ws;

    const size_t S = (size_t)NB * NC * NP;   // 16,777,216 floats (64 MiB)
    float* qkv   = ws + S;
    unsigned short* h1u   = (unsigned short*)ws;
    unsigned short* ctxu  = (unsigned short*)(ws + 2097152);
    unsigned short* convu = (unsigned short*)(ws + S);
    unsigned short* Fbufu = (unsigned short*)out;
    float* qrow    = ws;                       // 262144
    float* kheight = qrow + 262144;            // 262144
    float* kselb   = kheight + 262144;         // 262144
    float* vselb   = kselb + 262144;           // ends at 1048576
    int*   hswsl   = (int*)(ws + 1048576);     // 2048 ints
    float* rs_a    = ws + 1052672;             // 65536
    float* mrs_a   = rs_a + 65536;             // 65536
    float* Aab     = mrs_a + 65536;            // 768
    float* Bab     = Aab + 768;                // 768
    unsigned* pw_qkv = (unsigned*)out;
    unsigned* pwF    = (unsigned*)ws;
    float*    bF     = ws + 131072;

    size_t need = 4 * S * sizeof(float);
    if (ws_size < need) {
        float val = 1024.0f + (float)(ws_size >> 20);
        diag_fill<<<(out_size + 255) / 256, 256, 0, stream>>>(out, val, out_size);
        return;
    }

    // 0. prepack W_qkv*diag(g) for q,k rows only; cln stats; fold constants (all 768)
    pack_wg_kernel<<<512, 256, 0, stream>>>(w_qkv, g, pw_qkv, 512 * 256);
    cln_stats_kernel<<<1024, 256, 0, stream>>>(x, rs_a, mrs_a);
    ab_kernel<<<3, 256, 0, stream>>>(w_qkv, g, bc, Aab, Bab);
    // 2. q,k = fold( (W_qkv g) * x ) with fused l2norm + qrow/kheight  (O=512, lazy v)
    gemm_mfma<false, true, true, false, false><<<dim3(32, 4, NB), 512, 0, stream>>>(
        x, 256, 256, nullptr, 0, 256, (const float*)pw_qkv, nullptr, nullptr, qkv, 768, 512,
        rs_a, mrs_a, Aab, Bab, qrow, kheight);
    // 5. select (qprobe folded): top-k + k gather + index export
    select_kernel<<<NBH, 64, 0, stream>>>(qkv, qrow, kheight, kselb, hswsl);
    // 5b. lazy v: compute vsel directly from x with cln fold
    vsel_kernel<<<dim3(4, NBH), 256, 0, stream>>>(x, w_qkv, g, hswsl, rs_a, mrs_a,
                                                  Aab, Bab, vselb);
    // 6. attention -> compact bf16 ctx
    attn_kernel<<<dim3(16, NBH), 256, 0, stream>>>(qkv, kselb, vselb, ctxu);
    // 7. fused comb weight -> packed, into dead smalls
    fuse_comb_kernel<<<512, 256, 0, stream>>>(w_comb, w_out, b_out, b_comb, pwF, bF);
    // 8. conv branch -> compact bf16 (dead qkv space)
    dwconv_kernel<<<NB * NC, 256, 0, stream>>>(x, w_dw, b_dw, convu, NC);
    // 9. attn_out = W_fused * [ctx; conv] (bf16 B, 2-MFMA) + b_fused + x -> bf16 d_out
    gemm_mfma<false, true, false, true, true><<<dim3(32, 2, NB), 512, 0, stream>>>(
        (const float*)ctxu, 256, 256, (const float*)convu, 256, 512,
        (const float*)pwF, bF, x, (float*)Fbufu, 256, 256,
        nullptr, nullptr, nullptr, nullptr, nullptr, nullptr);
    // 10. h1 = W_ff1 * attn_out (bf16 B, 2-MFMA) + b_ff1 -> bf16 ws[0,2S)
    gemm_mfma<false, false, false, true, true><<<dim3(32, 8, NB), 512, 0, stream>>>(
        (const float*)Fbufu, 256, 256, nullptr, 0, 256, w_ff1, b_ff1, nullptr, (float*)h1u,
        1024, 1024, nullptr, nullptr, nullptr, nullptr, nullptr, nullptr);
    // 11. fused FF on bf16 h1 (in place)
    ff_fused_kernel<<<NB * NFF, 256, 0, stream>>>(h1u, w_ffdw, b_ffdw);
    // 12. y = W_ff2 * h1 (bf16 B, 2-MFMA) + b_ff2 -> d_out fp32
    gemm_mfma<false, false, false, false, true><<<dim3(32, 2, NB), 512, 0, stream>>>(
        (const float*)h1u, 1024, 1024, nullptr, 0, 1024, w_ff2, b_ff2, nullptr, out, 256, 256,
        nullptr, nullptr, nullptr, nullptr, nullptr, nullptr);
    // 13. final instance norm
    in_final_kernel<<<NB * NC, 256, 0, stream>>>(out);
}

// Round 22
// 725.107 us; speedup vs baseline: 1.6552x; 1.0655x over previous
//
#include <hip/hip_runtime.h>
#include <math.h>

#define NB 16
#define NC 256
#define NP 4096      // 64*64
#define NHEADS 8
#define NDH 32
#define NBH 128
#define NFF 1024
#define CEPS 1e-5f

typedef short s16x8 __attribute__((ext_vector_type(8)));
typedef float f32x4 __attribute__((ext_vector_type(4)));

// ---------------- diagnostic fill (guard trip) ----------------
__global__ __launch_bounds__(256) void diag_fill(float* __restrict__ out, float val, int n)
{
    int i = blockIdx.x * 256 + threadIdx.x;
    if (i < n) out[i] = val;
}

// ---------------- bf16 split helpers ----------------
__device__ inline unsigned short f2bf(float f) {
    unsigned u = __float_as_uint(f);
    return (unsigned short)((u + 0x7FFFu + ((u >> 16) & 1u)) >> 16);
}
__device__ inline float bf2f(unsigned short h) { return __uint_as_float(((unsigned)h) << 16); }
__device__ inline void split2(float f, unsigned short& hi, unsigned short& lo) {
    hi = f2bf(f);
    lo = f2bf(f - bf2f(hi));
}
// fast round-to-nearest split (6 ops)
__device__ inline void split_rn(float f, unsigned short& hi, unsigned short& lo) {
    unsigned u = __float_as_uint(f);
    unsigned tt = u + 0x8000u;
    hi = (unsigned short)(tt >> 16);
    float r = f - __uint_as_float(tt & 0xffff0000u);
    lo = (unsigned short)((__float_as_uint(r) + 0x8000u) >> 16);
}
// packed: (hi<<16)|lo
__device__ inline unsigned pack_hl(float f) {
    unsigned short h, lo; split2(f, h, lo);
    return ((unsigned)h << 16) | (unsigned)lo;
}
__device__ inline float packf(float f) { return __uint_as_float(pack_hl(f)); }

// ---------------- weight prepack with channel gain: pw = pack(w[o,c]*g[c]) ----------
__global__ __launch_bounds__(256) void pack_wg_kernel(
    const float* __restrict__ w, const float* __restrict__ g,
    unsigned* __restrict__ pw, int n)
{
    int i = blockIdx.x * 256 + threadIdx.x;
    if (i < n) pw[i] = pack_hl(w[i] * g[i & 255]);
}

// ---------------- cln stats: per (b,p) mean/rsqrt over 256 channels ----------------
__global__ __launch_bounds__(256) void cln_stats_kernel(
    const float* __restrict__ x, float* __restrict__ rs, float* __restrict__ mrs)
{
    __shared__ double red[512];
    int t = threadIdx.x;
    int i = t & 63, q = t >> 6;
    int col = blockIdx.x * 64 + i;
    int b = col >> 12, p = col & 4095;
    const float* src = x + (size_t)b * NC * NP + (size_t)(q * 64) * NP + p;
    double s = 0.0, s2 = 0.0;
    #pragma unroll 8
    for (int c = 0; c < 64; c++) { float v = src[(size_t)c * NP]; s += v; s2 += (double)v * v; }
    red[q * 64 + i] = s; red[256 + q * 64 + i] = s2;
    __syncthreads();
    if (q == 0) {
        double S  = red[i] + red[64 + i] + red[128 + i] + red[192 + i];
        double S2 = red[256 + i] + red[320 + i] + red[384 + i] + red[448 + i];
        double mean = S * (1.0 / 256.0);
        double var = S2 * (1.0 / 256.0) - mean * mean;
        double r = 1.0 / sqrt(var + (double)CEPS);
        rs[col]  = (float)r;
        mrs[col] = (float)(mean * r);
    }
}

// ---------------- A/B fold constants ----------------
__global__ __launch_bounds__(256) void ab_kernel(
    const float* __restrict__ wq, const float* __restrict__ g, const float* __restrict__ bc,
    float* __restrict__ Aab, float* __restrict__ Bab)
{
    int o = blockIdx.x * 256 + threadIdx.x;
    if (o >= 768) return;
    double a = 0.0, bsum = 0.0;
    for (int c = 0; c < 256; c++) {
        double w = wq[o * 256 + c];
        a += w * (double)g[c];
        bsum += w * (double)bc[c];
    }
    Aab[o] = (float)a; Bab[o] = (float)bsum;
}

// ---------------- fused comb weight: W_fused = [W_comb_L @ W_out | W_comb_R] ----------
__global__ __launch_bounds__(256) void fuse_comb_kernel(
    const float* __restrict__ w_comb, const float* __restrict__ w_out,
    const float* __restrict__ b_out, const float* __restrict__ b_comb,
    unsigned* __restrict__ pwF, float* __restrict__ bF)
{
    int idx = blockIdx.x * 256 + threadIdx.x;   // 131072
    int o = idx >> 9, cc = idx & 511;
    float val;
    if (cc < 256) {
        double s = 0.0;
        for (int k = 0; k < 256; k++)
            s += (double)w_comb[o * 512 + k] * (double)w_out[k * 256 + cc];
        val = (float)s;
    } else {
        val = w_comb[o * 512 + cc];
    }
    pwF[idx] = pack_hl(val);
    if (idx < 256) {
        double s = 0.0;
        for (int k = 0; k < 256; k++)
            s += (double)w_comb[idx * 512 + k] * (double)b_out[k];
        bF[idx] = (float)(s + (double)b_comb[idx]);
    }
}

// ---------------- split-bf16 MFMA GEMM: 128o x 128p tile, 8 waves (32x64/wave) --------
template<bool PACKO, bool PACKA, bool CLN, bool OBF16, bool BBF16>
__global__ __launch_bounds__(512) void gemm_mfma(
    const float* __restrict__ inA, int sA, int C1,
    const float* __restrict__ inB, int sB, int Ctot,
    const float* __restrict__ Wt, const float* __restrict__ bias,
    const float* __restrict__ resid, float* __restrict__ out, int sO, int O,
    const float* __restrict__ rs, const float* __restrict__ mrs,
    const float* __restrict__ Aab, const float* __restrict__ Bab,
    float* __restrict__ qrow, float* __restrict__ kheight)
{
    __shared__ __align__(16) unsigned short Ah[128 * 32], Al[128 * 32];
    __shared__ __align__(16) unsigned short Bh[128 * 32];
    __shared__ __align__(16) unsigned short Bl[BBF16 ? 16 : 128 * 32];
    char* cAh = (char*)Ah; char* cAl = (char*)Al;
    char* cBh = (char*)Bh; char* cBl = (char*)Bl;

    // ---- XCD-batch swizzle ----
    const unsigned npb = gridDim.x * gridDim.y;
    unsigned lin = blockIdx.x + gridDim.x * (blockIdx.y + gridDim.y * blockIdx.z);
    unsigned low = lin & 7u, rest = lin >> 3;
    unsigned high = (rest >= npb) ? 1u : 0u;
    unsigned idx = rest - high * npb;
    const int b = (int)(low + 8u * high);
    const int o0 = (int)(idx / gridDim.x) * 128, p0 = (int)(idx % gridDim.x) * 128;

    const int t = threadIdx.x;
    const int l = t & 63, w = t >> 6;
    const int wr = w & 3, wc = w >> 2;
    const int g = l >> 4, l15 = l & 15;
    const int slotl = (l & 3) ^ ((l >> 2) & 3);

    f32x4 acc[2][4];
    #pragma unroll
    for (int m = 0; m < 2; m++)
        #pragma unroll
        for (int n = 0; n < 4; n++) acc[m][n] = (f32x4){0.f, 0.f, 0.f, 0.f};

    const int arow = t >> 2;
    const int ak8 = (t & 3) * 8;
    const int aslot = (arow & 3) ^ ((arow >> 2) & 3);
    const int aoff = arow * 64 + ((((ak8 >> 3)) ^ aslot) << 4);
    const int bp = t & 127;
    const int bhk = t >> 7;
    const int bslot = (bp & 3) ^ ((bp >> 2) & 3);
    const int boffst = bp * 64 + ((bhk ^ bslot) << 4);

    uint4 wa0, wa1;
    unsigned pb[8];

    #define LOAD_TILE(K0)                                                                 \
    {                                                                                     \
        const unsigned* wsrc = (const unsigned*)Wt + (size_t)(o0 + arow) * Ctot + (K0) + ak8; \
        wa0 = *(const uint4*)(wsrc);                                                      \
        wa1 = *(const uint4*)(wsrc + 4);                                                  \
        _Pragma("unroll")                                                                 \
        for (int q = 0; q < 4; q++) {                                                     \
            int c2 = bhk * 8 + q * 2;                                                     \
            int cc = (K0) + c2;                                                           \
            if constexpr (BBF16) {                                                        \
                const unsigned short* s16 = (cc < C1)                                     \
                    ? (const unsigned short*)inA + ((size_t)b * sA + cc) * (size_t)NP + p0 + bp \
                    : (const unsigned short*)inB + ((size_t)b * sB + (cc - C1)) * (size_t)NP + p0 + bp; \
                unsigned short v0 = s16[0];                                               \
                unsigned short v1 = s16[NP];                                              \
                pb[q] = (unsigned)v0 | ((unsigned)v1 << 16);                              \
            } else {                                                                      \
                const float* srcp = (cc < C1) ? inA + ((size_t)b * sA + cc) * (size_t)NP  \
                                              : inB + ((size_t)b * sB + (cc - C1)) * (size_t)NP; \
                pb[2 * q]     = __float_as_uint(srcp[p0 + bp]);                           \
                pb[2 * q + 1] = __float_as_uint(srcp[(size_t)NP + p0 + bp]);              \
            }                                                                             \
        }                                                                                 \
    }

    #define STORE_LDS()                                                                   \
    {                                                                                     \
        if constexpr (PACKA) {                                                            \
            uint4 hq, lq;                                                                 \
            hq.x = __builtin_amdgcn_perm(wa0.y, wa0.x, 0x07060302u);                      \
            lq.x = __builtin_amdgcn_perm(wa0.y, wa0.x, 0x05040100u);                      \
            hq.y = __builtin_amdgcn_perm(wa0.w, wa0.z, 0x07060302u);                      \
            lq.y = __builtin_amdgcn_perm(wa0.w, wa0.z, 0x05040100u);                      \
            hq.z = __builtin_amdgcn_perm(wa1.y, wa1.x, 0x07060302u);                      \
            lq.z = __builtin_amdgcn_perm(wa1.y, wa1.x, 0x05040100u);                      \
            hq.w = __builtin_amdgcn_perm(wa1.w, wa1.z, 0x07060302u);                      \
            lq.w = __builtin_amdgcn_perm(wa1.w, wa1.z, 0x05040100u);                      \
            *(uint4*)(cAh + aoff) = hq;                                                   \
            *(uint4*)(cAl + aoff) = lq;                                                   \
        } else {                                                                          \
            ushort4 h0, l0, h1, l1;                                                       \
            split_rn(__uint_as_float(wa0.x), h0.x, l0.x);                                 \
            split_rn(__uint_as_float(wa0.y), h0.y, l0.y);                                 \
            split_rn(__uint_as_float(wa0.z), h0.z, l0.z);                                 \
            split_rn(__uint_as_float(wa0.w), h0.w, l0.w);                                 \
            split_rn(__uint_as_float(wa1.x), h1.x, l1.x);                                 \
            split_rn(__uint_as_float(wa1.y), h1.y, l1.y);                                 \
            split_rn(__uint_as_float(wa1.z), h1.z, l1.z);                                 \
            split_rn(__uint_as_float(wa1.w), h1.w, l1.w);                                 \
            *(ushort4*)(cAh + aoff) = h0; *(ushort4*)(cAh + aoff + 8) = h1;               \
            *(ushort4*)(cAl + aoff) = l0; *(ushort4*)(cAl + aoff + 8) = l1;               \
        }                                                                                 \
        if constexpr (BBF16) {                                                            \
            *(uint4*)(cBh + boffst) = (uint4){pb[0], pb[1], pb[2], pb[3]};                \
        } else {                                                                          \
            unsigned hp[4], lp[4];                                                        \
            _Pragma("unroll")                                                             \
            for (int q = 0; q < 4; q++) {                                                 \
                unsigned u0 = pb[2 * q], u1 = pb[2 * q + 1];                              \
                if constexpr (CLN) {                                                      \
                    unsigned short sh0, sl0, sh1, sl1;                                    \
                    split_rn(__uint_as_float(u0), sh0, sl0);                              \
                    split_rn(__uint_as_float(u1), sh1, sl1);                              \
                    hp[q] = (unsigned)sh0 | ((unsigned)sh1 << 16);                        \
                    lp[q] = (unsigned)sl0 | ((unsigned)sl1 << 16);                        \
                } else {                                                                  \
                    hp[q] = __builtin_amdgcn_perm(u1, u0, 0x07060302u);                   \
                    lp[q] = __builtin_amdgcn_perm(u1, u0, 0x05040100u);                   \
                }                                                                         \
            }                                                                             \
            *(uint4*)(cBh + boffst) = (uint4){hp[0], hp[1], hp[2], hp[3]};                \
            *(uint4*)(cBl + boffst) = (uint4){lp[0], lp[1], lp[2], lp[3]};                \
        }                                                                                 \
    }

    LOAD_TILE(0)

    for (int k0 = 0; k0 < Ctot; k0 += 32) {
        if (k0) __syncthreads();
        STORE_LDS()
        __syncthreads();
        if (k0 + 32 < Ctot) LOAD_TILE(k0 + 32)

        s16x8 ah[2], al[2];
        #pragma unroll
        for (int m = 0; m < 2; m++) {
            int ao = (wr * 32 + m * 16 + l15) * 64 + ((g ^ slotl) << 4);
            ah[m] = *(const s16x8*)(cAh + ao);
            al[m] = *(const s16x8*)(cAl + ao);
        }
        #pragma unroll
        for (int n = 0; n < 4; n++) {
            int bo = (wc * 64 + n * 16 + l15) * 64 + ((g ^ slotl) << 4);
            s16x8 bh = *(const s16x8*)(cBh + bo);
            if constexpr (BBF16) {
                #pragma unroll
                for (int m = 0; m < 2; m++) {
                    acc[m][n] = __builtin_amdgcn_mfma_f32_16x16x32_bf16(ah[m], bh, acc[m][n], 0, 0, 0);
                    acc[m][n] = __builtin_amdgcn_mfma_f32_16x16x32_bf16(al[m], bh, acc[m][n], 0, 0, 0);
                }
            } else {
                s16x8 bl = *(const s16x8*)(cBl + bo);
                #pragma unroll
                for (int m = 0; m < 2; m++) {
                    acc[m][n] = __builtin_amdgcn_mfma_f32_16x16x32_bf16(ah[m], bh, acc[m][n], 0, 0, 0);
                    acc[m][n] = __builtin_amdgcn_mfma_f32_16x16x32_bf16(ah[m], bl, acc[m][n], 0, 0, 0);
                    acc[m][n] = __builtin_amdgcn_mfma_f32_16x16x32_bf16(al[m], bh, acc[m][n], 0, 0, 0);
                }
            }
        }
    }
    #undef LOAD_TILE
    #undef STORE_LDS

    // ---- epilogue: D[row=(l>>4)*4+r][col=l&15] ----
    #pragma unroll
    for (int m = 0; m < 2; m++) {
        #pragma unroll
        for (int r = 0; r < 4; r++) {
            int orow = o0 + wr * 32 + m * 16 + g * 4 + r;
            float bs = (!CLN && bias) ? bias[orow] : 0.f;
            float Ao = CLN ? Aab[orow] : 0.f;
            float Bo = CLN ? Bab[orow] : 0.f;
            if constexpr (CLN) {
                float vv[4];
                #pragma unroll
                for (int n = 0; n < 4; n++) {
                    int pcol = p0 + wc * 64 + n * 16 + l15;
                    size_t cidx = (size_t)b * NP + pcol;
                    vv[n] = rs[cidx] * acc[m][n][r] - mrs[cidx] * Ao + Bo;
                }
                int which = orow >> 8;
                if (which < 2) {
                    float ss = vv[0] * vv[0] + vv[1] * vv[1] + vv[2] * vv[2] + vv[3] * vv[3];
                    ss += __shfl_xor(ss, 1); ss += __shfl_xor(ss, 2);
                    ss += __shfl_xor(ss, 4); ss += __shfl_xor(ss, 8);
                    float inv = 1.f / fmaxf(sqrtf(ss), 1e-12f);
                    float as = 0.f;
                    #pragma unroll
                    for (int n = 0; n < 4; n++) { vv[n] *= inv; as += fabsf(vv[n]); }
                    as += __shfl_xor(as, 1); as += __shfl_xor(as, 2);
                    as += __shfl_xor(as, 4); as += __shfl_xor(as, 8);
                    if (l15 == 0) {
                        int idx2 = orow & 255;
                        int head = idx2 >> 5, c = idx2 & 31;
                        int h = (p0 >> 6) + wc;
                        int rr = ((b << 3) + head) * 2048 + c * 64 + h;
                        (which == 0 ? qrow : kheight)[rr] = as;
                    }
                }
                #pragma unroll
                for (int n = 0; n < 4; n++) {
                    int pcol = p0 + wc * 64 + n * 16 + l15;
                    out[((size_t)b * sO + orow) * (size_t)NP + pcol] = vv[n];
                }
            } else {
                #pragma unroll
                for (int n = 0; n < 4; n++) {
                    int pcol = p0 + wc * 64 + n * 16 + l15;
                    float v = acc[m][n][r] + bs;
                    if (resid) v += resid[((size_t)b * O + orow) * (size_t)NP + pcol];
                    size_t oidx = ((size_t)b * sO + orow) * (size_t)NP + pcol;
                    if constexpr (OBF16)
                        ((unsigned short*)out)[oidx] = f2bf(v);
                    else
                        out[oidx] = PACKO ? packf(v) : v;
                }
            }
        }
    }
}

// ---------------- scores + top-k rows/cols + gather k (qprobe folded); exports idx ----
__global__ __launch_bounds__(64) void select_kernel(
    const float* __restrict__ qkv, const float* __restrict__ qrow,
    const float* __restrict__ kheight,
    float* __restrict__ ksel, int* __restrict__ hswsl)
{
    const int bh = blockIdx.x;
    const int b = bh >> 3, head = bh & 7;
    const int lane = threadIdx.x;
    __shared__ int hs[8], wsl[8];
    __shared__ float qp[32];
    if (lane < 32) {
        double s = 0.0;
        const float* qr = qrow + (size_t)bh * 2048 + lane * 64;
        for (int h = 0; h < 64; h++) s += qr[h];
        qp[lane] = (float)s;
    }
    __syncthreads();
    double scd = 0.0;
    for (int c = 0; c < 32; c++) scd += (double)qp[c] * kheight[((size_t)bh * 32 + c) * 64 + lane];
    float sc = (float)scd;
    for (int it = 0; it < 8; it++) {
        float v = sc; int id = lane;
        for (int off = 32; off; off >>= 1) {
            float ov = __shfl_xor(v, off); int oi = __shfl_xor(id, off);
            if (ov > v || (ov == v && oi < id)) { v = ov; id = oi; }
        }
        if (lane == 0) hs[it] = id;
        if (lane == id) sc = -3.4e38f;
    }
    __syncthreads();
    const float* kbase = qkv + ((size_t)b * 768 + 256 + head * 32) * NP;
    double sc2d = 0.0;
    for (int c = 0; c < 32; c++) {
        float kw = 0.f;
        for (int hi = 0; hi < 8; hi++)
            kw += fabsf(kbase[(size_t)c * NP + hs[hi] * 64 + lane]);
        sc2d += (double)qp[c] * kw;
    }
    float sc2 = (float)sc2d;
    for (int it = 0; it < 8; it++) {
        float v = sc2; int id = lane;
        for (int off = 32; off; off >>= 1) {
            float ov = __shfl_xor(v, off); int oi = __shfl_xor(id, off);
            if (ov > v || (ov == v && oi < id)) { v = ov; id = oi; }
        }
        if (lane == 0) wsl[it] = id;
        if (lane == id) sc2 = -3.4e38f;
    }
    __syncthreads();
    if (lane < 8) hswsl[bh * 16 + lane] = hs[lane];
    else if (lane < 16) hswsl[bh * 16 + lane] = wsl[lane - 8];
    int hi = lane >> 3, wi = lane & 7;
    int hh = hs[hi], ww = wsl[wi];
    for (int d = 0; d < 32; d++)
        ksel[((size_t)bh * 64 + lane) * 32 + d] = kbase[(size_t)d * NP + hh * 64 + ww];
}

// ---------------- lazy v: vsel[j][d] = rs*( (Wv g) . x[:,pos] ) - mrs*Av + Bv --------
__global__ __launch_bounds__(256) void vsel_kernel(
    const float* __restrict__ x, const float* __restrict__ w_qkv, const float* __restrict__ g,
    const int* __restrict__ hswsl, const float* __restrict__ rs, const float* __restrict__ mrs,
    const float* __restrict__ Aab, const float* __restrict__ Bab,
    float* __restrict__ vsel)
{
    __shared__ float Wg[32][257];
    __shared__ float xcol[16][257];
    __shared__ int pos_s[16];
    const int bh = blockIdx.y, b = bh >> 3, head = bh & 7;
    const int t = threadIdx.x;
    for (int i = t; i < 8192; i += 256) {
        int d = i >> 8, c = i & 255;
        Wg[d][c] = w_qkv[(size_t)(512 + head * 32 + d) * 256 + c] * g[c];
    }
    if (t < 16) {
        int j = blockIdx.x * 16 + t;
        int hh = hswsl[bh * 16 + (j >> 3)];
        int ww = hswsl[bh * 16 + 8 + (j & 7)];
        pos_s[t] = hh * 64 + ww;
    }
    __syncthreads();
    for (int i = t; i < 4096; i += 256) {
        int jj = i >> 8, c = i & 255;
        xcol[jj][c] = x[((size_t)b * 256 + c) * (size_t)NP + pos_s[jj]];
    }
    __syncthreads();
    const int l = t & 63, w = t >> 6;
    const int d = l & 31, ch = l >> 5;
    const float Av = Aab[512 + head * 32 + d];
    const float Bv = Bab[512 + head * 32 + d];
    for (int q = 0; q < 4; q++) {
        int jj = w * 4 + q;
        float s = 0.f;
        #pragma unroll
        for (int c = 0; c < 128; c++) s += Wg[d][ch * 128 + c] * xcol[jj][ch * 128 + c];
        s += __shfl_xor(s, 32);
        if (ch == 0) {
            int j = blockIdx.x * 16 + jj;
            size_t cidx = (size_t)b * NP + pos_s[jj];
            float val = rs[cidx] * s - mrs[cidx] * Av + Bv;
            vsel[((size_t)bh * 64 + j) * 32 + d] = val;
        }
    }
}

// ---------------- attention: writes compact bf16 ctx [b][256][NP] ----------------
__global__ __launch_bounds__(256) void attn_kernel(
    const float* __restrict__ qkv, const float* __restrict__ ksel, const float* __restrict__ vsel,
    unsigned short* __restrict__ ctxu)
{
    __shared__ __align__(16) float ks[64][32];
    __shared__ __align__(16) float vs[64][32];
    int bh = blockIdx.y, b = bh >> 3, head = bh & 7;
    int t = threadIdx.x;
    const float* kb = ksel + (size_t)bh * 2048;
    const float* vb = vsel + (size_t)bh * 2048;
    for (int i = 0; i < 8; i++) {
        ((float*)ks)[t + i * 256] = kb[t + i * 256];
        ((float*)vs)[t + i * 256] = vb[t + i * 256];
    }
    __syncthreads();
    int p = blockIdx.x * 256 + t;
    const float* qb = qkv + ((size_t)b * 768 + head * 32) * NP + p;
    unsigned short* ob = ctxu + ((size_t)b * 256 + head * 32) * NP + p;
    float q[32];
    #pragma unroll
    for (int d = 0; d < 32; d++) q[d] = qb[(size_t)d * NP];
    float s[64], m = -3.4e38f;
    for (int j = 0; j < 64; j++) {
        float dot = 0.f;
        #pragma unroll
        for (int d = 0; d < 32; d++) dot += q[d] * ks[j][d];
        s[j] = dot; m = fmaxf(m, dot);
    }
    float den = 0.f;
    for (int j = 0; j < 64; j++) { float e = __expf(s[j] - m); s[j] = e; den += e; }
    float o[32] = {};
    for (int j = 0; j < 64; j++) {
        float a = s[j];
        #pragma unroll
        for (int d = 0; d < 32; d++) o[d] += a * vs[j][d];
    }
    float r = 1.f / den;
    #pragma unroll
    for (int d = 0; d < 32; d++) ob[(size_t)d * NP] = f2bf(o[d] * r);
}

// ---------------- depthwise 3x3 on x; padded LDS, branch-free -------------
__global__ __launch_bounds__(256) void dwconv_kernel(
    const float* __restrict__ in, const float* __restrict__ w, const float* __restrict__ bias,
    unsigned short* __restrict__ out, int Cn)
{
    __shared__ __align__(16) float pl[66][67];
    int bcb = blockIdx.x;
    int c = bcb % Cn;
    const float2* src2 = (const float2*)(in + (size_t)bcb * NP);
    unsigned* dst2 = (unsigned*)(out + (size_t)bcb * NP);
    int t = threadIdx.x;
    if (t < 66) { pl[0][t] = 0.f; pl[65][t] = 0.f; }
    if (t >= 66 && t < 130) { int rr = t - 65; pl[rr][0] = 0.f; pl[rr][65] = 0.f; }
    float w9[9];
    #pragma unroll
    for (int k = 0; k < 9; k++) w9[k] = w[c * 9 + k];
    float bsv = bias[c];
    #pragma unroll
    for (int i = 0; i < 8; i++) {
        float2 f = src2[i * 256 + t];
        int pix = i * 512 + 2 * t;
        int y = pix >> 6, xx = pix & 63;
        pl[y + 1][xx + 1] = f.x;
        pl[y + 1][xx + 2] = f.y;
    }
    __syncthreads();
    float vv[16];
    #pragma unroll
    for (int j = 0; j < 16; j++) {
        int pix = (j >> 1) * 512 + 2 * t + (j & 1);
        int y = pix >> 6, xx = pix & 63;
        float acc = bsv;
        #pragma unroll
        for (int dy = 0; dy < 3; dy++)
            #pragma unroll
            for (int dx = 0; dx < 3; dx++)
                acc += w9[dy * 3 + dx] * pl[y + dy][xx + dx];
        vv[j] = acc;
    }
    #pragma unroll
    for (int i = 0; i < 8; i++) {
        unsigned u = (unsigned)f2bf(vv[2 * i]) | ((unsigned)f2bf(vv[2 * i + 1]) << 16);
        dst2[i * 256 + t] = u;
    }
}

// ---------------- fast gelu: A&S 7.1.25 3-term erf + hw rcp (max err ~2.5e-5) ---------
__device__ inline float gelu3(float x) {
    float z = x * 0.70710678118654752f;
    float a = fabsf(z);
    float t = __builtin_amdgcn_rcpf(fmaf(0.47047f, a, 1.0f));
    float p = t * (0.3480242f + t * (-0.0958798f + t * 0.7478556f));
    float e = __expf(-a * a);
    float r = 1.0f - p * e;                 // erf(|z|)
    float erfz = copysignf(r, z);
    return 0.5f * x * (1.0f + erfz);
}

// wave-shfl fp32 paired reduction + cross-wave LDS combine (2 barriers)
__device__ inline void wave_reduce2(float& a, float& b, float* sred, int t)
{
    #pragma unroll
    for (int off = 32; off; off >>= 1) { a += __shfl_xor(a, off); b += __shfl_xor(b, off); }
    int w = t >> 6, lane = t & 63;
    __syncthreads();
    if (lane == 0) { sred[w] = a; sred[4 + w] = b; }
    __syncthreads();
    a = sred[0] + sred[1] + sred[2] + sred[3];
    b = sred[4] + sred[5] + sred[6] + sred[7];
}

__device__ inline double block_reduce1(float s, double* red, int t)
{
    __syncthreads();
    red[t] = (double)s;
    __syncthreads();
    for (int st = 128; st; st >>= 1) {
        if (t < st) red[t] += red[t + st];
        __syncthreads();
    }
    return red[0];
}

// ---------------- fused FF on bf16 h; shfl stats; cheap gelu; padded conv -------------
__global__ __launch_bounds__(256) void ff_fused_kernel(
    unsigned short* __restrict__ h, const float* __restrict__ w, const float* __restrict__ bias)
{
    __shared__ __align__(16) float pl[66][67];
    __shared__ float sred[8];
    int plane = blockIdx.x;
    int c = plane & (NFF - 1);
    const unsigned* h2 = (const unsigned*)(h + (size_t)plane * NP);
    unsigned* h2w = (unsigned*)(h + (size_t)plane * NP);
    int t = threadIdx.x;
    if (t < 66) { pl[0][t] = 0.f; pl[65][t] = 0.f; }
    if (t >= 66 && t < 130) { int rr = t - 65; pl[rr][0] = 0.f; pl[rr][65] = 0.f; }

    float v[16]; float sf = 0.f, s2f = 0.f;
    #pragma unroll
    for (int i = 0; i < 8; i++) {
        unsigned u = h2[i * 256 + t];
        float x0 = bf2f((unsigned short)(u & 0xffffu));
        float x1 = bf2f((unsigned short)(u >> 16));
        v[2 * i] = x0; v[2 * i + 1] = x1;
        sf += x0 + x1;
        s2f += x0 * x0 + x1 * x1;
    }
    wave_reduce2(sf, s2f, sred, t);
    float mf = sf * (1.f / NP);
    float var = s2f * (1.f / NP) - mf * mf;
    float rs = rsqrtf(var + CEPS);

    float w9[9];
    #pragma unroll
    for (int k = 0; k < 9; k++) w9[k] = w[c * 9 + k];
    float bsv = bias[c];

    #pragma unroll
    for (int j = 0; j < 16; j++) {
        int pix = (j >> 1) * 512 + 2 * t + (j & 1);
        float gx = gelu3((v[j] - mf) * rs);
        v[j] = gx;
        pl[(pix >> 6) + 1][(pix & 63) + 1] = gx;
    }
    __syncthreads();

    float tv[16]; float sg = 0.f, s2g = 0.f;
    #pragma unroll
    for (int j = 0; j < 16; j++) {
        int pix = (j >> 1) * 512 + 2 * t + (j & 1);
        int y = pix >> 6, xx = pix & 63;
        float acc = bsv;
        #pragma unroll
        for (int dy = 0; dy < 3; dy++)
            #pragma unroll
            for (int dx = 0; dx < 3; dx++)
                acc += w9[dy * 3 + dx] * pl[y + dy][xx + dx];
        tv[j] = acc; sg += acc; s2g += acc * acc;
    }
    wave_reduce2(sg, s2g, sred, t);
    float mf2 = sg * (1.f / NP);
    float var2 = s2g * (1.f / NP) - mf2 * mf2;
    float rs2 = rsqrtf(var2 + CEPS);

    #pragma unroll
    for (int i = 0; i < 8; i++) {
        float o0 = v[2 * i]     + gelu3((tv[2 * i] - mf2) * rs2);
        float o1 = v[2 * i + 1] + gelu3((tv[2 * i + 1] - mf2) * rs2);
        unsigned u = (unsigned)f2bf(o0) | ((unsigned)f2bf(o1) << 16);
        h2w[i * 256 + t] = u;
    }
}

// ---------------- final instance norm in place on d_out (2-pass centered, f64 tree) ---
__global__ __launch_bounds__(256) void in_final_kernel(float* __restrict__ y)
{
    __shared__ double red[256];
    size_t base = (size_t)blockIdx.x * NP;
    int t = threadIdx.x;
    float v[16]; float sf = 0.f;
    #pragma unroll
    for (int i = 0; i < 16; i++) { float x = y[base + t + i * 256]; v[i] = x; sf += x; }
    double S = block_reduce1(sf, red, t);
    float mf = (float)(S * (1.0 / NP));
    float s2f = 0.f;
    #pragma unroll
    for (int i = 0; i < 16; i++) { float d = v[i] - mf; v[i] = d; s2f += d * d; }
    double S2 = block_reduce1(s2f, red, t);
    float rs = (float)(1.0 / sqrt(S2 * (1.0 / NP) + (double)CEPS));
    #pragma unroll
    for (int i = 0; i < 16; i++)
        y[base + t + i * 256] = v[i] * rs;
}

extern "C" void kernel_launch(void* const* d_in, const int* in_sizes, int n_in,
                              void* d_out, int out_size, void* d_ws, size_t ws_size,
                              hipStream_t stream)
{
    const float* x      = (const float*)d_in[0];
    const float* g      = (const float*)d_in[1];
    const float* bc     = (const float*)d_in[2];
    const float* w_qkv  = (const float*)d_in[3];
    const float* w_out  = (const float*)d_in[4];
    const float* b_out  = (const float*)d_in[5];
    const float* w_dw   = (const float*)d_in[6];
    const float* b_dw   = (const float*)d_in[7];
    const float* w_comb = (const float*)d_in[8];
    const float* b_comb = (const float*)d_in[9];
    const float* w_ff1  = (const float*)d_in[10];
    const float* b_ff1  = (const float*)d_in[11];
    const float* w_ffdw = (const float*)d_in[12];
    const float* b_ffdw = (const float*)d_in[13];
    const float* w_ff2  = (const float*)d_in[14];
    const float* b_ff2  = (const float*)d_in[15];
    float* out = (float*)d_out;
    float* ws  = (float*)d_ws;

    const size_t S = (size_t)NB * NC * NP;   // 16,777,216 floats (64 MiB)
    float* qkv   = ws + S;
    unsigned short* h1u   = (unsigned short*)ws;
    unsigned short* ctxu  = (unsigned short*)(ws + 2097152);
    unsigned short* convu = (unsigned short*)(ws + S);
    unsigned short* Fbufu = (unsigned short*)out;
    float* qrow    = ws;                       // 262144
    float* kheight = qrow + 262144;            // 262144
    float* kselb   = kheight + 262144;         // 262144
    float* vselb   = kselb + 262144;           // ends at 1048576
    int*   hswsl   = (int*)(ws + 1048576);     // 2048 ints
    float* rs_a    = ws + 1052672;             // 65536
    float* mrs_a   = rs_a + 65536;             // 65536
    float* Aab     = mrs_a + 65536;            // 768
    float* Bab     = Aab + 768;                // 768
    unsigned* pw_qkv = (unsigned*)out;
    unsigned* pwF    = (unsigned*)ws;
    float*    bF     = ws + 131072;

    size_t need = 4 * S * sizeof(float);
    if (ws_size < need) {
        float val = 1024.0f + (float)(ws_size >> 20);
        diag_fill<<<(out_size + 255) / 256, 256, 0, stream>>>(out, val, out_size);
        return;
    }

    // 0. prepack W_qkv*diag(g) for q,k rows; cln stats; fold constants
    pack_wg_kernel<<<512, 256, 0, stream>>>(w_qkv, g, pw_qkv, 512 * 256);
    cln_stats_kernel<<<1024, 256, 0, stream>>>(x, rs_a, mrs_a);
    ab_kernel<<<3, 256, 0, stream>>>(w_qkv, g, bc, Aab, Bab);
    // 2. q,k = fold( (W_qkv g) * x ) with fused l2norm + qrow/kheight  (O=512, lazy v)
    gemm_mfma<false, true, true, false, false><<<dim3(32, 4, NB), 512, 0, stream>>>(
        x, 256, 256, nullptr, 0, 256, (const float*)pw_qkv, nullptr, nullptr, qkv, 768, 512,
        rs_a, mrs_a, Aab, Bab, qrow, kheight);
    // 5. select: top-k + k gather + index export
    select_kernel<<<NBH, 64, 0, stream>>>(qkv, qrow, kheight, kselb, hswsl);
    // 5b. lazy v from x with cln fold
    vsel_kernel<<<dim3(4, NBH), 256, 0, stream>>>(x, w_qkv, g, hswsl, rs_a, mrs_a,
                                                  Aab, Bab, vselb);
    // 6. attention -> compact bf16 ctx
    attn_kernel<<<dim3(16, NBH), 256, 0, stream>>>(qkv, kselb, vselb, ctxu);
    // 7. fused comb weight -> packed, into dead smalls
    fuse_comb_kernel<<<512, 256, 0, stream>>>(w_comb, w_out, b_out, b_comb, pwF, bF);
    // 8. conv branch -> compact bf16 (dead qkv space)
    dwconv_kernel<<<NB * NC, 256, 0, stream>>>(x, w_dw, b_dw, convu, NC);
    // 9. attn_out = W_fused * [ctx; conv] (bf16 B, 2-MFMA) + b_fused + x -> bf16 d_out
    gemm_mfma<false, true, false, true, true><<<dim3(32, 2, NB), 512, 0, stream>>>(
        (const float*)ctxu, 256, 256, (const float*)convu, 256, 512,
        (const float*)pwF, bF, x, (float*)Fbufu, 256, 256,
        nullptr, nullptr, nullptr, nullptr, nullptr, nullptr);
    // 10. h1 = W_ff1 * attn_out (bf16 B, 2-MFMA) + b_ff1 -> bf16 ws[0,2S)
    gemm_mfma<false, false, false, true, true><<<dim3(32, 8, NB), 512, 0, stream>>>(
        (const float*)Fbufu, 256, 256, nullptr, 0, 256, w_ff1, b_ff1, nullptr, (float*)h1u,
        1024, 1024, nullptr, nullptr, nullptr, nullptr, nullptr, nullptr);
    // 11. fused FF on bf16 h1 (in place)
    ff_fused_kernel<<<NB * NFF, 256, 0, stream>>>(h1u, w_ffdw, b_ffdw);
    // 12. y = W_ff2 * h1 (bf16 B, 2-MFMA) + b_ff2 -> d_out fp32
    gemm_mfma<false, false, false, false, true><<<dim3(32, 2, NB), 512, 0, stream>>>(
        (const float*)h1u, 1024, 1024, nullptr, 0, 1024, w_ff2, b_ff2, nullptr, out, 256, 256,
        nullptr, nullptr, nullptr, nullptr, nullptr, nullptr);
    // 13. final instance norm
    in_final_kernel<<<NB * NC, 256, 0, stream>>>(out);
}

// Round 23
// 703.345 us; speedup vs baseline: 1.7064x; 1.0309x over previous
//
#include <hip/hip_runtime.h>
#include <math.h>

#define NB 16
#define NC 256
#define NP 4096      // 64*64
#define NHEADS 8
#define NDH 32
#define NBH 128
#define NFF 1024
#define CEPS 1e-5f

typedef short s16x8 __attribute__((ext_vector_type(8)));
typedef float f32x4 __attribute__((ext_vector_type(4)));

// ---------------- diagnostic fill (guard trip) ----------------
__global__ __launch_bounds__(256) void diag_fill(float* __restrict__ out, float val, int n)
{
    int i = blockIdx.x * 256 + threadIdx.x;
    if (i < n) out[i] = val;
}

// ---------------- bf16 split helpers ----------------
__device__ inline unsigned short f2bf(float f) {
    unsigned u = __float_as_uint(f);
    return (unsigned short)((u + 0x7FFFu + ((u >> 16) & 1u)) >> 16);
}
__device__ inline float bf2f(unsigned short h) { return __uint_as_float(((unsigned)h) << 16); }
__device__ inline void split2(float f, unsigned short& hi, unsigned short& lo) {
    hi = f2bf(f);
    lo = f2bf(f - bf2f(hi));
}
// fast round-to-nearest split (6 ops)
__device__ inline void split_rn(float f, unsigned short& hi, unsigned short& lo) {
    unsigned u = __float_as_uint(f);
    unsigned tt = u + 0x8000u;
    hi = (unsigned short)(tt >> 16);
    float r = f - __uint_as_float(tt & 0xffff0000u);
    lo = (unsigned short)((__float_as_uint(r) + 0x8000u) >> 16);
}
// packed: (hi<<16)|lo
__device__ inline unsigned pack_hl(float f) {
    unsigned short h, lo; split2(f, h, lo);
    return ((unsigned)h << 16) | (unsigned)lo;
}
__device__ inline float packf(float f) { return __uint_as_float(pack_hl(f)); }

// ---------------- weight prepack with channel gain: pw = pack(w[o,c]*g[c]) ----------
__global__ __launch_bounds__(256) void pack_wg_kernel(
    const float* __restrict__ w, const float* __restrict__ g,
    unsigned* __restrict__ pw, int n)
{
    int i = blockIdx.x * 256 + threadIdx.x;
    if (i < n) pw[i] = pack_hl(w[i] * g[i & 255]);
}

// ---------------- plain weight prepack: pw = pack(w[i]) ----------
__global__ __launch_bounds__(256) void pack_w_plain_kernel(
    const float* __restrict__ w, unsigned* __restrict__ pw, int n)
{
    int i = blockIdx.x * 256 + threadIdx.x;
    if (i < n) pw[i] = pack_hl(w[i]);
}

// ---------------- cln stats: per (b,p) mean/rsqrt over 256 channels ----------------
__global__ __launch_bounds__(256) void cln_stats_kernel(
    const float* __restrict__ x, float* __restrict__ rs, float* __restrict__ mrs)
{
    __shared__ double red[512];
    int t = threadIdx.x;
    int i = t & 63, q = t >> 6;
    int col = blockIdx.x * 64 + i;
    int b = col >> 12, p = col & 4095;
    const float* src = x + (size_t)b * NC * NP + (size_t)(q * 64) * NP + p;
    double s = 0.0, s2 = 0.0;
    #pragma unroll 8
    for (int c = 0; c < 64; c++) { float v = src[(size_t)c * NP]; s += v; s2 += (double)v * v; }
    red[q * 64 + i] = s; red[256 + q * 64 + i] = s2;
    __syncthreads();
    if (q == 0) {
        double S  = red[i] + red[64 + i] + red[128 + i] + red[192 + i];
        double S2 = red[256 + i] + red[320 + i] + red[384 + i] + red[448 + i];
        double mean = S * (1.0 / 256.0);
        double var = S2 * (1.0 / 256.0) - mean * mean;
        double r = 1.0 / sqrt(var + (double)CEPS);
        rs[col]  = (float)r;
        mrs[col] = (float)(mean * r);
    }
}

// ---------------- A/B fold constants ----------------
__global__ __launch_bounds__(256) void ab_kernel(
    const float* __restrict__ wq, const float* __restrict__ g, const float* __restrict__ bc,
    float* __restrict__ Aab, float* __restrict__ Bab)
{
    int o = blockIdx.x * 256 + threadIdx.x;
    if (o >= 768) return;
    double a = 0.0, bsum = 0.0;
    for (int c = 0; c < 256; c++) {
        double w = wq[o * 256 + c];
        a += w * (double)g[c];
        bsum += w * (double)bc[c];
    }
    Aab[o] = (float)a; Bab[o] = (float)bsum;
}

// ---------------- fused comb weight: W_fused = [W_comb_L @ W_out | W_comb_R] ----------
__global__ __launch_bounds__(256) void fuse_comb_kernel(
    const float* __restrict__ w_comb, const float* __restrict__ w_out,
    const float* __restrict__ b_out, const float* __restrict__ b_comb,
    unsigned* __restrict__ pwF, float* __restrict__ bF)
{
    int idx = blockIdx.x * 256 + threadIdx.x;   // 131072
    int o = idx >> 9, cc = idx & 511;
    float val;
    if (cc < 256) {
        double s = 0.0;
        for (int k = 0; k < 256; k++)
            s += (double)w_comb[o * 512 + k] * (double)w_out[k * 256 + cc];
        val = (float)s;
    } else {
        val = w_comb[o * 512 + cc];
    }
    pwF[idx] = pack_hl(val);
    if (idx < 256) {
        double s = 0.0;
        for (int k = 0; k < 256; k++)
            s += (double)w_comb[idx * 512 + k] * (double)b_out[k];
        bF[idx] = (float)(s + (double)b_comb[idx]);
    }
}

// ---------------- split-bf16 MFMA GEMM: 128o x 128p tile, 8 waves (32x64/wave) --------
template<bool PACKO, bool PACKA, bool CLN, bool OBF16, bool BBF16>
__global__ __launch_bounds__(512) void gemm_mfma(
    const float* __restrict__ inA, int sA, int C1,
    const float* __restrict__ inB, int sB, int Ctot,
    const float* __restrict__ Wt, const float* __restrict__ bias,
    const float* __restrict__ resid, float* __restrict__ out, int sO, int O,
    const float* __restrict__ rs, const float* __restrict__ mrs,
    const float* __restrict__ Aab, const float* __restrict__ Bab,
    float* __restrict__ qrow, float* __restrict__ kheight)
{
    __shared__ __align__(16) unsigned short Ah[128 * 32], Al[128 * 32];
    __shared__ __align__(16) unsigned short Bh[128 * 32];
    __shared__ __align__(16) unsigned short Bl[BBF16 ? 16 : 128 * 32];
    char* cAh = (char*)Ah; char* cAl = (char*)Al;
    char* cBh = (char*)Bh; char* cBl = (char*)Bl;

    // ---- XCD-batch swizzle ----
    const unsigned npb = gridDim.x * gridDim.y;
    unsigned lin = blockIdx.x + gridDim.x * (blockIdx.y + gridDim.y * blockIdx.z);
    unsigned low = lin & 7u, rest = lin >> 3;
    unsigned high = (rest >= npb) ? 1u : 0u;
    unsigned idx = rest - high * npb;
    const int b = (int)(low + 8u * high);
    const int o0 = (int)(idx / gridDim.x) * 128, p0 = (int)(idx % gridDim.x) * 128;

    const int t = threadIdx.x;
    const int l = t & 63, w = t >> 6;
    const int wr = w & 3, wc = w >> 2;
    const int g = l >> 4, l15 = l & 15;
    const int slotl = (l & 3) ^ ((l >> 2) & 3);

    f32x4 acc[2][4];
    #pragma unroll
    for (int m = 0; m < 2; m++)
        #pragma unroll
        for (int n = 0; n < 4; n++) acc[m][n] = (f32x4){0.f, 0.f, 0.f, 0.f};

    const int arow = t >> 2;
    const int ak8 = (t & 3) * 8;
    const int aslot = (arow & 3) ^ ((arow >> 2) & 3);
    const int aoff = arow * 64 + ((((ak8 >> 3)) ^ aslot) << 4);
    const int bp = t & 127;
    const int bhk = t >> 7;
    const int bslot = (bp & 3) ^ ((bp >> 2) & 3);
    const int boffst = bp * 64 + ((bhk ^ bslot) << 4);

    uint4 wa0, wa1;
    unsigned pb[8];

    #define LOAD_TILE(K0)                                                                 \
    {                                                                                     \
        const unsigned* wsrc = (const unsigned*)Wt + (size_t)(o0 + arow) * Ctot + (K0) + ak8; \
        wa0 = *(const uint4*)(wsrc);                                                      \
        wa1 = *(const uint4*)(wsrc + 4);                                                  \
        _Pragma("unroll")                                                                 \
        for (int q = 0; q < 4; q++) {                                                     \
            int c2 = bhk * 8 + q * 2;                                                     \
            int cc = (K0) + c2;                                                           \
            if constexpr (BBF16) {                                                        \
                const unsigned short* s16 = (cc < C1)                                     \
                    ? (const unsigned short*)inA + ((size_t)b * sA + cc) * (size_t)NP + p0 + bp \
                    : (const unsigned short*)inB + ((size_t)b * sB + (cc - C1)) * (size_t)NP + p0 + bp; \
                unsigned short v0 = s16[0];                                               \
                unsigned short v1 = s16[NP];                                              \
                pb[q] = (unsigned)v0 | ((unsigned)v1 << 16);                              \
            } else {                                                                      \
                const float* srcp = (cc < C1) ? inA + ((size_t)b * sA + cc) * (size_t)NP  \
                                              : inB + ((size_t)b * sB + (cc - C1)) * (size_t)NP; \
                pb[2 * q]     = __float_as_uint(srcp[p0 + bp]);                           \
                pb[2 * q + 1] = __float_as_uint(srcp[(size_t)NP + p0 + bp]);              \
            }                                                                             \
        }                                                                                 \
    }

    #define STORE_LDS()                                                                   \
    {                                                                                     \
        if constexpr (PACKA) {                                                            \
            uint4 hq, lq;                                                                 \
            hq.x = __builtin_amdgcn_perm(wa0.y, wa0.x, 0x07060302u);                      \
            lq.x = __builtin_amdgcn_perm(wa0.y, wa0.x, 0x05040100u);                      \
            hq.y = __builtin_amdgcn_perm(wa0.w, wa0.z, 0x07060302u);                      \
            lq.y = __builtin_amdgcn_perm(wa0.w, wa0.z, 0x05040100u);                      \
            hq.z = __builtin_amdgcn_perm(wa1.y, wa1.x, 0x07060302u);                      \
            lq.z = __builtin_amdgcn_perm(wa1.y, wa1.x, 0x05040100u);                      \
            hq.w = __builtin_amdgcn_perm(wa1.w, wa1.z, 0x07060302u);                      \
            lq.w = __builtin_amdgcn_perm(wa1.w, wa1.z, 0x05040100u);                      \
            *(uint4*)(cAh + aoff) = hq;                                                   \
            *(uint4*)(cAl + aoff) = lq;                                                   \
        } else {                                                                          \
            ushort4 h0, l0, h1, l1;                                                       \
            split_rn(__uint_as_float(wa0.x), h0.x, l0.x);                                 \
            split_rn(__uint_as_float(wa0.y), h0.y, l0.y);                                 \
            split_rn(__uint_as_float(wa0.z), h0.z, l0.z);                                 \
            split_rn(__uint_as_float(wa0.w), h0.w, l0.w);                                 \
            split_rn(__uint_as_float(wa1.x), h1.x, l1.x);                                 \
            split_rn(__uint_as_float(wa1.y), h1.y, l1.y);                                 \
            split_rn(__uint_as_float(wa1.z), h1.z, l1.z);                                 \
            split_rn(__uint_as_float(wa1.w), h1.w, l1.w);                                 \
            *(ushort4*)(cAh + aoff) = h0; *(ushort4*)(cAh + aoff + 8) = h1;               \
            *(ushort4*)(cAl + aoff) = l0; *(ushort4*)(cAl + aoff + 8) = l1;               \
        }                                                                                 \
        if constexpr (BBF16) {                                                            \
            *(uint4*)(cBh + boffst) = (uint4){pb[0], pb[1], pb[2], pb[3]};                \
        } else {                                                                          \
            unsigned hp[4], lp[4];                                                        \
            _Pragma("unroll")                                                             \
            for (int q = 0; q < 4; q++) {                                                 \
                unsigned u0 = pb[2 * q], u1 = pb[2 * q + 1];                              \
                if constexpr (CLN) {                                                      \
                    unsigned short sh0, sl0, sh1, sl1;                                    \
                    split_rn(__uint_as_float(u0), sh0, sl0);                              \
                    split_rn(__uint_as_float(u1), sh1, sl1);                              \
                    hp[q] = (unsigned)sh0 | ((unsigned)sh1 << 16);                        \
                    lp[q] = (unsigned)sl0 | ((unsigned)sl1 << 16);                        \
                } else {                                                                  \
                    hp[q] = __builtin_amdgcn_perm(u1, u0, 0x07060302u);                   \
                    lp[q] = __builtin_amdgcn_perm(u1, u0, 0x05040100u);                   \
                }                                                                         \
            }                                                                             \
            *(uint4*)(cBh + boffst) = (uint4){hp[0], hp[1], hp[2], hp[3]};                \
            *(uint4*)(cBl + boffst) = (uint4){lp[0], lp[1], lp[2], lp[3]};                \
        }                                                                                 \
    }

    LOAD_TILE(0)

    for (int k0 = 0; k0 < Ctot; k0 += 32) {
        if (k0) __syncthreads();
        STORE_LDS()
        __syncthreads();
        if (k0 + 32 < Ctot) LOAD_TILE(k0 + 32)

        s16x8 ah[2], al[2];
        #pragma unroll
        for (int m = 0; m < 2; m++) {
            int ao = (wr * 32 + m * 16 + l15) * 64 + ((g ^ slotl) << 4);
            ah[m] = *(const s16x8*)(cAh + ao);
            al[m] = *(const s16x8*)(cAl + ao);
        }
        #pragma unroll
        for (int n = 0; n < 4; n++) {
            int bo = (wc * 64 + n * 16 + l15) * 64 + ((g ^ slotl) << 4);
            s16x8 bh = *(const s16x8*)(cBh + bo);
            if constexpr (BBF16) {
                #pragma unroll
                for (int m = 0; m < 2; m++) {
                    acc[m][n] = __builtin_amdgcn_mfma_f32_16x16x32_bf16(ah[m], bh, acc[m][n], 0, 0, 0);
                    acc[m][n] = __builtin_amdgcn_mfma_f32_16x16x32_bf16(al[m], bh, acc[m][n], 0, 0, 0);
                }
            } else {
                s16x8 bl = *(const s16x8*)(cBl + bo);
                #pragma unroll
                for (int m = 0; m < 2; m++) {
                    acc[m][n] = __builtin_amdgcn_mfma_f32_16x16x32_bf16(ah[m], bh, acc[m][n], 0, 0, 0);
                    acc[m][n] = __builtin_amdgcn_mfma_f32_16x16x32_bf16(ah[m], bl, acc[m][n], 0, 0, 0);
                    acc[m][n] = __builtin_amdgcn_mfma_f32_16x16x32_bf16(al[m], bh, acc[m][n], 0, 0, 0);
                }
            }
        }
    }
    #undef LOAD_TILE
    #undef STORE_LDS

    // ---- epilogue: D[row=(l>>4)*4+r][col=l&15] ----
    #pragma unroll
    for (int m = 0; m < 2; m++) {
        #pragma unroll
        for (int r = 0; r < 4; r++) {
            int orow = o0 + wr * 32 + m * 16 + g * 4 + r;
            float bs = (!CLN && bias) ? bias[orow] : 0.f;
            float Ao = CLN ? Aab[orow] : 0.f;
            float Bo = CLN ? Bab[orow] : 0.f;
            if constexpr (CLN) {
                float vv[4];
                #pragma unroll
                for (int n = 0; n < 4; n++) {
                    int pcol = p0 + wc * 64 + n * 16 + l15;
                    size_t cidx = (size_t)b * NP + pcol;
                    vv[n] = rs[cidx] * acc[m][n][r] - mrs[cidx] * Ao + Bo;
                }
                int which = orow >> 8;
                if (which < 2) {
                    float ss = vv[0] * vv[0] + vv[1] * vv[1] + vv[2] * vv[2] + vv[3] * vv[3];
                    ss += __shfl_xor(ss, 1); ss += __shfl_xor(ss, 2);
                    ss += __shfl_xor(ss, 4); ss += __shfl_xor(ss, 8);
                    float inv = 1.f / fmaxf(sqrtf(ss), 1e-12f);
                    float as = 0.f;
                    #pragma unroll
                    for (int n = 0; n < 4; n++) { vv[n] *= inv; as += fabsf(vv[n]); }
                    as += __shfl_xor(as, 1); as += __shfl_xor(as, 2);
                    as += __shfl_xor(as, 4); as += __shfl_xor(as, 8);
                    if (l15 == 0) {
                        int idx2 = orow & 255;
                        int head = idx2 >> 5, c = idx2 & 31;
                        int h = (p0 >> 6) + wc;
                        int rr = ((b << 3) + head) * 2048 + c * 64 + h;
                        (which == 0 ? qrow : kheight)[rr] = as;
                    }
                }
                #pragma unroll
                for (int n = 0; n < 4; n++) {
                    int pcol = p0 + wc * 64 + n * 16 + l15;
                    out[((size_t)b * sO + orow) * (size_t)NP + pcol] = vv[n];
                }
            } else {
                #pragma unroll
                for (int n = 0; n < 4; n++) {
                    int pcol = p0 + wc * 64 + n * 16 + l15;
                    float v = acc[m][n][r] + bs;
                    if (resid) v += resid[((size_t)b * O + orow) * (size_t)NP + pcol];
                    size_t oidx = ((size_t)b * sO + orow) * (size_t)NP + pcol;
                    if constexpr (OBF16)
                        ((unsigned short*)out)[oidx] = f2bf(v);
                    else
                        out[oidx] = PACKO ? packf(v) : v;
                }
            }
        }
    }
}

// ---------------- scores + top-k rows/cols + gather k (qprobe folded); exports idx ----
__global__ __launch_bounds__(64) void select_kernel(
    const float* __restrict__ qkv, const float* __restrict__ qrow,
    const float* __restrict__ kheight,
    float* __restrict__ ksel, int* __restrict__ hswsl)
{
    const int bh = blockIdx.x;
    const int b = bh >> 3, head = bh & 7;
    const int lane = threadIdx.x;
    __shared__ int hs[8], wsl[8];
    __shared__ float qp[32];
    if (lane < 32) {
        double s = 0.0;
        const float* qr = qrow + (size_t)bh * 2048 + lane * 64;
        for (int h = 0; h < 64; h++) s += qr[h];
        qp[lane] = (float)s;
    }
    __syncthreads();
    double scd = 0.0;
    for (int c = 0; c < 32; c++) scd += (double)qp[c] * kheight[((size_t)bh * 32 + c) * 64 + lane];
    float sc = (float)scd;
    for (int it = 0; it < 8; it++) {
        float v = sc; int id = lane;
        for (int off = 32; off; off >>= 1) {
            float ov = __shfl_xor(v, off); int oi = __shfl_xor(id, off);
            if (ov > v || (ov == v && oi < id)) { v = ov; id = oi; }
        }
        if (lane == 0) hs[it] = id;
        if (lane == id) sc = -3.4e38f;
    }
    __syncthreads();
    const float* kbase = qkv + ((size_t)b * 768 + 256 + head * 32) * NP;
    double sc2d = 0.0;
    for (int c = 0; c < 32; c++) {
        float kw = 0.f;
        for (int hi = 0; hi < 8; hi++)
            kw += fabsf(kbase[(size_t)c * NP + hs[hi] * 64 + lane]);
        sc2d += (double)qp[c] * kw;
    }
    float sc2 = (float)sc2d;
    for (int it = 0; it < 8; it++) {
        float v = sc2; int id = lane;
        for (int off = 32; off; off >>= 1) {
            float ov = __shfl_xor(v, off); int oi = __shfl_xor(id, off);
            if (ov > v || (ov == v && oi < id)) { v = ov; id = oi; }
        }
        if (lane == 0) wsl[it] = id;
        if (lane == id) sc2 = -3.4e38f;
    }
    __syncthreads();
    if (lane < 8) hswsl[bh * 16 + lane] = hs[lane];
    else if (lane < 16) hswsl[bh * 16 + lane] = wsl[lane - 8];
    int hi = lane >> 3, wi = lane & 7;
    int hh = hs[hi], ww = wsl[wi];
    for (int d = 0; d < 32; d++)
        ksel[((size_t)bh * 64 + lane) * 32 + d] = kbase[(size_t)d * NP + hh * 64 + ww];
}

// ---------------- lazy v: vsel[j][d] = rs*( (Wv g) . x[:,pos] ) - mrs*Av + Bv --------
__global__ __launch_bounds__(256) void vsel_kernel(
    const float* __restrict__ x, const float* __restrict__ w_qkv, const float* __restrict__ g,
    const int* __restrict__ hswsl, const float* __restrict__ rs, const float* __restrict__ mrs,
    const float* __restrict__ Aab, const float* __restrict__ Bab,
    float* __restrict__ vsel)
{
    __shared__ float Wg[32][257];
    __shared__ float xcol[16][257];
    __shared__ int pos_s[16];
    const int bh = blockIdx.y, b = bh >> 3, head = bh & 7;
    const int t = threadIdx.x;
    for (int i = t; i < 8192; i += 256) {
        int d = i >> 8, c = i & 255;
        Wg[d][c] = w_qkv[(size_t)(512 + head * 32 + d) * 256 + c] * g[c];
    }
    if (t < 16) {
        int j = blockIdx.x * 16 + t;
        int hh = hswsl[bh * 16 + (j >> 3)];
        int ww = hswsl[bh * 16 + 8 + (j & 7)];
        pos_s[t] = hh * 64 + ww;
    }
    __syncthreads();
    for (int i = t; i < 4096; i += 256) {
        int jj = i >> 8, c = i & 255;
        xcol[jj][c] = x[((size_t)b * 256 + c) * (size_t)NP + pos_s[jj]];
    }
    __syncthreads();
    const int l = t & 63, w = t >> 6;
    const int d = l & 31, ch = l >> 5;
    const float Av = Aab[512 + head * 32 + d];
    const float Bv = Bab[512 + head * 32 + d];
    for (int q = 0; q < 4; q++) {
        int jj = w * 4 + q;
        float s = 0.f;
        #pragma unroll
        for (int c = 0; c < 128; c++) s += Wg[d][ch * 128 + c] * xcol[jj][ch * 128 + c];
        s += __shfl_xor(s, 32);
        if (ch == 0) {
            int j = blockIdx.x * 16 + jj;
            size_t cidx = (size_t)b * NP + pos_s[jj];
            float val = rs[cidx] * s - mrs[cidx] * Av + Bv;
            vsel[((size_t)bh * 64 + j) * 32 + d] = val;
        }
    }
}

// ---------------- attention: writes compact bf16 ctx [b][256][NP] ----------------
__global__ __launch_bounds__(256) void attn_kernel(
    const float* __restrict__ qkv, const float* __restrict__ ksel, const float* __restrict__ vsel,
    unsigned short* __restrict__ ctxu)
{
    __shared__ __align__(16) float ks[64][32];
    __shared__ __align__(16) float vs[64][32];
    int bh = blockIdx.y, b = bh >> 3, head = bh & 7;
    int t = threadIdx.x;
    const float* kb = ksel + (size_t)bh * 2048;
    const float* vb = vsel + (size_t)bh * 2048;
    for (int i = 0; i < 8; i++) {
        ((float*)ks)[t + i * 256] = kb[t + i * 256];
        ((float*)vs)[t + i * 256] = vb[t + i * 256];
    }
    __syncthreads();
    int p = blockIdx.x * 256 + t;
    const float* qb = qkv + ((size_t)b * 768 + head * 32) * NP + p;
    unsigned short* ob = ctxu + ((size_t)b * 256 + head * 32) * NP + p;
    float q[32];
    #pragma unroll
    for (int d = 0; d < 32; d++) q[d] = qb[(size_t)d * NP];
    float s[64], m = -3.4e38f;
    for (int j = 0; j < 64; j++) {
        float dot = 0.f;
        #pragma unroll
        for (int d = 0; d < 32; d++) dot += q[d] * ks[j][d];
        s[j] = dot; m = fmaxf(m, dot);
    }
    float den = 0.f;
    for (int j = 0; j < 64; j++) { float e = __expf(s[j] - m); s[j] = e; den += e; }
    float o[32] = {};
    for (int j = 0; j < 64; j++) {
        float a = s[j];
        #pragma unroll
        for (int d = 0; d < 32; d++) o[d] += a * vs[j][d];
    }
    float r = 1.f / den;
    #pragma unroll
    for (int d = 0; d < 32; d++) ob[(size_t)d * NP] = f2bf(o[d] * r);
}

// ---------------- depthwise 3x3 on x; padded LDS, branch-free -------------
__global__ __launch_bounds__(256) void dwconv_kernel(
    const float* __restrict__ in, const float* __restrict__ w, const float* __restrict__ bias,
    unsigned short* __restrict__ out, int Cn)
{
    __shared__ __align__(16) float pl[66][67];
    int bcb = blockIdx.x;
    int c = bcb % Cn;
    const float2* src2 = (const float2*)(in + (size_t)bcb * NP);
    unsigned* dst2 = (unsigned*)(out + (size_t)bcb * NP);
    int t = threadIdx.x;
    if (t < 66) { pl[0][t] = 0.f; pl[65][t] = 0.f; }
    if (t >= 66 && t < 130) { int rr = t - 65; pl[rr][0] = 0.f; pl[rr][65] = 0.f; }
    float w9[9];
    #pragma unroll
    for (int k = 0; k < 9; k++) w9[k] = w[c * 9 + k];
    float bsv = bias[c];
    #pragma unroll
    for (int i = 0; i < 8; i++) {
        float2 f = src2[i * 256 + t];
        int pix = i * 512 + 2 * t;
        int y = pix >> 6, xx = pix & 63;
        pl[y + 1][xx + 1] = f.x;
        pl[y + 1][xx + 2] = f.y;
    }
    __syncthreads();
    float vv[16];
    #pragma unroll
    for (int j = 0; j < 16; j++) {
        int pix = (j >> 1) * 512 + 2 * t + (j & 1);
        int y = pix >> 6, xx = pix & 63;
        float acc = bsv;
        #pragma unroll
        for (int dy = 0; dy < 3; dy++)
            #pragma unroll
            for (int dx = 0; dx < 3; dx++)
                acc += w9[dy * 3 + dx] * pl[y + dy][xx + dx];
        vv[j] = acc;
    }
    #pragma unroll
    for (int i = 0; i < 8; i++) {
        unsigned u = (unsigned)f2bf(vv[2 * i]) | ((unsigned)f2bf(vv[2 * i + 1]) << 16);
        dst2[i * 256 + t] = u;
    }
}

// ---------------- fast gelu: A&S 7.1.25 3-term erf + hw rcp (max err ~2.5e-5) ---------
__device__ inline float gelu3(float x) {
    float z = x * 0.70710678118654752f;
    float a = fabsf(z);
    float t = __builtin_amdgcn_rcpf(fmaf(0.47047f, a, 1.0f));
    float p = t * (0.3480242f + t * (-0.0958798f + t * 0.7478556f));
    float e = __expf(-a * a);
    float r = 1.0f - p * e;                 // erf(|z|)
    float erfz = copysignf(r, z);
    return 0.5f * x * (1.0f + erfz);
}

// wave-shfl fp32 paired reduction + cross-wave LDS combine (2 barriers)
__device__ inline void wave_reduce2(float& a, float& b, float* sred, int t)
{
    #pragma unroll
    for (int off = 32; off; off >>= 1) { a += __shfl_xor(a, off); b += __shfl_xor(b, off); }
    int w = t >> 6, lane = t & 63;
    __syncthreads();
    if (lane == 0) { sred[w] = a; sred[4 + w] = b; }
    __syncthreads();
    a = sred[0] + sred[1] + sred[2] + sred[3];
    b = sred[4] + sred[5] + sred[6] + sred[7];
}

__device__ inline double block_reduce1(float s, double* red, int t)
{
    __syncthreads();
    red[t] = (double)s;
    __syncthreads();
    for (int st = 128; st; st >>= 1) {
        if (t < st) red[t] += red[t + st];
        __syncthreads();
    }
    return red[0];
}

// ---------------- fused FF on bf16 h; shfl stats; cheap gelu; padded conv -------------
__global__ __launch_bounds__(256) void ff_fused_kernel(
    unsigned short* __restrict__ h, const float* __restrict__ w, const float* __restrict__ bias)
{
    __shared__ __align__(16) float pl[66][67];
    __shared__ float sred[8];
    int plane = blockIdx.x;
    int c = plane & (NFF - 1);
    const unsigned* h2 = (const unsigned*)(h + (size_t)plane * NP);
    unsigned* h2w = (unsigned*)(h + (size_t)plane * NP);
    int t = threadIdx.x;
    if (t < 66) { pl[0][t] = 0.f; pl[65][t] = 0.f; }
    if (t >= 66 && t < 130) { int rr = t - 65; pl[rr][0] = 0.f; pl[rr][65] = 0.f; }

    float v[16]; float sf = 0.f, s2f = 0.f;
    #pragma unroll
    for (int i = 0; i < 8; i++) {
        unsigned u = h2[i * 256 + t];
        float x0 = bf2f((unsigned short)(u & 0xffffu));
        float x1 = bf2f((unsigned short)(u >> 16));
        v[2 * i] = x0; v[2 * i + 1] = x1;
        sf += x0 + x1;
        s2f += x0 * x0 + x1 * x1;
    }
    wave_reduce2(sf, s2f, sred, t);
    float mf = sf * (1.f / NP);
    float var = s2f * (1.f / NP) - mf * mf;
    float rs = rsqrtf(var + CEPS);

    float w9[9];
    #pragma unroll
    for (int k = 0; k < 9; k++) w9[k] = w[c * 9 + k];
    float bsv = bias[c];

    #pragma unroll
    for (int j = 0; j < 16; j++) {
        int pix = (j >> 1) * 512 + 2 * t + (j & 1);
        float gx = gelu3((v[j] - mf) * rs);
        v[j] = gx;
        pl[(pix >> 6) + 1][(pix & 63) + 1] = gx;
    }
    __syncthreads();

    float tv[16]; float sg = 0.f, s2g = 0.f;
    #pragma unroll
    for (int j = 0; j < 16; j++) {
        int pix = (j >> 1) * 512 + 2 * t + (j & 1);
        int y = pix >> 6, xx = pix & 63;
        float acc = bsv;
        #pragma unroll
        for (int dy = 0; dy < 3; dy++)
            #pragma unroll
            for (int dx = 0; dx < 3; dx++)
                acc += w9[dy * 3 + dx] * pl[y + dy][xx + dx];
        tv[j] = acc; sg += acc; s2g += acc * acc;
    }
    wave_reduce2(sg, s2g, sred, t);
    float mf2 = sg * (1.f / NP);
    float var2 = s2g * (1.f / NP) - mf2 * mf2;
    float rs2 = rsqrtf(var2 + CEPS);

    #pragma unroll
    for (int i = 0; i < 8; i++) {
        float o0 = v[2 * i]     + gelu3((tv[2 * i] - mf2) * rs2);
        float o1 = v[2 * i + 1] + gelu3((tv[2 * i + 1] - mf2) * rs2);
        unsigned u = (unsigned)f2bf(o0) | ((unsigned)f2bf(o1) << 16);
        h2w[i * 256 + t] = u;
    }
}

// ---------------- final instance norm in place on d_out (2-pass centered, f64 tree) ---
__global__ __launch_bounds__(256) void in_final_kernel(float* __restrict__ y)
{
    __shared__ double red[256];
    size_t base = (size_t)blockIdx.x * NP;
    int t = threadIdx.x;
    float v[16]; float sf = 0.f;
    #pragma unroll
    for (int i = 0; i < 16; i++) { float x = y[base + t + i * 256]; v[i] = x; sf += x; }
    double S = block_reduce1(sf, red, t);
    float mf = (float)(S * (1.0 / NP));
    float s2f = 0.f;
    #pragma unroll
    for (int i = 0; i < 16; i++) { float d = v[i] - mf; v[i] = d; s2f += d * d; }
    double S2 = block_reduce1(s2f, red, t);
    float rs = (float)(1.0 / sqrt(S2 * (1.0 / NP) + (double)CEPS));
    #pragma unroll
    for (int i = 0; i < 16; i++)
        y[base + t + i * 256] = v[i] * rs;
}

extern "C" void kernel_launch(void* const* d_in, const int* in_sizes, int n_in,
                              void* d_out, int out_size, void* d_ws, size_t ws_size,
                              hipStream_t stream)
{
    const float* x      = (const float*)d_in[0];
    const float* g      = (const float*)d_in[1];
    const float* bc     = (const float*)d_in[2];
    const float* w_qkv  = (const float*)d_in[3];
    const float* w_out  = (const float*)d_in[4];
    const float* b_out  = (const float*)d_in[5];
    const float* w_dw   = (const float*)d_in[6];
    const float* b_dw   = (const float*)d_in[7];
    const float* w_comb = (const float*)d_in[8];
    const float* b_comb = (const float*)d_in[9];
    const float* w_ff1  = (const float*)d_in[10];
    const float* b_ff1  = (const float*)d_in[11];
    const float* w_ffdw = (const float*)d_in[12];
    const float* b_ffdw = (const float*)d_in[13];
    const float* w_ff2  = (const float*)d_in[14];
    const float* b_ff2  = (const float*)d_in[15];
    float* out = (float*)d_out;
    float* ws  = (float*)d_ws;

    const size_t S = (size_t)NB * NC * NP;   // 16,777,216 floats (64 MiB)
    // Memory plan (ws = 4S exactly):
    //   ws[0,S)    : smalls; cln stats; pwF+bF (7-9); all dead by step 10
    //   ws[S,4S)   : qkv fp32 (dead after attn); convu bf16 at ws+S (8-9)
    //   ws[0,2S)   : h1 bf16 (10+), in-place ff_fused (11), read by ff2 (12)
    //   ws[2S,..)  : pw_ff1 (1MB) + pw_ff2 (1MB), packed at step 7 (qkv region dead,
    //                convu ends at S+4.2M floats, h1u ends exactly at 2S) -> live 10-12
    float* qkv   = ws + S;
    unsigned short* h1u   = (unsigned short*)ws;
    unsigned short* ctxu  = (unsigned short*)(ws + 2097152);
    unsigned short* convu = (unsigned short*)(ws + S);
    unsigned short* Fbufu = (unsigned short*)out;
    float* qrow    = ws;                       // 262144
    float* kheight = qrow + 262144;            // 262144
    float* kselb   = kheight + 262144;         // 262144
    float* vselb   = kselb + 262144;           // ends at 1048576
    int*   hswsl   = (int*)(ws + 1048576);     // 2048 ints
    float* rs_a    = ws + 1052672;             // 65536
    float* mrs_a   = rs_a + 65536;             // 65536
    float* Aab     = mrs_a + 65536;            // 768
    float* Bab     = Aab + 768;                // 768
    unsigned* pw_qkv = (unsigned*)out;
    unsigned* pwF    = (unsigned*)ws;
    float*    bF     = ws + 131072;
    unsigned* pw_ff1 = (unsigned*)(ws + 2 * S);            // 262144 u32
    unsigned* pw_ff2 = (unsigned*)(ws + 2 * S) + 262144;   // 262144 u32

    size_t need = 4 * S * sizeof(float);
    if (ws_size < need) {
        float val = 1024.0f + (float)(ws_size >> 20);
        diag_fill<<<(out_size + 255) / 256, 256, 0, stream>>>(out, val, out_size);
        return;
    }

    // 0. prepack W_qkv*diag(g) for q,k rows; cln stats; fold constants
    pack_wg_kernel<<<512, 256, 0, stream>>>(w_qkv, g, pw_qkv, 512 * 256);
    cln_stats_kernel<<<1024, 256, 0, stream>>>(x, rs_a, mrs_a);
    ab_kernel<<<3, 256, 0, stream>>>(w_qkv, g, bc, Aab, Bab);
    // 2. q,k = fold( (W_qkv g) * x ) with fused l2norm + qrow/kheight  (O=512, lazy v)
    gemm_mfma<false, true, true, false, false><<<dim3(32, 4, NB), 512, 0, stream>>>(
        x, 256, 256, nullptr, 0, 256, (const float*)pw_qkv, nullptr, nullptr, qkv, 768, 512,
        rs_a, mrs_a, Aab, Bab, qrow, kheight);
    // 5. select: top-k + k gather + index export
    select_kernel<<<NBH, 64, 0, stream>>>(qkv, qrow, kheight, kselb, hswsl);
    // 5b. lazy v from x with cln fold
    vsel_kernel<<<dim3(4, NBH), 256, 0, stream>>>(x, w_qkv, g, hswsl, rs_a, mrs_a,
                                                  Aab, Bab, vselb);
    // 6. attention -> compact bf16 ctx
    attn_kernel<<<dim3(16, NBH), 256, 0, stream>>>(qkv, kselb, vselb, ctxu);
    // 7. fused comb weight -> packed; prepack ff1/ff2 weights into dead qkv tail
    fuse_comb_kernel<<<512, 256, 0, stream>>>(w_comb, w_out, b_out, b_comb, pwF, bF);
    pack_w_plain_kernel<<<1024, 256, 0, stream>>>(w_ff1, pw_ff1, 1024 * 256);
    pack_w_plain_kernel<<<1024, 256, 0, stream>>>(w_ff2, pw_ff2, 256 * 1024);
    // 8. conv branch -> compact bf16 (dead qkv space)
    dwconv_kernel<<<NB * NC, 256, 0, stream>>>(x, w_dw, b_dw, convu, NC);
    // 9. attn_out = W_fused * [ctx; conv] (bf16 B, 2-MFMA) + b_fused + x -> bf16 d_out
    gemm_mfma<false, true, false, true, true><<<dim3(32, 2, NB), 512, 0, stream>>>(
        (const float*)ctxu, 256, 256, (const float*)convu, 256, 512,
        (const float*)pwF, bF, x, (float*)Fbufu, 256, 256,
        nullptr, nullptr, nullptr, nullptr, nullptr, nullptr);
    // 10. h1 = (pw_ff1) * attn_out (bf16 B, 2-MFMA, packed A) + b_ff1 -> bf16 ws[0,2S)
    gemm_mfma<false, true, false, true, true><<<dim3(32, 8, NB), 512, 0, stream>>>(
        (const float*)Fbufu, 256, 256, nullptr, 0, 256, (const float*)pw_ff1, b_ff1, nullptr,
        (float*)h1u, 1024, 1024, nullptr, nullptr, nullptr, nullptr, nullptr, nullptr);
    // 11. fused FF on bf16 h1 (in place)
    ff_fused_kernel<<<NB * NFF, 256, 0, stream>>>(h1u, w_ffdw, b_ffdw);
    // 12. y = (pw_ff2) * h1 (bf16 B, 2-MFMA, packed A) + b_ff2 -> d_out fp32
    gemm_mfma<false, true, false, false, true><<<dim3(32, 2, NB), 512, 0, stream>>>(
        (const float*)h1u, 1024, 1024, nullptr, 0, 1024, (const float*)pw_ff2, b_ff2, nullptr,
        out, 256, 256, nullptr, nullptr, nullptr, nullptr, nullptr, nullptr);
    // 13. final instance norm
    in_final_kernel<<<NB * NC, 256, 0, stream>>>(out);
}